// Round 1
// baseline (4069.916 us; speedup 1.0000x reference)
//
#include <hip/hip_runtime.h>
#include <math.h>

#define ALPHA_LR 0.2f

#define Bq  32
#define Nq  128
#define Mq  1024
#define CDq 128
#define GDq 64
#define NHq 4
#define LDq 256
#define PDq 40

// ---------------------------------------------------------------------------
// Generic tiled fp32 GEMM: C = act(A @ B + bias) [* masks]
// TA=0: A[m*lda+k]; TA=1: A[k*lda+m]
// TB=0: B[k*ldb+n]; TB=1: B[n*ldb+k]
// ACT: 0 none, 1 leaky(0.2), 2 tanh
// MASKED: multiply by maskR[z*M+m]*maskC[z*N+n] after activation
// batched via blockIdx.z with element strides sA/sB/sC
// ---------------------------------------------------------------------------
template<int ACT, int TA, int TB, int MASKED>
__global__ __launch_bounds__(256) void gemm_k(
    int M, int N, int K,
    const float* __restrict__ A, int lda, long long sA,
    const float* __restrict__ Bm, int ldb, long long sB,
    const float* __restrict__ bias,
    float* __restrict__ C, int ldc, long long sC,
    const float* __restrict__ maskR, const float* __restrict__ maskC)
{
    int z = blockIdx.z;
    A  += (long long)z * sA;
    Bm += (long long)z * sB;
    C  += (long long)z * sC;

    __shared__ float As[16][68];
    __shared__ float Bs[16][68];

    int tid = threadIdx.x;
    int tx = tid % 16, ty = tid / 16;
    int m0 = blockIdx.y * 64, n0 = blockIdx.x * 64;

    float acc[4][4] = {};

    for (int k0 = 0; k0 < K; k0 += 16) {
        if (!TA) {
            int k = tid % 16, mBase = tid / 16;
            #pragma unroll
            for (int p = 0; p < 4; p++) {
                int m = mBase + p * 16;
                int gm = m0 + m, gk = k0 + k;
                float v = 0.f;
                if (gm < M && gk < K) v = A[(long long)gm * lda + gk];
                As[k][m] = v;
            }
        } else {
            int m = tid % 64, kBase = tid / 64;
            #pragma unroll
            for (int p = 0; p < 4; p++) {
                int k = kBase + p * 4;
                int gm = m0 + m, gk = k0 + k;
                float v = 0.f;
                if (gm < M && gk < K) v = A[(long long)gk * lda + gm];
                As[k][m] = v;
            }
        }
        if (!TB) {
            int n = tid % 64, kBase = tid / 64;
            #pragma unroll
            for (int p = 0; p < 4; p++) {
                int k = kBase + p * 4;
                int gn = n0 + n, gk = k0 + k;
                float v = 0.f;
                if (gn < N && gk < K) v = Bm[(long long)gk * ldb + gn];
                Bs[k][n] = v;
            }
        } else {
            int k = tid % 16, nBase = tid / 16;
            #pragma unroll
            for (int p = 0; p < 4; p++) {
                int n = nBase + p * 16;
                int gn = n0 + n, gk = k0 + k;
                float v = 0.f;
                if (gn < N && gk < K) v = Bm[(long long)gn * ldb + gk];
                Bs[k][n] = v;
            }
        }
        __syncthreads();
        #pragma unroll
        for (int kk = 0; kk < 16; kk++) {
            float a[4], b[4];
            #pragma unroll
            for (int i = 0; i < 4; i++) a[i] = As[kk][ty * 4 + i];
            #pragma unroll
            for (int j = 0; j < 4; j++) b[j] = Bs[kk][tx * 4 + j];
            #pragma unroll
            for (int i = 0; i < 4; i++)
                #pragma unroll
                for (int j = 0; j < 4; j++)
                    acc[i][j] += a[i] * b[j];
        }
        __syncthreads();
    }

    #pragma unroll
    for (int i = 0; i < 4; i++) {
        int gm = m0 + ty * 4 + i;
        if (gm >= M) continue;
        #pragma unroll
        for (int j = 0; j < 4; j++) {
            int gn = n0 + tx * 4 + j;
            if (gn >= N) continue;
            float v = acc[i][j];
            if (bias) v += bias[gn];
            if (ACT == 1) v = v > 0.f ? v : ALPHA_LR * v;
            else if (ACT == 2) v = tanhf(v);
            if (MASKED) v *= maskR[(long long)z * M + gm] * maskC[(long long)z * N + gn];
            C[(long long)gm * ldc + gn] = v;
        }
    }
}

static inline void run_gemm(hipStream_t stream, int act, bool tb_masked,
    int M, int N, int K,
    const float* A, int lda, long long sA,
    const float* B, int ldb, long long sB,
    const float* bias, float* C, int ldc, long long sC,
    int batch, const float* maskR = nullptr, const float* maskC = nullptr)
{
    dim3 grid((N + 63) / 64, (M + 63) / 64, batch);
    dim3 blk(256);
    if (tb_masked) {
        gemm_k<2, 0, 1, 1><<<grid, blk, 0, stream>>>(M, N, K, A, lda, sA, B, ldb, sB,
                                                     bias, C, ldc, sC, maskR, maskC);
    } else if (act == 0) {
        gemm_k<0, 0, 0, 0><<<grid, blk, 0, stream>>>(M, N, K, A, lda, sA, B, ldb, sB,
                                                     bias, C, ldc, sC, nullptr, nullptr);
    } else if (act == 1) {
        gemm_k<1, 0, 0, 0><<<grid, blk, 0, stream>>>(M, N, K, A, lda, sA, B, ldb, sB,
                                                     bias, C, ldc, sC, nullptr, nullptr);
    } else {
        gemm_k<2, 0, 0, 0><<<grid, blk, 0, stream>>>(M, N, K, A, lda, sA, B, ldb, sB,
                                                     bias, C, ldc, sC, nullptr, nullptr);
    }
}

// per-row GAT source/dest attention logits
__global__ __launch_bounds__(128) void gat_e_k(
    const float* __restrict__ Wh, int ldWh, int GD,
    const float* __restrict__ a, int aStride,
    float* __restrict__ esrc, float* __restrict__ edst, int rows)
{
    int row = blockIdx.x;
    int k = blockIdx.y;
    int g = threadIdx.x;
    float ws = 0.f, wd = 0.f;
    if (g < GD) {
        float wv = Wh[(long long)row * ldWh + k * GD + g];
        ws = wv * a[k * aStride + g];
        wd = wv * a[k * aStride + GD + g];
    }
    __shared__ float sb[2][128];
    sb[0][threadIdx.x] = ws; sb[1][threadIdx.x] = wd;
    __syncthreads();
    for (int off = 64; off > 0; off >>= 1) {
        if (threadIdx.x < off) {
            sb[0][threadIdx.x] += sb[0][threadIdx.x + off];
            sb[1][threadIdx.x] += sb[1][threadIdx.x + off];
        }
        __syncthreads();
    }
    if (threadIdx.x == 0) {
        esrc[(long long)k * rows + row] = sb[0][0];
        edst[(long long)k * rows + row] = sb[1][0];
    }
}

// GAT attention: softmax over neighbors + weighted sum + ELU
__global__ __launch_bounds__(128) void gat_attn_k(
    const float* __restrict__ Wh, int ldWh, int GD,
    const int* __restrict__ adj,
    const float* __restrict__ esrc, const float* __restrict__ edst,
    float* __restrict__ out, int ldOut)
{
    int row = blockIdx.x;          // b*N + n
    int k = blockIdx.y;
    int rows = gridDim.x;
    int b = row / Nq, n = row % Nq;
    int m = threadIdx.x;

    __shared__ float att[Nq];
    __shared__ float red[Nq];

    float e = esrc[(long long)k * rows + row] + edst[(long long)k * rows + b * Nq + m];
    e = e > 0.f ? e : ALPHA_LR * e;
    if (adj[(long long)b * Nq * Nq + n * Nq + m] <= 0) e = -9.0e15f;

    red[m] = e; __syncthreads();
    for (int off = 64; off > 0; off >>= 1) {
        if (m < off) red[m] = fmaxf(red[m], red[m + off]);
        __syncthreads();
    }
    float mx = red[0]; __syncthreads();
    float ex = expf(e - mx);
    att[m] = ex; red[m] = ex; __syncthreads();
    for (int off = 64; off > 0; off >>= 1) {
        if (m < off) red[m] += red[m + off];
        __syncthreads();
    }
    float inv = 1.0f / red[0];

    for (int g = threadIdx.x; g < GD; g += blockDim.x) {
        float s = 0.f;
        for (int mm = 0; mm < Nq; mm++)
            s += att[mm] * Wh[(long long)(b * Nq + mm) * ldWh + k * GD + g];
        s *= inv;
        s = s > 0.f ? s : expm1f(s);   // ELU
        out[(long long)row * ldOut + k * GD + g] = s;
    }
}

// 11x11 same-pad conv over (M, PD), single channel, + leaky
__global__ __launch_bounds__(256) void conv_k(
    const float* __restrict__ x, const float* __restrict__ W,
    const float* __restrict__ bptr, float* __restrict__ y)
{
    __shared__ float w[121];
    if (threadIdx.x < 121) w[threadIdx.x] = W[threadIdx.x];
    __syncthreads();
    long long idx = (long long)blockIdx.x * blockDim.x + threadIdx.x;
    long long total = (long long)Bq * Mq * PDq;
    if (idx >= total) return;
    int d = (int)(idx % PDq);
    long long t = idx / PDq;
    int m = (int)(t % Mq);
    int b = (int)(t / Mq);
    const float* xb = x + (long long)b * Mq * PDq;
    float s = 0.f;
    #pragma unroll
    for (int i = 0; i < 11; i++) {
        int mm = m + i - 5;
        if (mm < 0 || mm >= Mq) continue;
        #pragma unroll
        for (int j = 0; j < 11; j++) {
            int dd = d + j - 5;
            if (dd < 0 || dd >= PDq) continue;
            s += xb[(long long)mm * PDq + dd] * w[i * 11 + j];
        }
    }
    s += *bptr;
    y[idx] = s > 0.f ? s : ALPHA_LR * s;
}

// out[row] = x[row,:LD] . w
__global__ __launch_bounds__(256) void rowdot_k(
    const float* __restrict__ x, const float* __restrict__ w, float* __restrict__ out)
{
    int row = blockIdx.x, t = threadIdx.x;
    float s = x[(long long)row * LDq + t] * w[t];
    __shared__ float red[256];
    red[t] = s; __syncthreads();
    for (int off = 128; off > 0; off >>= 1) {
        if (t < off) red[t] += red[t + off];
        __syncthreads();
    }
    if (t == 0) out[row] = red[0];
}

// out[b,m] = sum_n A[b,n,m] * q[b,n]
__global__ __launch_bounds__(256) void colsum_k(
    const float* __restrict__ A, const float* __restrict__ q, float* __restrict__ out)
{
    int b = blockIdx.y;
    int m = blockIdx.x * 256 + threadIdx.x;
    const float* Ab = A + (long long)b * Nq * Mq;
    const float* qb = q + (long long)b * Nq;
    float s = 0.f;
    for (int n = 0; n < Nq; n++) s += Ab[(long long)n * Mq + m] * qb[n];
    out[(long long)b * Mq + m] = s;
}

// score_c[row=b*N+n] = hb[row]·w1 + A[b,n,:]·r[b,:] + bias
__global__ __launch_bounds__(256) void scoreC_k(
    const float* __restrict__ hb, const float* __restrict__ A,
    const float* __restrict__ r, const float* __restrict__ w1,
    const float* __restrict__ bptr, float* __restrict__ score)
{
    int row = blockIdx.x;
    int b = row / Nq;
    int t = threadIdx.x;
    float s = hb[(long long)row * LDq + t] * w1[t];
    const float* Ar = A + (long long)row * Mq;
    const float* rb = r + (long long)b * Mq;
    for (int m = t; m < Mq; m += 256) s += Ar[m] * rb[m];
    __shared__ float red[256];
    red[t] = s; __syncthreads();
    for (int off = 128; off > 0; off >>= 1) {
        if (t < off) red[t] += red[t + off];
        __syncthreads();
    }
    if (t == 0) score[row] = red[0] + bptr[0];
}

// score_p[row=b*M+m] = hpb[row]·w1 + csum[row] + bias
__global__ __launch_bounds__(256) void scoreP_k(
    const float* __restrict__ hpb, const float* __restrict__ csum,
    const float* __restrict__ w1, const float* __restrict__ bptr,
    float* __restrict__ score)
{
    int row = blockIdx.x;
    int t = threadIdx.x;
    float s = hpb[(long long)row * LDq + t] * w1[t];
    __shared__ float red[256];
    red[t] = s; __syncthreads();
    for (int off = 128; off > 0; off >>= 1) {
        if (t < off) red[t] += red[t + off];
        __syncthreads();
    }
    if (t == 0) score[row] = red[0] + csum[row] + bptr[0];
}

// masked softmax in place over L, one block per batch row
__global__ __launch_bounds__(256) void msoftmax_k(
    float* __restrict__ score, const float* __restrict__ mask, int L)
{
    int b = blockIdx.x;
    float* s = score + (long long)b * L;
    const float* mk = mask + (long long)b * L;
    int t = threadIdx.x;
    __shared__ float red[256];
    float mx = -1e30f;
    for (int i = t; i < L; i += 256) mx = fmaxf(mx, s[i]);
    red[t] = mx; __syncthreads();
    for (int off = 128; off > 0; off >>= 1) {
        if (t < off) red[t] = fmaxf(red[t], red[t + off]);
        __syncthreads();
    }
    mx = red[0]; __syncthreads();
    float sum = 0.f;
    for (int i = t; i < L; i += 256) {
        float e = expf(s[i] - mx) * mk[i];
        s[i] = e; sum += e;
    }
    red[t] = sum; __syncthreads();
    for (int off = 128; off > 0; off >>= 1) {
        if (t < off) red[t] += red[t + off];
        __syncthreads();
    }
    float inv = 1.0f / (red[0] + 1e-6f);
    __syncthreads();
    for (int i = t; i < L; i += 256) s[i] *= inv;
}

// out[b*outStride + l] = sum_r feat[b,r,l] * att[b,r]
__global__ __launch_bounds__(256) void wsum_k(
    const float* __restrict__ feat, const float* __restrict__ att,
    float* __restrict__ out, int L, int outStride)
{
    int b = blockIdx.x, l = threadIdx.x;
    const float* fb = feat + (long long)b * L * LDq;
    const float* ab = att + (long long)b * L;
    float s = 0.f;
    for (int r = 0; r < L; r++) s += fb[(long long)r * LDq + l] * ab[r];
    out[(long long)b * outStride + l] = s;
}

// v[b,256:512]=fps, v[b,768]=invT, v[b,769]=T
__global__ __launch_bounds__(256) void vfill_k(
    const float* __restrict__ fps, const float* __restrict__ invT,
    const float* __restrict__ T, float* __restrict__ v)
{
    int b = blockIdx.x, t = threadIdx.x;
    v[(long long)b * 770 + 256 + t] = fps[(long long)b * 256 + t];
    if (t == 0) {
        v[(long long)b * 770 + 768] = invT[b];
        v[(long long)b * 770 + 769] = T[b];
    }
}

// out[b] = v[b,:770]·W + b
__global__ __launch_bounds__(256) void final_k(
    const float* __restrict__ v, const float* __restrict__ W,
    const float* __restrict__ bptr, float* __restrict__ out)
{
    int b = blockIdx.x, t = threadIdx.x;
    float s = 0.f;
    for (int i = t; i < 770; i += 256) s += v[(long long)b * 770 + i] * W[i];
    __shared__ float red[256];
    red[t] = s; __syncthreads();
    for (int off = 128; off > 0; off >>= 1) {
        if (t < off) red[t] += red[t + off];
        __syncthreads();
    }
    if (t == 0) out[b] = red[0] + bptr[0];
}

extern "C" void kernel_launch(void* const* d_in, const int* in_sizes, int n_in,
                              void* d_out, int out_size, void* d_ws, size_t ws_size,
                              hipStream_t stream)
{
    const float* atoms_emb = (const float*)d_in[0];
    const int*   adjacency = (const int*)d_in[1];
    const float* atoms_mask= (const float*)d_in[2];
    const float* amino_emb = (const float*)d_in[3];
    const float* amino_mask= (const float*)d_in[4];
    const float* fps       = (const float*)d_in[5];
    const float* inv_Temp  = (const float*)d_in[6];
    const float* Temp      = (const float*)d_in[7];
    const float* bert_W    = (const float*)d_in[8];
    const float* bert_b    = (const float*)d_in[9];
    const float* gat_W     = (const float*)d_in[10];
    const float* gat_a     = (const float*)d_in[11];
    const float* gatout_W  = (const float*)d_in[12];
    const float* gatout_a  = (const float*)d_in[13];
    const float* Wcomp_W   = (const float*)d_in[14];
    const float* Wcomp_b   = (const float*)d_in[15];
    const float* prot_W    = (const float*)d_in[16];
    const float* prot_b    = (const float*)d_in[17];
    const float* conv_W    = (const float*)d_in[18];
    const float* conv_b    = (const float*)d_in[19];
    const float* Wprot_W   = (const float*)d_in[20];
    const float* Wprot_b   = (const float*)d_in[21];
    const float* U         = (const float*)d_in[22];
    const float* tc2p_W    = (const float*)d_in[23];
    const float* tc2p_b    = (const float*)d_in[24];
    const float* tp2c_W    = (const float*)d_in[25];
    const float* tp2c_b    = (const float*)d_in[26];
    const float* bhc_W     = (const float*)d_in[27];
    const float* bhc_b     = (const float*)d_in[28];
    const float* bhp_W     = (const float*)d_in[29];
    const float* bhp_b     = (const float*)d_in[30];
    const float* battc_W   = (const float*)d_in[31];
    const float* battc_b   = (const float*)d_in[32];
    const float* battp_W   = (const float*)d_in[33];
    const float* battp_b   = (const float*)d_in[34];
    const float* combc_W   = (const float*)d_in[35];
    const float* combc_b   = (const float*)d_in[36];
    const float* combp_W   = (const float*)d_in[37];
    const float* combp_b   = (const float*)d_in[38];
    const float* Wout_W    = (const float*)d_in[39];
    const float* Wout_b    = (const float*)d_in[40];
    const float* out_W     = (const float*)d_in[41];
    const float* out_b     = (const float*)d_in[42];
    float* out = (float*)d_out;

    // ---- workspace layout (floats) ----
    float* w = (float*)d_ws;
    float* av    = w; w += (long long)Bq*Nq*LDq;
    float* pv    = w; w += (long long)Bq*Mq*LDq;
    float* sx    = w; w += (long long)Bq*Mq*LDq;   // scratch: early phase / tp -> hpb
    float* Abuf  = w; w += (long long)Bq*Nq*Mq;
    float* bufU  = w; w += (long long)Bq*Nq*LDq;   // avU -> hb
    float* bufTC = w; w += (long long)Bq*Nq*LDq;
    float* esrc  = w; w += (long long)NHq*Bq*Nq;
    float* edst  = w; w += (long long)NHq*Bq*Nq;
    float* scoreC= w; w += (long long)Bq*Nq;
    float* scoreP= w; w += (long long)Bq*Mq;
    float* rbuf  = w; w += (long long)Bq*Mq;
    float* qbuf  = w; w += (long long)Bq*Nq;
    float* csum  = w; w += (long long)Bq*Mq;
    float* cf    = w; w += (long long)Bq*4*LDq;
    float* pf    = w; w += (long long)Bq*4*LDq;
    float* v1    = w; w += (long long)Bq*770;
    float* v2    = w; w += (long long)Bq*770;

    // early-phase aliases inside sx (dead before BIDAT loop reuses sx)
    float* h     = sx;
    float* WhAll = h + (long long)Bq*Nq*CDq;
    float* multi = WhAll + (long long)Bq*Nq*NHq*GDq;
    float* Wh2   = multi + (long long)Bq*Nq*NHq*GDq;
    float* avp   = Wh2 + (long long)Bq*Nq*CDq;
    float* c0    = avp + (long long)Bq*Nq*CDq;
    float* c1    = c0 + (long long)Bq*Mq*PDq;

    int rowsA = Bq * Nq;     // 4096
    int rowsP = Bq * Mq;     // 32768

    // 1. h = atoms_emb @ bert_W + bert_b
    run_gemm(stream, 0, false, rowsA, CDq, 300, atoms_emb, 300, 0,
             bert_W, CDq, 0, bert_b, h, CDq, 0, 1);

    // 2. Wh_all[b,n,k,g] = h @ gat_W[k]  (batched over heads, C offset per head)
    run_gemm(stream, 0, false, rowsA, GDq, CDq, h, CDq, 0,
             gat_W, GDq, (long long)CDq*GDq, nullptr,
             WhAll, NHq*GDq, GDq, NHq);

    // 3-4. GAT heads attention -> multi (ELU)
    gat_e_k<<<dim3(rowsA, NHq), 128, 0, stream>>>(WhAll, NHq*GDq, GDq, gat_a, 2*GDq,
                                                  esrc, edst, rowsA);
    gat_attn_k<<<dim3(rowsA, NHq), 128, 0, stream>>>(WhAll, NHq*GDq, GDq, adjacency,
                                                     esrc, edst, multi, NHq*GDq);

    // 5-7. GAT out layer -> avp (ELU)
    run_gemm(stream, 0, false, rowsA, CDq, NHq*GDq, multi, NHq*GDq, 0,
             gatout_W, CDq, 0, nullptr, Wh2, CDq, 0, 1);
    gat_e_k<<<dim3(rowsA, 1), 128, 0, stream>>>(Wh2, CDq, CDq, gatout_a, 2*CDq,
                                                esrc, edst, rowsA);
    gat_attn_k<<<dim3(rowsA, 1), 128, 0, stream>>>(Wh2, CDq, CDq, adjacency,
                                                   esrc, edst, avp, CDq);

    // 8. av = leaky(avp @ Wcomp_W + b)
    run_gemm(stream, 1, false, rowsA, LDq, CDq, avp, CDq, 0,
             Wcomp_W, LDq, 0, Wcomp_b, av, LDq, 0, 1);

    // 9. pv0 = amino_emb @ prot_W + b
    run_gemm(stream, 0, false, rowsP, PDq, 1024, amino_emb, 1024, 0,
             prot_W, PDq, 0, prot_b, c0, PDq, 0, 1);

    // 10. 3x conv 11x11 + leaky (ping-pong c0/c1)
    {
        long long total = (long long)Bq*Mq*PDq;
        int blocks = (int)((total + 255) / 256);
        conv_k<<<blocks, 256, 0, stream>>>(c0, conv_W + 0*121, conv_b + 0, c1);
        conv_k<<<blocks, 256, 0, stream>>>(c1, conv_W + 1*121, conv_b + 1, c0);
        conv_k<<<blocks, 256, 0, stream>>>(c0, conv_W + 2*121, conv_b + 2, c1);
    }

    // 11. pv = leaky(x @ Wprot_W + b)
    run_gemm(stream, 1, false, rowsP, LDq, PDq, c1, PDq, 0,
             Wprot_W, LDq, 0, Wprot_b, pv, LDq, 0, 1);

    // 12. BIDAT loop
    for (int i = 0; i < 4; i++) {
        const float* Ui      = U      + (long long)i*LDq*LDq;
        const float* tp2cWi  = tp2c_W + (long long)i*LDq*LDq;
        const float* tp2cbi  = tp2c_b + (long long)i*LDq;
        const float* tc2pWi  = tc2p_W + (long long)i*LDq*LDq;
        const float* tc2pbi  = tc2p_b + (long long)i*LDq;
        const float* bhcWi   = bhc_W  + (long long)i*LDq*LDq;
        const float* bhcbi   = bhc_b  + (long long)i*LDq;
        const float* bhpWi   = bhp_W  + (long long)i*LDq*LDq;
        const float* bhpbi   = bhp_b  + (long long)i*LDq;
        const float* battcWi = battc_W+ (long long)i*2*LDq;
        const float* battcbi = battc_b+ i;
        const float* battpWi = battp_W+ (long long)i*2*LDq;
        const float* battpbi = battp_b+ i;

        // avU = av @ U[i]
        run_gemm(stream, 0, false, rowsA, LDq, LDq, av, LDq, 0,
                 Ui, LDq, 0, nullptr, bufU, LDq, 0, 1);
        // A = tanh(avU @ pv^T) * masks   (batched NT)
        run_gemm(stream, 2, true, Nq, Mq, LDq,
                 bufU, LDq, (long long)Nq*LDq,
                 pv, LDq, (long long)Mq*LDq,
                 nullptr, Abuf, Mq, (long long)Nq*Mq, Bq,
                 atoms_mask, amino_mask);
        // tp = tanh(pv @ tp2c_W + b)
        run_gemm(stream, 2, false, rowsP, LDq, LDq, pv, LDq, 0,
                 tp2cWi, LDq, 0, tp2cbi, sx, LDq, 0, 1);
        // r[b,m] = tp[b,m,:]·battc_W[LD:]
        rowdot_k<<<rowsP, 256, 0, stream>>>(sx, battcWi + LDq, rbuf);
        // tc = tanh(av @ tc2p_W + b)
        run_gemm(stream, 2, false, rowsA, LDq, LDq, av, LDq, 0,
                 tc2pWi, LDq, 0, tc2pbi, bufTC, LDq, 0, 1);
        // q[b,n] = tc[b,n,:]·battp_W[LD:]
        rowdot_k<<<rowsA, 256, 0, stream>>>(bufTC, battpWi + LDq, qbuf);
        // hb = tanh(av @ bhc_W + b)   (reuse bufU)
        run_gemm(stream, 2, false, rowsA, LDq, LDq, av, LDq, 0,
                 bhcWi, LDq, 0, bhcbi, bufU, LDq, 0, 1);
        // hpb = tanh(pv @ bhp_W + b)  (reuse sx)
        run_gemm(stream, 2, false, rowsP, LDq, LDq, pv, LDq, 0,
                 bhpWi, LDq, 0, bhpbi, sx, LDq, 0, 1);
        // csum[b,m] = sum_n A[b,n,m]*q[b,n]
        colsum_k<<<dim3(Mq/256, Bq), 256, 0, stream>>>(Abuf, qbuf, csum);
        // attention scores
        scoreC_k<<<rowsA, 256, 0, stream>>>(bufU, Abuf, rbuf, battcWi, battcbi, scoreC);
        scoreP_k<<<rowsP, 256, 0, stream>>>(sx, csum, battpWi, battpbi, scoreP);
        // masked softmax
        msoftmax_k<<<Bq, 256, 0, stream>>>(scoreC, atoms_mask, Nq);
        msoftmax_k<<<Bq, 256, 0, stream>>>(scoreP, amino_mask, Mq);
        // pooled features
        wsum_k<<<Bq, 256, 0, stream>>>(av, scoreC, cf + (long long)i*LDq, Nq, 4*LDq);
        wsum_k<<<Bq, 256, 0, stream>>>(pv, scoreP, pf + (long long)i*LDq, Mq, 4*LDq);
    }

    // 13. head
    run_gemm(stream, 0, false, Bq, LDq, 4*LDq, cf, 4*LDq, 0,
             combc_W, LDq, 0, combc_b, v1, 770, 0, 1);
    run_gemm(stream, 0, false, Bq, LDq, 4*LDq, pf, 4*LDq, 0,
             combp_W, LDq, 0, combp_b, v1 + 512, 770, 0, 1);
    vfill_k<<<Bq, 256, 0, stream>>>(fps, inv_Temp, Temp, v1);

    run_gemm(stream, 1, false, Bq, 770, 770, v1, 770, 0,
             Wout_W + 0ll*770*770, 770, 0, Wout_b + 0*770, v2, 770, 0, 1);
    run_gemm(stream, 1, false, Bq, 770, 770, v2, 770, 0,
             Wout_W + 1ll*770*770, 770, 0, Wout_b + 1*770, v1, 770, 0, 1);
    run_gemm(stream, 1, false, Bq, 770, 770, v1, 770, 0,
             Wout_W + 2ll*770*770, 770, 0, Wout_b + 2*770, v2, 770, 0, 1);

    final_k<<<Bq, 256, 0, stream>>>(v2, out_W, out_b, out);

    (void)in_sizes; (void)n_in; (void)out_size; (void)ws_size;
}

// Round 2
// 3018.052 us; speedup vs baseline: 1.3485x; 1.3485x over previous
//
#include <hip/hip_runtime.h>
#include <math.h>

#define ALPHA_LR 0.2f

#define Bq  32
#define Nq  128
#define Mq  1024
#define CDq 128
#define GDq 64
#define NHq 4
#define LDq 256
#define PDq 40

// ---------------------------------------------------------------------------
// Generic tiled fp32 GEMM: C = act(A @ B + bias) [* masks]
// TA=0: A[m*lda+k]; TA=1: A[k*lda+m]
// TB=0: B[k*ldb+n]; TB=1: B[n*ldb+k]
// ACT: 0 none, 1 leaky(0.2), 2 tanh
// MASKED: multiply by maskR[z*M+m]*maskC[z*N+n] after activation
// batched via blockIdx.z with element strides sA/sB/sC
// ---------------------------------------------------------------------------
template<int ACT, int TA, int TB, int MASKED>
__global__ __launch_bounds__(256) void gemm_k(
    int M, int N, int K,
    const float* __restrict__ A, int lda, long long sA,
    const float* __restrict__ Bm, int ldb, long long sB,
    const float* __restrict__ bias,
    float* __restrict__ C, int ldc, long long sC,
    const float* __restrict__ maskR, const float* __restrict__ maskC)
{
    int z = blockIdx.z;
    A  += (long long)z * sA;
    Bm += (long long)z * sB;
    C  += (long long)z * sC;

    __shared__ float As[16][68];
    __shared__ float Bs[16][68];

    int tid = threadIdx.x;
    int tx = tid % 16, ty = tid / 16;
    int m0 = blockIdx.y * 64, n0 = blockIdx.x * 64;

    float acc[4][4] = {};

    for (int k0 = 0; k0 < K; k0 += 16) {
        if (!TA) {
            int k = tid % 16, mBase = tid / 16;
            #pragma unroll
            for (int p = 0; p < 4; p++) {
                int m = mBase + p * 16;
                int gm = m0 + m, gk = k0 + k;
                float v = 0.f;
                if (gm < M && gk < K) v = A[(long long)gm * lda + gk];
                As[k][m] = v;
            }
        } else {
            int m = tid % 64, kBase = tid / 64;
            #pragma unroll
            for (int p = 0; p < 4; p++) {
                int k = kBase + p * 4;
                int gm = m0 + m, gk = k0 + k;
                float v = 0.f;
                if (gm < M && gk < K) v = A[(long long)gk * lda + gm];
                As[k][m] = v;
            }
        }
        if (!TB) {
            int n = tid % 64, kBase = tid / 64;
            #pragma unroll
            for (int p = 0; p < 4; p++) {
                int k = kBase + p * 4;
                int gn = n0 + n, gk = k0 + k;
                float v = 0.f;
                if (gn < N && gk < K) v = Bm[(long long)gk * ldb + gn];
                Bs[k][n] = v;
            }
        } else {
            int k = tid % 16, nBase = tid / 16;
            #pragma unroll
            for (int p = 0; p < 4; p++) {
                int n = nBase + p * 16;
                int gn = n0 + n, gk = k0 + k;
                float v = 0.f;
                if (gn < N && gk < K) v = Bm[(long long)gn * ldb + gk];
                Bs[k][n] = v;
            }
        }
        __syncthreads();
        #pragma unroll
        for (int kk = 0; kk < 16; kk++) {
            float a[4], b[4];
            #pragma unroll
            for (int i = 0; i < 4; i++) a[i] = As[kk][ty * 4 + i];
            #pragma unroll
            for (int j = 0; j < 4; j++) b[j] = Bs[kk][tx * 4 + j];
            #pragma unroll
            for (int i = 0; i < 4; i++)
                #pragma unroll
                for (int j = 0; j < 4; j++)
                    acc[i][j] += a[i] * b[j];
        }
        __syncthreads();
    }

    #pragma unroll
    for (int i = 0; i < 4; i++) {
        int gm = m0 + ty * 4 + i;
        if (gm >= M) continue;
        #pragma unroll
        for (int j = 0; j < 4; j++) {
            int gn = n0 + tx * 4 + j;
            if (gn >= N) continue;
            float v = acc[i][j];
            if (bias) v += bias[gn];
            if (ACT == 1) v = v > 0.f ? v : ALPHA_LR * v;
            else if (ACT == 2) v = tanhf(v);
            if (MASKED) v *= maskR[(long long)z * M + gm] * maskC[(long long)z * N + gn];
            C[(long long)gm * ldc + gn] = v;
        }
    }
}

static inline void run_gemm(hipStream_t stream, int act, bool tb_masked,
    int M, int N, int K,
    const float* A, int lda, long long sA,
    const float* B, int ldb, long long sB,
    const float* bias, float* C, int ldc, long long sC,
    int batch, const float* maskR = nullptr, const float* maskC = nullptr)
{
    dim3 grid((N + 63) / 64, (M + 63) / 64, batch);
    dim3 blk(256);
    if (tb_masked) {
        gemm_k<2, 0, 1, 1><<<grid, blk, 0, stream>>>(M, N, K, A, lda, sA, B, ldb, sB,
                                                     bias, C, ldc, sC, maskR, maskC);
    } else if (act == 0) {
        gemm_k<0, 0, 0, 0><<<grid, blk, 0, stream>>>(M, N, K, A, lda, sA, B, ldb, sB,
                                                     bias, C, ldc, sC, nullptr, nullptr);
    } else if (act == 1) {
        gemm_k<1, 0, 0, 0><<<grid, blk, 0, stream>>>(M, N, K, A, lda, sA, B, ldb, sB,
                                                     bias, C, ldc, sC, nullptr, nullptr);
    } else {
        gemm_k<2, 0, 0, 0><<<grid, blk, 0, stream>>>(M, N, K, A, lda, sA, B, ldb, sB,
                                                     bias, C, ldc, sC, nullptr, nullptr);
    }
}

// per-row GAT source/dest attention logits
__global__ __launch_bounds__(128) void gat_e_k(
    const float* __restrict__ Wh, int ldWh, int GD,
    const float* __restrict__ a, int aStride,
    float* __restrict__ esrc, float* __restrict__ edst, int rows)
{
    int row = blockIdx.x;
    int k = blockIdx.y;
    int g = threadIdx.x;
    float ws = 0.f, wd = 0.f;
    if (g < GD) {
        float wv = Wh[(long long)row * ldWh + k * GD + g];
        ws = wv * a[k * aStride + g];
        wd = wv * a[k * aStride + GD + g];
    }
    __shared__ float sb[2][128];
    sb[0][threadIdx.x] = ws; sb[1][threadIdx.x] = wd;
    __syncthreads();
    for (int off = 64; off > 0; off >>= 1) {
        if (threadIdx.x < off) {
            sb[0][threadIdx.x] += sb[0][threadIdx.x + off];
            sb[1][threadIdx.x] += sb[1][threadIdx.x + off];
        }
        __syncthreads();
    }
    if (threadIdx.x == 0) {
        esrc[(long long)k * rows + row] = sb[0][0];
        edst[(long long)k * rows + row] = sb[1][0];
    }
}

// GAT attention: softmax over neighbors + weighted sum + ELU
__global__ __launch_bounds__(128) void gat_attn_k(
    const float* __restrict__ Wh, int ldWh, int GD,
    const int* __restrict__ adj,
    const float* __restrict__ esrc, const float* __restrict__ edst,
    float* __restrict__ out, int ldOut)
{
    int row = blockIdx.x;          // b*N + n
    int k = blockIdx.y;
    int rows = gridDim.x;
    int b = row / Nq, n = row % Nq;
    int m = threadIdx.x;

    __shared__ float att[Nq];
    __shared__ float red[Nq];

    float e = esrc[(long long)k * rows + row] + edst[(long long)k * rows + b * Nq + m];
    e = e > 0.f ? e : ALPHA_LR * e;
    if (adj[(long long)b * Nq * Nq + n * Nq + m] <= 0) e = -9.0e15f;

    red[m] = e; __syncthreads();
    for (int off = 64; off > 0; off >>= 1) {
        if (m < off) red[m] = fmaxf(red[m], red[m + off]);
        __syncthreads();
    }
    float mx = red[0]; __syncthreads();
    float ex = expf(e - mx);
    att[m] = ex; red[m] = ex; __syncthreads();
    for (int off = 64; off > 0; off >>= 1) {
        if (m < off) red[m] += red[m + off];
        __syncthreads();
    }
    float inv = 1.0f / red[0];

    for (int g = threadIdx.x; g < GD; g += blockDim.x) {
        float s = 0.f;
        for (int mm = 0; mm < Nq; mm++)
            s += att[mm] * Wh[(long long)(b * Nq + mm) * ldWh + k * GD + g];
        s *= inv;
        s = s > 0.f ? s : expm1f(s);   // ELU
        out[(long long)row * ldOut + k * GD + g] = s;
    }
}

// 11x11 same-pad conv over (M, PD), single channel, + leaky
__global__ __launch_bounds__(256) void conv_k(
    const float* __restrict__ x, const float* __restrict__ W,
    const float* __restrict__ bptr, float* __restrict__ y)
{
    __shared__ float w[121];
    if (threadIdx.x < 121) w[threadIdx.x] = W[threadIdx.x];
    __syncthreads();
    long long idx = (long long)blockIdx.x * blockDim.x + threadIdx.x;
    long long total = (long long)Bq * Mq * PDq;
    if (idx >= total) return;
    int d = (int)(idx % PDq);
    long long t = idx / PDq;
    int m = (int)(t % Mq);
    int b = (int)(t / Mq);
    const float* xb = x + (long long)b * Mq * PDq;
    float s = 0.f;
    #pragma unroll
    for (int i = 0; i < 11; i++) {
        int mm = m + i - 5;
        if (mm < 0 || mm >= Mq) continue;
        #pragma unroll
        for (int j = 0; j < 11; j++) {
            int dd = d + j - 5;
            if (dd < 0 || dd >= PDq) continue;
            s += xb[(long long)mm * PDq + dd] * w[i * 11 + j];
        }
    }
    s += *bptr;
    y[idx] = s > 0.f ? s : ALPHA_LR * s;
}

// out[row] = x[row,:LD] . w
__global__ __launch_bounds__(256) void rowdot_k(
    const float* __restrict__ x, const float* __restrict__ w, float* __restrict__ out)
{
    int row = blockIdx.x, t = threadIdx.x;
    float s = x[(long long)row * LDq + t] * w[t];
    __shared__ float red[256];
    red[t] = s; __syncthreads();
    for (int off = 128; off > 0; off >>= 1) {
        if (t < off) red[t] += red[t + off];
        __syncthreads();
    }
    if (t == 0) out[row] = red[0];
}

// out[b,m] = sum_n A[b,n,m] * q[b,n]
__global__ __launch_bounds__(256) void colsum_k(
    const float* __restrict__ A, const float* __restrict__ q, float* __restrict__ out)
{
    int b = blockIdx.y;
    int m = blockIdx.x * 256 + threadIdx.x;
    const float* Ab = A + (long long)b * Nq * Mq;
    const float* qb = q + (long long)b * Nq;
    float s = 0.f;
    for (int n = 0; n < Nq; n++) s += Ab[(long long)n * Mq + m] * qb[n];
    out[(long long)b * Mq + m] = s;
}

// score_c[row=b*N+n] = hb[row]·w1 + A[b,n,:]·r[b,:] + bias
__global__ __launch_bounds__(256) void scoreC_k(
    const float* __restrict__ hb, const float* __restrict__ A,
    const float* __restrict__ r, const float* __restrict__ w1,
    const float* __restrict__ bptr, float* __restrict__ score)
{
    int row = blockIdx.x;
    int b = row / Nq;
    int t = threadIdx.x;
    float s = hb[(long long)row * LDq + t] * w1[t];
    const float* Ar = A + (long long)row * Mq;
    const float* rb = r + (long long)b * Mq;
    for (int m = t; m < Mq; m += 256) s += Ar[m] * rb[m];
    __shared__ float red[256];
    red[t] = s; __syncthreads();
    for (int off = 128; off > 0; off >>= 1) {
        if (t < off) red[t] += red[t + off];
        __syncthreads();
    }
    if (t == 0) score[row] = red[0] + bptr[0];
}

// score_p[row=b*M+m] = hpb[row]·w1 + csum[row] + bias
__global__ __launch_bounds__(256) void scoreP_k(
    const float* __restrict__ hpb, const float* __restrict__ csum,
    const float* __restrict__ w1, const float* __restrict__ bptr,
    float* __restrict__ score)
{
    int row = blockIdx.x;
    int t = threadIdx.x;
    float s = hpb[(long long)row * LDq + t] * w1[t];
    __shared__ float red[256];
    red[t] = s; __syncthreads();
    for (int off = 128; off > 0; off >>= 1) {
        if (t < off) red[t] += red[t + off];
        __syncthreads();
    }
    if (t == 0) score[row] = red[0] + csum[row] + bptr[0];
}

// masked softmax in place over L, one block per batch row
__global__ __launch_bounds__(256) void msoftmax_k(
    float* __restrict__ score, const float* __restrict__ mask, int L)
{
    int b = blockIdx.x;
    float* s = score + (long long)b * L;
    const float* mk = mask + (long long)b * L;
    int t = threadIdx.x;
    __shared__ float red[256];
    float mx = -1e30f;
    for (int i = t; i < L; i += 256) mx = fmaxf(mx, s[i]);
    red[t] = mx; __syncthreads();
    for (int off = 128; off > 0; off >>= 1) {
        if (t < off) red[t] = fmaxf(red[t], red[t + off]);
        __syncthreads();
    }
    mx = red[0]; __syncthreads();
    float sum = 0.f;
    for (int i = t; i < L; i += 256) {
        float e = expf(s[i] - mx) * mk[i];
        s[i] = e; sum += e;
    }
    red[t] = sum; __syncthreads();
    for (int off = 128; off > 0; off >>= 1) {
        if (t < off) red[t] += red[t + off];
        __syncthreads();
    }
    float inv = 1.0f / (red[0] + 1e-6f);
    __syncthreads();
    for (int i = t; i < L; i += 256) s[i] *= inv;
}

// ---------------------------------------------------------------------------
// weighted sum, two-stage (deterministic, 512 blocks instead of 32)
// stage 1: partial[(b*16+c)*LDq + l] = sum_{r in chunk c} feat[b,r,l]*att[b,r]
// ---------------------------------------------------------------------------
__global__ __launch_bounds__(256) void wsum1_k(
    const float* __restrict__ feat, const float* __restrict__ att,
    float* __restrict__ partial, int L)
{
    int b = blockIdx.x, c = blockIdx.y, l = threadIdx.x;
    int chunk = L / 16;
    const float* fb = feat + (long long)b * L * LDq;
    const float* ab = att + (long long)b * L;
    float s = 0.f;
    int r0 = c * chunk, r1 = r0 + chunk;
    for (int r = r0; r < r1; r++) s += fb[(long long)r * LDq + l] * ab[r];
    partial[((long long)b * 16 + c) * LDq + l] = s;
}

// stage 2: out[b*outStride + l] = sum_c partial[(b*16+c)*LDq + l]
__global__ __launch_bounds__(256) void wsum2_k(
    const float* __restrict__ partial, float* __restrict__ out, int outStride)
{
    int b = blockIdx.x, l = threadIdx.x;
    float s = 0.f;
    #pragma unroll
    for (int c = 0; c < 16; c++) s += partial[((long long)b * 16 + c) * LDq + l];
    out[(long long)b * outStride + l] = s;
}

// v[b,256:512]=fps, v[b,768]=invT, v[b,769]=T
__global__ __launch_bounds__(256) void vfill_k(
    const float* __restrict__ fps, const float* __restrict__ invT,
    const float* __restrict__ T, float* __restrict__ v)
{
    int b = blockIdx.x, t = threadIdx.x;
    v[(long long)b * 770 + 256 + t] = fps[(long long)b * 256 + t];
    if (t == 0) {
        v[(long long)b * 770 + 768] = invT[b];
        v[(long long)b * 770 + 769] = T[b];
    }
}

// out[b] = v[b,:770]·W + b
__global__ __launch_bounds__(256) void final_k(
    const float* __restrict__ v, const float* __restrict__ W,
    const float* __restrict__ bptr, float* __restrict__ out)
{
    int b = blockIdx.x, t = threadIdx.x;
    float s = 0.f;
    for (int i = t; i < 770; i += 256) s += v[(long long)b * 770 + i] * W[i];
    __shared__ float red[256];
    red[t] = s; __syncthreads();
    for (int off = 128; off > 0; off >>= 1) {
        if (t < off) red[t] += red[t + off];
        __syncthreads();
    }
    if (t == 0) out[b] = red[0] + bptr[0];
}

extern "C" void kernel_launch(void* const* d_in, const int* in_sizes, int n_in,
                              void* d_out, int out_size, void* d_ws, size_t ws_size,
                              hipStream_t stream)
{
    const float* atoms_emb = (const float*)d_in[0];
    const int*   adjacency = (const int*)d_in[1];
    const float* atoms_mask= (const float*)d_in[2];
    const float* amino_emb = (const float*)d_in[3];
    const float* amino_mask= (const float*)d_in[4];
    const float* fps       = (const float*)d_in[5];
    const float* inv_Temp  = (const float*)d_in[6];
    const float* Temp      = (const float*)d_in[7];
    const float* bert_W    = (const float*)d_in[8];
    const float* bert_b    = (const float*)d_in[9];
    const float* gat_W     = (const float*)d_in[10];
    const float* gat_a     = (const float*)d_in[11];
    const float* gatout_W  = (const float*)d_in[12];
    const float* gatout_a  = (const float*)d_in[13];
    const float* Wcomp_W   = (const float*)d_in[14];
    const float* Wcomp_b   = (const float*)d_in[15];
    const float* prot_W    = (const float*)d_in[16];
    const float* prot_b    = (const float*)d_in[17];
    const float* conv_W    = (const float*)d_in[18];
    const float* conv_b    = (const float*)d_in[19];
    const float* Wprot_W   = (const float*)d_in[20];
    const float* Wprot_b   = (const float*)d_in[21];
    const float* U         = (const float*)d_in[22];
    const float* tc2p_W    = (const float*)d_in[23];
    const float* tc2p_b    = (const float*)d_in[24];
    const float* tp2c_W    = (const float*)d_in[25];
    const float* tp2c_b    = (const float*)d_in[26];
    const float* bhc_W     = (const float*)d_in[27];
    const float* bhc_b     = (const float*)d_in[28];
    const float* bhp_W     = (const float*)d_in[29];
    const float* bhp_b     = (const float*)d_in[30];
    const float* battc_W   = (const float*)d_in[31];
    const float* battc_b   = (const float*)d_in[32];
    const float* battp_W   = (const float*)d_in[33];
    const float* battp_b   = (const float*)d_in[34];
    const float* combc_W   = (const float*)d_in[35];
    const float* combc_b   = (const float*)d_in[36];
    const float* combp_W   = (const float*)d_in[37];
    const float* combp_b   = (const float*)d_in[38];
    const float* Wout_W    = (const float*)d_in[39];
    const float* Wout_b    = (const float*)d_in[40];
    const float* out_W     = (const float*)d_in[41];
    const float* out_b     = (const float*)d_in[42];
    float* out = (float*)d_out;

    // ---- workspace layout (floats) ----
    float* w = (float*)d_ws;
    float* av    = w; w += (long long)Bq*Nq*LDq;
    float* pv    = w; w += (long long)Bq*Mq*LDq;
    float* sx    = w; w += (long long)Bq*Mq*LDq;   // scratch: early phase / tp -> hpb
    float* Abuf  = w; w += (long long)Bq*Nq*Mq;
    float* bufU  = w; w += (long long)Bq*Nq*LDq;   // avU -> hb
    float* bufTC = w; w += (long long)Bq*Nq*LDq;   // tc -> wsum partials
    float* esrc  = w; w += (long long)NHq*Bq*Nq;
    float* edst  = w; w += (long long)NHq*Bq*Nq;
    float* scoreC= w; w += (long long)Bq*Nq;
    float* scoreP= w; w += (long long)Bq*Mq;
    float* rbuf  = w; w += (long long)Bq*Mq;
    float* qbuf  = w; w += (long long)Bq*Nq;
    float* csum  = w; w += (long long)Bq*Mq;
    float* cf    = w; w += (long long)Bq*4*LDq;
    float* pf    = w; w += (long long)Bq*4*LDq;
    float* v1    = w; w += (long long)Bq*770;
    float* v2    = w; w += (long long)Bq*770;

    // early-phase aliases inside sx (dead before BIDAT loop reuses sx)
    float* h     = sx;
    float* WhAll = h + (long long)Bq*Nq*CDq;
    float* multi = WhAll + (long long)Bq*Nq*NHq*GDq;
    float* Wh2   = multi + (long long)Bq*Nq*NHq*GDq;
    float* avp   = Wh2 + (long long)Bq*Nq*CDq;
    float* c0    = avp + (long long)Bq*Nq*CDq;
    float* c1    = c0 + (long long)Bq*Mq*PDq;

    // wsum partial scratch: reuse bufTC (tc is dead by the time wsum runs);
    // needs 32*16*256 = 131072 floats <= bufTC's 1,048,576
    float* wpart = bufTC;

    int rowsA = Bq * Nq;     // 4096
    int rowsP = Bq * Mq;     // 32768

    // 1. h = atoms_emb @ bert_W + bert_b
    run_gemm(stream, 0, false, rowsA, CDq, 300, atoms_emb, 300, 0,
             bert_W, CDq, 0, bert_b, h, CDq, 0, 1);

    // 2. Wh_all[b,n,k,g] = h @ gat_W[k]  (batched over heads, C offset per head)
    run_gemm(stream, 0, false, rowsA, GDq, CDq, h, CDq, 0,
             gat_W, GDq, (long long)CDq*GDq, nullptr,
             WhAll, NHq*GDq, GDq, NHq);

    // 3-4. GAT heads attention -> multi (ELU)
    gat_e_k<<<dim3(rowsA, NHq), 128, 0, stream>>>(WhAll, NHq*GDq, GDq, gat_a, 2*GDq,
                                                  esrc, edst, rowsA);
    gat_attn_k<<<dim3(rowsA, NHq), 128, 0, stream>>>(WhAll, NHq*GDq, GDq, adjacency,
                                                     esrc, edst, multi, NHq*GDq);

    // 5-7. GAT out layer -> avp (ELU)
    run_gemm(stream, 0, false, rowsA, CDq, NHq*GDq, multi, NHq*GDq, 0,
             gatout_W, CDq, 0, nullptr, Wh2, CDq, 0, 1);
    gat_e_k<<<dim3(rowsA, 1), 128, 0, stream>>>(Wh2, CDq, CDq, gatout_a, 2*CDq,
                                                esrc, edst, rowsA);
    gat_attn_k<<<dim3(rowsA, 1), 128, 0, stream>>>(Wh2, CDq, CDq, adjacency,
                                                   esrc, edst, avp, CDq);

    // 8. av = leaky(avp @ Wcomp_W + b)
    run_gemm(stream, 1, false, rowsA, LDq, CDq, avp, CDq, 0,
             Wcomp_W, LDq, 0, Wcomp_b, av, LDq, 0, 1);

    // 9. pv0 = amino_emb @ prot_W + b
    run_gemm(stream, 0, false, rowsP, PDq, 1024, amino_emb, 1024, 0,
             prot_W, PDq, 0, prot_b, c0, PDq, 0, 1);

    // 10. 3x conv 11x11 + leaky (ping-pong c0/c1)
    {
        long long total = (long long)Bq*Mq*PDq;
        int blocks = (int)((total + 255) / 256);
        conv_k<<<blocks, 256, 0, stream>>>(c0, conv_W + 0*121, conv_b + 0, c1);
        conv_k<<<blocks, 256, 0, stream>>>(c1, conv_W + 1*121, conv_b + 1, c0);
        conv_k<<<blocks, 256, 0, stream>>>(c0, conv_W + 2*121, conv_b + 2, c1);
    }

    // 11. pv = leaky(x @ Wprot_W + b)
    run_gemm(stream, 1, false, rowsP, LDq, PDq, c1, PDq, 0,
             Wprot_W, LDq, 0, Wprot_b, pv, LDq, 0, 1);

    // 12. BIDAT loop
    for (int i = 0; i < 4; i++) {
        const float* Ui      = U      + (long long)i*LDq*LDq;
        const float* tp2cWi  = tp2c_W + (long long)i*LDq*LDq;
        const float* tp2cbi  = tp2c_b + (long long)i*LDq;
        const float* tc2pWi  = tc2p_W + (long long)i*LDq*LDq;
        const float* tc2pbi  = tc2p_b + (long long)i*LDq;
        const float* bhcWi   = bhc_W  + (long long)i*LDq*LDq;
        const float* bhcbi   = bhc_b  + (long long)i*LDq;
        const float* bhpWi   = bhp_W  + (long long)i*LDq*LDq;
        const float* bhpbi   = bhp_b  + (long long)i*LDq;
        const float* battcWi = battc_W+ (long long)i*2*LDq;
        const float* battcbi = battc_b+ i;
        const float* battpWi = battp_W+ (long long)i*2*LDq;
        const float* battpbi = battp_b+ i;

        // avU = av @ U[i]
        run_gemm(stream, 0, false, rowsA, LDq, LDq, av, LDq, 0,
                 Ui, LDq, 0, nullptr, bufU, LDq, 0, 1);
        // A = tanh(avU @ pv^T) * masks   (batched NT)
        run_gemm(stream, 2, true, Nq, Mq, LDq,
                 bufU, LDq, (long long)Nq*LDq,
                 pv, LDq, (long long)Mq*LDq,
                 nullptr, Abuf, Mq, (long long)Nq*Mq, Bq,
                 atoms_mask, amino_mask);
        // tp = tanh(pv @ tp2c_W + b)
        run_gemm(stream, 2, false, rowsP, LDq, LDq, pv, LDq, 0,
                 tp2cWi, LDq, 0, tp2cbi, sx, LDq, 0, 1);
        // r[b,m] = tp[b,m,:]·battc_W[LD:]
        rowdot_k<<<rowsP, 256, 0, stream>>>(sx, battcWi + LDq, rbuf);
        // tc = tanh(av @ tc2p_W + b)
        run_gemm(stream, 2, false, rowsA, LDq, LDq, av, LDq, 0,
                 tc2pWi, LDq, 0, tc2pbi, bufTC, LDq, 0, 1);
        // q[b,n] = tc[b,n,:]·battp_W[LD:]
        rowdot_k<<<rowsA, 256, 0, stream>>>(bufTC, battpWi + LDq, qbuf);
        // hb = tanh(av @ bhc_W + b)   (reuse bufU)
        run_gemm(stream, 2, false, rowsA, LDq, LDq, av, LDq, 0,
                 bhcWi, LDq, 0, bhcbi, bufU, LDq, 0, 1);
        // hpb = tanh(pv @ bhp_W + b)  (reuse sx)
        run_gemm(stream, 2, false, rowsP, LDq, LDq, pv, LDq, 0,
                 bhpWi, LDq, 0, bhpbi, sx, LDq, 0, 1);
        // csum[b,m] = sum_n A[b,n,m]*q[b,n]
        colsum_k<<<dim3(Mq/256, Bq), 256, 0, stream>>>(Abuf, qbuf, csum);
        // attention scores
        scoreC_k<<<rowsA, 256, 0, stream>>>(bufU, Abuf, rbuf, battcWi, battcbi, scoreC);
        scoreP_k<<<rowsP, 256, 0, stream>>>(sx, csum, battpWi, battpbi, scoreP);
        // masked softmax
        msoftmax_k<<<Bq, 256, 0, stream>>>(scoreC, atoms_mask, Nq);
        msoftmax_k<<<Bq, 256, 0, stream>>>(scoreP, amino_mask, Mq);
        // pooled features (two-stage; tc in bufTC is dead now -> wpart scratch)
        wsum1_k<<<dim3(Bq, 16), 256, 0, stream>>>(av, scoreC, wpart, Nq);
        wsum2_k<<<Bq, 256, 0, stream>>>(wpart, cf + (long long)i*LDq, 4*LDq);
        wsum1_k<<<dim3(Bq, 16), 256, 0, stream>>>(pv, scoreP, wpart, Mq);
        wsum2_k<<<Bq, 256, 0, stream>>>(wpart, pf + (long long)i*LDq, 4*LDq);
    }

    // 13. head
    run_gemm(stream, 0, false, Bq, LDq, 4*LDq, cf, 4*LDq, 0,
             combc_W, LDq, 0, combc_b, v1, 770, 0, 1);
    run_gemm(stream, 0, false, Bq, LDq, 4*LDq, pf, 4*LDq, 0,
             combp_W, LDq, 0, combp_b, v1 + 512, 770, 0, 1);
    vfill_k<<<Bq, 256, 0, stream>>>(fps, inv_Temp, Temp, v1);

    run_gemm(stream, 1, false, Bq, 770, 770, v1, 770, 0,
             Wout_W + 0ll*770*770, 770, 0, Wout_b + 0*770, v2, 770, 0, 1);
    run_gemm(stream, 1, false, Bq, 770, 770, v2, 770, 0,
             Wout_W + 1ll*770*770, 770, 0, Wout_b + 1*770, v1, 770, 0, 1);
    run_gemm(stream, 1, false, Bq, 770, 770, v1, 770, 0,
             Wout_W + 2ll*770*770, 770, 0, Wout_b + 2*770, v2, 770, 0, 1);

    final_k<<<Bq, 256, 0, stream>>>(v2, out_W, out_b, out);

    (void)in_sizes; (void)n_in; (void)out_size; (void)ws_size;
}

// Round 3
// 2624.090 us; speedup vs baseline: 1.5510x; 1.1501x over previous
//
#include <hip/hip_runtime.h>
#include <math.h>

#define ALPHA_LR 0.2f

#define Bq  32
#define Nq  128
#define Mq  1024
#define CDq 128
#define GDq 64
#define NHq 4
#define LDq 256
#define PDq 40

typedef unsigned short ushort_t;
typedef __attribute__((ext_vector_type(8))) short bf16x8;
typedef __attribute__((ext_vector_type(4))) float f32x4;

__device__ __forceinline__ ushort_t f2bf(float f) {
    union { float f; unsigned u; } x; x.f = f;
    unsigned r = x.u + 0x7FFFu + ((x.u >> 16) & 1u);   // RNE
    return (ushort_t)(r >> 16);
}

// ---------------------------------------------------------------------------
// MFMA bf16 NT GEMM: C = act(A @ Bt^T + bias) [* masks]
// A: [M][lda] bf16 (or fp32 if AF32), Bt: [Npad][ldb] bf16 (= B^T, K-major)
// Each wave: 16 rows x NT*16 cols. grid.x = M/64 (4 waves/block),
// grid.y = N/(NT*16), grid.z = batch. K % 32 == 0. M % 16 == 0.
// C/D layout (m89-verified): col = lane&15, row = (lane>>4)*4 + reg.
// A/B fragment: idx lane&15 = row/col, k = 8*(lane>>4) + e (symmetric, so any
// hw k-interleave cancels between A and B).
// ---------------------------------------------------------------------------
template<int ACT, int MASKED, int HAS_BIAS, int NT, int AF32>
__global__ __launch_bounds__(256) void mfma_nt_k(
    int M, int N, int K, int Nout,
    const void* __restrict__ Av, int lda, long long sA,
    const ushort_t* __restrict__ Bt, int ldb, long long sB,
    const float* __restrict__ bias,
    float* __restrict__ C, int ldc, long long sC,
    const float* __restrict__ maskR, const float* __restrict__ maskC)
{
    int z = blockIdx.z;
    Bt += (long long)z * sB;
    C  += (long long)z * sC;

    int wave = threadIdx.x >> 6;
    int lane = threadIdx.x & 63;
    int lr = lane & 15;
    int kg = lane >> 4;
    int m0 = (blockIdx.x * 4 + wave) * 16;
    int n0 = blockIdx.y * (NT * 16);
    if (m0 >= M) return;

    f32x4 acc[NT];
    #pragma unroll
    for (int t = 0; t < NT; t++) acc[t] = (f32x4){0.f, 0.f, 0.f, 0.f};

    const ushort_t* Ab = nullptr;
    const float*    Af = nullptr;
    if (AF32) Af = (const float*)Av + (long long)z * sA + (long long)(m0 + lr) * lda + kg * 8;
    else      Ab = (const ushort_t*)Av + (long long)z * sA + (long long)(m0 + lr) * lda + kg * 8;
    const ushort_t* Bbase = Bt + (long long)(n0 + lr) * ldb + kg * 8;

    for (int k0 = 0; k0 < K; k0 += 32) {
        bf16x8 a;
        if (AF32) {
            float4 a0 = *(const float4*)(Af + k0);
            float4 a1 = *(const float4*)(Af + k0 + 4);
            a[0] = (short)f2bf(a0.x); a[1] = (short)f2bf(a0.y);
            a[2] = (short)f2bf(a0.z); a[3] = (short)f2bf(a0.w);
            a[4] = (short)f2bf(a1.x); a[5] = (short)f2bf(a1.y);
            a[6] = (short)f2bf(a1.z); a[7] = (short)f2bf(a1.w);
        } else {
            a = *(const bf16x8*)(Ab + k0);
        }
        #pragma unroll
        for (int t = 0; t < NT; t++) {
            bf16x8 b = *(const bf16x8*)(Bbase + (long long)t * 16 * ldb + k0);
            acc[t] = __builtin_amdgcn_mfma_f32_16x16x32_bf16(a, b, acc[t], 0, 0, 0);
        }
    }

    int row0 = m0 + kg * 4;
    #pragma unroll
    for (int t = 0; t < NT; t++) {
        int col = n0 + t * 16 + lr;
        if (col >= Nout) continue;
        float bv = HAS_BIAS ? bias[col] : 0.f;
        float mC = MASKED ? maskC[(long long)z * N + col] : 1.f;
        #pragma unroll
        for (int r = 0; r < 4; r++) {
            float v = acc[t][r] + bv;
            if (ACT == 1) v = v > 0.f ? v : ALPHA_LR * v;
            else if (ACT == 2) v = tanhf(v);
            if (MASKED) v *= maskR[(long long)z * M + row0 + r] * mC;
            C[(long long)(row0 + r) * ldc + col] = v;
        }
    }
}

// fp32 -> bf16, 4 elems/thread, n % 4 == 0
__global__ __launch_bounds__(256) void cvt_bf16_k(
    const float* __restrict__ in, ushort_t* __restrict__ out, long long n4)
{
    long long i = (long long)blockIdx.x * 256 + threadIdx.x;
    if (i >= n4) return;
    float4 v = ((const float4*)in)[i];
    ushort4 o;
    o.x = f2bf(v.x); o.y = f2bf(v.y); o.z = f2bf(v.z); o.w = f2bf(v.w);
    ((ushort4*)out)[i] = o;
}

// W[K][Nsrc] fp32 -> Wt[Npad][Kp] bf16 (transposed, zero-padded), batched z
__global__ __launch_bounds__(256) void wtcvt_k(
    const float* __restrict__ W, ushort_t* __restrict__ Wt,
    int K, int Nsrc, int Npad, int Kp)
{
    int z = blockIdx.z;
    const float* Wz = W + (long long)z * K * Nsrc;
    ushort_t* Oz = Wt + (long long)z * Npad * Kp;
    int idx = blockIdx.x * 256 + threadIdx.x;
    if (idx >= Npad * Kp) return;
    int n = idx / Kp, k = idx % Kp;
    float v = (k < K && n < Nsrc) ? Wz[(long long)k * Nsrc + n] : 0.f;
    Oz[idx] = f2bf(v);
}

// ---------------------------------------------------------------------------
// Generic tiled fp32 GEMM (kept for small/odd-K GEMMs)
// ---------------------------------------------------------------------------
template<int ACT, int TA, int TB, int MASKED>
__global__ __launch_bounds__(256) void gemm_k(
    int M, int N, int K,
    const float* __restrict__ A, int lda, long long sA,
    const float* __restrict__ Bm, int ldb, long long sB,
    const float* __restrict__ bias,
    float* __restrict__ C, int ldc, long long sC,
    const float* __restrict__ maskR, const float* __restrict__ maskC)
{
    int z = blockIdx.z;
    A  += (long long)z * sA;
    Bm += (long long)z * sB;
    C  += (long long)z * sC;

    __shared__ float As[16][68];
    __shared__ float Bs[16][68];

    int tid = threadIdx.x;
    int tx = tid % 16, ty = tid / 16;
    int m0 = blockIdx.y * 64, n0 = blockIdx.x * 64;

    float acc[4][4] = {};

    for (int k0 = 0; k0 < K; k0 += 16) {
        if (!TA) {
            int k = tid % 16, mBase = tid / 16;
            #pragma unroll
            for (int p = 0; p < 4; p++) {
                int m = mBase + p * 16;
                int gm = m0 + m, gk = k0 + k;
                float v = 0.f;
                if (gm < M && gk < K) v = A[(long long)gm * lda + gk];
                As[k][m] = v;
            }
        } else {
            int m = tid % 64, kBase = tid / 64;
            #pragma unroll
            for (int p = 0; p < 4; p++) {
                int k = kBase + p * 4;
                int gm = m0 + m, gk = k0 + k;
                float v = 0.f;
                if (gm < M && gk < K) v = A[(long long)gk * lda + gm];
                As[k][m] = v;
            }
        }
        if (!TB) {
            int n = tid % 64, kBase = tid / 64;
            #pragma unroll
            for (int p = 0; p < 4; p++) {
                int k = kBase + p * 4;
                int gn = n0 + n, gk = k0 + k;
                float v = 0.f;
                if (gn < N && gk < K) v = Bm[(long long)gk * ldb + gn];
                Bs[k][n] = v;
            }
        } else {
            int k = tid % 16, nBase = tid / 16;
            #pragma unroll
            for (int p = 0; p < 4; p++) {
                int n = nBase + p * 16;
                int gn = n0 + n, gk = k0 + k;
                float v = 0.f;
                if (gn < N && gk < K) v = Bm[(long long)gn * ldb + gk];
                Bs[k][n] = v;
            }
        }
        __syncthreads();
        #pragma unroll
        for (int kk = 0; kk < 16; kk++) {
            float a[4], b[4];
            #pragma unroll
            for (int i = 0; i < 4; i++) a[i] = As[kk][ty * 4 + i];
            #pragma unroll
            for (int j = 0; j < 4; j++) b[j] = Bs[kk][tx * 4 + j];
            #pragma unroll
            for (int i = 0; i < 4; i++)
                #pragma unroll
                for (int j = 0; j < 4; j++)
                    acc[i][j] += a[i] * b[j];
        }
        __syncthreads();
    }

    #pragma unroll
    for (int i = 0; i < 4; i++) {
        int gm = m0 + ty * 4 + i;
        if (gm >= M) continue;
        #pragma unroll
        for (int j = 0; j < 4; j++) {
            int gn = n0 + tx * 4 + j;
            if (gn >= N) continue;
            float v = acc[i][j];
            if (bias) v += bias[gn];
            if (ACT == 1) v = v > 0.f ? v : ALPHA_LR * v;
            else if (ACT == 2) v = tanhf(v);
            if (MASKED) v *= maskR[(long long)z * M + gm] * maskC[(long long)z * N + gn];
            C[(long long)gm * ldc + gn] = v;
        }
    }
}

static inline void run_gemm(hipStream_t stream, int act, bool tb_masked,
    int M, int N, int K,
    const float* A, int lda, long long sA,
    const float* B, int ldb, long long sB,
    const float* bias, float* C, int ldc, long long sC,
    int batch, const float* maskR = nullptr, const float* maskC = nullptr)
{
    dim3 grid((N + 63) / 64, (M + 63) / 64, batch);
    dim3 blk(256);
    if (tb_masked) {
        gemm_k<2, 0, 1, 1><<<grid, blk, 0, stream>>>(M, N, K, A, lda, sA, B, ldb, sB,
                                                     bias, C, ldc, sC, maskR, maskC);
    } else if (act == 0) {
        gemm_k<0, 0, 0, 0><<<grid, blk, 0, stream>>>(M, N, K, A, lda, sA, B, ldb, sB,
                                                     bias, C, ldc, sC, nullptr, nullptr);
    } else if (act == 1) {
        gemm_k<1, 0, 0, 0><<<grid, blk, 0, stream>>>(M, N, K, A, lda, sA, B, ldb, sB,
                                                     bias, C, ldc, sC, nullptr, nullptr);
    } else {
        gemm_k<2, 0, 0, 0><<<grid, blk, 0, stream>>>(M, N, K, A, lda, sA, B, ldb, sB,
                                                     bias, C, ldc, sC, nullptr, nullptr);
    }
}

// per-row GAT source/dest attention logits
__global__ __launch_bounds__(128) void gat_e_k(
    const float* __restrict__ Wh, int ldWh, int GD,
    const float* __restrict__ a, int aStride,
    float* __restrict__ esrc, float* __restrict__ edst, int rows)
{
    int row = blockIdx.x;
    int k = blockIdx.y;
    int g = threadIdx.x;
    float ws = 0.f, wd = 0.f;
    if (g < GD) {
        float wv = Wh[(long long)row * ldWh + k * GD + g];
        ws = wv * a[k * aStride + g];
        wd = wv * a[k * aStride + GD + g];
    }
    __shared__ float sb[2][128];
    sb[0][threadIdx.x] = ws; sb[1][threadIdx.x] = wd;
    __syncthreads();
    for (int off = 64; off > 0; off >>= 1) {
        if (threadIdx.x < off) {
            sb[0][threadIdx.x] += sb[0][threadIdx.x + off];
            sb[1][threadIdx.x] += sb[1][threadIdx.x + off];
        }
        __syncthreads();
    }
    if (threadIdx.x == 0) {
        esrc[(long long)k * rows + row] = sb[0][0];
        edst[(long long)k * rows + row] = sb[1][0];
    }
}

// GAT attention: softmax over neighbors + weighted sum + ELU
__global__ __launch_bounds__(128) void gat_attn_k(
    const float* __restrict__ Wh, int ldWh, int GD,
    const int* __restrict__ adj,
    const float* __restrict__ esrc, const float* __restrict__ edst,
    float* __restrict__ out, int ldOut)
{
    int row = blockIdx.x;          // b*N + n
    int k = blockIdx.y;
    int rows = gridDim.x;
    int b = row / Nq, n = row % Nq;
    int m = threadIdx.x;

    __shared__ float att[Nq];
    __shared__ float red[Nq];

    float e = esrc[(long long)k * rows + row] + edst[(long long)k * rows + b * Nq + m];
    e = e > 0.f ? e : ALPHA_LR * e;
    if (adj[(long long)b * Nq * Nq + n * Nq + m] <= 0) e = -9.0e15f;

    red[m] = e; __syncthreads();
    for (int off = 64; off > 0; off >>= 1) {
        if (m < off) red[m] = fmaxf(red[m], red[m + off]);
        __syncthreads();
    }
    float mx = red[0]; __syncthreads();
    float ex = expf(e - mx);
    att[m] = ex; red[m] = ex; __syncthreads();
    for (int off = 64; off > 0; off >>= 1) {
        if (m < off) red[m] += red[m + off];
        __syncthreads();
    }
    float inv = 1.0f / red[0];

    for (int g = threadIdx.x; g < GD; g += blockDim.x) {
        float s = 0.f;
        for (int mm = 0; mm < Nq; mm++)
            s += att[mm] * Wh[(long long)(b * Nq + mm) * ldWh + k * GD + g];
        s *= inv;
        s = s > 0.f ? s : expm1f(s);   // ELU
        out[(long long)row * ldOut + k * GD + g] = s;
    }
}

// 11x11 same-pad conv over (M, PD), single channel, + leaky
__global__ __launch_bounds__(256) void conv_k(
    const float* __restrict__ x, const float* __restrict__ W,
    const float* __restrict__ bptr, float* __restrict__ y)
{
    __shared__ float w[121];
    if (threadIdx.x < 121) w[threadIdx.x] = W[threadIdx.x];
    __syncthreads();
    long long idx = (long long)blockIdx.x * blockDim.x + threadIdx.x;
    long long total = (long long)Bq * Mq * PDq;
    if (idx >= total) return;
    int d = (int)(idx % PDq);
    long long t = idx / PDq;
    int m = (int)(t % Mq);
    int b = (int)(t / Mq);
    const float* xb = x + (long long)b * Mq * PDq;
    float s = 0.f;
    #pragma unroll
    for (int i = 0; i < 11; i++) {
        int mm = m + i - 5;
        if (mm < 0 || mm >= Mq) continue;
        #pragma unroll
        for (int j = 0; j < 11; j++) {
            int dd = d + j - 5;
            if (dd < 0 || dd >= PDq) continue;
            s += xb[(long long)mm * PDq + dd] * w[i * 11 + j];
        }
    }
    s += *bptr;
    y[idx] = s > 0.f ? s : ALPHA_LR * s;
}

// out[row] = x[row,:LD] . w
__global__ __launch_bounds__(256) void rowdot_k(
    const float* __restrict__ x, const float* __restrict__ w, float* __restrict__ out)
{
    int row = blockIdx.x, t = threadIdx.x;
    float s = x[(long long)row * LDq + t] * w[t];
    __shared__ float red[256];
    red[t] = s; __syncthreads();
    for (int off = 128; off > 0; off >>= 1) {
        if (t < off) red[t] += red[t + off];
        __syncthreads();
    }
    if (t == 0) out[row] = red[0];
}

// out[b,m] = sum_n A[b,n,m] * q[b,n]
__global__ __launch_bounds__(256) void colsum_k(
    const float* __restrict__ A, const float* __restrict__ q, float* __restrict__ out)
{
    int b = blockIdx.y;
    int m = blockIdx.x * 256 + threadIdx.x;
    const float* Ab = A + (long long)b * Nq * Mq;
    const float* qb = q + (long long)b * Nq;
    float s = 0.f;
    for (int n = 0; n < Nq; n++) s += Ab[(long long)n * Mq + m] * qb[n];
    out[(long long)b * Mq + m] = s;
}

// score_c[row=b*N+n] = hb[row]·w1 + A[b,n,:]·r[b,:] + bias
__global__ __launch_bounds__(256) void scoreC_k(
    const float* __restrict__ hb, const float* __restrict__ A,
    const float* __restrict__ r, const float* __restrict__ w1,
    const float* __restrict__ bptr, float* __restrict__ score)
{
    int row = blockIdx.x;
    int b = row / Nq;
    int t = threadIdx.x;
    float s = hb[(long long)row * LDq + t] * w1[t];
    const float* Ar = A + (long long)row * Mq;
    const float* rb = r + (long long)b * Mq;
    for (int m = t; m < Mq; m += 256) s += Ar[m] * rb[m];
    __shared__ float red[256];
    red[t] = s; __syncthreads();
    for (int off = 128; off > 0; off >>= 1) {
        if (t < off) red[t] += red[t + off];
        __syncthreads();
    }
    if (t == 0) score[row] = red[0] + bptr[0];
}

// score_p[row=b*M+m] = hpb[row]·w1 + csum[row] + bias
__global__ __launch_bounds__(256) void scoreP_k(
    const float* __restrict__ hpb, const float* __restrict__ csum,
    const float* __restrict__ w1, const float* __restrict__ bptr,
    float* __restrict__ score)
{
    int row = blockIdx.x;
    int t = threadIdx.x;
    float s = hpb[(long long)row * LDq + t] * w1[t];
    __shared__ float red[256];
    red[t] = s; __syncthreads();
    for (int off = 128; off > 0; off >>= 1) {
        if (t < off) red[t] += red[t + off];
        __syncthreads();
    }
    if (t == 0) score[row] = red[0] + csum[row] + bptr[0];
}

// masked softmax in place over L, one block per batch row
__global__ __launch_bounds__(256) void msoftmax_k(
    float* __restrict__ score, const float* __restrict__ mask, int L)
{
    int b = blockIdx.x;
    float* s = score + (long long)b * L;
    const float* mk = mask + (long long)b * L;
    int t = threadIdx.x;
    __shared__ float red[256];
    float mx = -1e30f;
    for (int i = t; i < L; i += 256) mx = fmaxf(mx, s[i]);
    red[t] = mx; __syncthreads();
    for (int off = 128; off > 0; off >>= 1) {
        if (t < off) red[t] = fmaxf(red[t], red[t + off]);
        __syncthreads();
    }
    mx = red[0]; __syncthreads();
    float sum = 0.f;
    for (int i = t; i < L; i += 256) {
        float e = expf(s[i] - mx) * mk[i];
        s[i] = e; sum += e;
    }
    red[t] = sum; __syncthreads();
    for (int off = 128; off > 0; off >>= 1) {
        if (t < off) red[t] += red[t + off];
        __syncthreads();
    }
    float inv = 1.0f / (red[0] + 1e-6f);
    __syncthreads();
    for (int i = t; i < L; i += 256) s[i] *= inv;
}

// weighted sum stage 1: partial over 16 chunks
__global__ __launch_bounds__(256) void wsum1_k(
    const float* __restrict__ feat, const float* __restrict__ att,
    float* __restrict__ partial, int L)
{
    int b = blockIdx.x, c = blockIdx.y, l = threadIdx.x;
    int chunk = L / 16;
    const float* fb = feat + (long long)b * L * LDq;
    const float* ab = att + (long long)b * L;
    float s = 0.f;
    int r0 = c * chunk, r1 = r0 + chunk;
    for (int r = r0; r < r1; r++) s += fb[(long long)r * LDq + l] * ab[r];
    partial[((long long)b * 16 + c) * LDq + l] = s;
}

// weighted sum stage 2
__global__ __launch_bounds__(256) void wsum2_k(
    const float* __restrict__ partial, float* __restrict__ out, int outStride)
{
    int b = blockIdx.x, l = threadIdx.x;
    float s = 0.f;
    #pragma unroll
    for (int c = 0; c < 16; c++) s += partial[((long long)b * 16 + c) * LDq + l];
    out[(long long)b * outStride + l] = s;
}

// v[b,256:512]=fps, v[b,768]=invT, v[b,769]=T
__global__ __launch_bounds__(256) void vfill_k(
    const float* __restrict__ fps, const float* __restrict__ invT,
    const float* __restrict__ T, float* __restrict__ v)
{
    int b = blockIdx.x, t = threadIdx.x;
    v[(long long)b * 770 + 256 + t] = fps[(long long)b * 256 + t];
    if (t == 0) {
        v[(long long)b * 770 + 768] = invT[b];
        v[(long long)b * 770 + 769] = T[b];
    }
}

// out[b] = v[b,:770]·W + b
__global__ __launch_bounds__(256) void final_k(
    const float* __restrict__ v, const float* __restrict__ W,
    const float* __restrict__ bptr, float* __restrict__ out)
{
    int b = blockIdx.x, t = threadIdx.x;
    float s = 0.f;
    for (int i = t; i < 770; i += 256) s += v[(long long)b * 770 + i] * W[i];
    __shared__ float red[256];
    red[t] = s; __syncthreads();
    for (int off = 128; off > 0; off >>= 1) {
        if (t < off) red[t] += red[t + off];
        __syncthreads();
    }
    if (t == 0) out[b] = red[0] + bptr[0];
}

extern "C" void kernel_launch(void* const* d_in, const int* in_sizes, int n_in,
                              void* d_out, int out_size, void* d_ws, size_t ws_size,
                              hipStream_t stream)
{
    const float* atoms_emb = (const float*)d_in[0];
    const int*   adjacency = (const int*)d_in[1];
    const float* atoms_mask= (const float*)d_in[2];
    const float* amino_emb = (const float*)d_in[3];
    const float* amino_mask= (const float*)d_in[4];
    const float* fps       = (const float*)d_in[5];
    const float* inv_Temp  = (const float*)d_in[6];
    const float* Temp      = (const float*)d_in[7];
    const float* bert_W    = (const float*)d_in[8];
    const float* bert_b    = (const float*)d_in[9];
    const float* gat_W     = (const float*)d_in[10];
    const float* gat_a     = (const float*)d_in[11];
    const float* gatout_W  = (const float*)d_in[12];
    const float* gatout_a  = (const float*)d_in[13];
    const float* Wcomp_W   = (const float*)d_in[14];
    const float* Wcomp_b   = (const float*)d_in[15];
    const float* prot_W    = (const float*)d_in[16];
    const float* prot_b    = (const float*)d_in[17];
    const float* conv_W    = (const float*)d_in[18];
    const float* conv_b    = (const float*)d_in[19];
    const float* Wprot_W   = (const float*)d_in[20];
    const float* Wprot_b   = (const float*)d_in[21];
    const float* U         = (const float*)d_in[22];
    const float* tc2p_W    = (const float*)d_in[23];
    const float* tc2p_b    = (const float*)d_in[24];
    const float* tp2c_W    = (const float*)d_in[25];
    const float* tp2c_b    = (const float*)d_in[26];
    const float* bhc_W     = (const float*)d_in[27];
    const float* bhc_b     = (const float*)d_in[28];
    const float* bhp_W     = (const float*)d_in[29];
    const float* bhp_b     = (const float*)d_in[30];
    const float* battc_W   = (const float*)d_in[31];
    const float* battc_b   = (const float*)d_in[32];
    const float* battp_W   = (const float*)d_in[33];
    const float* battp_b   = (const float*)d_in[34];
    const float* combc_W   = (const float*)d_in[35];
    const float* combc_b   = (const float*)d_in[36];
    const float* combp_W   = (const float*)d_in[37];
    const float* combp_b   = (const float*)d_in[38];
    const float* Wout_W    = (const float*)d_in[39];
    const float* Wout_b    = (const float*)d_in[40];
    const float* out_W     = (const float*)d_in[41];
    const float* out_b     = (const float*)d_in[42];
    float* out = (float*)d_out;

    // ---- workspace layout (floats) ----
    float* w = (float*)d_ws;
    float* av    = w; w += (long long)Bq*Nq*LDq;
    float* pv    = w; w += (long long)Bq*Mq*LDq;
    float* sx    = w; w += (long long)Bq*Mq*LDq;   // early-phase scratch / tp -> hpb
    float* Abuf  = w; w += (long long)Bq*Nq*Mq;
    float* bufU  = w; w += (long long)Bq*Nq*LDq;   // avU -> hb
    float* bufTC = w; w += (long long)Bq*Nq*LDq;   // tc -> wsum partials
    float* esrc  = w; w += (long long)NHq*Bq*Nq;
    float* edst  = w; w += (long long)NHq*Bq*Nq;
    float* scoreC= w; w += (long long)Bq*Nq;
    float* scoreP= w; w += (long long)Bq*Mq;
    float* rbuf  = w; w += (long long)Bq*Mq;
    float* qbuf  = w; w += (long long)Bq*Nq;
    float* csum  = w; w += (long long)Bq*Mq;
    float* cf    = w; w += (long long)Bq*4*LDq;
    float* pf    = w; w += (long long)Bq*4*LDq;
    float* v1    = w; w += (long long)Bq*770;
    float* v2    = w; w += (long long)Bq*770;
    // bf16 buffers (carved as float-space, used as ushort)
    ushort_t* pv_bf  = (ushort_t*)w; w += (long long)Bq*Mq*LDq/2;
    ushort_t* av_bf  = (ushort_t*)w; w += (long long)Bq*Nq*LDq/2;
    ushort_t* avU_bf = (ushort_t*)w; w += (long long)Bq*Nq*LDq/2;
    ushort_t* Ut_bf    = (ushort_t*)w; w += (long long)4*LDq*LDq/2;
    ushort_t* tp2cT_bf = (ushort_t*)w; w += (long long)4*LDq*LDq/2;
    ushort_t* tc2pT_bf = (ushort_t*)w; w += (long long)4*LDq*LDq/2;
    ushort_t* bhcT_bf  = (ushort_t*)w; w += (long long)4*LDq*LDq/2;
    ushort_t* bhpT_bf  = (ushort_t*)w; w += (long long)4*LDq*LDq/2;
    ushort_t* protWt_bf= (ushort_t*)w; w += (long long)48*1024/2;

    // early-phase aliases inside sx (dead before BIDAT loop reuses sx)
    float* h     = sx;
    float* WhAll = h + (long long)Bq*Nq*CDq;
    float* multi = WhAll + (long long)Bq*Nq*NHq*GDq;
    float* Wh2   = multi + (long long)Bq*Nq*NHq*GDq;
    float* avp   = Wh2 + (long long)Bq*Nq*CDq;
    float* c0    = avp + (long long)Bq*Nq*CDq;
    float* c1    = c0 + (long long)Bq*Mq*PDq;

    float* wpart = bufTC;   // wsum partials (tc dead by then)

    int rowsA = Bq * Nq;     // 4096
    int rowsP = Bq * Mq;     // 32768

    // ---- weight transpose-converts (once) ----
    wtcvt_k<<<dim3(256, 1, 4), 256, 0, stream>>>(U,      Ut_bf,    LDq, LDq, LDq, LDq);
    wtcvt_k<<<dim3(256, 1, 4), 256, 0, stream>>>(tp2c_W, tp2cT_bf, LDq, LDq, LDq, LDq);
    wtcvt_k<<<dim3(256, 1, 4), 256, 0, stream>>>(tc2p_W, tc2pT_bf, LDq, LDq, LDq, LDq);
    wtcvt_k<<<dim3(256, 1, 4), 256, 0, stream>>>(bhc_W,  bhcT_bf,  LDq, LDq, LDq, LDq);
    wtcvt_k<<<dim3(256, 1, 4), 256, 0, stream>>>(bhp_W,  bhpT_bf,  LDq, LDq, LDq, LDq);
    wtcvt_k<<<dim3((48*1024+255)/256, 1, 1), 256, 0, stream>>>(prot_W, protWt_bf, 1024, 40, 48, 1024);

    // 1. h = atoms_emb @ bert_W + bert_b   (K=300, keep fp32)
    run_gemm(stream, 0, false, rowsA, CDq, 300, atoms_emb, 300, 0,
             bert_W, CDq, 0, bert_b, h, CDq, 0, 1);

    // 2. Wh_all = h @ gat_W[k] (batched heads)
    run_gemm(stream, 0, false, rowsA, GDq, CDq, h, CDq, 0,
             gat_W, GDq, (long long)CDq*GDq, nullptr,
             WhAll, NHq*GDq, GDq, NHq);

    // 3-4. GAT heads -> multi (ELU)
    gat_e_k<<<dim3(rowsA, NHq), 128, 0, stream>>>(WhAll, NHq*GDq, GDq, gat_a, 2*GDq,
                                                  esrc, edst, rowsA);
    gat_attn_k<<<dim3(rowsA, NHq), 128, 0, stream>>>(WhAll, NHq*GDq, GDq, adjacency,
                                                     esrc, edst, multi, NHq*GDq);

    // 5-7. GAT out layer -> avp (ELU)
    run_gemm(stream, 0, false, rowsA, CDq, NHq*GDq, multi, NHq*GDq, 0,
             gatout_W, CDq, 0, nullptr, Wh2, CDq, 0, 1);
    gat_e_k<<<dim3(rowsA, 1), 128, 0, stream>>>(Wh2, CDq, CDq, gatout_a, 2*CDq,
                                                esrc, edst, rowsA);
    gat_attn_k<<<dim3(rowsA, 1), 128, 0, stream>>>(Wh2, CDq, CDq, adjacency,
                                                   esrc, edst, avp, CDq);

    // 8. av = leaky(avp @ Wcomp_W + b)
    run_gemm(stream, 1, false, rowsA, LDq, CDq, avp, CDq, 0,
             Wcomp_W, LDq, 0, Wcomp_b, av, LDq, 0, 1);
    cvt_bf16_k<<<(rowsA*LDq/4 + 255)/256, 256, 0, stream>>>(av, av_bf, (long long)rowsA*LDq/4);

    // 9. pv0 = amino_emb @ prot_W + b  -> MFMA (AF32 A-operand, N padded to 48)
    mfma_nt_k<0, 0, 1, 3, 1><<<dim3(rowsP/64, 1, 1), 256, 0, stream>>>(
        rowsP, 48, 1024, 40,
        (const void*)amino_emb, 1024, 0,
        protWt_bf, 1024, 0,
        prot_b, c0, PDq, 0, nullptr, nullptr);

    // 10. 3x conv 11x11 + leaky
    {
        long long total = (long long)Bq*Mq*PDq;
        int blocks = (int)((total + 255) / 256);
        conv_k<<<blocks, 256, 0, stream>>>(c0, conv_W + 0*121, conv_b + 0, c1);
        conv_k<<<blocks, 256, 0, stream>>>(c1, conv_W + 1*121, conv_b + 1, c0);
        conv_k<<<blocks, 256, 0, stream>>>(c0, conv_W + 2*121, conv_b + 2, c1);
    }

    // 11. pv = leaky(x @ Wprot_W + b)  (K=40, keep fp32)
    run_gemm(stream, 1, false, rowsP, LDq, PDq, c1, PDq, 0,
             Wprot_W, LDq, 0, Wprot_b, pv, LDq, 0, 1);
    cvt_bf16_k<<<(rowsP*LDq/4 + 255)/256, 256, 0, stream>>>(pv, pv_bf, (long long)rowsP*LDq/4);

    // 12. BIDAT loop
    for (int i = 0; i < 4; i++) {
        const ushort_t* UtI    = Ut_bf    + (long long)i*LDq*LDq;
        const ushort_t* tp2cTI = tp2cT_bf + (long long)i*LDq*LDq;
        const ushort_t* tc2pTI = tc2pT_bf + (long long)i*LDq*LDq;
        const ushort_t* bhcTI  = bhcT_bf  + (long long)i*LDq*LDq;
        const ushort_t* bhpTI  = bhpT_bf  + (long long)i*LDq*LDq;
        const float* tp2cbi  = tp2c_b + (long long)i*LDq;
        const float* tc2pbi  = tc2p_b + (long long)i*LDq;
        const float* bhcbi   = bhc_b  + (long long)i*LDq;
        const float* bhpbi   = bhp_b  + (long long)i*LDq;
        const float* battcWi = battc_W+ (long long)i*2*LDq;
        const float* battcbi = battc_b+ i;
        const float* battpWi = battp_W+ (long long)i*2*LDq;
        const float* battpbi = battp_b+ i;

        // avU = av @ U[i]
        mfma_nt_k<0, 0, 0, 16, 0><<<dim3(rowsA/64, 1, 1), 256, 0, stream>>>(
            rowsA, LDq, LDq, LDq, (const void*)av_bf, LDq, 0,
            UtI, LDq, 0, nullptr, bufU, LDq, 0, nullptr, nullptr);
        cvt_bf16_k<<<(rowsA*LDq/4 + 255)/256, 256, 0, stream>>>(bufU, avU_bf, (long long)rowsA*LDq/4);

        // A = tanh(avU @ pv^T) * masks   (batched, Bt = pv_bf rows)
        mfma_nt_k<2, 1, 0, 16, 0><<<dim3(Nq/64, Mq/256, Bq), 256, 0, stream>>>(
            Nq, Mq, LDq, Mq,
            (const void*)avU_bf, LDq, (long long)Nq*LDq,
            pv_bf, LDq, (long long)Mq*LDq,
            nullptr, Abuf, Mq, (long long)Nq*Mq,
            atoms_mask, amino_mask);

        // tp = tanh(pv @ tp2c_W + b) -> sx
        mfma_nt_k<2, 0, 1, 16, 0><<<dim3(rowsP/64, 1, 1), 256, 0, stream>>>(
            rowsP, LDq, LDq, LDq, (const void*)pv_bf, LDq, 0,
            tp2cTI, LDq, 0, tp2cbi, sx, LDq, 0, nullptr, nullptr);
        rowdot_k<<<rowsP, 256, 0, stream>>>(sx, battcWi + LDq, rbuf);

        // tc = tanh(av @ tc2p_W + b) -> bufTC
        mfma_nt_k<2, 0, 1, 16, 0><<<dim3(rowsA/64, 1, 1), 256, 0, stream>>>(
            rowsA, LDq, LDq, LDq, (const void*)av_bf, LDq, 0,
            tc2pTI, LDq, 0, tc2pbi, bufTC, LDq, 0, nullptr, nullptr);
        rowdot_k<<<rowsA, 256, 0, stream>>>(bufTC, battpWi + LDq, qbuf);

        // hb = tanh(av @ bhc_W + b) -> bufU (avU_bf already extracted)
        mfma_nt_k<2, 0, 1, 16, 0><<<dim3(rowsA/64, 1, 1), 256, 0, stream>>>(
            rowsA, LDq, LDq, LDq, (const void*)av_bf, LDq, 0,
            bhcTI, LDq, 0, bhcbi, bufU, LDq, 0, nullptr, nullptr);

        // hpb = tanh(pv @ bhp_W + b) -> sx (tp consumed by rowdot)
        mfma_nt_k<2, 0, 1, 16, 0><<<dim3(rowsP/64, 1, 1), 256, 0, stream>>>(
            rowsP, LDq, LDq, LDq, (const void*)pv_bf, LDq, 0,
            bhpTI, LDq, 0, bhpbi, sx, LDq, 0, nullptr, nullptr);

        // csum[b,m] = sum_n A[b,n,m]*q[b,n]
        colsum_k<<<dim3(Mq/256, Bq), 256, 0, stream>>>(Abuf, qbuf, csum);
        // attention scores
        scoreC_k<<<rowsA, 256, 0, stream>>>(bufU, Abuf, rbuf, battcWi, battcbi, scoreC);
        scoreP_k<<<rowsP, 256, 0, stream>>>(sx, csum, battpWi, battpbi, scoreP);
        // masked softmax
        msoftmax_k<<<Bq, 256, 0, stream>>>(scoreC, atoms_mask, Nq);
        msoftmax_k<<<Bq, 256, 0, stream>>>(scoreP, amino_mask, Mq);
        // pooled features
        wsum1_k<<<dim3(Bq, 16), 256, 0, stream>>>(av, scoreC, wpart, Nq);
        wsum2_k<<<Bq, 256, 0, stream>>>(wpart, cf + (long long)i*LDq, 4*LDq);
        wsum1_k<<<dim3(Bq, 16), 256, 0, stream>>>(pv, scoreP, wpart, Mq);
        wsum2_k<<<Bq, 256, 0, stream>>>(wpart, pf + (long long)i*LDq, 4*LDq);
    }

    // 13. head (tiny, fp32)
    run_gemm(stream, 0, false, Bq, LDq, 4*LDq, cf, 4*LDq, 0,
             combc_W, LDq, 0, combc_b, v1, 770, 0, 1);
    run_gemm(stream, 0, false, Bq, LDq, 4*LDq, pf, 4*LDq, 0,
             combp_W, LDq, 0, combp_b, v1 + 512, 770, 0, 1);
    vfill_k<<<Bq, 256, 0, stream>>>(fps, inv_Temp, Temp, v1);

    run_gemm(stream, 1, false, Bq, 770, 770, v1, 770, 0,
             Wout_W + 0ll*770*770, 770, 0, Wout_b + 0*770, v2, 770, 0, 1);
    run_gemm(stream, 1, false, Bq, 770, 770, v2, 770, 0,
             Wout_W + 1ll*770*770, 770, 0, Wout_b + 1*770, v1, 770, 0, 1);
    run_gemm(stream, 1, false, Bq, 770, 770, v1, 770, 0,
             Wout_W + 2ll*770*770, 770, 0, Wout_b + 2*770, v2, 770, 0, 1);

    final_k<<<Bq, 256, 0, stream>>>(v2, out_W, out_b, out);

    (void)in_sizes; (void)n_in; (void)out_size; (void)ws_size;
}

// Round 5
// 2289.368 us; speedup vs baseline: 1.7777x; 1.1462x over previous
//
#include <hip/hip_runtime.h>
#include <math.h>

#define ALPHA_LR 0.2f

#define Bq  32
#define Nq  128
#define Mq  1024
#define CDq 128
#define GDq 64
#define NHq 4
#define LDq 256
#define PDq 40

typedef unsigned short ushort_t;
typedef __attribute__((ext_vector_type(8))) short bf16x8;
typedef __attribute__((ext_vector_type(4))) float f32x4;

__device__ __forceinline__ ushort_t f2bf(float f) {
    union { float f; unsigned u; } x; x.f = f;
    unsigned r = x.u + 0x7FFFu + ((x.u >> 16) & 1u);   // RNE
    return (ushort_t)(r >> 16);
}

// ---------------------------------------------------------------------------
// MFMA bf16 NT GEMM: C = act(A @ Bt^T + bias) [* masks]
// A: [M][lda] bf16 (or fp32 if AF32), Bt: [Npad][ldb] bf16 (= B^T, K-major)
// Each wave: 16 rows x NT*16 cols. grid.x = M/64 (4 waves/block),
// grid.y = N/(NT*16), grid.z = batch. K % 32 == 0. M % 16 == 0.
// C/D layout (m89-verified): col = lane&15, row = (lane>>4)*4 + reg.
// ---------------------------------------------------------------------------
template<int ACT, int MASKED, int HAS_BIAS, int NT, int AF32>
__global__ __launch_bounds__(256) void mfma_nt_k(
    int M, int N, int K, int Nout,
    const void* __restrict__ Av, int lda, long long sA,
    const ushort_t* __restrict__ Bt, int ldb, long long sB,
    const float* __restrict__ bias,
    float* __restrict__ C, int ldc, long long sC,
    const float* __restrict__ maskR, const float* __restrict__ maskC)
{
    int z = blockIdx.z;
    Bt += (long long)z * sB;
    C  += (long long)z * sC;

    int wave = threadIdx.x >> 6;
    int lane = threadIdx.x & 63;
    int lr = lane & 15;
    int kg = lane >> 4;
    int m0 = (blockIdx.x * 4 + wave) * 16;
    int n0 = blockIdx.y * (NT * 16);
    if (m0 >= M) return;

    f32x4 acc[NT];
    #pragma unroll
    for (int t = 0; t < NT; t++) acc[t] = (f32x4){0.f, 0.f, 0.f, 0.f};

    const ushort_t* Ab = nullptr;
    const float*    Af = nullptr;
    if (AF32) Af = (const float*)Av + (long long)z * sA + (long long)(m0 + lr) * lda + kg * 8;
    else      Ab = (const ushort_t*)Av + (long long)z * sA + (long long)(m0 + lr) * lda + kg * 8;
    const ushort_t* Bbase = Bt + (long long)(n0 + lr) * ldb + kg * 8;

    for (int k0 = 0; k0 < K; k0 += 32) {
        bf16x8 a;
        if (AF32) {
            float4 a0 = *(const float4*)(Af + k0);
            float4 a1 = *(const float4*)(Af + k0 + 4);
            a[0] = (short)f2bf(a0.x); a[1] = (short)f2bf(a0.y);
            a[2] = (short)f2bf(a0.z); a[3] = (short)f2bf(a0.w);
            a[4] = (short)f2bf(a1.x); a[5] = (short)f2bf(a1.y);
            a[6] = (short)f2bf(a1.z); a[7] = (short)f2bf(a1.w);
        } else {
            a = *(const bf16x8*)(Ab + k0);
        }
        #pragma unroll
        for (int t = 0; t < NT; t++) {
            bf16x8 b = *(const bf16x8*)(Bbase + (long long)t * 16 * ldb + k0);
            acc[t] = __builtin_amdgcn_mfma_f32_16x16x32_bf16(a, b, acc[t], 0, 0, 0);
        }
    }

    int row0 = m0 + kg * 4;
    #pragma unroll
    for (int t = 0; t < NT; t++) {
        int col = n0 + t * 16 + lr;
        if (col >= Nout) continue;
        float bv = HAS_BIAS ? bias[col] : 0.f;
        float mC = MASKED ? maskC[(long long)z * N + col] : 1.f;
        #pragma unroll
        for (int r = 0; r < 4; r++) {
            float v = acc[t][r] + bv;
            if (ACT == 1) v = v > 0.f ? v : ALPHA_LR * v;
            else if (ACT == 2) v = tanhf(v);
            if (MASKED) v *= maskR[(long long)z * M + row0 + r] * mC;
            C[(long long)(row0 + r) * ldc + col] = v;
        }
    }
}

// fp32 -> bf16, 4 elems/thread, n % 4 == 0
__global__ __launch_bounds__(256) void cvt_bf16_k(
    const float* __restrict__ in, ushort_t* __restrict__ out, long long n4)
{
    long long i = (long long)blockIdx.x * 256 + threadIdx.x;
    if (i >= n4) return;
    float4 v = ((const float4*)in)[i];
    ushort4 o;
    o.x = f2bf(v.x); o.y = f2bf(v.y); o.z = f2bf(v.z); o.w = f2bf(v.w);
    ((ushort4*)out)[i] = o;
}

// W[K][Nsrc] fp32 -> Wt[Npad][Kp] bf16 (transposed, zero-padded), batched z
__global__ __launch_bounds__(256) void wtcvt_k(
    const float* __restrict__ W, ushort_t* __restrict__ Wt,
    int K, int Nsrc, int Npad, int Kp)
{
    int z = blockIdx.z;
    const float* Wz = W + (long long)z * K * Nsrc;
    ushort_t* Oz = Wt + (long long)z * Npad * Kp;
    int idx = blockIdx.x * 256 + threadIdx.x;
    if (idx >= Npad * Kp) return;
    int n = idx / Kp, k = idx % Kp;
    float v = (k < K && n < Nsrc) ? Wz[(long long)k * Nsrc + n] : 0.f;
    Oz[idx] = f2bf(v);
}

// ---------------------------------------------------------------------------
// Generic tiled fp32 GEMM (kept for small/odd-K GEMMs)
// ---------------------------------------------------------------------------
template<int ACT, int TA, int TB, int MASKED>
__global__ __launch_bounds__(256) void gemm_k(
    int M, int N, int K,
    const float* __restrict__ A, int lda, long long sA,
    const float* __restrict__ Bm, int ldb, long long sB,
    const float* __restrict__ bias,
    float* __restrict__ C, int ldc, long long sC,
    const float* __restrict__ maskR, const float* __restrict__ maskC)
{
    int z = blockIdx.z;
    A  += (long long)z * sA;
    Bm += (long long)z * sB;
    C  += (long long)z * sC;

    __shared__ float As[16][68];
    __shared__ float Bs[16][68];

    int tid = threadIdx.x;
    int tx = tid % 16, ty = tid / 16;
    int m0 = blockIdx.y * 64, n0 = blockIdx.x * 64;

    float acc[4][4] = {};

    for (int k0 = 0; k0 < K; k0 += 16) {
        if (!TA) {
            int k = tid % 16, mBase = tid / 16;
            #pragma unroll
            for (int p = 0; p < 4; p++) {
                int m = mBase + p * 16;
                int gm = m0 + m, gk = k0 + k;
                float v = 0.f;
                if (gm < M && gk < K) v = A[(long long)gm * lda + gk];
                As[k][m] = v;
            }
        } else {
            int m = tid % 64, kBase = tid / 64;
            #pragma unroll
            for (int p = 0; p < 4; p++) {
                int k = kBase + p * 4;
                int gm = m0 + m, gk = k0 + k;
                float v = 0.f;
                if (gm < M && gk < K) v = A[(long long)gk * lda + gm];
                As[k][m] = v;
            }
        }
        if (!TB) {
            int n = tid % 64, kBase = tid / 64;
            #pragma unroll
            for (int p = 0; p < 4; p++) {
                int k = kBase + p * 4;
                int gn = n0 + n, gk = k0 + k;
                float v = 0.f;
                if (gn < N && gk < K) v = Bm[(long long)gk * ldb + gn];
                Bs[k][n] = v;
            }
        } else {
            int k = tid % 16, nBase = tid / 16;
            #pragma unroll
            for (int p = 0; p < 4; p++) {
                int n = nBase + p * 16;
                int gn = n0 + n, gk = k0 + k;
                float v = 0.f;
                if (gn < N && gk < K) v = Bm[(long long)gn * ldb + gk];
                Bs[k][n] = v;
            }
        }
        __syncthreads();
        #pragma unroll
        for (int kk = 0; kk < 16; kk++) {
            float a[4], b[4];
            #pragma unroll
            for (int i = 0; i < 4; i++) a[i] = As[kk][ty * 4 + i];
            #pragma unroll
            for (int j = 0; j < 4; j++) b[j] = Bs[kk][tx * 4 + j];
            #pragma unroll
            for (int i = 0; i < 4; i++)
                #pragma unroll
                for (int j = 0; j < 4; j++)
                    acc[i][j] += a[i] * b[j];
        }
        __syncthreads();
    }

    #pragma unroll
    for (int i = 0; i < 4; i++) {
        int gm = m0 + ty * 4 + i;
        if (gm >= M) continue;
        #pragma unroll
        for (int j = 0; j < 4; j++) {
            int gn = n0 + tx * 4 + j;
            if (gn >= N) continue;
            float v = acc[i][j];
            if (bias) v += bias[gn];
            if (ACT == 1) v = v > 0.f ? v : ALPHA_LR * v;
            else if (ACT == 2) v = tanhf(v);
            if (MASKED) v *= maskR[(long long)z * M + gm] * maskC[(long long)z * N + gn];
            C[(long long)gm * ldc + gn] = v;
        }
    }
}

static inline void run_gemm(hipStream_t stream, int act, bool tb_masked,
    int M, int N, int K,
    const float* A, int lda, long long sA,
    const float* B, int ldb, long long sB,
    const float* bias, float* C, int ldc, long long sC,
    int batch, const float* maskR = nullptr, const float* maskC = nullptr)
{
    dim3 grid((N + 63) / 64, (M + 63) / 64, batch);
    dim3 blk(256);
    if (tb_masked) {
        gemm_k<2, 0, 1, 1><<<grid, blk, 0, stream>>>(M, N, K, A, lda, sA, B, ldb, sB,
                                                     bias, C, ldc, sC, maskR, maskC);
    } else if (act == 0) {
        gemm_k<0, 0, 0, 0><<<grid, blk, 0, stream>>>(M, N, K, A, lda, sA, B, ldb, sB,
                                                     bias, C, ldc, sC, nullptr, nullptr);
    } else if (act == 1) {
        gemm_k<1, 0, 0, 0><<<grid, blk, 0, stream>>>(M, N, K, A, lda, sA, B, ldb, sB,
                                                     bias, C, ldc, sC, nullptr, nullptr);
    } else {
        gemm_k<2, 0, 0, 0><<<grid, blk, 0, stream>>>(M, N, K, A, lda, sA, B, ldb, sB,
                                                     bias, C, ldc, sC, nullptr, nullptr);
    }
}

// per-row GAT source/dest attention logits
__global__ __launch_bounds__(128) void gat_e_k(
    const float* __restrict__ Wh, int ldWh, int GD,
    const float* __restrict__ a, int aStride,
    float* __restrict__ esrc, float* __restrict__ edst, int rows)
{
    int row = blockIdx.x;
    int k = blockIdx.y;
    int g = threadIdx.x;
    float ws = 0.f, wd = 0.f;
    if (g < GD) {
        float wv = Wh[(long long)row * ldWh + k * GD + g];
        ws = wv * a[k * aStride + g];
        wd = wv * a[k * aStride + GD + g];
    }
    __shared__ float sb[2][128];
    sb[0][threadIdx.x] = ws; sb[1][threadIdx.x] = wd;
    __syncthreads();
    for (int off = 64; off > 0; off >>= 1) {
        if (threadIdx.x < off) {
            sb[0][threadIdx.x] += sb[0][threadIdx.x + off];
            sb[1][threadIdx.x] += sb[1][threadIdx.x + off];
        }
        __syncthreads();
    }
    if (threadIdx.x == 0) {
        esrc[(long long)k * rows + row] = sb[0][0];
        edst[(long long)k * rows + row] = sb[1][0];
    }
}

// GAT attention: softmax over neighbors + weighted sum + ELU
__global__ __launch_bounds__(128) void gat_attn_k(
    const float* __restrict__ Wh, int ldWh, int GD,
    const int* __restrict__ adj,
    const float* __restrict__ esrc, const float* __restrict__ edst,
    float* __restrict__ out, int ldOut)
{
    int row = blockIdx.x;          // b*N + n
    int k = blockIdx.y;
    int rows = gridDim.x;
    int b = row / Nq, n = row % Nq;
    int m = threadIdx.x;

    __shared__ float att[Nq];
    __shared__ float red[Nq];

    float e = esrc[(long long)k * rows + row] + edst[(long long)k * rows + b * Nq + m];
    e = e > 0.f ? e : ALPHA_LR * e;
    if (adj[(long long)b * Nq * Nq + n * Nq + m] <= 0) e = -9.0e15f;

    red[m] = e; __syncthreads();
    for (int off = 64; off > 0; off >>= 1) {
        if (m < off) red[m] = fmaxf(red[m], red[m + off]);
        __syncthreads();
    }
    float mx = red[0]; __syncthreads();
    float ex = expf(e - mx);
    att[m] = ex; red[m] = ex; __syncthreads();
    for (int off = 64; off > 0; off >>= 1) {
        if (m < off) red[m] += red[m + off];
        __syncthreads();
    }
    float inv = 1.0f / red[0];

    for (int g = threadIdx.x; g < GD; g += blockDim.x) {
        float s = 0.f;
        for (int mm = 0; mm < Nq; mm++)
            s += att[mm] * Wh[(long long)(b * Nq + mm) * ldWh + k * GD + g];
        s *= inv;
        s = s > 0.f ? s : expm1f(s);   // ELU
        out[(long long)row * ldOut + k * GD + g] = s;
    }
}

// 11x11 same-pad conv over (M, PD), single channel, + leaky
__global__ __launch_bounds__(256) void conv_k(
    const float* __restrict__ x, const float* __restrict__ W,
    const float* __restrict__ bptr, float* __restrict__ y)
{
    __shared__ float w[121];
    if (threadIdx.x < 121) w[threadIdx.x] = W[threadIdx.x];
    __syncthreads();
    long long idx = (long long)blockIdx.x * blockDim.x + threadIdx.x;
    long long total = (long long)Bq * Mq * PDq;
    if (idx >= total) return;
    int d = (int)(idx % PDq);
    long long t = idx / PDq;
    int m = (int)(t % Mq);
    int b = (int)(t / Mq);
    const float* xb = x + (long long)b * Mq * PDq;
    float s = 0.f;
    #pragma unroll
    for (int i = 0; i < 11; i++) {
        int mm = m + i - 5;
        if (mm < 0 || mm >= Mq) continue;
        #pragma unroll
        for (int j = 0; j < 11; j++) {
            int dd = d + j - 5;
            if (dd < 0 || dd >= PDq) continue;
            s += xb[(long long)mm * PDq + dd] * w[i * 11 + j];
        }
    }
    s += *bptr;
    y[idx] = s > 0.f ? s : ALPHA_LR * s;
}

// out[row] = x[row,:LD] . w
__global__ __launch_bounds__(256) void rowdot_k(
    const float* __restrict__ x, const float* __restrict__ w, float* __restrict__ out)
{
    int row = blockIdx.x, t = threadIdx.x;
    float s = x[(long long)row * LDq + t] * w[t];
    __shared__ float red[256];
    red[t] = s; __syncthreads();
    for (int off = 128; off > 0; off >>= 1) {
        if (t < off) red[t] += red[t + off];
        __syncthreads();
    }
    if (t == 0) out[row] = red[0];
}

// out[b,m] = sum_n A[b,n,m] * q[b,n]
__global__ __launch_bounds__(256) void colsum_k(
    const float* __restrict__ A, const float* __restrict__ q, float* __restrict__ out)
{
    int b = blockIdx.y;
    int m = blockIdx.x * 256 + threadIdx.x;
    const float* Ab = A + (long long)b * Nq * Mq;
    const float* qb = q + (long long)b * Nq;
    float s = 0.f;
    for (int n = 0; n < Nq; n++) s += Ab[(long long)n * Mq + m] * qb[n];
    out[(long long)b * Mq + m] = s;
}

// score_c[row=b*N+n] = hb[row]·w1 + A[b,n,:]·r[b,:] + bias
__global__ __launch_bounds__(256) void scoreC_k(
    const float* __restrict__ hb, const float* __restrict__ A,
    const float* __restrict__ r, const float* __restrict__ w1,
    const float* __restrict__ bptr, float* __restrict__ score)
{
    int row = blockIdx.x;
    int b = row / Nq;
    int t = threadIdx.x;
    float s = hb[(long long)row * LDq + t] * w1[t];
    const float* Ar = A + (long long)row * Mq;
    const float* rb = r + (long long)b * Mq;
    for (int m = t; m < Mq; m += 256) s += Ar[m] * rb[m];
    __shared__ float red[256];
    red[t] = s; __syncthreads();
    for (int off = 128; off > 0; off >>= 1) {
        if (t < off) red[t] += red[t + off];
        __syncthreads();
    }
    if (t == 0) score[row] = red[0] + bptr[0];
}

// score_p[row=b*M+m] = hpb[row]·w1 + csum[row] + bias
__global__ __launch_bounds__(256) void scoreP_k(
    const float* __restrict__ hpb, const float* __restrict__ csum,
    const float* __restrict__ w1, const float* __restrict__ bptr,
    float* __restrict__ score)
{
    int row = blockIdx.x;
    int t = threadIdx.x;
    float s = hpb[(long long)row * LDq + t] * w1[t];
    __shared__ float red[256];
    red[t] = s; __syncthreads();
    for (int off = 128; off > 0; off >>= 1) {
        if (t < off) red[t] += red[t + off];
        __syncthreads();
    }
    if (t == 0) score[row] = red[0] + csum[row] + bptr[0];
}

// masked softmax in place over L, one block per batch row
__global__ __launch_bounds__(256) void msoftmax_k(
    float* __restrict__ score, const float* __restrict__ mask, int L)
{
    int b = blockIdx.x;
    float* s = score + (long long)b * L;
    const float* mk = mask + (long long)b * L;
    int t = threadIdx.x;
    __shared__ float red[256];
    float mx = -1e30f;
    for (int i = t; i < L; i += 256) mx = fmaxf(mx, s[i]);
    red[t] = mx; __syncthreads();
    for (int off = 128; off > 0; off >>= 1) {
        if (t < off) red[t] = fmaxf(red[t], red[t + off]);
        __syncthreads();
    }
    mx = red[0]; __syncthreads();
    float sum = 0.f;
    for (int i = t; i < L; i += 256) {
        float e = expf(s[i] - mx) * mk[i];
        s[i] = e; sum += e;
    }
    red[t] = sum; __syncthreads();
    for (int off = 128; off > 0; off >>= 1) {
        if (t < off) red[t] += red[t + off];
        __syncthreads();
    }
    float inv = 1.0f / (red[0] + 1e-6f);
    __syncthreads();
    for (int i = t; i < L; i += 256) s[i] *= inv;
}

// weighted sum stage 1: partial over 16 chunks
__global__ __launch_bounds__(256) void wsum1_k(
    const float* __restrict__ feat, const float* __restrict__ att,
    float* __restrict__ partial, int L)
{
    int b = blockIdx.x, c = blockIdx.y, l = threadIdx.x;
    int chunk = L / 16;
    const float* fb = feat + (long long)b * L * LDq;
    const float* ab = att + (long long)b * L;
    float s = 0.f;
    int r0 = c * chunk, r1 = r0 + chunk;
    for (int r = r0; r < r1; r++) s += fb[(long long)r * LDq + l] * ab[r];
    partial[((long long)b * 16 + c) * LDq + l] = s;
}

// weighted sum stage 2
__global__ __launch_bounds__(256) void wsum2_k(
    const float* __restrict__ partial, float* __restrict__ out, int outStride)
{
    int b = blockIdx.x, l = threadIdx.x;
    float s = 0.f;
    #pragma unroll
    for (int c = 0; c < 16; c++) s += partial[((long long)b * 16 + c) * LDq + l];
    out[(long long)b * outStride + l] = s;
}

// ---------------------------------------------------------------------------
// Fused head, one block (256 threads) per batch row b:
//   v[0:256]  = cf[b] @ combc_W + combc_b
//   v[256:512]= fps[b]
//   v[512:768]= pf[b] @ combp_W + combp_b
//   v[768]=invT, v[769]=T
//   3x: v = leaky(v @ Wout_W[j] + Wout_b[j])
//   out[b] = v · out_W + out_b
// Thread t owns cols {t, 256+t, 512+t}; threads 0..1 also own col 768+t.
// (BUGFIX r4: previous `t<258` guard assumed 258 threads; cols 768/769 were
// never computed, leaving uninitialized LDS in the layer input.)
// ---------------------------------------------------------------------------
__global__ __launch_bounds__(256) void head_k(
    const float* __restrict__ cf, const float* __restrict__ pf,
    const float* __restrict__ fps, const float* __restrict__ invT,
    const float* __restrict__ T,
    const float* __restrict__ combc_W, const float* __restrict__ combc_b,
    const float* __restrict__ combp_W, const float* __restrict__ combp_b,
    const float* __restrict__ Wout_W, const float* __restrict__ Wout_b,
    const float* __restrict__ out_W, const float* __restrict__ out_b,
    float* __restrict__ outp)
{
    int b = blockIdx.x, t = threadIdx.x;
    __shared__ float vc[1024];
    __shared__ float vp[1024];
    __shared__ float vcur[772];
    __shared__ float vnext[772];
    __shared__ float red[256];

    for (int i = t; i < 1024; i += 256) {
        vc[i] = cf[(long long)b * 1024 + i];
        vp[i] = pf[(long long)b * 1024 + i];
    }
    __syncthreads();

    {
        float sc = combc_b[t], sp = combp_b[t];
        #pragma unroll 4
        for (int k = 0; k < 1024; k++) {
            sc += vc[k] * combc_W[(long long)k * 256 + t];
            sp += vp[k] * combp_W[(long long)k * 256 + t];
        }
        vcur[t] = sc;
        vcur[256 + t] = fps[(long long)b * 256 + t];
        vcur[512 + t] = sp;
    }
    if (t == 0) { vcur[768] = invT[b]; vcur[769] = T[b]; }
    __syncthreads();

    for (int j = 0; j < 3; j++) {
        const float* W  = Wout_W + (long long)j * 770 * 770;
        const float* bb = Wout_b + (long long)j * 770;
        float s0 = bb[t];
        float s1 = bb[256 + t];
        float s2 = bb[512 + t];                       // cols 512..767
        float s3 = (t < 2) ? bb[768 + t] : 0.f;       // cols 768,769
        int i3 = (t < 2) ? (768 + t) : 769;
        #pragma unroll 4
        for (int k = 0; k < 770; k++) {
            float v = vcur[k];
            const float* Wk = W + (long long)k * 770;
            s0 += v * Wk[t];
            s1 += v * Wk[256 + t];
            s2 += v * Wk[512 + t];
            s3 += v * Wk[i3];
        }
        s0 = s0 > 0.f ? s0 : ALPHA_LR * s0;
        s1 = s1 > 0.f ? s1 : ALPHA_LR * s1;
        s2 = s2 > 0.f ? s2 : ALPHA_LR * s2;
        s3 = s3 > 0.f ? s3 : ALPHA_LR * s3;
        __syncthreads();
        vnext[t] = s0;
        vnext[256 + t] = s1;
        vnext[512 + t] = s2;
        if (t < 2) vnext[768 + t] = s3;
        __syncthreads();
        for (int n = t; n < 770; n += 256) vcur[n] = vnext[n];
        __syncthreads();
    }

    float s = 0.f;
    for (int i = t; i < 770; i += 256) s += vcur[i] * out_W[i];
    red[t] = s; __syncthreads();
    for (int off = 128; off > 0; off >>= 1) {
        if (t < off) red[t] += red[t + off];
        __syncthreads();
    }
    if (t == 0) outp[b] = red[0] + out_b[0];
}

extern "C" void kernel_launch(void* const* d_in, const int* in_sizes, int n_in,
                              void* d_out, int out_size, void* d_ws, size_t ws_size,
                              hipStream_t stream)
{
    const float* atoms_emb = (const float*)d_in[0];
    const int*   adjacency = (const int*)d_in[1];
    const float* atoms_mask= (const float*)d_in[2];
    const float* amino_emb = (const float*)d_in[3];
    const float* amino_mask= (const float*)d_in[4];
    const float* fps       = (const float*)d_in[5];
    const float* inv_Temp  = (const float*)d_in[6];
    const float* Temp      = (const float*)d_in[7];
    const float* bert_W    = (const float*)d_in[8];
    const float* bert_b    = (const float*)d_in[9];
    const float* gat_W     = (const float*)d_in[10];
    const float* gat_a     = (const float*)d_in[11];
    const float* gatout_W  = (const float*)d_in[12];
    const float* gatout_a  = (const float*)d_in[13];
    const float* Wcomp_W   = (const float*)d_in[14];
    const float* Wcomp_b   = (const float*)d_in[15];
    const float* prot_W    = (const float*)d_in[16];
    const float* prot_b    = (const float*)d_in[17];
    const float* conv_W    = (const float*)d_in[18];
    const float* conv_b    = (const float*)d_in[19];
    const float* Wprot_W   = (const float*)d_in[20];
    const float* Wprot_b   = (const float*)d_in[21];
    const float* U         = (const float*)d_in[22];
    const float* tc2p_W    = (const float*)d_in[23];
    const float* tc2p_b    = (const float*)d_in[24];
    const float* tp2c_W    = (const float*)d_in[25];
    const float* tp2c_b    = (const float*)d_in[26];
    const float* bhc_W     = (const float*)d_in[27];
    const float* bhc_b     = (const float*)d_in[28];
    const float* bhp_W     = (const float*)d_in[29];
    const float* bhp_b     = (const float*)d_in[30];
    const float* battc_W   = (const float*)d_in[31];
    const float* battc_b   = (const float*)d_in[32];
    const float* battp_W   = (const float*)d_in[33];
    const float* battp_b   = (const float*)d_in[34];
    const float* combc_W   = (const float*)d_in[35];
    const float* combc_b   = (const float*)d_in[36];
    const float* combp_W   = (const float*)d_in[37];
    const float* combp_b   = (const float*)d_in[38];
    const float* Wout_W    = (const float*)d_in[39];
    const float* Wout_b    = (const float*)d_in[40];
    const float* out_W     = (const float*)d_in[41];
    const float* out_b     = (const float*)d_in[42];
    float* out = (float*)d_out;

    // ---- workspace layout (floats) ----
    float* w = (float*)d_ws;
    float* av    = w; w += (long long)Bq*Nq*LDq;
    float* pv    = w; w += (long long)Bq*Mq*LDq;
    float* sx    = w; w += (long long)Bq*Mq*LDq;   // early-phase scratch / tp -> hpb
    float* Abuf  = w; w += (long long)Bq*Nq*Mq;
    float* bufU  = w; w += (long long)Bq*Nq*LDq;   // avU -> hb
    float* bufTC = w; w += (long long)Bq*Nq*LDq;   // tc -> wsum partials
    float* esrc  = w; w += (long long)NHq*Bq*Nq;
    float* edst  = w; w += (long long)NHq*Bq*Nq;
    float* scoreC= w; w += (long long)Bq*Nq;
    float* scoreP= w; w += (long long)Bq*Mq;
    float* rbuf  = w; w += (long long)Bq*Mq;
    float* qbuf  = w; w += (long long)Bq*Nq;
    float* csum  = w; w += (long long)Bq*Mq;
    float* cf    = w; w += (long long)Bq*4*LDq;
    float* pf    = w; w += (long long)Bq*4*LDq;
    // bf16 buffers (carved as float-space, used as ushort)
    ushort_t* pv_bf  = (ushort_t*)w; w += (long long)Bq*Mq*LDq/2;
    ushort_t* av_bf  = (ushort_t*)w; w += (long long)Bq*Nq*LDq/2;
    ushort_t* avU_bf = (ushort_t*)w; w += (long long)Bq*Nq*LDq/2;
    ushort_t* Ut_bf    = (ushort_t*)w; w += (long long)4*LDq*LDq/2;
    ushort_t* tp2cT_bf = (ushort_t*)w; w += (long long)4*LDq*LDq/2;
    ushort_t* tc2pT_bf = (ushort_t*)w; w += (long long)4*LDq*LDq/2;
    ushort_t* bhcT_bf  = (ushort_t*)w; w += (long long)4*LDq*LDq/2;
    ushort_t* bhpT_bf  = (ushort_t*)w; w += (long long)4*LDq*LDq/2;
    ushort_t* protWt_bf= (ushort_t*)w; w += (long long)48*1024/2;

    // early-phase aliases inside sx (dead before BIDAT loop reuses sx)
    float* h     = sx;
    float* WhAll = h + (long long)Bq*Nq*CDq;
    float* multi = WhAll + (long long)Bq*Nq*NHq*GDq;
    float* Wh2   = multi + (long long)Bq*Nq*NHq*GDq;
    float* avp   = Wh2 + (long long)Bq*Nq*CDq;
    float* c0    = avp + (long long)Bq*Nq*CDq;
    float* c1    = c0 + (long long)Bq*Mq*PDq;

    float* wpart = bufTC;   // wsum partials (tc dead by then)

    int rowsA = Bq * Nq;     // 4096
    int rowsP = Bq * Mq;     // 32768

    // ---- weight transpose-converts (once) ----
    wtcvt_k<<<dim3(256, 1, 4), 256, 0, stream>>>(U,      Ut_bf,    LDq, LDq, LDq, LDq);
    wtcvt_k<<<dim3(256, 1, 4), 256, 0, stream>>>(tp2c_W, tp2cT_bf, LDq, LDq, LDq, LDq);
    wtcvt_k<<<dim3(256, 1, 4), 256, 0, stream>>>(tc2p_W, tc2pT_bf, LDq, LDq, LDq, LDq);
    wtcvt_k<<<dim3(256, 1, 4), 256, 0, stream>>>(bhc_W,  bhcT_bf,  LDq, LDq, LDq, LDq);
    wtcvt_k<<<dim3(256, 1, 4), 256, 0, stream>>>(bhp_W,  bhpT_bf,  LDq, LDq, LDq, LDq);
    wtcvt_k<<<dim3((48*1024+255)/256, 1, 1), 256, 0, stream>>>(prot_W, protWt_bf, 1024, 40, 48, 1024);

    // 1. h = atoms_emb @ bert_W + bert_b   (K=300, keep fp32)
    run_gemm(stream, 0, false, rowsA, CDq, 300, atoms_emb, 300, 0,
             bert_W, CDq, 0, bert_b, h, CDq, 0, 1);

    // 2. Wh_all = h @ gat_W[k] (batched heads)
    run_gemm(stream, 0, false, rowsA, GDq, CDq, h, CDq, 0,
             gat_W, GDq, (long long)CDq*GDq, nullptr,
             WhAll, NHq*GDq, GDq, NHq);

    // 3-4. GAT heads -> multi (ELU)
    gat_e_k<<<dim3(rowsA, NHq), 128, 0, stream>>>(WhAll, NHq*GDq, GDq, gat_a, 2*GDq,
                                                  esrc, edst, rowsA);
    gat_attn_k<<<dim3(rowsA, NHq), 128, 0, stream>>>(WhAll, NHq*GDq, GDq, adjacency,
                                                     esrc, edst, multi, NHq*GDq);

    // 5-7. GAT out layer -> avp (ELU)
    run_gemm(stream, 0, false, rowsA, CDq, NHq*GDq, multi, NHq*GDq, 0,
             gatout_W, CDq, 0, nullptr, Wh2, CDq, 0, 1);
    gat_e_k<<<dim3(rowsA, 1), 128, 0, stream>>>(Wh2, CDq, CDq, gatout_a, 2*CDq,
                                                esrc, edst, rowsA);
    gat_attn_k<<<dim3(rowsA, 1), 128, 0, stream>>>(Wh2, CDq, CDq, adjacency,
                                                   esrc, edst, avp, CDq);

    // 8. av = leaky(avp @ Wcomp_W + b)
    run_gemm(stream, 1, false, rowsA, LDq, CDq, avp, CDq, 0,
             Wcomp_W, LDq, 0, Wcomp_b, av, LDq, 0, 1);
    cvt_bf16_k<<<(rowsA*LDq/4 + 255)/256, 256, 0, stream>>>(av, av_bf, (long long)rowsA*LDq/4);

    // 9. pv0 = amino_emb @ prot_W + b  -> MFMA (AF32 A-operand, N padded to 48)
    mfma_nt_k<0, 0, 1, 3, 1><<<dim3(rowsP/64, 1, 1), 256, 0, stream>>>(
        rowsP, 48, 1024, 40,
        (const void*)amino_emb, 1024, 0,
        protWt_bf, 1024, 0,
        prot_b, c0, PDq, 0, nullptr, nullptr);

    // 10. 3x conv 11x11 + leaky
    {
        long long total = (long long)Bq*Mq*PDq;
        int blocks = (int)((total + 255) / 256);
        conv_k<<<blocks, 256, 0, stream>>>(c0, conv_W + 0*121, conv_b + 0, c1);
        conv_k<<<blocks, 256, 0, stream>>>(c1, conv_W + 1*121, conv_b + 1, c0);
        conv_k<<<blocks, 256, 0, stream>>>(c0, conv_W + 2*121, conv_b + 2, c1);
    }

    // 11. pv = leaky(x @ Wprot_W + b)  (K=40, keep fp32)
    run_gemm(stream, 1, false, rowsP, LDq, PDq, c1, PDq, 0,
             Wprot_W, LDq, 0, Wprot_b, pv, LDq, 0, 1);
    cvt_bf16_k<<<(rowsP*LDq/4 + 255)/256, 256, 0, stream>>>(pv, pv_bf, (long long)rowsP*LDq/4);

    // 12. BIDAT loop
    for (int i = 0; i < 4; i++) {
        const ushort_t* UtI    = Ut_bf    + (long long)i*LDq*LDq;
        const ushort_t* tp2cTI = tp2cT_bf + (long long)i*LDq*LDq;
        const ushort_t* tc2pTI = tc2pT_bf + (long long)i*LDq*LDq;
        const ushort_t* bhcTI  = bhcT_bf  + (long long)i*LDq*LDq;
        const ushort_t* bhpTI  = bhpT_bf  + (long long)i*LDq*LDq;
        const float* tp2cbi  = tp2c_b + (long long)i*LDq;
        const float* tc2pbi  = tc2p_b + (long long)i*LDq;
        const float* bhcbi   = bhc_b  + (long long)i*LDq;
        const float* bhpbi   = bhp_b  + (long long)i*LDq;
        const float* battcWi = battc_W+ (long long)i*2*LDq;
        const float* battcbi = battc_b+ i;
        const float* battpWi = battp_W+ (long long)i*2*LDq;
        const float* battpbi = battp_b+ i;

        // avU = av @ U[i]
        mfma_nt_k<0, 0, 0, 16, 0><<<dim3(rowsA/64, 1, 1), 256, 0, stream>>>(
            rowsA, LDq, LDq, LDq, (const void*)av_bf, LDq, 0,
            UtI, LDq, 0, nullptr, bufU, LDq, 0, nullptr, nullptr);
        cvt_bf16_k<<<(rowsA*LDq/4 + 255)/256, 256, 0, stream>>>(bufU, avU_bf, (long long)rowsA*LDq/4);

        // A = tanh(avU @ pv^T) * masks   (batched, Bt = pv_bf rows)
        mfma_nt_k<2, 1, 0, 16, 0><<<dim3(Nq/64, Mq/256, Bq), 256, 0, stream>>>(
            Nq, Mq, LDq, Mq,
            (const void*)avU_bf, LDq, (long long)Nq*LDq,
            pv_bf, LDq, (long long)Mq*LDq,
            nullptr, Abuf, Mq, (long long)Nq*Mq,
            atoms_mask, amino_mask);

        // tp = tanh(pv @ tp2c_W + b) -> sx
        mfma_nt_k<2, 0, 1, 16, 0><<<dim3(rowsP/64, 1, 1), 256, 0, stream>>>(
            rowsP, LDq, LDq, LDq, (const void*)pv_bf, LDq, 0,
            tp2cTI, LDq, 0, tp2cbi, sx, LDq, 0, nullptr, nullptr);
        rowdot_k<<<rowsP, 256, 0, stream>>>(sx, battcWi + LDq, rbuf);

        // tc = tanh(av @ tc2p_W + b) -> bufTC
        mfma_nt_k<2, 0, 1, 16, 0><<<dim3(rowsA/64, 1, 1), 256, 0, stream>>>(
            rowsA, LDq, LDq, LDq, (const void*)av_bf, LDq, 0,
            tc2pTI, LDq, 0, tc2pbi, bufTC, LDq, 0, nullptr, nullptr);
        rowdot_k<<<rowsA, 256, 0, stream>>>(bufTC, battpWi + LDq, qbuf);

        // hb = tanh(av @ bhc_W + b) -> bufU (avU_bf already extracted)
        mfma_nt_k<2, 0, 1, 16, 0><<<dim3(rowsA/64, 1, 1), 256, 0, stream>>>(
            rowsA, LDq, LDq, LDq, (const void*)av_bf, LDq, 0,
            bhcTI, LDq, 0, bhcbi, bufU, LDq, 0, nullptr, nullptr);

        // hpb = tanh(pv @ bhp_W + b) -> sx (tp consumed by rowdot)
        mfma_nt_k<2, 0, 1, 16, 0><<<dim3(rowsP/64, 1, 1), 256, 0, stream>>>(
            rowsP, LDq, LDq, LDq, (const void*)pv_bf, LDq, 0,
            bhpTI, LDq, 0, bhpbi, sx, LDq, 0, nullptr, nullptr);

        // csum[b,m] = sum_n A[b,n,m]*q[b,n]
        colsum_k<<<dim3(Mq/256, Bq), 256, 0, stream>>>(Abuf, qbuf, csum);
        // attention scores
        scoreC_k<<<rowsA, 256, 0, stream>>>(bufU, Abuf, rbuf, battcWi, battcbi, scoreC);
        scoreP_k<<<rowsP, 256, 0, stream>>>(sx, csum, battpWi, battpbi, scoreP);
        // masked softmax
        msoftmax_k<<<Bq, 256, 0, stream>>>(scoreC, atoms_mask, Nq);
        msoftmax_k<<<Bq, 256, 0, stream>>>(scoreP, amino_mask, Mq);
        // pooled features
        wsum1_k<<<dim3(Bq, 16), 256, 0, stream>>>(av, scoreC, wpart, Nq);
        wsum2_k<<<Bq, 256, 0, stream>>>(wpart, cf + (long long)i*LDq, 4*LDq);
        wsum1_k<<<dim3(Bq, 16), 256, 0, stream>>>(pv, scoreP, wpart, Mq);
        wsum2_k<<<Bq, 256, 0, stream>>>(wpart, pf + (long long)i*LDq, 4*LDq);
    }

    // 13. fused head
    head_k<<<Bq, 256, 0, stream>>>(cf, pf, fps, inv_Temp, Temp,
                                   combc_W, combc_b, combp_W, combp_b,
                                   Wout_W, Wout_b, out_W, out_b, out);

    (void)in_sizes; (void)n_in; (void)out_size; (void)ws_size;
}

// Round 6
// 2007.138 us; speedup vs baseline: 2.0277x; 1.1406x over previous
//
#include <hip/hip_runtime.h>
#include <math.h>

#define ALPHA_LR 0.2f

#define Bq  32
#define Nq  128
#define Mq  1024
#define CDq 128
#define GDq 64
#define NHq 4
#define LDq 256
#define PDq 40

typedef unsigned short ushort_t;
typedef __attribute__((ext_vector_type(8))) short bf16x8;
typedef __attribute__((ext_vector_type(4))) float f32x4;

__device__ __forceinline__ ushort_t f2bf(float f) {
    union { float f; unsigned u; } x; x.f = f;
    unsigned r = x.u + 0x7FFFu + ((x.u >> 16) & 1u);   // RNE
    return (ushort_t)(r >> 16);
}

// ---------------------------------------------------------------------------
// MFMA bf16 NT GEMM: C = act(A @ Bt^T + bias) [* masks]
// A: [M][lda] bf16 (or fp32 if AF32), Bt: [Npad][ldb] bf16 (= B^T, K-major)
// Each wave: 16 rows x NT*16 cols. grid.x = M/64 (4 waves/block),
// grid.y = N/(NT*16), grid.z = batch. K % 32 == 0. M % 16 == 0.
// C/D layout (m89-verified): col = lane&15, row = (lane>>4)*4 + reg.
// ---------------------------------------------------------------------------
template<int ACT, int MASKED, int HAS_BIAS, int NT, int AF32>
__global__ __launch_bounds__(256) void mfma_nt_k(
    int M, int N, int K, int Nout,
    const void* __restrict__ Av, int lda, long long sA,
    const ushort_t* __restrict__ Bt, int ldb, long long sB,
    const float* __restrict__ bias,
    float* __restrict__ C, int ldc, long long sC,
    const float* __restrict__ maskR, const float* __restrict__ maskC)
{
    int z = blockIdx.z;
    Bt += (long long)z * sB;
    C  += (long long)z * sC;

    int wave = threadIdx.x >> 6;
    int lane = threadIdx.x & 63;
    int lr = lane & 15;
    int kg = lane >> 4;
    int m0 = (blockIdx.x * 4 + wave) * 16;
    int n0 = blockIdx.y * (NT * 16);
    if (m0 >= M) return;

    f32x4 acc[NT];
    #pragma unroll
    for (int t = 0; t < NT; t++) acc[t] = (f32x4){0.f, 0.f, 0.f, 0.f};

    const ushort_t* Ab = nullptr;
    const float*    Af = nullptr;
    if (AF32) Af = (const float*)Av + (long long)z * sA + (long long)(m0 + lr) * lda + kg * 8;
    else      Ab = (const ushort_t*)Av + (long long)z * sA + (long long)(m0 + lr) * lda + kg * 8;
    const ushort_t* Bbase = Bt + (long long)(n0 + lr) * ldb + kg * 8;

    for (int k0 = 0; k0 < K; k0 += 32) {
        bf16x8 a;
        if (AF32) {
            float4 a0 = *(const float4*)(Af + k0);
            float4 a1 = *(const float4*)(Af + k0 + 4);
            a[0] = (short)f2bf(a0.x); a[1] = (short)f2bf(a0.y);
            a[2] = (short)f2bf(a0.z); a[3] = (short)f2bf(a0.w);
            a[4] = (short)f2bf(a1.x); a[5] = (short)f2bf(a1.y);
            a[6] = (short)f2bf(a1.z); a[7] = (short)f2bf(a1.w);
        } else {
            a = *(const bf16x8*)(Ab + k0);
        }
        #pragma unroll
        for (int t = 0; t < NT; t++) {
            bf16x8 b = *(const bf16x8*)(Bbase + (long long)t * 16 * ldb + k0);
            acc[t] = __builtin_amdgcn_mfma_f32_16x16x32_bf16(a, b, acc[t], 0, 0, 0);
        }
    }

    int row0 = m0 + kg * 4;
    #pragma unroll
    for (int t = 0; t < NT; t++) {
        int col = n0 + t * 16 + lr;
        if (col >= Nout) continue;
        float bv = HAS_BIAS ? bias[col] : 0.f;
        float mC = MASKED ? maskC[(long long)z * N + col] : 1.f;
        #pragma unroll
        for (int r = 0; r < 4; r++) {
            float v = acc[t][r] + bv;
            if (ACT == 1) v = v > 0.f ? v : ALPHA_LR * v;
            else if (ACT == 2) v = tanhf(v);
            if (MASKED) v *= maskR[(long long)z * M + row0 + r] * mC;
            C[(long long)(row0 + r) * ldc + col] = v;
        }
    }
}

// fp32 -> bf16, 4 elems/thread, n % 4 == 0
__global__ __launch_bounds__(256) void cvt_bf16_k(
    const float* __restrict__ in, ushort_t* __restrict__ out, long long n4)
{
    long long i = (long long)blockIdx.x * 256 + threadIdx.x;
    if (i >= n4) return;
    float4 v = ((const float4*)in)[i];
    ushort4 o;
    o.x = f2bf(v.x); o.y = f2bf(v.y); o.z = f2bf(v.z); o.w = f2bf(v.w);
    ((ushort4*)out)[i] = o;
}

// W[K][Nsrc] fp32 -> Wt[Npad][Kp] bf16 (transposed, zero-padded), batched z
__global__ __launch_bounds__(256) void wtcvt_k(
    const float* __restrict__ W, ushort_t* __restrict__ Wt,
    int K, int Nsrc, int Npad, int Kp)
{
    int z = blockIdx.z;
    const float* Wz = W + (long long)z * K * Nsrc;
    ushort_t* Oz = Wt + (long long)z * Npad * Kp;
    int idx = blockIdx.x * 256 + threadIdx.x;
    if (idx >= Npad * Kp) return;
    int n = idx / Kp, k = idx % Kp;
    float v = (k < K && n < Nsrc) ? Wz[(long long)k * Nsrc + n] : 0.f;
    Oz[idx] = f2bf(v);
}

// ---------------------------------------------------------------------------
// Generic tiled fp32 GEMM (kept for small/odd-K GEMMs)
// ---------------------------------------------------------------------------
template<int ACT, int TA, int TB, int MASKED>
__global__ __launch_bounds__(256) void gemm_k(
    int M, int N, int K,
    const float* __restrict__ A, int lda, long long sA,
    const float* __restrict__ Bm, int ldb, long long sB,
    const float* __restrict__ bias,
    float* __restrict__ C, int ldc, long long sC,
    const float* __restrict__ maskR, const float* __restrict__ maskC)
{
    int z = blockIdx.z;
    A  += (long long)z * sA;
    Bm += (long long)z * sB;
    C  += (long long)z * sC;

    __shared__ float As[16][68];
    __shared__ float Bs[16][68];

    int tid = threadIdx.x;
    int tx = tid % 16, ty = tid / 16;
    int m0 = blockIdx.y * 64, n0 = blockIdx.x * 64;

    float acc[4][4] = {};

    for (int k0 = 0; k0 < K; k0 += 16) {
        if (!TA) {
            int k = tid % 16, mBase = tid / 16;
            #pragma unroll
            for (int p = 0; p < 4; p++) {
                int m = mBase + p * 16;
                int gm = m0 + m, gk = k0 + k;
                float v = 0.f;
                if (gm < M && gk < K) v = A[(long long)gm * lda + gk];
                As[k][m] = v;
            }
        } else {
            int m = tid % 64, kBase = tid / 64;
            #pragma unroll
            for (int p = 0; p < 4; p++) {
                int k = kBase + p * 4;
                int gm = m0 + m, gk = k0 + k;
                float v = 0.f;
                if (gm < M && gk < K) v = A[(long long)gk * lda + gm];
                As[k][m] = v;
            }
        }
        if (!TB) {
            int n = tid % 64, kBase = tid / 64;
            #pragma unroll
            for (int p = 0; p < 4; p++) {
                int k = kBase + p * 4;
                int gn = n0 + n, gk = k0 + k;
                float v = 0.f;
                if (gn < N && gk < K) v = Bm[(long long)gk * ldb + gn];
                Bs[k][n] = v;
            }
        } else {
            int k = tid % 16, nBase = tid / 16;
            #pragma unroll
            for (int p = 0; p < 4; p++) {
                int n = nBase + p * 16;
                int gn = n0 + n, gk = k0 + k;
                float v = 0.f;
                if (gn < N && gk < K) v = Bm[(long long)gn * ldb + gk];
                Bs[k][n] = v;
            }
        }
        __syncthreads();
        #pragma unroll
        for (int kk = 0; kk < 16; kk++) {
            float a[4], b[4];
            #pragma unroll
            for (int i = 0; i < 4; i++) a[i] = As[kk][ty * 4 + i];
            #pragma unroll
            for (int j = 0; j < 4; j++) b[j] = Bs[kk][tx * 4 + j];
            #pragma unroll
            for (int i = 0; i < 4; i++)
                #pragma unroll
                for (int j = 0; j < 4; j++)
                    acc[i][j] += a[i] * b[j];
        }
        __syncthreads();
    }

    #pragma unroll
    for (int i = 0; i < 4; i++) {
        int gm = m0 + ty * 4 + i;
        if (gm >= M) continue;
        #pragma unroll
        for (int j = 0; j < 4; j++) {
            int gn = n0 + tx * 4 + j;
            if (gn >= N) continue;
            float v = acc[i][j];
            if (bias) v += bias[gn];
            if (ACT == 1) v = v > 0.f ? v : ALPHA_LR * v;
            else if (ACT == 2) v = tanhf(v);
            if (MASKED) v *= maskR[(long long)z * M + gm] * maskC[(long long)z * N + gn];
            C[(long long)gm * ldc + gn] = v;
        }
    }
}

static inline void run_gemm(hipStream_t stream, int act, bool tb_masked,
    int M, int N, int K,
    const float* A, int lda, long long sA,
    const float* B, int ldb, long long sB,
    const float* bias, float* C, int ldc, long long sC,
    int batch, const float* maskR = nullptr, const float* maskC = nullptr)
{
    dim3 grid((N + 63) / 64, (M + 63) / 64, batch);
    dim3 blk(256);
    if (tb_masked) {
        gemm_k<2, 0, 1, 1><<<grid, blk, 0, stream>>>(M, N, K, A, lda, sA, B, ldb, sB,
                                                     bias, C, ldc, sC, maskR, maskC);
    } else if (act == 0) {
        gemm_k<0, 0, 0, 0><<<grid, blk, 0, stream>>>(M, N, K, A, lda, sA, B, ldb, sB,
                                                     bias, C, ldc, sC, nullptr, nullptr);
    } else if (act == 1) {
        gemm_k<1, 0, 0, 0><<<grid, blk, 0, stream>>>(M, N, K, A, lda, sA, B, ldb, sB,
                                                     bias, C, ldc, sC, nullptr, nullptr);
    } else {
        gemm_k<2, 0, 0, 0><<<grid, blk, 0, stream>>>(M, N, K, A, lda, sA, B, ldb, sB,
                                                     bias, C, ldc, sC, nullptr, nullptr);
    }
}

// per-row GAT source/dest attention logits
__global__ __launch_bounds__(128) void gat_e_k(
    const float* __restrict__ Wh, int ldWh, int GD,
    const float* __restrict__ a, int aStride,
    float* __restrict__ esrc, float* __restrict__ edst, int rows)
{
    int row = blockIdx.x;
    int k = blockIdx.y;
    int g = threadIdx.x;
    float ws = 0.f, wd = 0.f;
    if (g < GD) {
        float wv = Wh[(long long)row * ldWh + k * GD + g];
        ws = wv * a[k * aStride + g];
        wd = wv * a[k * aStride + GD + g];
    }
    __shared__ float sb[2][128];
    sb[0][threadIdx.x] = ws; sb[1][threadIdx.x] = wd;
    __syncthreads();
    for (int off = 64; off > 0; off >>= 1) {
        if (threadIdx.x < off) {
            sb[0][threadIdx.x] += sb[0][threadIdx.x + off];
            sb[1][threadIdx.x] += sb[1][threadIdx.x + off];
        }
        __syncthreads();
    }
    if (threadIdx.x == 0) {
        esrc[(long long)k * rows + row] = sb[0][0];
        edst[(long long)k * rows + row] = sb[1][0];
    }
}

// GAT attention: softmax over neighbors + weighted sum + ELU
__global__ __launch_bounds__(128) void gat_attn_k(
    const float* __restrict__ Wh, int ldWh, int GD,
    const int* __restrict__ adj,
    const float* __restrict__ esrc, const float* __restrict__ edst,
    float* __restrict__ out, int ldOut)
{
    int row = blockIdx.x;          // b*N + n
    int k = blockIdx.y;
    int rows = gridDim.x;
    int b = row / Nq, n = row % Nq;
    int m = threadIdx.x;

    __shared__ float att[Nq];
    __shared__ float red[Nq];

    float e = esrc[(long long)k * rows + row] + edst[(long long)k * rows + b * Nq + m];
    e = e > 0.f ? e : ALPHA_LR * e;
    if (adj[(long long)b * Nq * Nq + n * Nq + m] <= 0) e = -9.0e15f;

    red[m] = e; __syncthreads();
    for (int off = 64; off > 0; off >>= 1) {
        if (m < off) red[m] = fmaxf(red[m], red[m + off]);
        __syncthreads();
    }
    float mx = red[0]; __syncthreads();
    float ex = expf(e - mx);
    att[m] = ex; red[m] = ex; __syncthreads();
    for (int off = 64; off > 0; off >>= 1) {
        if (m < off) red[m] += red[m + off];
        __syncthreads();
    }
    float inv = 1.0f / red[0];

    for (int g = threadIdx.x; g < GD; g += blockDim.x) {
        float s = 0.f;
        for (int mm = 0; mm < Nq; mm++)
            s += att[mm] * Wh[(long long)(b * Nq + mm) * ldWh + k * GD + g];
        s *= inv;
        s = s > 0.f ? s : expm1f(s);   // ELU
        out[(long long)row * ldOut + k * GD + g] = s;
    }
}

// 11x11 same-pad conv over (M, PD), single channel, + leaky
__global__ __launch_bounds__(256) void conv_k(
    const float* __restrict__ x, const float* __restrict__ W,
    const float* __restrict__ bptr, float* __restrict__ y)
{
    __shared__ float w[121];
    if (threadIdx.x < 121) w[threadIdx.x] = W[threadIdx.x];
    __syncthreads();
    long long idx = (long long)blockIdx.x * blockDim.x + threadIdx.x;
    long long total = (long long)Bq * Mq * PDq;
    if (idx >= total) return;
    int d = (int)(idx % PDq);
    long long t = idx / PDq;
    int m = (int)(t % Mq);
    int b = (int)(t / Mq);
    const float* xb = x + (long long)b * Mq * PDq;
    float s = 0.f;
    #pragma unroll
    for (int i = 0; i < 11; i++) {
        int mm = m + i - 5;
        if (mm < 0 || mm >= Mq) continue;
        #pragma unroll
        for (int j = 0; j < 11; j++) {
            int dd = d + j - 5;
            if (dd < 0 || dd >= PDq) continue;
            s += xb[(long long)mm * PDq + dd] * w[i * 11 + j];
        }
    }
    s += *bptr;
    y[idx] = s > 0.f ? s : ALPHA_LR * s;
}

// out[row] = x[row,:LD] . w
__global__ __launch_bounds__(256) void rowdot_k(
    const float* __restrict__ x, const float* __restrict__ w, float* __restrict__ out)
{
    int row = blockIdx.x, t = threadIdx.x;
    float s = x[(long long)row * LDq + t] * w[t];
    __shared__ float red[256];
    red[t] = s; __syncthreads();
    for (int off = 128; off > 0; off >>= 1) {
        if (t < off) red[t] += red[t + off];
        __syncthreads();
    }
    if (t == 0) out[row] = red[0];
}

// out[b,m] = sum_n A[b,n,m] * q[b,n]
__global__ __launch_bounds__(256) void colsum_k(
    const float* __restrict__ A, const float* __restrict__ q, float* __restrict__ out)
{
    int b = blockIdx.y;
    int m = blockIdx.x * 256 + threadIdx.x;
    const float* Ab = A + (long long)b * Nq * Mq;
    const float* qb = q + (long long)b * Nq;
    float s = 0.f;
    for (int n = 0; n < Nq; n++) s += Ab[(long long)n * Mq + m] * qb[n];
    out[(long long)b * Mq + m] = s;
}

// score_c[row=b*N+n] = hb[row]·w1 + A[b,n,:]·r[b,:] + bias
__global__ __launch_bounds__(256) void scoreC_k(
    const float* __restrict__ hb, const float* __restrict__ A,
    const float* __restrict__ r, const float* __restrict__ w1,
    const float* __restrict__ bptr, float* __restrict__ score)
{
    int row = blockIdx.x;
    int b = row / Nq;
    int t = threadIdx.x;
    float s = hb[(long long)row * LDq + t] * w1[t];
    const float* Ar = A + (long long)row * Mq;
    const float* rb = r + (long long)b * Mq;
    for (int m = t; m < Mq; m += 256) s += Ar[m] * rb[m];
    __shared__ float red[256];
    red[t] = s; __syncthreads();
    for (int off = 128; off > 0; off >>= 1) {
        if (t < off) red[t] += red[t + off];
        __syncthreads();
    }
    if (t == 0) score[row] = red[0] + bptr[0];
}

// score_p[row=b*M+m] = hpb[row]·w1 + csum[row] + bias
__global__ __launch_bounds__(256) void scoreP_k(
    const float* __restrict__ hpb, const float* __restrict__ csum,
    const float* __restrict__ w1, const float* __restrict__ bptr,
    float* __restrict__ score)
{
    int row = blockIdx.x;
    int t = threadIdx.x;
    float s = hpb[(long long)row * LDq + t] * w1[t];
    __shared__ float red[256];
    red[t] = s; __syncthreads();
    for (int off = 128; off > 0; off >>= 1) {
        if (t < off) red[t] += red[t + off];
        __syncthreads();
    }
    if (t == 0) score[row] = red[0] + csum[row] + bptr[0];
}

// masked softmax in place over L, one block per batch row
__global__ __launch_bounds__(256) void msoftmax_k(
    float* __restrict__ score, const float* __restrict__ mask, int L)
{
    int b = blockIdx.x;
    float* s = score + (long long)b * L;
    const float* mk = mask + (long long)b * L;
    int t = threadIdx.x;
    __shared__ float red[256];
    float mx = -1e30f;
    for (int i = t; i < L; i += 256) mx = fmaxf(mx, s[i]);
    red[t] = mx; __syncthreads();
    for (int off = 128; off > 0; off >>= 1) {
        if (t < off) red[t] = fmaxf(red[t], red[t + off]);
        __syncthreads();
    }
    mx = red[0]; __syncthreads();
    float sum = 0.f;
    for (int i = t; i < L; i += 256) {
        float e = expf(s[i] - mx) * mk[i];
        s[i] = e; sum += e;
    }
    red[t] = sum; __syncthreads();
    for (int off = 128; off > 0; off >>= 1) {
        if (t < off) red[t] += red[t + off];
        __syncthreads();
    }
    float inv = 1.0f / (red[0] + 1e-6f);
    __syncthreads();
    for (int i = t; i < L; i += 256) s[i] *= inv;
}

// weighted sum stage 1: partial over 16 chunks
__global__ __launch_bounds__(256) void wsum1_k(
    const float* __restrict__ feat, const float* __restrict__ att,
    float* __restrict__ partial, int L)
{
    int b = blockIdx.x, c = blockIdx.y, l = threadIdx.x;
    int chunk = L / 16;
    const float* fb = feat + (long long)b * L * LDq;
    const float* ab = att + (long long)b * L;
    float s = 0.f;
    int r0 = c * chunk, r1 = r0 + chunk;
    for (int r = r0; r < r1; r++) s += fb[(long long)r * LDq + l] * ab[r];
    partial[((long long)b * 16 + c) * LDq + l] = s;
}

// weighted sum stage 2
__global__ __launch_bounds__(256) void wsum2_k(
    const float* __restrict__ partial, float* __restrict__ out, int outStride)
{
    int b = blockIdx.x, l = threadIdx.x;
    float s = 0.f;
    #pragma unroll
    for (int c = 0; c < 16; c++) s += partial[((long long)b * 16 + c) * LDq + l];
    out[(long long)b * outStride + l] = s;
}

// ---------------------------------------------------------------------------
// Skinny dense layer for the head (r6: replaces the 1-block/row fused head_k,
// which was latency-bound at 1.5% occupancy / 686 µs):
//   vout[b, colBase+col] = act(sum_k vin[b,k]*W[k*ldw+col] + bias[col])
// grid = (B, ceil(OD/64)); block = 256 = 64 cols x 4 k-slices.
// W loads are coalesced (64 consecutive cols/wave) and L2-resident.
// ---------------------------------------------------------------------------
template<int ACT>
__global__ __launch_bounds__(256) void headlin_k(
    const float* __restrict__ vin, int ldv, int VD,
    const float* __restrict__ W, int ldw,
    const float* __restrict__ bias,
    float* __restrict__ vout, int ldo, int OD, int colBase)
{
    int b = blockIdx.x;
    int c = threadIdx.x & 63;
    int s = threadIdx.x >> 6;
    int col = blockIdx.y * 64 + c;

    __shared__ float vs[1024];
    for (int i = threadIdx.x; i < VD; i += 256) vs[i] = vin[(long long)b * ldv + i];
    __syncthreads();

    float sum = 0.f;
    if (col < OD) {
        int k0 = (VD * s) >> 2, k1 = (VD * (s + 1)) >> 2;
        #pragma unroll 4
        for (int k = k0; k < k1; k++)
            sum += vs[k] * W[(long long)k * ldw + col];
    }
    __shared__ float red[4][64];
    red[s][c] = sum;
    __syncthreads();
    if (s == 0 && col < OD) {
        float t = red[0][c] + red[1][c] + red[2][c] + red[3][c] + bias[col];
        if (ACT == 1) t = t > 0.f ? t : ALPHA_LR * t;
        vout[(long long)b * ldo + colBase + col] = t;
    }
}

// v[b,256:512]=fps, v[b,768]=invT, v[b,769]=T
__global__ __launch_bounds__(256) void vfill_k(
    const float* __restrict__ fps, const float* __restrict__ invT,
    const float* __restrict__ T, float* __restrict__ v)
{
    int b = blockIdx.x, t = threadIdx.x;
    v[(long long)b * 770 + 256 + t] = fps[(long long)b * 256 + t];
    if (t == 0) {
        v[(long long)b * 770 + 768] = invT[b];
        v[(long long)b * 770 + 769] = T[b];
    }
}

// out[b] = v[b,:770]·W + b
__global__ __launch_bounds__(256) void final_k(
    const float* __restrict__ v, const float* __restrict__ W,
    const float* __restrict__ bptr, float* __restrict__ out)
{
    int b = blockIdx.x, t = threadIdx.x;
    float s = 0.f;
    for (int i = t; i < 770; i += 256) s += v[(long long)b * 770 + i] * W[i];
    __shared__ float red[256];
    red[t] = s; __syncthreads();
    for (int off = 128; off > 0; off >>= 1) {
        if (t < off) red[t] += red[t + off];
        __syncthreads();
    }
    if (t == 0) out[b] = red[0] + bptr[0];
}

extern "C" void kernel_launch(void* const* d_in, const int* in_sizes, int n_in,
                              void* d_out, int out_size, void* d_ws, size_t ws_size,
                              hipStream_t stream)
{
    const float* atoms_emb = (const float*)d_in[0];
    const int*   adjacency = (const int*)d_in[1];
    const float* atoms_mask= (const float*)d_in[2];
    const float* amino_emb = (const float*)d_in[3];
    const float* amino_mask= (const float*)d_in[4];
    const float* fps       = (const float*)d_in[5];
    const float* inv_Temp  = (const float*)d_in[6];
    const float* Temp      = (const float*)d_in[7];
    const float* bert_W    = (const float*)d_in[8];
    const float* bert_b    = (const float*)d_in[9];
    const float* gat_W     = (const float*)d_in[10];
    const float* gat_a     = (const float*)d_in[11];
    const float* gatout_W  = (const float*)d_in[12];
    const float* gatout_a  = (const float*)d_in[13];
    const float* Wcomp_W   = (const float*)d_in[14];
    const float* Wcomp_b   = (const float*)d_in[15];
    const float* prot_W    = (const float*)d_in[16];
    const float* prot_b    = (const float*)d_in[17];
    const float* conv_W    = (const float*)d_in[18];
    const float* conv_b    = (const float*)d_in[19];
    const float* Wprot_W   = (const float*)d_in[20];
    const float* Wprot_b   = (const float*)d_in[21];
    const float* U         = (const float*)d_in[22];
    const float* tc2p_W    = (const float*)d_in[23];
    const float* tc2p_b    = (const float*)d_in[24];
    const float* tp2c_W    = (const float*)d_in[25];
    const float* tp2c_b    = (const float*)d_in[26];
    const float* bhc_W     = (const float*)d_in[27];
    const float* bhc_b     = (const float*)d_in[28];
    const float* bhp_W     = (const float*)d_in[29];
    const float* bhp_b     = (const float*)d_in[30];
    const float* battc_W   = (const float*)d_in[31];
    const float* battc_b   = (const float*)d_in[32];
    const float* battp_W   = (const float*)d_in[33];
    const float* battp_b   = (const float*)d_in[34];
    const float* combc_W   = (const float*)d_in[35];
    const float* combc_b   = (const float*)d_in[36];
    const float* combp_W   = (const float*)d_in[37];
    const float* combp_b   = (const float*)d_in[38];
    const float* Wout_W    = (const float*)d_in[39];
    const float* Wout_b    = (const float*)d_in[40];
    const float* out_W     = (const float*)d_in[41];
    const float* out_b     = (const float*)d_in[42];
    float* out = (float*)d_out;

    // ---- workspace layout (floats) ----
    float* w = (float*)d_ws;
    float* av    = w; w += (long long)Bq*Nq*LDq;
    float* pv    = w; w += (long long)Bq*Mq*LDq;
    float* sx    = w; w += (long long)Bq*Mq*LDq;   // early-phase scratch / tp -> hpb
    float* Abuf  = w; w += (long long)Bq*Nq*Mq;
    float* bufU  = w; w += (long long)Bq*Nq*LDq;   // avU -> hb
    float* bufTC = w; w += (long long)Bq*Nq*LDq;   // tc -> wsum partials
    float* esrc  = w; w += (long long)NHq*Bq*Nq;
    float* edst  = w; w += (long long)NHq*Bq*Nq;
    float* scoreC= w; w += (long long)Bq*Nq;
    float* scoreP= w; w += (long long)Bq*Mq;
    float* rbuf  = w; w += (long long)Bq*Mq;
    float* qbuf  = w; w += (long long)Bq*Nq;
    float* csum  = w; w += (long long)Bq*Mq;
    float* cf    = w; w += (long long)Bq*4*LDq;
    float* pf    = w; w += (long long)Bq*4*LDq;
    float* v1    = w; w += (long long)Bq*770;
    float* v2    = w; w += (long long)Bq*770;
    // bf16 buffers (carved as float-space, used as ushort)
    ushort_t* pv_bf  = (ushort_t*)w; w += (long long)Bq*Mq*LDq/2;
    ushort_t* av_bf  = (ushort_t*)w; w += (long long)Bq*Nq*LDq/2;
    ushort_t* avU_bf = (ushort_t*)w; w += (long long)Bq*Nq*LDq/2;
    ushort_t* Ut_bf    = (ushort_t*)w; w += (long long)4*LDq*LDq/2;
    ushort_t* tp2cT_bf = (ushort_t*)w; w += (long long)4*LDq*LDq/2;
    ushort_t* tc2pT_bf = (ushort_t*)w; w += (long long)4*LDq*LDq/2;
    ushort_t* bhcT_bf  = (ushort_t*)w; w += (long long)4*LDq*LDq/2;
    ushort_t* bhpT_bf  = (ushort_t*)w; w += (long long)4*LDq*LDq/2;
    ushort_t* protWt_bf= (ushort_t*)w; w += (long long)48*1024/2;

    // early-phase aliases inside sx (dead before BIDAT loop reuses sx)
    float* h     = sx;
    float* WhAll = h + (long long)Bq*Nq*CDq;
    float* multi = WhAll + (long long)Bq*Nq*NHq*GDq;
    float* Wh2   = multi + (long long)Bq*Nq*NHq*GDq;
    float* avp   = Wh2 + (long long)Bq*Nq*CDq;
    float* c0    = avp + (long long)Bq*Nq*CDq;
    float* c1    = c0 + (long long)Bq*Mq*PDq;

    float* wpart = bufTC;   // wsum partials (tc dead by then)

    int rowsA = Bq * Nq;     // 4096
    int rowsP = Bq * Mq;     // 32768

    // ---- weight transpose-converts (once) ----
    wtcvt_k<<<dim3(256, 1, 4), 256, 0, stream>>>(U,      Ut_bf,    LDq, LDq, LDq, LDq);
    wtcvt_k<<<dim3(256, 1, 4), 256, 0, stream>>>(tp2c_W, tp2cT_bf, LDq, LDq, LDq, LDq);
    wtcvt_k<<<dim3(256, 1, 4), 256, 0, stream>>>(tc2p_W, tc2pT_bf, LDq, LDq, LDq, LDq);
    wtcvt_k<<<dim3(256, 1, 4), 256, 0, stream>>>(bhc_W,  bhcT_bf,  LDq, LDq, LDq, LDq);
    wtcvt_k<<<dim3(256, 1, 4), 256, 0, stream>>>(bhp_W,  bhpT_bf,  LDq, LDq, LDq, LDq);
    wtcvt_k<<<dim3((48*1024+255)/256, 1, 1), 256, 0, stream>>>(prot_W, protWt_bf, 1024, 40, 48, 1024);

    // 1. h = atoms_emb @ bert_W + bert_b   (K=300, keep fp32)
    run_gemm(stream, 0, false, rowsA, CDq, 300, atoms_emb, 300, 0,
             bert_W, CDq, 0, bert_b, h, CDq, 0, 1);

    // 2. Wh_all = h @ gat_W[k] (batched heads)
    run_gemm(stream, 0, false, rowsA, GDq, CDq, h, CDq, 0,
             gat_W, GDq, (long long)CDq*GDq, nullptr,
             WhAll, NHq*GDq, GDq, NHq);

    // 3-4. GAT heads -> multi (ELU)
    gat_e_k<<<dim3(rowsA, NHq), 128, 0, stream>>>(WhAll, NHq*GDq, GDq, gat_a, 2*GDq,
                                                  esrc, edst, rowsA);
    gat_attn_k<<<dim3(rowsA, NHq), 128, 0, stream>>>(WhAll, NHq*GDq, GDq, adjacency,
                                                     esrc, edst, multi, NHq*GDq);

    // 5-7. GAT out layer -> avp (ELU)
    run_gemm(stream, 0, false, rowsA, CDq, NHq*GDq, multi, NHq*GDq, 0,
             gatout_W, CDq, 0, nullptr, Wh2, CDq, 0, 1);
    gat_e_k<<<dim3(rowsA, 1), 128, 0, stream>>>(Wh2, CDq, CDq, gatout_a, 2*CDq,
                                                esrc, edst, rowsA);
    gat_attn_k<<<dim3(rowsA, 1), 128, 0, stream>>>(Wh2, CDq, CDq, adjacency,
                                                   esrc, edst, avp, CDq);

    // 8. av = leaky(avp @ Wcomp_W + b)
    run_gemm(stream, 1, false, rowsA, LDq, CDq, avp, CDq, 0,
             Wcomp_W, LDq, 0, Wcomp_b, av, LDq, 0, 1);
    cvt_bf16_k<<<(rowsA*LDq/4 + 255)/256, 256, 0, stream>>>(av, av_bf, (long long)rowsA*LDq/4);

    // 9. pv0 = amino_emb @ prot_W + b  -> MFMA (AF32 A-operand, N padded to 48)
    mfma_nt_k<0, 0, 1, 3, 1><<<dim3(rowsP/64, 1, 1), 256, 0, stream>>>(
        rowsP, 48, 1024, 40,
        (const void*)amino_emb, 1024, 0,
        protWt_bf, 1024, 0,
        prot_b, c0, PDq, 0, nullptr, nullptr);

    // 10. 3x conv 11x11 + leaky
    {
        long long total = (long long)Bq*Mq*PDq;
        int blocks = (int)((total + 255) / 256);
        conv_k<<<blocks, 256, 0, stream>>>(c0, conv_W + 0*121, conv_b + 0, c1);
        conv_k<<<blocks, 256, 0, stream>>>(c1, conv_W + 1*121, conv_b + 1, c0);
        conv_k<<<blocks, 256, 0, stream>>>(c0, conv_W + 2*121, conv_b + 2, c1);
    }

    // 11. pv = leaky(x @ Wprot_W + b)  (K=40, keep fp32)
    run_gemm(stream, 1, false, rowsP, LDq, PDq, c1, PDq, 0,
             Wprot_W, LDq, 0, Wprot_b, pv, LDq, 0, 1);
    cvt_bf16_k<<<(rowsP*LDq/4 + 255)/256, 256, 0, stream>>>(pv, pv_bf, (long long)rowsP*LDq/4);

    // 12. BIDAT loop
    for (int i = 0; i < 4; i++) {
        const ushort_t* UtI    = Ut_bf    + (long long)i*LDq*LDq;
        const ushort_t* tp2cTI = tp2cT_bf + (long long)i*LDq*LDq;
        const ushort_t* tc2pTI = tc2pT_bf + (long long)i*LDq*LDq;
        const ushort_t* bhcTI  = bhcT_bf  + (long long)i*LDq*LDq;
        const ushort_t* bhpTI  = bhpT_bf  + (long long)i*LDq*LDq;
        const float* tp2cbi  = tp2c_b + (long long)i*LDq;
        const float* tc2pbi  = tc2p_b + (long long)i*LDq;
        const float* bhcbi   = bhc_b  + (long long)i*LDq;
        const float* bhpbi   = bhp_b  + (long long)i*LDq;
        const float* battcWi = battc_W+ (long long)i*2*LDq;
        const float* battcbi = battc_b+ i;
        const float* battpWi = battp_W+ (long long)i*2*LDq;
        const float* battpbi = battp_b+ i;

        // avU = av @ U[i]
        mfma_nt_k<0, 0, 0, 16, 0><<<dim3(rowsA/64, 1, 1), 256, 0, stream>>>(
            rowsA, LDq, LDq, LDq, (const void*)av_bf, LDq, 0,
            UtI, LDq, 0, nullptr, bufU, LDq, 0, nullptr, nullptr);
        cvt_bf16_k<<<(rowsA*LDq/4 + 255)/256, 256, 0, stream>>>(bufU, avU_bf, (long long)rowsA*LDq/4);

        // A = tanh(avU @ pv^T) * masks   (batched, Bt = pv_bf rows)
        mfma_nt_k<2, 1, 0, 16, 0><<<dim3(Nq/64, Mq/256, Bq), 256, 0, stream>>>(
            Nq, Mq, LDq, Mq,
            (const void*)avU_bf, LDq, (long long)Nq*LDq,
            pv_bf, LDq, (long long)Mq*LDq,
            nullptr, Abuf, Mq, (long long)Nq*Mq,
            atoms_mask, amino_mask);

        // tp = tanh(pv @ tp2c_W + b) -> sx
        mfma_nt_k<2, 0, 1, 16, 0><<<dim3(rowsP/64, 1, 1), 256, 0, stream>>>(
            rowsP, LDq, LDq, LDq, (const void*)pv_bf, LDq, 0,
            tp2cTI, LDq, 0, tp2cbi, sx, LDq, 0, nullptr, nullptr);
        rowdot_k<<<rowsP, 256, 0, stream>>>(sx, battcWi + LDq, rbuf);

        // tc = tanh(av @ tc2p_W + b) -> bufTC
        mfma_nt_k<2, 0, 1, 16, 0><<<dim3(rowsA/64, 1, 1), 256, 0, stream>>>(
            rowsA, LDq, LDq, LDq, (const void*)av_bf, LDq, 0,
            tc2pTI, LDq, 0, tc2pbi, bufTC, LDq, 0, nullptr, nullptr);
        rowdot_k<<<rowsA, 256, 0, stream>>>(bufTC, battpWi + LDq, qbuf);

        // hb = tanh(av @ bhc_W + b) -> bufU (avU_bf already extracted)
        mfma_nt_k<2, 0, 1, 16, 0><<<dim3(rowsA/64, 1, 1), 256, 0, stream>>>(
            rowsA, LDq, LDq, LDq, (const void*)av_bf, LDq, 0,
            bhcTI, LDq, 0, bhcbi, bufU, LDq, 0, nullptr, nullptr);

        // hpb = tanh(pv @ bhp_W + b) -> sx (tp consumed by rowdot)
        mfma_nt_k<2, 0, 1, 16, 0><<<dim3(rowsP/64, 1, 1), 256, 0, stream>>>(
            rowsP, LDq, LDq, LDq, (const void*)pv_bf, LDq, 0,
            bhpTI, LDq, 0, bhpbi, sx, LDq, 0, nullptr, nullptr);

        // csum[b,m] = sum_n A[b,n,m]*q[b,n]
        colsum_k<<<dim3(Mq/256, Bq), 256, 0, stream>>>(Abuf, qbuf, csum);
        // attention scores
        scoreC_k<<<rowsA, 256, 0, stream>>>(bufU, Abuf, rbuf, battcWi, battcbi, scoreC);
        scoreP_k<<<rowsP, 256, 0, stream>>>(sx, csum, battpWi, battpbi, scoreP);
        // masked softmax
        msoftmax_k<<<Bq, 256, 0, stream>>>(scoreC, atoms_mask, Nq);
        msoftmax_k<<<Bq, 256, 0, stream>>>(scoreP, amino_mask, Mq);
        // pooled features
        wsum1_k<<<dim3(Bq, 16), 256, 0, stream>>>(av, scoreC, wpart, Nq);
        wsum2_k<<<Bq, 256, 0, stream>>>(wpart, cf + (long long)i*LDq, 4*LDq);
        wsum1_k<<<dim3(Bq, 16), 256, 0, stream>>>(pv, scoreP, wpart, Mq);
        wsum2_k<<<Bq, 256, 0, stream>>>(wpart, pf + (long long)i*LDq, 4*LDq);
    }

    // 13. head: per-layer skinny kernels (416/128 blocks), high TLP
    headlin_k<0><<<dim3(Bq, 4), 256, 0, stream>>>(cf, 4*LDq, 4*LDq,
        combc_W, LDq, combc_b, v1, 770, LDq, 0);
    headlin_k<0><<<dim3(Bq, 4), 256, 0, stream>>>(pf, 4*LDq, 4*LDq,
        combp_W, LDq, combp_b, v1, 770, LDq, 512);
    vfill_k<<<Bq, 256, 0, stream>>>(fps, inv_Temp, Temp, v1);

    headlin_k<1><<<dim3(Bq, 13), 256, 0, stream>>>(v1, 770, 770,
        Wout_W + 0ll*770*770, 770, Wout_b + 0*770, v2, 770, 770, 0);
    headlin_k<1><<<dim3(Bq, 13), 256, 0, stream>>>(v2, 770, 770,
        Wout_W + 1ll*770*770, 770, Wout_b + 1*770, v1, 770, 770, 0);
    headlin_k<1><<<dim3(Bq, 13), 256, 0, stream>>>(v1, 770, 770,
        Wout_W + 2ll*770*770, 770, Wout_b + 2*770, v2, 770, 770, 0);

    final_k<<<Bq, 256, 0, stream>>>(v2, out_W, out_b, out);

    (void)in_sizes; (void)n_in; (void)out_size; (void)ws_size;
}

// Round 7
// 1623.143 us; speedup vs baseline: 2.5074x; 1.2366x over previous
//
#include <hip/hip_runtime.h>
#include <math.h>

#define ALPHA_LR 0.2f

#define Bq  32
#define Nq  128
#define Mq  1024
#define CDq 128
#define GDq 64
#define NHq 4
#define LDq 256
#define PDq 40

typedef unsigned short ushort_t;
typedef __attribute__((ext_vector_type(8))) short bf16x8;
typedef __attribute__((ext_vector_type(4))) float f32x4;

__device__ __forceinline__ ushort_t f2bf(float f) {
    union { float f; unsigned u; } x; x.f = f;
    unsigned r = x.u + 0x7FFFu + ((x.u >> 16) & 1u);   // RNE
    return (ushort_t)(r >> 16);
}

// ---------------------------------------------------------------------------
// MFMA bf16 NT GEMM: C = act(A @ Bt^T + bias) [* masks]
// A: [M][lda] bf16 (or fp32 if AF32), Bt: [Npad][ldb] bf16 (= B^T, K-major)
// Each wave: 16 rows x NT*16 cols. grid.x = M/64 (4 waves/block),
// grid.y = N/(NT*16), grid.z = batch. K % 32 == 0. M % 16 == 0.
// C/D layout (m89-verified): col = lane&15, row = (lane>>4)*4 + reg.
// REDUCE=1 (requires NT*16==N, grid.y==1, MASKED=0, ACT=2): instead of
// storing the tile, computes out[row] = sum_col tanh(val+bias[col])*w2[col]
// via in-wave shfl_xor reduction; w2 passed in maskR; C is out[M].
// (r7: the 4 tanh GEMMs are each consumed only as a dot with a fixed vector
//  — materializing 33.5 MB to reduce it to 128 KB was the r6 bottleneck.)
// ---------------------------------------------------------------------------
template<int ACT, int MASKED, int HAS_BIAS, int NT, int AF32, int REDUCE = 0>
__global__ __launch_bounds__(256) void mfma_nt_k(
    int M, int N, int K, int Nout,
    const void* __restrict__ Av, int lda, long long sA,
    const ushort_t* __restrict__ Bt, int ldb, long long sB,
    const float* __restrict__ bias,
    float* __restrict__ C, int ldc, long long sC,
    const float* __restrict__ maskR, const float* __restrict__ maskC)
{
    int z = blockIdx.z;
    Bt += (long long)z * sB;
    C  += (long long)z * sC;

    int wave = threadIdx.x >> 6;
    int lane = threadIdx.x & 63;
    int lr = lane & 15;
    int kg = lane >> 4;
    int m0 = (blockIdx.x * 4 + wave) * 16;
    int n0 = blockIdx.y * (NT * 16);
    if (m0 >= M) return;

    f32x4 acc[NT];
    #pragma unroll
    for (int t = 0; t < NT; t++) acc[t] = (f32x4){0.f, 0.f, 0.f, 0.f};

    const ushort_t* Ab = nullptr;
    const float*    Af = nullptr;
    if (AF32) Af = (const float*)Av + (long long)z * sA + (long long)(m0 + lr) * lda + kg * 8;
    else      Ab = (const ushort_t*)Av + (long long)z * sA + (long long)(m0 + lr) * lda + kg * 8;
    const ushort_t* Bbase = Bt + (long long)(n0 + lr) * ldb + kg * 8;

    for (int k0 = 0; k0 < K; k0 += 32) {
        bf16x8 a;
        if (AF32) {
            float4 a0 = *(const float4*)(Af + k0);
            float4 a1 = *(const float4*)(Af + k0 + 4);
            a[0] = (short)f2bf(a0.x); a[1] = (short)f2bf(a0.y);
            a[2] = (short)f2bf(a0.z); a[3] = (short)f2bf(a0.w);
            a[4] = (short)f2bf(a1.x); a[5] = (short)f2bf(a1.y);
            a[6] = (short)f2bf(a1.z); a[7] = (short)f2bf(a1.w);
        } else {
            a = *(const bf16x8*)(Ab + k0);
        }
        #pragma unroll
        for (int t = 0; t < NT; t++) {
            bf16x8 b = *(const bf16x8*)(Bbase + (long long)t * 16 * ldb + k0);
            acc[t] = __builtin_amdgcn_mfma_f32_16x16x32_bf16(a, b, acc[t], 0, 0, 0);
        }
    }

    if (REDUCE) {
        const float* w2 = maskR;
        float rs[4] = {0.f, 0.f, 0.f, 0.f};
        #pragma unroll
        for (int t = 0; t < NT; t++) {
            int col = n0 + t * 16 + lr;
            float bv = HAS_BIAS ? bias[col] : 0.f;
            float wv = w2[col];
            #pragma unroll
            for (int r = 0; r < 4; r++)
                rs[r] += tanhf(acc[t][r] + bv) * wv;
        }
        #pragma unroll
        for (int r = 0; r < 4; r++) {
            rs[r] += __shfl_xor(rs[r], 1, 64);
            rs[r] += __shfl_xor(rs[r], 2, 64);
            rs[r] += __shfl_xor(rs[r], 4, 64);
            rs[r] += __shfl_xor(rs[r], 8, 64);
        }
        if (lr == 0) {
            int row0 = m0 + kg * 4;
            #pragma unroll
            for (int r = 0; r < 4; r++)
                C[row0 + r] = rs[r];
        }
        return;
    }

    int row0 = m0 + kg * 4;
    #pragma unroll
    for (int t = 0; t < NT; t++) {
        int col = n0 + t * 16 + lr;
        if (col >= Nout) continue;
        float bv = HAS_BIAS ? bias[col] : 0.f;
        float mC = MASKED ? maskC[(long long)z * N + col] : 1.f;
        #pragma unroll
        for (int r = 0; r < 4; r++) {
            float v = acc[t][r] + bv;
            if (ACT == 1) v = v > 0.f ? v : ALPHA_LR * v;
            else if (ACT == 2) v = tanhf(v);
            if (MASKED) v *= maskR[(long long)z * M + row0 + r] * mC;
            C[(long long)(row0 + r) * ldc + col] = v;
        }
    }
}

// fp32 -> bf16, 4 elems/thread, n % 4 == 0
__global__ __launch_bounds__(256) void cvt_bf16_k(
    const float* __restrict__ in, ushort_t* __restrict__ out, long long n4)
{
    long long i = (long long)blockIdx.x * 256 + threadIdx.x;
    if (i >= n4) return;
    float4 v = ((const float4*)in)[i];
    ushort4 o;
    o.x = f2bf(v.x); o.y = f2bf(v.y); o.z = f2bf(v.z); o.w = f2bf(v.w);
    ((ushort4*)out)[i] = o;
}

// W[K][Nsrc] fp32 -> Wt[Npad][Kp] bf16 (transposed, zero-padded), batched z
__global__ __launch_bounds__(256) void wtcvt_k(
    const float* __restrict__ W, ushort_t* __restrict__ Wt,
    int K, int Nsrc, int Npad, int Kp)
{
    int z = blockIdx.z;
    const float* Wz = W + (long long)z * K * Nsrc;
    ushort_t* Oz = Wt + (long long)z * Npad * Kp;
    int idx = blockIdx.x * 256 + threadIdx.x;
    if (idx >= Npad * Kp) return;
    int n = idx / Kp, k = idx % Kp;
    float v = (k < K && n < Nsrc) ? Wz[(long long)k * Nsrc + n] : 0.f;
    Oz[idx] = f2bf(v);
}

// ---------------------------------------------------------------------------
// Generic tiled fp32 GEMM (kept for small/odd-K GEMMs)
// ---------------------------------------------------------------------------
template<int ACT, int TA, int TB, int MASKED>
__global__ __launch_bounds__(256) void gemm_k(
    int M, int N, int K,
    const float* __restrict__ A, int lda, long long sA,
    const float* __restrict__ Bm, int ldb, long long sB,
    const float* __restrict__ bias,
    float* __restrict__ C, int ldc, long long sC,
    const float* __restrict__ maskR, const float* __restrict__ maskC)
{
    int z = blockIdx.z;
    A  += (long long)z * sA;
    Bm += (long long)z * sB;
    C  += (long long)z * sC;

    __shared__ float As[16][68];
    __shared__ float Bs[16][68];

    int tid = threadIdx.x;
    int tx = tid % 16, ty = tid / 16;
    int m0 = blockIdx.y * 64, n0 = blockIdx.x * 64;

    float acc[4][4] = {};

    for (int k0 = 0; k0 < K; k0 += 16) {
        if (!TA) {
            int k = tid % 16, mBase = tid / 16;
            #pragma unroll
            for (int p = 0; p < 4; p++) {
                int m = mBase + p * 16;
                int gm = m0 + m, gk = k0 + k;
                float v = 0.f;
                if (gm < M && gk < K) v = A[(long long)gm * lda + gk];
                As[k][m] = v;
            }
        } else {
            int m = tid % 64, kBase = tid / 64;
            #pragma unroll
            for (int p = 0; p < 4; p++) {
                int k = kBase + p * 4;
                int gm = m0 + m, gk = k0 + k;
                float v = 0.f;
                if (gm < M && gk < K) v = A[(long long)gk * lda + gm];
                As[k][m] = v;
            }
        }
        if (!TB) {
            int n = tid % 64, kBase = tid / 64;
            #pragma unroll
            for (int p = 0; p < 4; p++) {
                int k = kBase + p * 4;
                int gn = n0 + n, gk = k0 + k;
                float v = 0.f;
                if (gn < N && gk < K) v = Bm[(long long)gk * ldb + gn];
                Bs[k][n] = v;
            }
        } else {
            int k = tid % 16, nBase = tid / 16;
            #pragma unroll
            for (int p = 0; p < 4; p++) {
                int n = nBase + p * 16;
                int gn = n0 + n, gk = k0 + k;
                float v = 0.f;
                if (gn < N && gk < K) v = Bm[(long long)gn * ldb + gk];
                Bs[k][n] = v;
            }
        }
        __syncthreads();
        #pragma unroll
        for (int kk = 0; kk < 16; kk++) {
            float a[4], b[4];
            #pragma unroll
            for (int i = 0; i < 4; i++) a[i] = As[kk][ty * 4 + i];
            #pragma unroll
            for (int j = 0; j < 4; j++) b[j] = Bs[kk][tx * 4 + j];
            #pragma unroll
            for (int i = 0; i < 4; i++)
                #pragma unroll
                for (int j = 0; j < 4; j++)
                    acc[i][j] += a[i] * b[j];
        }
        __syncthreads();
    }

    #pragma unroll
    for (int i = 0; i < 4; i++) {
        int gm = m0 + ty * 4 + i;
        if (gm >= M) continue;
        #pragma unroll
        for (int j = 0; j < 4; j++) {
            int gn = n0 + tx * 4 + j;
            if (gn >= N) continue;
            float v = acc[i][j];
            if (bias) v += bias[gn];
            if (ACT == 1) v = v > 0.f ? v : ALPHA_LR * v;
            else if (ACT == 2) v = tanhf(v);
            if (MASKED) v *= maskR[(long long)z * M + gm] * maskC[(long long)z * N + gn];
            C[(long long)gm * ldc + gn] = v;
        }
    }
}

static inline void run_gemm(hipStream_t stream, int act, bool tb_masked,
    int M, int N, int K,
    const float* A, int lda, long long sA,
    const float* B, int ldb, long long sB,
    const float* bias, float* C, int ldc, long long sC,
    int batch, const float* maskR = nullptr, const float* maskC = nullptr)
{
    dim3 grid((N + 63) / 64, (M + 63) / 64, batch);
    dim3 blk(256);
    if (tb_masked) {
        gemm_k<2, 0, 1, 1><<<grid, blk, 0, stream>>>(M, N, K, A, lda, sA, B, ldb, sB,
                                                     bias, C, ldc, sC, maskR, maskC);
    } else if (act == 0) {
        gemm_k<0, 0, 0, 0><<<grid, blk, 0, stream>>>(M, N, K, A, lda, sA, B, ldb, sB,
                                                     bias, C, ldc, sC, nullptr, nullptr);
    } else if (act == 1) {
        gemm_k<1, 0, 0, 0><<<grid, blk, 0, stream>>>(M, N, K, A, lda, sA, B, ldb, sB,
                                                     bias, C, ldc, sC, nullptr, nullptr);
    } else {
        gemm_k<2, 0, 0, 0><<<grid, blk, 0, stream>>>(M, N, K, A, lda, sA, B, ldb, sB,
                                                     bias, C, ldc, sC, nullptr, nullptr);
    }
}

// per-row GAT source/dest attention logits
__global__ __launch_bounds__(128) void gat_e_k(
    const float* __restrict__ Wh, int ldWh, int GD,
    const float* __restrict__ a, int aStride,
    float* __restrict__ esrc, float* __restrict__ edst, int rows)
{
    int row = blockIdx.x;
    int k = blockIdx.y;
    int g = threadIdx.x;
    float ws = 0.f, wd = 0.f;
    if (g < GD) {
        float wv = Wh[(long long)row * ldWh + k * GD + g];
        ws = wv * a[k * aStride + g];
        wd = wv * a[k * aStride + GD + g];
    }
    __shared__ float sb[2][128];
    sb[0][threadIdx.x] = ws; sb[1][threadIdx.x] = wd;
    __syncthreads();
    for (int off = 64; off > 0; off >>= 1) {
        if (threadIdx.x < off) {
            sb[0][threadIdx.x] += sb[0][threadIdx.x + off];
            sb[1][threadIdx.x] += sb[1][threadIdx.x + off];
        }
        __syncthreads();
    }
    if (threadIdx.x == 0) {
        esrc[(long long)k * rows + row] = sb[0][0];
        edst[(long long)k * rows + row] = sb[1][0];
    }
}

// GAT attention: softmax over neighbors + weighted sum + ELU
__global__ __launch_bounds__(128) void gat_attn_k(
    const float* __restrict__ Wh, int ldWh, int GD,
    const int* __restrict__ adj,
    const float* __restrict__ esrc, const float* __restrict__ edst,
    float* __restrict__ out, int ldOut)
{
    int row = blockIdx.x;          // b*N + n
    int k = blockIdx.y;
    int rows = gridDim.x;
    int b = row / Nq, n = row % Nq;
    int m = threadIdx.x;

    __shared__ float att[Nq];
    __shared__ float red[Nq];

    float e = esrc[(long long)k * rows + row] + edst[(long long)k * rows + b * Nq + m];
    e = e > 0.f ? e : ALPHA_LR * e;
    if (adj[(long long)b * Nq * Nq + n * Nq + m] <= 0) e = -9.0e15f;

    red[m] = e; __syncthreads();
    for (int off = 64; off > 0; off >>= 1) {
        if (m < off) red[m] = fmaxf(red[m], red[m + off]);
        __syncthreads();
    }
    float mx = red[0]; __syncthreads();
    float ex = expf(e - mx);
    att[m] = ex; red[m] = ex; __syncthreads();
    for (int off = 64; off > 0; off >>= 1) {
        if (m < off) red[m] += red[m + off];
        __syncthreads();
    }
    float inv = 1.0f / red[0];

    for (int g = threadIdx.x; g < GD; g += blockDim.x) {
        float s = 0.f;
        for (int mm = 0; mm < Nq; mm++)
            s += att[mm] * Wh[(long long)(b * Nq + mm) * ldWh + k * GD + g];
        s *= inv;
        s = s > 0.f ? s : expm1f(s);   // ELU
        out[(long long)row * ldOut + k * GD + g] = s;
    }
}

// 11x11 same-pad conv over (M, PD), single channel, + leaky
__global__ __launch_bounds__(256) void conv_k(
    const float* __restrict__ x, const float* __restrict__ W,
    const float* __restrict__ bptr, float* __restrict__ y)
{
    __shared__ float w[121];
    if (threadIdx.x < 121) w[threadIdx.x] = W[threadIdx.x];
    __syncthreads();
    long long idx = (long long)blockIdx.x * blockDim.x + threadIdx.x;
    long long total = (long long)Bq * Mq * PDq;
    if (idx >= total) return;
    int d = (int)(idx % PDq);
    long long t = idx / PDq;
    int m = (int)(t % Mq);
    int b = (int)(t / Mq);
    const float* xb = x + (long long)b * Mq * PDq;
    float s = 0.f;
    #pragma unroll
    for (int i = 0; i < 11; i++) {
        int mm = m + i - 5;
        if (mm < 0 || mm >= Mq) continue;
        #pragma unroll
        for (int j = 0; j < 11; j++) {
            int dd = d + j - 5;
            if (dd < 0 || dd >= PDq) continue;
            s += xb[(long long)mm * PDq + dd] * w[i * 11 + j];
        }
    }
    s += *bptr;
    y[idx] = s > 0.f ? s : ALPHA_LR * s;
}

// out[b,m] = sum_n A[b,n,m] * q[b,n]
__global__ __launch_bounds__(256) void colsum_k(
    const float* __restrict__ A, const float* __restrict__ q, float* __restrict__ out)
{
    int b = blockIdx.y;
    int m = blockIdx.x * 256 + threadIdx.x;
    const float* Ab = A + (long long)b * Nq * Mq;
    const float* qb = q + (long long)b * Nq;
    float s = 0.f;
    for (int n = 0; n < Nq; n++) s += Ab[(long long)n * Mq + m] * qb[n];
    out[(long long)b * Mq + m] = s;
}

// score_c[row=b*N+n] = hbdot[row] + A[b,n,:]·r[b,:] + bias
__global__ __launch_bounds__(256) void scoreC_k(
    const float* __restrict__ hbdot, const float* __restrict__ A,
    const float* __restrict__ r,
    const float* __restrict__ bptr, float* __restrict__ score)
{
    int row = blockIdx.x;
    int b = row / Nq;
    int t = threadIdx.x;
    const float* Ar = A + (long long)row * Mq;
    const float* rb = r + (long long)b * Mq;
    float s = 0.f;
    for (int m = t; m < Mq; m += 256) s += Ar[m] * rb[m];
    __shared__ float red[256];
    red[t] = s; __syncthreads();
    for (int off = 128; off > 0; off >>= 1) {
        if (t < off) red[t] += red[t + off];
        __syncthreads();
    }
    if (t == 0) score[row] = red[0] + hbdot[row] + bptr[0];
}

// score_p[i] = hpbdot[i] + csum[i] + bias  (elementwise over rowsP)
__global__ __launch_bounds__(256) void scorePadd_k(
    float* __restrict__ score, const float* __restrict__ csum,
    const float* __restrict__ bptr)
{
    int i = blockIdx.x * 256 + threadIdx.x;
    score[i] = score[i] + csum[i] + bptr[0];
}

// masked softmax in place over L, one block per batch row
__global__ __launch_bounds__(256) void msoftmax_k(
    float* __restrict__ score, const float* __restrict__ mask, int L)
{
    int b = blockIdx.x;
    float* s = score + (long long)b * L;
    const float* mk = mask + (long long)b * L;
    int t = threadIdx.x;
    __shared__ float red[256];
    float mx = -1e30f;
    for (int i = t; i < L; i += 256) mx = fmaxf(mx, s[i]);
    red[t] = mx; __syncthreads();
    for (int off = 128; off > 0; off >>= 1) {
        if (t < off) red[t] = fmaxf(red[t], red[t + off]);
        __syncthreads();
    }
    mx = red[0]; __syncthreads();
    float sum = 0.f;
    for (int i = t; i < L; i += 256) {
        float e = expf(s[i] - mx) * mk[i];
        s[i] = e; sum += e;
    }
    red[t] = sum; __syncthreads();
    for (int off = 128; off > 0; off >>= 1) {
        if (t < off) red[t] += red[t + off];
        __syncthreads();
    }
    float inv = 1.0f / (red[0] + 1e-6f);
    __syncthreads();
    for (int i = t; i < L; i += 256) s[i] *= inv;
}

// weighted sum stage 1: partial over 16 chunks
__global__ __launch_bounds__(256) void wsum1_k(
    const float* __restrict__ feat, const float* __restrict__ att,
    float* __restrict__ partial, int L)
{
    int b = blockIdx.x, c = blockIdx.y, l = threadIdx.x;
    int chunk = L / 16;
    const float* fb = feat + (long long)b * L * LDq;
    const float* ab = att + (long long)b * L;
    float s = 0.f;
    int r0 = c * chunk, r1 = r0 + chunk;
    for (int r = r0; r < r1; r++) s += fb[(long long)r * LDq + l] * ab[r];
    partial[((long long)b * 16 + c) * LDq + l] = s;
}

// weighted sum stage 2
__global__ __launch_bounds__(256) void wsum2_k(
    const float* __restrict__ partial, float* __restrict__ out, int outStride)
{
    int b = blockIdx.x, l = threadIdx.x;
    float s = 0.f;
    #pragma unroll
    for (int c = 0; c < 16; c++) s += partial[((long long)b * 16 + c) * LDq + l];
    out[(long long)b * outStride + l] = s;
}

// ---------------------------------------------------------------------------
// Skinny dense layer for the head:
//   vout[b, colBase+col] = act(sum_k vin[b,k]*W[k*ldw+col] + bias[col])
// grid = (B, ceil(OD/64)); block = 256 = 64 cols x 4 k-slices.
// ---------------------------------------------------------------------------
template<int ACT>
__global__ __launch_bounds__(256) void headlin_k(
    const float* __restrict__ vin, int ldv, int VD,
    const float* __restrict__ W, int ldw,
    const float* __restrict__ bias,
    float* __restrict__ vout, int ldo, int OD, int colBase)
{
    int b = blockIdx.x;
    int c = threadIdx.x & 63;
    int s = threadIdx.x >> 6;
    int col = blockIdx.y * 64 + c;

    __shared__ float vs[1024];
    for (int i = threadIdx.x; i < VD; i += 256) vs[i] = vin[(long long)b * ldv + i];
    __syncthreads();

    float sum = 0.f;
    if (col < OD) {
        int k0 = (VD * s) >> 2, k1 = (VD * (s + 1)) >> 2;
        #pragma unroll 4
        for (int k = k0; k < k1; k++)
            sum += vs[k] * W[(long long)k * ldw + col];
    }
    __shared__ float red[4][64];
    red[s][c] = sum;
    __syncthreads();
    if (s == 0 && col < OD) {
        float t = red[0][c] + red[1][c] + red[2][c] + red[3][c] + bias[col];
        if (ACT == 1) t = t > 0.f ? t : ALPHA_LR * t;
        vout[(long long)b * ldo + colBase + col] = t;
    }
}

// v[b,256:512]=fps, v[b,768]=invT, v[b,769]=T
__global__ __launch_bounds__(256) void vfill_k(
    const float* __restrict__ fps, const float* __restrict__ invT,
    const float* __restrict__ T, float* __restrict__ v)
{
    int b = blockIdx.x, t = threadIdx.x;
    v[(long long)b * 770 + 256 + t] = fps[(long long)b * 256 + t];
    if (t == 0) {
        v[(long long)b * 770 + 768] = invT[b];
        v[(long long)b * 770 + 769] = T[b];
    }
}

// out[b] = v[b,:770]·W + b
__global__ __launch_bounds__(256) void final_k(
    const float* __restrict__ v, const float* __restrict__ W,
    const float* __restrict__ bptr, float* __restrict__ out)
{
    int b = blockIdx.x, t = threadIdx.x;
    float s = 0.f;
    for (int i = t; i < 770; i += 256) s += v[(long long)b * 770 + i] * W[i];
    __shared__ float red[256];
    red[t] = s; __syncthreads();
    for (int off = 128; off > 0; off >>= 1) {
        if (t < off) red[t] += red[t + off];
        __syncthreads();
    }
    if (t == 0) out[b] = red[0] + bptr[0];
}

extern "C" void kernel_launch(void* const* d_in, const int* in_sizes, int n_in,
                              void* d_out, int out_size, void* d_ws, size_t ws_size,
                              hipStream_t stream)
{
    const float* atoms_emb = (const float*)d_in[0];
    const int*   adjacency = (const int*)d_in[1];
    const float* atoms_mask= (const float*)d_in[2];
    const float* amino_emb = (const float*)d_in[3];
    const float* amino_mask= (const float*)d_in[4];
    const float* fps       = (const float*)d_in[5];
    const float* inv_Temp  = (const float*)d_in[6];
    const float* Temp      = (const float*)d_in[7];
    const float* bert_W    = (const float*)d_in[8];
    const float* bert_b    = (const float*)d_in[9];
    const float* gat_W     = (const float*)d_in[10];
    const float* gat_a     = (const float*)d_in[11];
    const float* gatout_W  = (const float*)d_in[12];
    const float* gatout_a  = (const float*)d_in[13];
    const float* Wcomp_W   = (const float*)d_in[14];
    const float* Wcomp_b   = (const float*)d_in[15];
    const float* prot_W    = (const float*)d_in[16];
    const float* prot_b    = (const float*)d_in[17];
    const float* conv_W    = (const float*)d_in[18];
    const float* conv_b    = (const float*)d_in[19];
    const float* Wprot_W   = (const float*)d_in[20];
    const float* Wprot_b   = (const float*)d_in[21];
    const float* U         = (const float*)d_in[22];
    const float* tc2p_W    = (const float*)d_in[23];
    const float* tc2p_b    = (const float*)d_in[24];
    const float* tp2c_W    = (const float*)d_in[25];
    const float* tp2c_b    = (const float*)d_in[26];
    const float* bhc_W     = (const float*)d_in[27];
    const float* bhc_b     = (const float*)d_in[28];
    const float* bhp_W     = (const float*)d_in[29];
    const float* bhp_b     = (const float*)d_in[30];
    const float* battc_W   = (const float*)d_in[31];
    const float* battc_b   = (const float*)d_in[32];
    const float* battp_W   = (const float*)d_in[33];
    const float* battp_b   = (const float*)d_in[34];
    const float* combc_W   = (const float*)d_in[35];
    const float* combc_b   = (const float*)d_in[36];
    const float* combp_W   = (const float*)d_in[37];
    const float* combp_b   = (const float*)d_in[38];
    const float* Wout_W    = (const float*)d_in[39];
    const float* Wout_b    = (const float*)d_in[40];
    const float* out_W     = (const float*)d_in[41];
    const float* out_b     = (const float*)d_in[42];
    float* out = (float*)d_out;

    // ---- workspace layout (floats) ----
    float* w = (float*)d_ws;
    float* av    = w; w += (long long)Bq*Nq*LDq;
    float* pv    = w; w += (long long)Bq*Mq*LDq;
    float* sx    = w; w += (long long)Bq*Mq*LDq;   // early-phase scratch only
    float* Abuf  = w; w += (long long)Bq*Nq*Mq;
    float* bufU  = w; w += (long long)Bq*Nq*LDq;   // avU fp32
    float* bufTC = w; w += (long long)Bq*Nq*LDq;   // wsum partials
    float* esrc  = w; w += (long long)NHq*Bq*Nq;   // GAT logits -> hbdot
    float* edst  = w; w += (long long)NHq*Bq*Nq;
    float* scoreC= w; w += (long long)Bq*Nq;
    float* scoreP= w; w += (long long)Bq*Mq;       // hpbdot lands here directly
    float* rbuf  = w; w += (long long)Bq*Mq;
    float* qbuf  = w; w += (long long)Bq*Nq;
    float* csum  = w; w += (long long)Bq*Mq;
    float* cf    = w; w += (long long)Bq*4*LDq;
    float* pf    = w; w += (long long)Bq*4*LDq;
    float* v1    = w; w += (long long)Bq*770;
    float* v2    = w; w += (long long)Bq*770;
    // bf16 buffers (carved as float-space, used as ushort)
    ushort_t* pv_bf  = (ushort_t*)w; w += (long long)Bq*Mq*LDq/2;
    ushort_t* av_bf  = (ushort_t*)w; w += (long long)Bq*Nq*LDq/2;
    ushort_t* avU_bf = (ushort_t*)w; w += (long long)Bq*Nq*LDq/2;
    ushort_t* Ut_bf    = (ushort_t*)w; w += (long long)4*LDq*LDq/2;
    ushort_t* tp2cT_bf = (ushort_t*)w; w += (long long)4*LDq*LDq/2;
    ushort_t* tc2pT_bf = (ushort_t*)w; w += (long long)4*LDq*LDq/2;
    ushort_t* bhcT_bf  = (ushort_t*)w; w += (long long)4*LDq*LDq/2;
    ushort_t* bhpT_bf  = (ushort_t*)w; w += (long long)4*LDq*LDq/2;
    ushort_t* protWt_bf= (ushort_t*)w; w += (long long)48*1024/2;

    // early-phase aliases inside sx (dead before BIDAT loop)
    float* h     = sx;
    float* WhAll = h + (long long)Bq*Nq*CDq;
    float* multi = WhAll + (long long)Bq*Nq*NHq*GDq;
    float* Wh2   = multi + (long long)Bq*Nq*NHq*GDq;
    float* avp   = Wh2 + (long long)Bq*Nq*CDq;
    float* c0    = avp + (long long)Bq*Nq*CDq;
    float* c1    = c0 + (long long)Bq*Mq*PDq;

    float* wpart = bufTC;   // wsum partials
    float* hbdot = esrc;    // rowsA floats; esrc dead after GAT phase

    int rowsA = Bq * Nq;     // 4096
    int rowsP = Bq * Mq;     // 32768

    // ---- weight transpose-converts (once) ----
    wtcvt_k<<<dim3(256, 1, 4), 256, 0, stream>>>(U,      Ut_bf,    LDq, LDq, LDq, LDq);
    wtcvt_k<<<dim3(256, 1, 4), 256, 0, stream>>>(tp2c_W, tp2cT_bf, LDq, LDq, LDq, LDq);
    wtcvt_k<<<dim3(256, 1, 4), 256, 0, stream>>>(tc2p_W, tc2pT_bf, LDq, LDq, LDq, LDq);
    wtcvt_k<<<dim3(256, 1, 4), 256, 0, stream>>>(bhc_W,  bhcT_bf,  LDq, LDq, LDq, LDq);
    wtcvt_k<<<dim3(256, 1, 4), 256, 0, stream>>>(bhp_W,  bhpT_bf,  LDq, LDq, LDq, LDq);
    wtcvt_k<<<dim3((48*1024+255)/256, 1, 1), 256, 0, stream>>>(prot_W, protWt_bf, 1024, 40, 48, 1024);

    // 1. h = atoms_emb @ bert_W + bert_b   (K=300, fp32)
    run_gemm(stream, 0, false, rowsA, CDq, 300, atoms_emb, 300, 0,
             bert_W, CDq, 0, bert_b, h, CDq, 0, 1);

    // 2. Wh_all = h @ gat_W[k] (batched heads)
    run_gemm(stream, 0, false, rowsA, GDq, CDq, h, CDq, 0,
             gat_W, GDq, (long long)CDq*GDq, nullptr,
             WhAll, NHq*GDq, GDq, NHq);

    // 3-4. GAT heads -> multi (ELU)
    gat_e_k<<<dim3(rowsA, NHq), 128, 0, stream>>>(WhAll, NHq*GDq, GDq, gat_a, 2*GDq,
                                                  esrc, edst, rowsA);
    gat_attn_k<<<dim3(rowsA, NHq), 128, 0, stream>>>(WhAll, NHq*GDq, GDq, adjacency,
                                                     esrc, edst, multi, NHq*GDq);

    // 5-7. GAT out layer -> avp (ELU)
    run_gemm(stream, 0, false, rowsA, CDq, NHq*GDq, multi, NHq*GDq, 0,
             gatout_W, CDq, 0, nullptr, Wh2, CDq, 0, 1);
    gat_e_k<<<dim3(rowsA, 1), 128, 0, stream>>>(Wh2, CDq, CDq, gatout_a, 2*CDq,
                                                esrc, edst, rowsA);
    gat_attn_k<<<dim3(rowsA, 1), 128, 0, stream>>>(Wh2, CDq, CDq, adjacency,
                                                   esrc, edst, avp, CDq);

    // 8. av = leaky(avp @ Wcomp_W + b)
    run_gemm(stream, 1, false, rowsA, LDq, CDq, avp, CDq, 0,
             Wcomp_W, LDq, 0, Wcomp_b, av, LDq, 0, 1);
    cvt_bf16_k<<<(rowsA*LDq/4 + 255)/256, 256, 0, stream>>>(av, av_bf, (long long)rowsA*LDq/4);

    // 9. pv0 = amino_emb @ prot_W + b  -> MFMA (AF32 A-operand, N padded to 48)
    mfma_nt_k<0, 0, 1, 3, 1><<<dim3(rowsP/64, 1, 1), 256, 0, stream>>>(
        rowsP, 48, 1024, 40,
        (const void*)amino_emb, 1024, 0,
        protWt_bf, 1024, 0,
        prot_b, c0, PDq, 0, nullptr, nullptr);

    // 10. 3x conv 11x11 + leaky
    {
        long long total = (long long)Bq*Mq*PDq;
        int blocks = (int)((total + 255) / 256);
        conv_k<<<blocks, 256, 0, stream>>>(c0, conv_W + 0*121, conv_b + 0, c1);
        conv_k<<<blocks, 256, 0, stream>>>(c1, conv_W + 1*121, conv_b + 1, c0);
        conv_k<<<blocks, 256, 0, stream>>>(c0, conv_W + 2*121, conv_b + 2, c1);
    }

    // 11. pv = leaky(x @ Wprot_W + b)  (K=40, fp32)
    run_gemm(stream, 1, false, rowsP, LDq, PDq, c1, PDq, 0,
             Wprot_W, LDq, 0, Wprot_b, pv, LDq, 0, 1);
    cvt_bf16_k<<<(rowsP*LDq/4 + 255)/256, 256, 0, stream>>>(pv, pv_bf, (long long)rowsP*LDq/4);

    // 12. BIDAT loop
    for (int i = 0; i < 4; i++) {
        const ushort_t* UtI    = Ut_bf    + (long long)i*LDq*LDq;
        const ushort_t* tp2cTI = tp2cT_bf + (long long)i*LDq*LDq;
        const ushort_t* tc2pTI = tc2pT_bf + (long long)i*LDq*LDq;
        const ushort_t* bhcTI  = bhcT_bf  + (long long)i*LDq*LDq;
        const ushort_t* bhpTI  = bhpT_bf  + (long long)i*LDq*LDq;
        const float* tp2cbi  = tp2c_b + (long long)i*LDq;
        const float* tc2pbi  = tc2p_b + (long long)i*LDq;
        const float* bhcbi   = bhc_b  + (long long)i*LDq;
        const float* bhpbi   = bhp_b  + (long long)i*LDq;
        const float* battcWi = battc_W+ (long long)i*2*LDq;
        const float* battcbi = battc_b+ i;
        const float* battpWi = battp_W+ (long long)i*2*LDq;
        const float* battpbi = battp_b+ i;

        // avU = av @ U[i]   (NT=4: 256 blocks for occupancy)
        mfma_nt_k<0, 0, 0, 4, 0><<<dim3(rowsA/64, 4, 1), 256, 0, stream>>>(
            rowsA, LDq, LDq, LDq, (const void*)av_bf, LDq, 0,
            UtI, LDq, 0, nullptr, bufU, LDq, 0, nullptr, nullptr);
        cvt_bf16_k<<<(rowsA*LDq/4 + 255)/256, 256, 0, stream>>>(bufU, avU_bf, (long long)rowsA*LDq/4);

        // A = tanh(avU @ pv^T) * masks   (NT=8: 512 blocks)
        mfma_nt_k<2, 1, 0, 8, 0><<<dim3(Nq/64, Mq/128, Bq), 256, 0, stream>>>(
            Nq, Mq, LDq, Mq,
            (const void*)avU_bf, LDq, (long long)Nq*LDq,
            pv_bf, LDq, (long long)Mq*LDq,
            nullptr, Abuf, Mq, (long long)Nq*Mq,
            atoms_mask, amino_mask);

        // r[b,m]   = tanh(pv@tp2c+b)·battc2   (REDUCE GEMM -> rbuf)
        mfma_nt_k<2, 0, 1, 16, 0, 1><<<dim3(rowsP/64, 1, 1), 256, 0, stream>>>(
            rowsP, LDq, LDq, LDq, (const void*)pv_bf, LDq, 0,
            tp2cTI, LDq, 0, tp2cbi, rbuf, 1, 0, battcWi + LDq, nullptr);

        // q[b,n]   = tanh(av@tc2p+b)·battp2   (REDUCE -> qbuf)
        mfma_nt_k<2, 0, 1, 16, 0, 1><<<dim3(rowsA/64, 1, 1), 256, 0, stream>>>(
            rowsA, LDq, LDq, LDq, (const void*)av_bf, LDq, 0,
            tc2pTI, LDq, 0, tc2pbi, qbuf, 1, 0, battpWi + LDq, nullptr);

        // hbdot[row] = tanh(av@bhc+b)·battc1  (REDUCE -> hbdot)
        mfma_nt_k<2, 0, 1, 16, 0, 1><<<dim3(rowsA/64, 1, 1), 256, 0, stream>>>(
            rowsA, LDq, LDq, LDq, (const void*)av_bf, LDq, 0,
            bhcTI, LDq, 0, bhcbi, hbdot, 1, 0, battcWi, nullptr);

        // hpbdot[row] = tanh(pv@bhp+b)·battp1 (REDUCE -> scoreP directly)
        mfma_nt_k<2, 0, 1, 16, 0, 1><<<dim3(rowsP/64, 1, 1), 256, 0, stream>>>(
            rowsP, LDq, LDq, LDq, (const void*)pv_bf, LDq, 0,
            bhpTI, LDq, 0, bhpbi, scoreP, 1, 0, battpWi, nullptr);

        // csum[b,m] = sum_n A[b,n,m]*q[b,n]
        colsum_k<<<dim3(Mq/256, Bq), 256, 0, stream>>>(Abuf, qbuf, csum);
        // attention scores
        scoreC_k<<<rowsA, 256, 0, stream>>>(hbdot, Abuf, rbuf, battcbi, scoreC);
        scorePadd_k<<<rowsP/256, 256, 0, stream>>>(scoreP, csum, battpbi);
        // masked softmax
        msoftmax_k<<<Bq, 256, 0, stream>>>(scoreC, atoms_mask, Nq);
        msoftmax_k<<<Bq, 256, 0, stream>>>(scoreP, amino_mask, Mq);
        // pooled features
        wsum1_k<<<dim3(Bq, 16), 256, 0, stream>>>(av, scoreC, wpart, Nq);
        wsum2_k<<<Bq, 256, 0, stream>>>(wpart, cf + (long long)i*LDq, 4*LDq);
        wsum1_k<<<dim3(Bq, 16), 256, 0, stream>>>(pv, scoreP, wpart, Mq);
        wsum2_k<<<Bq, 256, 0, stream>>>(wpart, pf + (long long)i*LDq, 4*LDq);
    }

    // 13. head: per-layer skinny kernels
    headlin_k<0><<<dim3(Bq, 4), 256, 0, stream>>>(cf, 4*LDq, 4*LDq,
        combc_W, LDq, combc_b, v1, 770, LDq, 0);
    headlin_k<0><<<dim3(Bq, 4), 256, 0, stream>>>(pf, 4*LDq, 4*LDq,
        combp_W, LDq, combp_b, v1, 770, LDq, 512);
    vfill_k<<<Bq, 256, 0, stream>>>(fps, inv_Temp, Temp, v1);

    headlin_k<1><<<dim3(Bq, 13), 256, 0, stream>>>(v1, 770, 770,
        Wout_W + 0ll*770*770, 770, Wout_b + 0*770, v2, 770, 770, 0);
    headlin_k<1><<<dim3(Bq, 13), 256, 0, stream>>>(v2, 770, 770,
        Wout_W + 1ll*770*770, 770, Wout_b + 1*770, v1, 770, 770, 0);
    headlin_k<1><<<dim3(Bq, 13), 256, 0, stream>>>(v1, 770, 770,
        Wout_W + 2ll*770*770, 770, Wout_b + 2*770, v2, 770, 770, 0);

    final_k<<<Bq, 256, 0, stream>>>(v2, out_W, out_b, out);

    (void)in_sizes; (void)n_in; (void)out_size; (void)ws_size;
}

// Round 8
// 1367.253 us; speedup vs baseline: 2.9767x; 1.1872x over previous
//
#include <hip/hip_runtime.h>
#include <math.h>

#define ALPHA_LR 0.2f

#define Bq  32
#define Nq  128
#define Mq  1024
#define CDq 128
#define GDq 64
#define NHq 4
#define LDq 256
#define PDq 40

typedef unsigned short ushort_t;
typedef __attribute__((ext_vector_type(8))) short bf16x8;
typedef __attribute__((ext_vector_type(4))) float f32x4;

__device__ __forceinline__ ushort_t f2bf(float f) {
    union { float f; unsigned u; } x; x.f = f;
    unsigned r = x.u + 0x7FFFu + ((x.u >> 16) & 1u);   // RNE
    return (ushort_t)(r >> 16);
}

// ---------------------------------------------------------------------------
// MFMA bf16 NT GEMM: C = act(A @ Bt^T + bias) [* masks]
// A: [M][lda] bf16 (or fp32 if AF32), Bt: [Npad][ldb] bf16 (= B^T, K-major)
// Each wave: 16 rows x NT*16 cols. grid.x = M/64 (4 waves/block),
// grid.y = N/(NT*16), grid.z = batch. K % 32 == 0. M % 16 == 0.
// C/D layout (m89-verified): col = lane&15, row = (lane>>4)*4 + reg.
// REDUCE=1 (requires NT*16==N, grid.y==1, MASKED=0): out[row] =
//   sum_col tanh(val+bias[col])*w2[col]; w2 = maskR + z*sW2; C = out base.
// Per-z strides sBias/sW2/sC allow batching independent weight sets (r8:
// all reduce-GEMMs are BIDAT-loop-invariant -> one z=4 launch per family).
// ---------------------------------------------------------------------------
template<int ACT, int MASKED, int HAS_BIAS, int NT, int AF32, int REDUCE = 0>
__global__ __launch_bounds__(256) void mfma_nt_k(
    int M, int N, int K, int Nout,
    const void* __restrict__ Av, int lda, long long sA,
    const ushort_t* __restrict__ Bt, int ldb, long long sB,
    const float* __restrict__ bias, long long sBias,
    float* __restrict__ C, int ldc, long long sC,
    const float* __restrict__ maskR, long long sW2,
    const float* __restrict__ maskC)
{
    int z = blockIdx.z;
    Bt += (long long)z * sB;
    C  += (long long)z * sC;
    if (HAS_BIAS) bias += (long long)z * sBias;

    int wave = threadIdx.x >> 6;
    int lane = threadIdx.x & 63;
    int lr = lane & 15;
    int kg = lane >> 4;
    int m0 = (blockIdx.x * 4 + wave) * 16;
    int n0 = blockIdx.y * (NT * 16);
    if (m0 >= M) return;

    f32x4 acc[NT];
    #pragma unroll
    for (int t = 0; t < NT; t++) acc[t] = (f32x4){0.f, 0.f, 0.f, 0.f};

    const ushort_t* Ab = nullptr;
    const float*    Af = nullptr;
    if (AF32) Af = (const float*)Av + (long long)z * sA + (long long)(m0 + lr) * lda + kg * 8;
    else      Ab = (const ushort_t*)Av + (long long)z * sA + (long long)(m0 + lr) * lda + kg * 8;
    const ushort_t* Bbase = Bt + (long long)(n0 + lr) * ldb + kg * 8;

    for (int k0 = 0; k0 < K; k0 += 32) {
        bf16x8 a;
        if (AF32) {
            float4 a0 = *(const float4*)(Af + k0);
            float4 a1 = *(const float4*)(Af + k0 + 4);
            a[0] = (short)f2bf(a0.x); a[1] = (short)f2bf(a0.y);
            a[2] = (short)f2bf(a0.z); a[3] = (short)f2bf(a0.w);
            a[4] = (short)f2bf(a1.x); a[5] = (short)f2bf(a1.y);
            a[6] = (short)f2bf(a1.z); a[7] = (short)f2bf(a1.w);
        } else {
            a = *(const bf16x8*)(Ab + k0);
        }
        #pragma unroll
        for (int t = 0; t < NT; t++) {
            bf16x8 b = *(const bf16x8*)(Bbase + (long long)t * 16 * ldb + k0);
            acc[t] = __builtin_amdgcn_mfma_f32_16x16x32_bf16(a, b, acc[t], 0, 0, 0);
        }
    }

    if (REDUCE) {
        const float* w2 = maskR + (long long)z * sW2;
        float rs[4] = {0.f, 0.f, 0.f, 0.f};
        #pragma unroll
        for (int t = 0; t < NT; t++) {
            int col = n0 + t * 16 + lr;
            float bv = HAS_BIAS ? bias[col] : 0.f;
            float wv = w2[col];
            #pragma unroll
            for (int r = 0; r < 4; r++)
                rs[r] += tanhf(acc[t][r] + bv) * wv;
        }
        #pragma unroll
        for (int r = 0; r < 4; r++) {
            rs[r] += __shfl_xor(rs[r], 1, 64);
            rs[r] += __shfl_xor(rs[r], 2, 64);
            rs[r] += __shfl_xor(rs[r], 4, 64);
            rs[r] += __shfl_xor(rs[r], 8, 64);
        }
        if (lr == 0) {
            int row0 = m0 + kg * 4;
            #pragma unroll
            for (int r = 0; r < 4; r++)
                C[row0 + r] = rs[r];
        }
        return;
    }

    int row0 = m0 + kg * 4;
    #pragma unroll
    for (int t = 0; t < NT; t++) {
        int col = n0 + t * 16 + lr;
        if (col >= Nout) continue;
        float bv = HAS_BIAS ? bias[col] : 0.f;
        float mC = MASKED ? maskC[(long long)z * N + col] : 1.f;
        #pragma unroll
        for (int r = 0; r < 4; r++) {
            float v = acc[t][r] + bv;
            if (ACT == 1) v = v > 0.f ? v : ALPHA_LR * v;
            else if (ACT == 2) v = tanhf(v);
            if (MASKED) v *= maskR[(long long)z * M + row0 + r] * mC;
            C[(long long)(row0 + r) * ldc + col] = v;
        }
    }
}

// fp32 -> bf16, 4 elems/thread, n % 4 == 0
__global__ __launch_bounds__(256) void cvt_bf16_k(
    const float* __restrict__ in, ushort_t* __restrict__ out, long long n4)
{
    long long i = (long long)blockIdx.x * 256 + threadIdx.x;
    if (i >= n4) return;
    float4 v = ((const float4*)in)[i];
    ushort4 o;
    o.x = f2bf(v.x); o.y = f2bf(v.y); o.z = f2bf(v.z); o.w = f2bf(v.w);
    ((ushort4*)out)[i] = o;
}

// W[K][Nsrc] fp32 -> Wt[Npad][Kp] bf16 (transposed, zero-padded), batched z
__global__ __launch_bounds__(256) void wtcvt_k(
    const float* __restrict__ W, ushort_t* __restrict__ Wt,
    int K, int Nsrc, int Npad, int Kp)
{
    int z = blockIdx.z;
    const float* Wz = W + (long long)z * K * Nsrc;
    ushort_t* Oz = Wt + (long long)z * Npad * Kp;
    int idx = blockIdx.x * 256 + threadIdx.x;
    if (idx >= Npad * Kp) return;
    int n = idx / Kp, k = idx % Kp;
    float v = (k < K && n < Nsrc) ? Wz[(long long)k * Nsrc + n] : 0.f;
    Oz[idx] = f2bf(v);
}

// ---------------------------------------------------------------------------
// Generic tiled fp32 GEMM (kept for small/odd-K GEMMs)
// ---------------------------------------------------------------------------
template<int ACT, int TA, int TB, int MASKED>
__global__ __launch_bounds__(256) void gemm_k(
    int M, int N, int K,
    const float* __restrict__ A, int lda, long long sA,
    const float* __restrict__ Bm, int ldb, long long sB,
    const float* __restrict__ bias,
    float* __restrict__ C, int ldc, long long sC,
    const float* __restrict__ maskR, const float* __restrict__ maskC)
{
    int z = blockIdx.z;
    A  += (long long)z * sA;
    Bm += (long long)z * sB;
    C  += (long long)z * sC;

    __shared__ float As[16][68];
    __shared__ float Bs[16][68];

    int tid = threadIdx.x;
    int tx = tid % 16, ty = tid / 16;
    int m0 = blockIdx.y * 64, n0 = blockIdx.x * 64;

    float acc[4][4] = {};

    for (int k0 = 0; k0 < K; k0 += 16) {
        if (!TA) {
            int k = tid % 16, mBase = tid / 16;
            #pragma unroll
            for (int p = 0; p < 4; p++) {
                int m = mBase + p * 16;
                int gm = m0 + m, gk = k0 + k;
                float v = 0.f;
                if (gm < M && gk < K) v = A[(long long)gm * lda + gk];
                As[k][m] = v;
            }
        } else {
            int m = tid % 64, kBase = tid / 64;
            #pragma unroll
            for (int p = 0; p < 4; p++) {
                int k = kBase + p * 4;
                int gm = m0 + m, gk = k0 + k;
                float v = 0.f;
                if (gm < M && gk < K) v = A[(long long)gk * lda + gm];
                As[k][m] = v;
            }
        }
        if (!TB) {
            int n = tid % 64, kBase = tid / 64;
            #pragma unroll
            for (int p = 0; p < 4; p++) {
                int k = kBase + p * 4;
                int gn = n0 + n, gk = k0 + k;
                float v = 0.f;
                if (gn < N && gk < K) v = Bm[(long long)gk * ldb + gn];
                Bs[k][n] = v;
            }
        } else {
            int k = tid % 16, nBase = tid / 16;
            #pragma unroll
            for (int p = 0; p < 4; p++) {
                int n = nBase + p * 16;
                int gn = n0 + n, gk = k0 + k;
                float v = 0.f;
                if (gn < N && gk < K) v = Bm[(long long)gn * ldb + gk];
                Bs[k][n] = v;
            }
        }
        __syncthreads();
        #pragma unroll
        for (int kk = 0; kk < 16; kk++) {
            float a[4], b[4];
            #pragma unroll
            for (int i = 0; i < 4; i++) a[i] = As[kk][ty * 4 + i];
            #pragma unroll
            for (int j = 0; j < 4; j++) b[j] = Bs[kk][tx * 4 + j];
            #pragma unroll
            for (int i = 0; i < 4; i++)
                #pragma unroll
                for (int j = 0; j < 4; j++)
                    acc[i][j] += a[i] * b[j];
        }
        __syncthreads();
    }

    #pragma unroll
    for (int i = 0; i < 4; i++) {
        int gm = m0 + ty * 4 + i;
        if (gm >= M) continue;
        #pragma unroll
        for (int j = 0; j < 4; j++) {
            int gn = n0 + tx * 4 + j;
            if (gn >= N) continue;
            float v = acc[i][j];
            if (bias) v += bias[gn];
            if (ACT == 1) v = v > 0.f ? v : ALPHA_LR * v;
            else if (ACT == 2) v = tanhf(v);
            if (MASKED) v *= maskR[(long long)z * M + gm] * maskC[(long long)z * N + gn];
            C[(long long)gm * ldc + gn] = v;
        }
    }
}

static inline void run_gemm(hipStream_t stream, int act, bool tb_masked,
    int M, int N, int K,
    const float* A, int lda, long long sA,
    const float* B, int ldb, long long sB,
    const float* bias, float* C, int ldc, long long sC,
    int batch, const float* maskR = nullptr, const float* maskC = nullptr)
{
    dim3 grid((N + 63) / 64, (M + 63) / 64, batch);
    dim3 blk(256);
    if (tb_masked) {
        gemm_k<2, 0, 1, 1><<<grid, blk, 0, stream>>>(M, N, K, A, lda, sA, B, ldb, sB,
                                                     bias, C, ldc, sC, maskR, maskC);
    } else if (act == 0) {
        gemm_k<0, 0, 0, 0><<<grid, blk, 0, stream>>>(M, N, K, A, lda, sA, B, ldb, sB,
                                                     bias, C, ldc, sC, nullptr, nullptr);
    } else if (act == 1) {
        gemm_k<1, 0, 0, 0><<<grid, blk, 0, stream>>>(M, N, K, A, lda, sA, B, ldb, sB,
                                                     bias, C, ldc, sC, nullptr, nullptr);
    } else {
        gemm_k<2, 0, 0, 0><<<grid, blk, 0, stream>>>(M, N, K, A, lda, sA, B, ldb, sB,
                                                     bias, C, ldc, sC, nullptr, nullptr);
    }
}

// per-row GAT source/dest attention logits
__global__ __launch_bounds__(128) void gat_e_k(
    const float* __restrict__ Wh, int ldWh, int GD,
    const float* __restrict__ a, int aStride,
    float* __restrict__ esrc, float* __restrict__ edst, int rows)
{
    int row = blockIdx.x;
    int k = blockIdx.y;
    int g = threadIdx.x;
    float ws = 0.f, wd = 0.f;
    if (g < GD) {
        float wv = Wh[(long long)row * ldWh + k * GD + g];
        ws = wv * a[k * aStride + g];
        wd = wv * a[k * aStride + GD + g];
    }
    __shared__ float sb[2][128];
    sb[0][threadIdx.x] = ws; sb[1][threadIdx.x] = wd;
    __syncthreads();
    for (int off = 64; off > 0; off >>= 1) {
        if (threadIdx.x < off) {
            sb[0][threadIdx.x] += sb[0][threadIdx.x + off];
            sb[1][threadIdx.x] += sb[1][threadIdx.x + off];
        }
        __syncthreads();
    }
    if (threadIdx.x == 0) {
        esrc[(long long)k * rows + row] = sb[0][0];
        edst[(long long)k * rows + row] = sb[1][0];
    }
}

// GAT attention: softmax over neighbors + weighted sum + ELU
__global__ __launch_bounds__(128) void gat_attn_k(
    const float* __restrict__ Wh, int ldWh, int GD,
    const int* __restrict__ adj,
    const float* __restrict__ esrc, const float* __restrict__ edst,
    float* __restrict__ out, int ldOut)
{
    int row = blockIdx.x;          // b*N + n
    int k = blockIdx.y;
    int rows = gridDim.x;
    int b = row / Nq, n = row % Nq;
    int m = threadIdx.x;

    __shared__ float att[Nq];
    __shared__ float red[Nq];

    float e = esrc[(long long)k * rows + row] + edst[(long long)k * rows + b * Nq + m];
    e = e > 0.f ? e : ALPHA_LR * e;
    if (adj[(long long)b * Nq * Nq + n * Nq + m] <= 0) e = -9.0e15f;

    red[m] = e; __syncthreads();
    for (int off = 64; off > 0; off >>= 1) {
        if (m < off) red[m] = fmaxf(red[m], red[m + off]);
        __syncthreads();
    }
    float mx = red[0]; __syncthreads();
    float ex = expf(e - mx);
    att[m] = ex; red[m] = ex; __syncthreads();
    for (int off = 64; off > 0; off >>= 1) {
        if (m < off) red[m] += red[m + off];
        __syncthreads();
    }
    float inv = 1.0f / red[0];

    for (int g = threadIdx.x; g < GD; g += blockDim.x) {
        float s = 0.f;
        for (int mm = 0; mm < Nq; mm++)
            s += att[mm] * Wh[(long long)(b * Nq + mm) * ldWh + k * GD + g];
        s *= inv;
        s = s > 0.f ? s : expm1f(s);   // ELU
        out[(long long)row * ldOut + k * GD + g] = s;
    }
}

// 11x11 same-pad conv over (M, PD), single channel, + leaky
__global__ __launch_bounds__(256) void conv_k(
    const float* __restrict__ x, const float* __restrict__ W,
    const float* __restrict__ bptr, float* __restrict__ y)
{
    __shared__ float w[121];
    if (threadIdx.x < 121) w[threadIdx.x] = W[threadIdx.x];
    __syncthreads();
    long long idx = (long long)blockIdx.x * blockDim.x + threadIdx.x;
    long long total = (long long)Bq * Mq * PDq;
    if (idx >= total) return;
    int d = (int)(idx % PDq);
    long long t = idx / PDq;
    int m = (int)(t % Mq);
    int b = (int)(t / Mq);
    const float* xb = x + (long long)b * Mq * PDq;
    float s = 0.f;
    #pragma unroll
    for (int i = 0; i < 11; i++) {
        int mm = m + i - 5;
        if (mm < 0 || mm >= Mq) continue;
        #pragma unroll
        for (int j = 0; j < 11; j++) {
            int dd = d + j - 5;
            if (dd < 0 || dd >= PDq) continue;
            s += xb[(long long)mm * PDq + dd] * w[i * 11 + j];
        }
    }
    s += *bptr;
    y[idx] = s > 0.f ? s : ALPHA_LR * s;
}

// out[b,m] = sum_n A[b,n,m] * q[b,n]
__global__ __launch_bounds__(256) void colsum_k(
    const float* __restrict__ A, const float* __restrict__ q, float* __restrict__ out)
{
    int b = blockIdx.y;
    int m = blockIdx.x * 256 + threadIdx.x;
    const float* Ab = A + (long long)b * Nq * Mq;
    const float* qb = q + (long long)b * Nq;
    float s = 0.f;
    for (int n = 0; n < Nq; n++) s += Ab[(long long)n * Mq + m] * qb[n];
    out[(long long)b * Mq + m] = s;
}

// score_c[row=b*N+n] = hbdot[row] + A[b,n,:]·r[b,:] + bias
__global__ __launch_bounds__(256) void scoreC_k(
    const float* __restrict__ hbdot, const float* __restrict__ A,
    const float* __restrict__ r,
    const float* __restrict__ bptr, float* __restrict__ score)
{
    int row = blockIdx.x;
    int b = row / Nq;
    int t = threadIdx.x;
    const float* Ar = A + (long long)row * Mq;
    const float* rb = r + (long long)b * Mq;
    float s = 0.f;
    for (int m = t; m < Mq; m += 256) s += Ar[m] * rb[m];
    __shared__ float red[256];
    red[t] = s; __syncthreads();
    for (int off = 128; off > 0; off >>= 1) {
        if (t < off) red[t] += red[t + off];
        __syncthreads();
    }
    if (t == 0) score[row] = red[0] + hbdot[row] + bptr[0];
}

// score_p[i] = hpbdot[i] + csum[i] + bias
__global__ __launch_bounds__(256) void scorePadd_k(
    float* __restrict__ score, const float* __restrict__ hpbdot,
    const float* __restrict__ csum, const float* __restrict__ bptr)
{
    int i = blockIdx.x * 256 + threadIdx.x;
    score[i] = hpbdot[i] + csum[i] + bptr[0];
}

// masked softmax in place over L, one block per batch row
__global__ __launch_bounds__(256) void msoftmax_k(
    float* __restrict__ score, const float* __restrict__ mask, int L)
{
    int b = blockIdx.x;
    float* s = score + (long long)b * L;
    const float* mk = mask + (long long)b * L;
    int t = threadIdx.x;
    __shared__ float red[256];
    float mx = -1e30f;
    for (int i = t; i < L; i += 256) mx = fmaxf(mx, s[i]);
    red[t] = mx; __syncthreads();
    for (int off = 128; off > 0; off >>= 1) {
        if (t < off) red[t] = fmaxf(red[t], red[t + off]);
        __syncthreads();
    }
    mx = red[0]; __syncthreads();
    float sum = 0.f;
    for (int i = t; i < L; i += 256) {
        float e = expf(s[i] - mx) * mk[i];
        s[i] = e; sum += e;
    }
    red[t] = sum; __syncthreads();
    for (int off = 128; off > 0; off >>= 1) {
        if (t < off) red[t] += red[t + off];
        __syncthreads();
    }
    float inv = 1.0f / (red[0] + 1e-6f);
    __syncthreads();
    for (int i = t; i < L; i += 256) s[i] *= inv;
}

// weighted sum stage 1: partial over 16 chunks
__global__ __launch_bounds__(256) void wsum1_k(
    const float* __restrict__ feat, const float* __restrict__ att,
    float* __restrict__ partial, int L)
{
    int b = blockIdx.x, c = blockIdx.y, l = threadIdx.x;
    int chunk = L / 16;
    const float* fb = feat + (long long)b * L * LDq;
    const float* ab = att + (long long)b * L;
    float s = 0.f;
    int r0 = c * chunk, r1 = r0 + chunk;
    for (int r = r0; r < r1; r++) s += fb[(long long)r * LDq + l] * ab[r];
    partial[((long long)b * 16 + c) * LDq + l] = s;
}

// weighted sum stage 2
__global__ __launch_bounds__(256) void wsum2_k(
    const float* __restrict__ partial, float* __restrict__ out, int outStride)
{
    int b = blockIdx.x, l = threadIdx.x;
    float s = 0.f;
    #pragma unroll
    for (int c = 0; c < 16; c++) s += partial[((long long)b * 16 + c) * LDq + l];
    out[(long long)b * outStride + l] = s;
}

// ---------------------------------------------------------------------------
// Skinny dense layer for the head
// ---------------------------------------------------------------------------
template<int ACT>
__global__ __launch_bounds__(256) void headlin_k(
    const float* __restrict__ vin, int ldv, int VD,
    const float* __restrict__ W, int ldw,
    const float* __restrict__ bias,
    float* __restrict__ vout, int ldo, int OD, int colBase)
{
    int b = blockIdx.x;
    int c = threadIdx.x & 63;
    int s = threadIdx.x >> 6;
    int col = blockIdx.y * 64 + c;

    __shared__ float vs[1024];
    for (int i = threadIdx.x; i < VD; i += 256) vs[i] = vin[(long long)b * ldv + i];
    __syncthreads();

    float sum = 0.f;
    if (col < OD) {
        int k0 = (VD * s) >> 2, k1 = (VD * (s + 1)) >> 2;
        #pragma unroll 4
        for (int k = k0; k < k1; k++)
            sum += vs[k] * W[(long long)k * ldw + col];
    }
    __shared__ float red[4][64];
    red[s][c] = sum;
    __syncthreads();
    if (s == 0 && col < OD) {
        float t = red[0][c] + red[1][c] + red[2][c] + red[3][c] + bias[col];
        if (ACT == 1) t = t > 0.f ? t : ALPHA_LR * t;
        vout[(long long)b * ldo + colBase + col] = t;
    }
}

// v[b,256:512]=fps, v[b,768]=invT, v[b,769]=T
__global__ __launch_bounds__(256) void vfill_k(
    const float* __restrict__ fps, const float* __restrict__ invT,
    const float* __restrict__ T, float* __restrict__ v)
{
    int b = blockIdx.x, t = threadIdx.x;
    v[(long long)b * 770 + 256 + t] = fps[(long long)b * 256 + t];
    if (t == 0) {
        v[(long long)b * 770 + 768] = invT[b];
        v[(long long)b * 770 + 769] = T[b];
    }
}

// out[b] = v[b,:770]·W + b
__global__ __launch_bounds__(256) void final_k(
    const float* __restrict__ v, const float* __restrict__ W,
    const float* __restrict__ bptr, float* __restrict__ out)
{
    int b = blockIdx.x, t = threadIdx.x;
    float s = 0.f;
    for (int i = t; i < 770; i += 256) s += v[(long long)b * 770 + i] * W[i];
    __shared__ float red[256];
    red[t] = s; __syncthreads();
    for (int off = 128; off > 0; off >>= 1) {
        if (t < off) red[t] += red[t + off];
        __syncthreads();
    }
    if (t == 0) out[b] = red[0] + bptr[0];
}

extern "C" void kernel_launch(void* const* d_in, const int* in_sizes, int n_in,
                              void* d_out, int out_size, void* d_ws, size_t ws_size,
                              hipStream_t stream)
{
    const float* atoms_emb = (const float*)d_in[0];
    const int*   adjacency = (const int*)d_in[1];
    const float* atoms_mask= (const float*)d_in[2];
    const float* amino_emb = (const float*)d_in[3];
    const float* amino_mask= (const float*)d_in[4];
    const float* fps       = (const float*)d_in[5];
    const float* inv_Temp  = (const float*)d_in[6];
    const float* Temp      = (const float*)d_in[7];
    const float* bert_W    = (const float*)d_in[8];
    const float* bert_b    = (const float*)d_in[9];
    const float* gat_W     = (const float*)d_in[10];
    const float* gat_a     = (const float*)d_in[11];
    const float* gatout_W  = (const float*)d_in[12];
    const float* gatout_a  = (const float*)d_in[13];
    const float* Wcomp_W   = (const float*)d_in[14];
    const float* Wcomp_b   = (const float*)d_in[15];
    const float* prot_W    = (const float*)d_in[16];
    const float* prot_b    = (const float*)d_in[17];
    const float* conv_W    = (const float*)d_in[18];
    const float* conv_b    = (const float*)d_in[19];
    const float* Wprot_W   = (const float*)d_in[20];
    const float* Wprot_b   = (const float*)d_in[21];
    const float* U         = (const float*)d_in[22];
    const float* tc2p_W    = (const float*)d_in[23];
    const float* tc2p_b    = (const float*)d_in[24];
    const float* tp2c_W    = (const float*)d_in[25];
    const float* tp2c_b    = (const float*)d_in[26];
    const float* bhc_W     = (const float*)d_in[27];
    const float* bhc_b     = (const float*)d_in[28];
    const float* bhp_W     = (const float*)d_in[29];
    const float* bhp_b     = (const float*)d_in[30];
    const float* battc_W   = (const float*)d_in[31];
    const float* battc_b   = (const float*)d_in[32];
    const float* battp_W   = (const float*)d_in[33];
    const float* battp_b   = (const float*)d_in[34];
    const float* combc_W   = (const float*)d_in[35];
    const float* combc_b   = (const float*)d_in[36];
    const float* combp_W   = (const float*)d_in[37];
    const float* combp_b   = (const float*)d_in[38];
    const float* Wout_W    = (const float*)d_in[39];
    const float* Wout_b    = (const float*)d_in[40];
    const float* out_W     = (const float*)d_in[41];
    const float* out_b     = (const float*)d_in[42];
    float* out = (float*)d_out;

    // ---- workspace layout (floats) ----
    float* w = (float*)d_ws;
    float* av    = w; w += (long long)Bq*Nq*LDq;
    float* pv    = w; w += (long long)Bq*Mq*LDq;
    float* sx    = w; w += (long long)Bq*Mq*LDq;   // early scratch -> precomp pool
    float* Abuf  = w; w += (long long)Bq*Nq*Mq;
    float* bufU  = w; w += (long long)Bq*Nq*LDq;   // (unused in loop now)
    float* bufTC = w; w += (long long)Bq*Nq*LDq;   // wsum partials
    float* esrc  = w; w += (long long)NHq*Bq*Nq;
    float* edst  = w; w += (long long)NHq*Bq*Nq;
    float* scoreC= w; w += (long long)Bq*Nq;
    float* scoreP= w; w += (long long)Bq*Mq;
    float* rbuf  = w; w += (long long)Bq*Mq;
    float* qbuf  = w; w += (long long)Bq*Nq;
    float* csum  = w; w += (long long)Bq*Mq;
    float* cf    = w; w += (long long)Bq*4*LDq;
    float* pf    = w; w += (long long)Bq*4*LDq;
    float* v1    = w; w += (long long)Bq*770;
    float* v2    = w; w += (long long)Bq*770;
    // bf16 buffers (carved as float-space, used as ushort)
    ushort_t* pv_bf  = (ushort_t*)w; w += (long long)Bq*Mq*LDq/2;
    ushort_t* av_bf  = (ushort_t*)w; w += (long long)Bq*Nq*LDq/2;
    ushort_t* avU_bf = (ushort_t*)w; w += (long long)Bq*Nq*LDq/2;   // (unused)
    ushort_t* Ut_bf    = (ushort_t*)w; w += (long long)4*LDq*LDq/2;
    ushort_t* tp2cT_bf = (ushort_t*)w; w += (long long)4*LDq*LDq/2;
    ushort_t* tc2pT_bf = (ushort_t*)w; w += (long long)4*LDq*LDq/2;
    ushort_t* bhcT_bf  = (ushort_t*)w; w += (long long)4*LDq*LDq/2;
    ushort_t* bhpT_bf  = (ushort_t*)w; w += (long long)4*LDq*LDq/2;
    ushort_t* protWt_bf= (ushort_t*)w; w += (long long)48*1024/2;

    int rowsA = Bq * Nq;     // 4096
    int rowsP = Bq * Mq;     // 32768

    // early-phase aliases inside sx (dead before BIDAT precompute)
    float* h     = sx;
    float* WhAll = h + (long long)Bq*Nq*CDq;
    float* multi = WhAll + (long long)Bq*Nq*NHq*GDq;
    float* Wh2   = multi + (long long)Bq*Nq*NHq*GDq;
    float* avp   = Wh2 + (long long)Bq*Nq*CDq;
    float* c0    = avp + (long long)Bq*Nq*CDq;
    float* c1    = c0 + (long long)Bq*Mq*PDq;

    // BIDAT-precompute pool in sx (r8: all reduce-GEMMs + avU are loop-
    // invariant; hoisted + batched over z=4). Needs 26.3 MB <= sx's 33.5 MB.
    float*    rbuf_all   = sx;                                    // 4*rowsP
    float*    hpbdot_all = rbuf_all   + (long long)4*rowsP;       // 4*rowsP
    float*    qbuf_all   = hpbdot_all + (long long)4*rowsP;       // 4*rowsA
    float*    hbdot_all  = qbuf_all   + (long long)4*rowsA;       // 4*rowsA
    float*    bufU_all   = hbdot_all  + (long long)4*rowsA;       // 4*rowsA*LDq
    ushort_t* avU_all_bf = (ushort_t*)(bufU_all + (long long)4*rowsA*LDq); // 4*rowsA*LDq bf16

    float* wpart = bufTC;   // wsum partials

    // ---- weight transpose-converts (once) ----
    wtcvt_k<<<dim3(256, 1, 4), 256, 0, stream>>>(U,      Ut_bf,    LDq, LDq, LDq, LDq);
    wtcvt_k<<<dim3(256, 1, 4), 256, 0, stream>>>(tp2c_W, tp2cT_bf, LDq, LDq, LDq, LDq);
    wtcvt_k<<<dim3(256, 1, 4), 256, 0, stream>>>(tc2p_W, tc2pT_bf, LDq, LDq, LDq, LDq);
    wtcvt_k<<<dim3(256, 1, 4), 256, 0, stream>>>(bhc_W,  bhcT_bf,  LDq, LDq, LDq, LDq);
    wtcvt_k<<<dim3(256, 1, 4), 256, 0, stream>>>(bhp_W,  bhpT_bf,  LDq, LDq, LDq, LDq);
    wtcvt_k<<<dim3((48*1024+255)/256, 1, 1), 256, 0, stream>>>(prot_W, protWt_bf, 1024, 40, 48, 1024);

    // 1. h = atoms_emb @ bert_W + bert_b   (K=300, fp32)
    run_gemm(stream, 0, false, rowsA, CDq, 300, atoms_emb, 300, 0,
             bert_W, CDq, 0, bert_b, h, CDq, 0, 1);

    // 2. Wh_all = h @ gat_W[k] (batched heads)
    run_gemm(stream, 0, false, rowsA, GDq, CDq, h, CDq, 0,
             gat_W, GDq, (long long)CDq*GDq, nullptr,
             WhAll, NHq*GDq, GDq, NHq);

    // 3-4. GAT heads -> multi (ELU)
    gat_e_k<<<dim3(rowsA, NHq), 128, 0, stream>>>(WhAll, NHq*GDq, GDq, gat_a, 2*GDq,
                                                  esrc, edst, rowsA);
    gat_attn_k<<<dim3(rowsA, NHq), 128, 0, stream>>>(WhAll, NHq*GDq, GDq, adjacency,
                                                     esrc, edst, multi, NHq*GDq);

    // 5-7. GAT out layer -> avp (ELU)
    run_gemm(stream, 0, false, rowsA, CDq, NHq*GDq, multi, NHq*GDq, 0,
             gatout_W, CDq, 0, nullptr, Wh2, CDq, 0, 1);
    gat_e_k<<<dim3(rowsA, 1), 128, 0, stream>>>(Wh2, CDq, CDq, gatout_a, 2*CDq,
                                                esrc, edst, rowsA);
    gat_attn_k<<<dim3(rowsA, 1), 128, 0, stream>>>(Wh2, CDq, CDq, adjacency,
                                                   esrc, edst, avp, CDq);

    // 8. av = leaky(avp @ Wcomp_W + b)
    run_gemm(stream, 1, false, rowsA, LDq, CDq, avp, CDq, 0,
             Wcomp_W, LDq, 0, Wcomp_b, av, LDq, 0, 1);
    cvt_bf16_k<<<(rowsA*LDq/4 + 255)/256, 256, 0, stream>>>(av, av_bf, (long long)rowsA*LDq/4);

    // 9. pv0 = amino_emb @ prot_W + b  -> MFMA (AF32 A-operand, N padded to 48)
    mfma_nt_k<0, 0, 1, 3, 1><<<dim3(rowsP/64, 1, 1), 256, 0, stream>>>(
        rowsP, 48, 1024, 40,
        (const void*)amino_emb, 1024, 0,
        protWt_bf, 1024, 0,
        prot_b, 0, c0, PDq, 0, nullptr, 0, nullptr);

    // 10. 3x conv 11x11 + leaky
    {
        long long total = (long long)Bq*Mq*PDq;
        int blocks = (int)((total + 255) / 256);
        conv_k<<<blocks, 256, 0, stream>>>(c0, conv_W + 0*121, conv_b + 0, c1);
        conv_k<<<blocks, 256, 0, stream>>>(c1, conv_W + 1*121, conv_b + 1, c0);
        conv_k<<<blocks, 256, 0, stream>>>(c0, conv_W + 2*121, conv_b + 2, c1);
    }

    // 11. pv = leaky(x @ Wprot_W + b)  (K=40, fp32)
    run_gemm(stream, 1, false, rowsP, LDq, PDq, c1, PDq, 0,
             Wprot_W, LDq, 0, Wprot_b, pv, LDq, 0, 1);
    cvt_bf16_k<<<(rowsP*LDq/4 + 255)/256, 256, 0, stream>>>(pv, pv_bf, (long long)rowsP*LDq/4);

    // ---- BIDAT precompute (loop-invariant, batched over z = i = 0..3) ----
    // r_all[i]      = tanh(pv@tp2c[i]+b)·battc2[i]   (rowsP, 2048 blocks)
    mfma_nt_k<2, 0, 1, 16, 0, 1><<<dim3(rowsP/64, 1, 4), 256, 0, stream>>>(
        rowsP, LDq, LDq, LDq, (const void*)pv_bf, LDq, 0,
        tp2cT_bf, LDq, (long long)LDq*LDq,
        tp2c_b, LDq, rbuf_all, 1, rowsP,
        battc_W + LDq, 2*LDq, nullptr);
    // hpbdot_all[i] = tanh(pv@bhp[i]+b)·battp1[i]
    mfma_nt_k<2, 0, 1, 16, 0, 1><<<dim3(rowsP/64, 1, 4), 256, 0, stream>>>(
        rowsP, LDq, LDq, LDq, (const void*)pv_bf, LDq, 0,
        bhpT_bf, LDq, (long long)LDq*LDq,
        bhp_b, LDq, hpbdot_all, 1, rowsP,
        battp_W, 2*LDq, nullptr);
    // q_all[i]      = tanh(av@tc2p[i]+b)·battp2[i]   (rowsA)
    mfma_nt_k<2, 0, 1, 16, 0, 1><<<dim3(rowsA/64, 1, 4), 256, 0, stream>>>(
        rowsA, LDq, LDq, LDq, (const void*)av_bf, LDq, 0,
        tc2pT_bf, LDq, (long long)LDq*LDq,
        tc2p_b, LDq, qbuf_all, 1, rowsA,
        battp_W + LDq, 2*LDq, nullptr);
    // hbdot_all[i]  = tanh(av@bhc[i]+b)·battc1[i]
    mfma_nt_k<2, 0, 1, 16, 0, 1><<<dim3(rowsA/64, 1, 4), 256, 0, stream>>>(
        rowsA, LDq, LDq, LDq, (const void*)av_bf, LDq, 0,
        bhcT_bf, LDq, (long long)LDq*LDq,
        bhc_b, LDq, hbdot_all, 1, rowsA,
        battc_W, 2*LDq, nullptr);
    // avU_all[i] = av @ U[i]   (NT=4, 1024 blocks)
    mfma_nt_k<0, 0, 0, 4, 0><<<dim3(rowsA/64, 4, 4), 256, 0, stream>>>(
        rowsA, LDq, LDq, LDq, (const void*)av_bf, LDq, 0,
        Ut_bf, LDq, (long long)LDq*LDq,
        nullptr, 0, bufU_all, LDq, (long long)rowsA*LDq,
        nullptr, 0, nullptr);
    cvt_bf16_k<<<((long long)4*rowsA*LDq/4 + 255)/256, 256, 0, stream>>>(
        bufU_all, avU_all_bf, (long long)4*rowsA*LDq/4);

    // ---- 12. BIDAT loop (per-iter: A-GEMM + reductions + softmax + pool) ----
    for (int i = 0; i < 4; i++) {
        const float* battcbi = battc_b + i;
        const float* battpbi = battp_b + i;
        const ushort_t* avUI = avU_all_bf + (long long)i*rowsA*LDq;
        const float* rI    = rbuf_all   + (long long)i*rowsP;
        const float* hpI   = hpbdot_all + (long long)i*rowsP;
        const float* qI    = qbuf_all   + (long long)i*rowsA;
        const float* hbI   = hbdot_all  + (long long)i*rowsA;

        // A = tanh(avU @ pv^T) * masks   (NT=8: 512 blocks)
        mfma_nt_k<2, 1, 0, 8, 0><<<dim3(Nq/64, Mq/128, Bq), 256, 0, stream>>>(
            Nq, Mq, LDq, Mq,
            (const void*)avUI, LDq, (long long)Nq*LDq,
            pv_bf, LDq, (long long)Mq*LDq,
            nullptr, 0, Abuf, Mq, (long long)Nq*Mq,
            atoms_mask, 0, amino_mask);

        // csum[b,m] = sum_n A[b,n,m]*q[b,n]
        colsum_k<<<dim3(Mq/256, Bq), 256, 0, stream>>>(Abuf, qI, csum);
        // attention scores
        scoreC_k<<<rowsA, 256, 0, stream>>>(hbI, Abuf, rI, battcbi, scoreC);
        scorePadd_k<<<rowsP/256, 256, 0, stream>>>(scoreP, hpI, csum, battpbi);
        // masked softmax
        msoftmax_k<<<Bq, 256, 0, stream>>>(scoreC, atoms_mask, Nq);
        msoftmax_k<<<Bq, 256, 0, stream>>>(scoreP, amino_mask, Mq);
        // pooled features
        wsum1_k<<<dim3(Bq, 16), 256, 0, stream>>>(av, scoreC, wpart, Nq);
        wsum2_k<<<Bq, 256, 0, stream>>>(wpart, cf + (long long)i*LDq, 4*LDq);
        wsum1_k<<<dim3(Bq, 16), 256, 0, stream>>>(pv, scoreP, wpart, Mq);
        wsum2_k<<<Bq, 256, 0, stream>>>(wpart, pf + (long long)i*LDq, 4*LDq);
    }

    // 13. head: per-layer skinny kernels
    headlin_k<0><<<dim3(Bq, 4), 256, 0, stream>>>(cf, 4*LDq, 4*LDq,
        combc_W, LDq, combc_b, v1, 770, LDq, 0);
    headlin_k<0><<<dim3(Bq, 4), 256, 0, stream>>>(pf, 4*LDq, 4*LDq,
        combp_W, LDq, combp_b, v1, 770, LDq, 512);
    vfill_k<<<Bq, 256, 0, stream>>>(fps, inv_Temp, Temp, v1);

    headlin_k<1><<<dim3(Bq, 13), 256, 0, stream>>>(v1, 770, 770,
        Wout_W + 0ll*770*770, 770, Wout_b + 0*770, v2, 770, 770, 0);
    headlin_k<1><<<dim3(Bq, 13), 256, 0, stream>>>(v2, 770, 770,
        Wout_W + 1ll*770*770, 770, Wout_b + 1*770, v1, 770, 770, 0);
    headlin_k<1><<<dim3(Bq, 13), 256, 0, stream>>>(v1, 770, 770,
        Wout_W + 2ll*770*770, 770, Wout_b + 2*770, v2, 770, 770, 0);

    final_k<<<Bq, 256, 0, stream>>>(v2, out_W, out_b, out);

    (void)in_sizes; (void)n_in; (void)out_size; (void)ws_size;
    (void)bufU; (void)avU_bf; (void)rbuf; (void)qbuf;
}

// Round 9
// 1256.357 us; speedup vs baseline: 3.2395x; 1.0883x over previous
//
#include <hip/hip_runtime.h>
#include <math.h>

#define ALPHA_LR 0.2f

#define Bq  32
#define Nq  128
#define Mq  1024
#define CDq 128
#define GDq 64
#define NHq 4
#define LDq 256
#define PDq 40

typedef unsigned short ushort_t;
typedef __attribute__((ext_vector_type(8))) short bf16x8;
typedef __attribute__((ext_vector_type(4))) float f32x4;

__device__ __forceinline__ ushort_t f2bf(float f) {
    union { float f; unsigned u; } x; x.f = f;
    unsigned r = x.u + 0x7FFFu + ((x.u >> 16) & 1u);   // RNE
    return (ushort_t)(r >> 16);
}

// ---------------------------------------------------------------------------
// MFMA bf16 NT GEMM: C = act(A @ Bt^T + bias) [* masks]
// A: [M][lda] bf16 (or fp32 if AF32), Bt: [Npad][ldb] bf16 (= B^T, K-major)
// Each wave: 16 rows x NT*16 cols. grid.x = M/64 (4 waves/block),
// grid.y = N/(NT*16), grid.z = batch. K % 32 == 0. M % 16 == 0.
// C/D layout (m89-verified): col = lane&15, row = (lane>>4)*4 + reg.
// ---------------------------------------------------------------------------
template<int ACT, int MASKED, int HAS_BIAS, int NT, int AF32>
__global__ __launch_bounds__(256) void mfma_nt_k(
    int M, int N, int K, int Nout,
    const void* __restrict__ Av, int lda, long long sA,
    const ushort_t* __restrict__ Bt, int ldb, long long sB,
    const float* __restrict__ bias, long long sBias,
    float* __restrict__ C, int ldc, long long sC,
    const float* __restrict__ maskR, long long sW2,
    const float* __restrict__ maskC)
{
    int z = blockIdx.z;
    Bt += (long long)z * sB;
    C  += (long long)z * sC;
    if (HAS_BIAS) bias += (long long)z * sBias;

    int wave = threadIdx.x >> 6;
    int lane = threadIdx.x & 63;
    int lr = lane & 15;
    int kg = lane >> 4;
    int m0 = (blockIdx.x * 4 + wave) * 16;
    int n0 = blockIdx.y * (NT * 16);
    if (m0 >= M) return;

    f32x4 acc[NT];
    #pragma unroll
    for (int t = 0; t < NT; t++) acc[t] = (f32x4){0.f, 0.f, 0.f, 0.f};

    const ushort_t* Ab = nullptr;
    const float*    Af = nullptr;
    if (AF32) Af = (const float*)Av + (long long)z * sA + (long long)(m0 + lr) * lda + kg * 8;
    else      Ab = (const ushort_t*)Av + (long long)z * sA + (long long)(m0 + lr) * lda + kg * 8;
    const ushort_t* Bbase = Bt + (long long)(n0 + lr) * ldb + kg * 8;

    for (int k0 = 0; k0 < K; k0 += 32) {
        bf16x8 a;
        if (AF32) {
            float4 a0 = *(const float4*)(Af + k0);
            float4 a1 = *(const float4*)(Af + k0 + 4);
            a[0] = (short)f2bf(a0.x); a[1] = (short)f2bf(a0.y);
            a[2] = (short)f2bf(a0.z); a[3] = (short)f2bf(a0.w);
            a[4] = (short)f2bf(a1.x); a[5] = (short)f2bf(a1.y);
            a[6] = (short)f2bf(a1.z); a[7] = (short)f2bf(a1.w);
        } else {
            a = *(const bf16x8*)(Ab + k0);
        }
        #pragma unroll
        for (int t = 0; t < NT; t++) {
            bf16x8 b = *(const bf16x8*)(Bbase + (long long)t * 16 * ldb + k0);
            acc[t] = __builtin_amdgcn_mfma_f32_16x16x32_bf16(a, b, acc[t], 0, 0, 0);
        }
    }

    int row0 = m0 + kg * 4;
    #pragma unroll
    for (int t = 0; t < NT; t++) {
        int col = n0 + t * 16 + lr;
        if (col >= Nout) continue;
        float bv = HAS_BIAS ? bias[col] : 0.f;
        float mC = MASKED ? maskC[(long long)z * N + col] : 1.f;
        #pragma unroll
        for (int r = 0; r < 4; r++) {
            float v = acc[t][r] + bv;
            if (ACT == 1) v = v > 0.f ? v : ALPHA_LR * v;
            else if (ACT == 2) v = tanhf(v);
            if (MASKED) v *= maskR[(long long)z * M + row0 + r] * mC;
            C[(long long)(row0 + r) * ldc + col] = v;
        }
    }
}

// ---------------------------------------------------------------------------
// Occupancy-optimized reduce GEMM (r9: replaces the NT=16 REDUCE path that
// ran at 23% occupancy / 211 µs — 64 acc VGPRs starved the SIMDs):
//   out[z][row] = sum_col tanh((A @ Bt[z]^T)[row,col] + bias[z][col]) * w2[z][col]
// Block = 4 waves = 32 rows x 2 col-halves (NT=8, 32 acc VGPRs/wave).
// grid = (M/32, 1, Z). K%32==0, N fixed at 256 (LDq).
// ---------------------------------------------------------------------------
__global__ __launch_bounds__(256) void mfma_reduce_k(
    int M, int K,
    const ushort_t* __restrict__ A, int lda,
    const ushort_t* __restrict__ Bt, int ldb, long long sB,
    const float* __restrict__ bias, long long sBias,
    const float* __restrict__ w2, long long sW2,
    float* __restrict__ C, long long sC)
{
    int z = blockIdx.z;
    Bt   += (long long)z * sB;
    bias += (long long)z * sBias;
    w2   += (long long)z * sW2;
    C    += (long long)z * sC;

    int wave = threadIdx.x >> 6;
    int lane = threadIdx.x & 63;
    int lr = lane & 15;
    int kg = lane >> 4;
    int rg = wave >> 1;        // row group 0..1
    int half = wave & 1;       // column half 0..1
    int m0 = (blockIdx.x * 2 + rg) * 16;
    int n0 = half * 128;

    f32x4 acc[8];
    #pragma unroll
    for (int t = 0; t < 8; t++) acc[t] = (f32x4){0.f, 0.f, 0.f, 0.f};

    const ushort_t* Ab = A + (long long)(m0 + lr) * lda + kg * 8;
    const ushort_t* Bb = Bt + (long long)(n0 + lr) * ldb + kg * 8;

    for (int k0 = 0; k0 < K; k0 += 32) {
        bf16x8 a = *(const bf16x8*)(Ab + k0);
        #pragma unroll
        for (int t = 0; t < 8; t++) {
            bf16x8 b = *(const bf16x8*)(Bb + (long long)t * 16 * ldb + k0);
            acc[t] = __builtin_amdgcn_mfma_f32_16x16x32_bf16(a, b, acc[t], 0, 0, 0);
        }
    }

    float rs[4] = {0.f, 0.f, 0.f, 0.f};
    #pragma unroll
    for (int t = 0; t < 8; t++) {
        int col = n0 + t * 16 + lr;
        float bv = bias[col];
        float wv = w2[col];
        #pragma unroll
        for (int r = 0; r < 4; r++)
            rs[r] += tanhf(acc[t][r] + bv) * wv;
    }
    #pragma unroll
    for (int r = 0; r < 4; r++) {
        rs[r] += __shfl_xor(rs[r], 1, 64);
        rs[r] += __shfl_xor(rs[r], 2, 64);
        rs[r] += __shfl_xor(rs[r], 4, 64);
        rs[r] += __shfl_xor(rs[r], 8, 64);
    }
    __shared__ float lds[2][16][2];
    if (lr == 0) {
        #pragma unroll
        for (int r = 0; r < 4; r++)
            lds[rg][kg * 4 + r][half] = rs[r];
    }
    __syncthreads();
    int t = threadIdx.x;
    if (t < 32) {
        int g = t >> 4, row = t & 15;
        C[(long long)(blockIdx.x * 2 + g) * 16 + row] = lds[g][row][0] + lds[g][row][1];
    }
}

// fp32 -> bf16, 4 elems/thread, n % 4 == 0
__global__ __launch_bounds__(256) void cvt_bf16_k(
    const float* __restrict__ in, ushort_t* __restrict__ out, long long n4)
{
    long long i = (long long)blockIdx.x * 256 + threadIdx.x;
    if (i >= n4) return;
    float4 v = ((const float4*)in)[i];
    ushort4 o;
    o.x = f2bf(v.x); o.y = f2bf(v.y); o.z = f2bf(v.z); o.w = f2bf(v.w);
    ((ushort4*)out)[i] = o;
}

// W[K][Nsrc] fp32 -> Wt[Npad][Kp] bf16 (transposed, zero-padded), batched z
__global__ __launch_bounds__(256) void wtcvt_k(
    const float* __restrict__ W, ushort_t* __restrict__ Wt,
    int K, int Nsrc, int Npad, int Kp)
{
    int z = blockIdx.z;
    const float* Wz = W + (long long)z * K * Nsrc;
    ushort_t* Oz = Wt + (long long)z * Npad * Kp;
    int idx = blockIdx.x * 256 + threadIdx.x;
    if (idx >= Npad * Kp) return;
    int n = idx / Kp, k = idx % Kp;
    float v = (k < K && n < Nsrc) ? Wz[(long long)k * Nsrc + n] : 0.f;
    Oz[idx] = f2bf(v);
}

// ---------------------------------------------------------------------------
// Generic tiled fp32 GEMM (kept for small/odd-K GEMMs)
// ---------------------------------------------------------------------------
template<int ACT, int TA, int TB, int MASKED>
__global__ __launch_bounds__(256) void gemm_k(
    int M, int N, int K,
    const float* __restrict__ A, int lda, long long sA,
    const float* __restrict__ Bm, int ldb, long long sB,
    const float* __restrict__ bias,
    float* __restrict__ C, int ldc, long long sC,
    const float* __restrict__ maskR, const float* __restrict__ maskC)
{
    int z = blockIdx.z;
    A  += (long long)z * sA;
    Bm += (long long)z * sB;
    C  += (long long)z * sC;

    __shared__ float As[16][68];
    __shared__ float Bs[16][68];

    int tid = threadIdx.x;
    int tx = tid % 16, ty = tid / 16;
    int m0 = blockIdx.y * 64, n0 = blockIdx.x * 64;

    float acc[4][4] = {};

    for (int k0 = 0; k0 < K; k0 += 16) {
        if (!TA) {
            int k = tid % 16, mBase = tid / 16;
            #pragma unroll
            for (int p = 0; p < 4; p++) {
                int m = mBase + p * 16;
                int gm = m0 + m, gk = k0 + k;
                float v = 0.f;
                if (gm < M && gk < K) v = A[(long long)gm * lda + gk];
                As[k][m] = v;
            }
        } else {
            int m = tid % 64, kBase = tid / 64;
            #pragma unroll
            for (int p = 0; p < 4; p++) {
                int k = kBase + p * 4;
                int gm = m0 + m, gk = k0 + k;
                float v = 0.f;
                if (gm < M && gk < K) v = A[(long long)gk * lda + gm];
                As[k][m] = v;
            }
        }
        if (!TB) {
            int n = tid % 64, kBase = tid / 64;
            #pragma unroll
            for (int p = 0; p < 4; p++) {
                int k = kBase + p * 4;
                int gn = n0 + n, gk = k0 + k;
                float v = 0.f;
                if (gn < N && gk < K) v = Bm[(long long)gk * ldb + gn];
                Bs[k][n] = v;
            }
        } else {
            int k = tid % 16, nBase = tid / 16;
            #pragma unroll
            for (int p = 0; p < 4; p++) {
                int n = nBase + p * 16;
                int gn = n0 + n, gk = k0 + k;
                float v = 0.f;
                if (gn < N && gk < K) v = Bm[(long long)gn * ldb + gk];
                Bs[k][n] = v;
            }
        }
        __syncthreads();
        #pragma unroll
        for (int kk = 0; kk < 16; kk++) {
            float a[4], b[4];
            #pragma unroll
            for (int i = 0; i < 4; i++) a[i] = As[kk][ty * 4 + i];
            #pragma unroll
            for (int j = 0; j < 4; j++) b[j] = Bs[kk][tx * 4 + j];
            #pragma unroll
            for (int i = 0; i < 4; i++)
                #pragma unroll
                for (int j = 0; j < 4; j++)
                    acc[i][j] += a[i] * b[j];
        }
        __syncthreads();
    }

    #pragma unroll
    for (int i = 0; i < 4; i++) {
        int gm = m0 + ty * 4 + i;
        if (gm >= M) continue;
        #pragma unroll
        for (int j = 0; j < 4; j++) {
            int gn = n0 + tx * 4 + j;
            if (gn >= N) continue;
            float v = acc[i][j];
            if (bias) v += bias[gn];
            if (ACT == 1) v = v > 0.f ? v : ALPHA_LR * v;
            else if (ACT == 2) v = tanhf(v);
            if (MASKED) v *= maskR[(long long)z * M + gm] * maskC[(long long)z * N + gn];
            C[(long long)gm * ldc + gn] = v;
        }
    }
}

static inline void run_gemm(hipStream_t stream, int act, bool tb_masked,
    int M, int N, int K,
    const float* A, int lda, long long sA,
    const float* B, int ldb, long long sB,
    const float* bias, float* C, int ldc, long long sC,
    int batch, const float* maskR = nullptr, const float* maskC = nullptr)
{
    dim3 grid((N + 63) / 64, (M + 63) / 64, batch);
    dim3 blk(256);
    if (tb_masked) {
        gemm_k<2, 0, 1, 1><<<grid, blk, 0, stream>>>(M, N, K, A, lda, sA, B, ldb, sB,
                                                     bias, C, ldc, sC, maskR, maskC);
    } else if (act == 0) {
        gemm_k<0, 0, 0, 0><<<grid, blk, 0, stream>>>(M, N, K, A, lda, sA, B, ldb, sB,
                                                     bias, C, ldc, sC, nullptr, nullptr);
    } else if (act == 1) {
        gemm_k<1, 0, 0, 0><<<grid, blk, 0, stream>>>(M, N, K, A, lda, sA, B, ldb, sB,
                                                     bias, C, ldc, sC, nullptr, nullptr);
    } else {
        gemm_k<2, 0, 0, 0><<<grid, blk, 0, stream>>>(M, N, K, A, lda, sA, B, ldb, sB,
                                                     bias, C, ldc, sC, nullptr, nullptr);
    }
}

// per-row GAT source/dest attention logits
__global__ __launch_bounds__(128) void gat_e_k(
    const float* __restrict__ Wh, int ldWh, int GD,
    const float* __restrict__ a, int aStride,
    float* __restrict__ esrc, float* __restrict__ edst, int rows)
{
    int row = blockIdx.x;
    int k = blockIdx.y;
    int g = threadIdx.x;
    float ws = 0.f, wd = 0.f;
    if (g < GD) {
        float wv = Wh[(long long)row * ldWh + k * GD + g];
        ws = wv * a[k * aStride + g];
        wd = wv * a[k * aStride + GD + g];
    }
    __shared__ float sb[2][128];
    sb[0][threadIdx.x] = ws; sb[1][threadIdx.x] = wd;
    __syncthreads();
    for (int off = 64; off > 0; off >>= 1) {
        if (threadIdx.x < off) {
            sb[0][threadIdx.x] += sb[0][threadIdx.x + off];
            sb[1][threadIdx.x] += sb[1][threadIdx.x + off];
        }
        __syncthreads();
    }
    if (threadIdx.x == 0) {
        esrc[(long long)k * rows + row] = sb[0][0];
        edst[(long long)k * rows + row] = sb[1][0];
    }
}

// GAT attention: softmax over neighbors + weighted sum + ELU
__global__ __launch_bounds__(128) void gat_attn_k(
    const float* __restrict__ Wh, int ldWh, int GD,
    const int* __restrict__ adj,
    const float* __restrict__ esrc, const float* __restrict__ edst,
    float* __restrict__ out, int ldOut)
{
    int row = blockIdx.x;          // b*N + n
    int k = blockIdx.y;
    int rows = gridDim.x;
    int b = row / Nq, n = row % Nq;
    int m = threadIdx.x;

    __shared__ float att[Nq];
    __shared__ float red[Nq];

    float e = esrc[(long long)k * rows + row] + edst[(long long)k * rows + b * Nq + m];
    e = e > 0.f ? e : ALPHA_LR * e;
    if (adj[(long long)b * Nq * Nq + n * Nq + m] <= 0) e = -9.0e15f;

    red[m] = e; __syncthreads();
    for (int off = 64; off > 0; off >>= 1) {
        if (m < off) red[m] = fmaxf(red[m], red[m + off]);
        __syncthreads();
    }
    float mx = red[0]; __syncthreads();
    float ex = expf(e - mx);
    att[m] = ex; red[m] = ex; __syncthreads();
    for (int off = 64; off > 0; off >>= 1) {
        if (m < off) red[m] += red[m + off];
        __syncthreads();
    }
    float inv = 1.0f / red[0];

    for (int g = threadIdx.x; g < GD; g += blockDim.x) {
        float s = 0.f;
        for (int mm = 0; mm < Nq; mm++)
            s += att[mm] * Wh[(long long)(b * Nq + mm) * ldWh + k * GD + g];
        s *= inv;
        s = s > 0.f ? s : expm1f(s);   // ELU
        out[(long long)row * ldOut + k * GD + g] = s;
    }
}

// 11x11 same-pad conv over (M, PD), single channel, + leaky
__global__ __launch_bounds__(256) void conv_k(
    const float* __restrict__ x, const float* __restrict__ W,
    const float* __restrict__ bptr, float* __restrict__ y)
{
    __shared__ float w[121];
    if (threadIdx.x < 121) w[threadIdx.x] = W[threadIdx.x];
    __syncthreads();
    long long idx = (long long)blockIdx.x * blockDim.x + threadIdx.x;
    long long total = (long long)Bq * Mq * PDq;
    if (idx >= total) return;
    int d = (int)(idx % PDq);
    long long t = idx / PDq;
    int m = (int)(t % Mq);
    int b = (int)(t / Mq);
    const float* xb = x + (long long)b * Mq * PDq;
    float s = 0.f;
    #pragma unroll
    for (int i = 0; i < 11; i++) {
        int mm = m + i - 5;
        if (mm < 0 || mm >= Mq) continue;
        #pragma unroll
        for (int j = 0; j < 11; j++) {
            int dd = d + j - 5;
            if (dd < 0 || dd >= PDq) continue;
            s += xb[(long long)mm * PDq + dd] * w[i * 11 + j];
        }
    }
    s += *bptr;
    y[idx] = s > 0.f ? s : ALPHA_LR * s;
}

// out[b,m] = sum_n A[b,n,m] * q[b,n]
__global__ __launch_bounds__(256) void colsum_k(
    const float* __restrict__ A, const float* __restrict__ q, float* __restrict__ out)
{
    int b = blockIdx.y;
    int m = blockIdx.x * 256 + threadIdx.x;
    const float* Ab = A + (long long)b * Nq * Mq;
    const float* qb = q + (long long)b * Nq;
    float s = 0.f;
    for (int n = 0; n < Nq; n++) s += Ab[(long long)n * Mq + m] * qb[n];
    out[(long long)b * Mq + m] = s;
}

// score_c[row=b*N+n] = hbdot[row] + A[b,n,:]·r[b,:] + bias
__global__ __launch_bounds__(256) void scoreC_k(
    const float* __restrict__ hbdot, const float* __restrict__ A,
    const float* __restrict__ r,
    const float* __restrict__ bptr, float* __restrict__ score)
{
    int row = blockIdx.x;
    int b = row / Nq;
    int t = threadIdx.x;
    const float* Ar = A + (long long)row * Mq;
    const float* rb = r + (long long)b * Mq;
    float s = 0.f;
    for (int m = t; m < Mq; m += 256) s += Ar[m] * rb[m];
    __shared__ float red[256];
    red[t] = s; __syncthreads();
    for (int off = 128; off > 0; off >>= 1) {
        if (t < off) red[t] += red[t + off];
        __syncthreads();
    }
    if (t == 0) score[row] = red[0] + hbdot[row] + bptr[0];
}

// score_p[i] = hpbdot[i] + csum[i] + bias
__global__ __launch_bounds__(256) void scorePadd_k(
    float* __restrict__ score, const float* __restrict__ hpbdot,
    const float* __restrict__ csum, const float* __restrict__ bptr)
{
    int i = blockIdx.x * 256 + threadIdx.x;
    score[i] = hpbdot[i] + csum[i] + bptr[0];
}

// masked softmax in place over L, one block per batch row
__global__ __launch_bounds__(256) void msoftmax_k(
    float* __restrict__ score, const float* __restrict__ mask, int L)
{
    int b = blockIdx.x;
    float* s = score + (long long)b * L;
    const float* mk = mask + (long long)b * L;
    int t = threadIdx.x;
    __shared__ float red[256];
    float mx = -1e30f;
    for (int i = t; i < L; i += 256) mx = fmaxf(mx, s[i]);
    red[t] = mx; __syncthreads();
    for (int off = 128; off > 0; off >>= 1) {
        if (t < off) red[t] = fmaxf(red[t], red[t + off]);
        __syncthreads();
    }
    mx = red[0]; __syncthreads();
    float sum = 0.f;
    for (int i = t; i < L; i += 256) {
        float e = expf(s[i] - mx) * mk[i];
        s[i] = e; sum += e;
    }
    red[t] = sum; __syncthreads();
    for (int off = 128; off > 0; off >>= 1) {
        if (t < off) red[t] += red[t + off];
        __syncthreads();
    }
    float inv = 1.0f / (red[0] + 1e-6f);
    __syncthreads();
    for (int i = t; i < L; i += 256) s[i] *= inv;
}

// weighted sum stage 1: partial over 16 chunks
__global__ __launch_bounds__(256) void wsum1_k(
    const float* __restrict__ feat, const float* __restrict__ att,
    float* __restrict__ partial, int L)
{
    int b = blockIdx.x, c = blockIdx.y, l = threadIdx.x;
    int chunk = L / 16;
    const float* fb = feat + (long long)b * L * LDq;
    const float* ab = att + (long long)b * L;
    float s = 0.f;
    int r0 = c * chunk, r1 = r0 + chunk;
    for (int r = r0; r < r1; r++) s += fb[(long long)r * LDq + l] * ab[r];
    partial[((long long)b * 16 + c) * LDq + l] = s;
}

// weighted sum stage 2
__global__ __launch_bounds__(256) void wsum2_k(
    const float* __restrict__ partial, float* __restrict__ out, int outStride)
{
    int b = blockIdx.x, l = threadIdx.x;
    float s = 0.f;
    #pragma unroll
    for (int c = 0; c < 16; c++) s += partial[((long long)b * 16 + c) * LDq + l];
    out[(long long)b * outStride + l] = s;
}

// ---------------------------------------------------------------------------
// Skinny dense layer for the head
// ---------------------------------------------------------------------------
template<int ACT>
__global__ __launch_bounds__(256) void headlin_k(
    const float* __restrict__ vin, int ldv, int VD,
    const float* __restrict__ W, int ldw,
    const float* __restrict__ bias,
    float* __restrict__ vout, int ldo, int OD, int colBase)
{
    int b = blockIdx.x;
    int c = threadIdx.x & 63;
    int s = threadIdx.x >> 6;
    int col = blockIdx.y * 64 + c;

    __shared__ float vs[1024];
    for (int i = threadIdx.x; i < VD; i += 256) vs[i] = vin[(long long)b * ldv + i];
    __syncthreads();

    float sum = 0.f;
    if (col < OD) {
        int k0 = (VD * s) >> 2, k1 = (VD * (s + 1)) >> 2;
        #pragma unroll 4
        for (int k = k0; k < k1; k++)
            sum += vs[k] * W[(long long)k * ldw + col];
    }
    __shared__ float red[4][64];
    red[s][c] = sum;
    __syncthreads();
    if (s == 0 && col < OD) {
        float t = red[0][c] + red[1][c] + red[2][c] + red[3][c] + bias[col];
        if (ACT == 1) t = t > 0.f ? t : ALPHA_LR * t;
        vout[(long long)b * ldo + colBase + col] = t;
    }
}

// v[b,256:512]=fps, v[b,768]=invT, v[b,769]=T
__global__ __launch_bounds__(256) void vfill_k(
    const float* __restrict__ fps, const float* __restrict__ invT,
    const float* __restrict__ T, float* __restrict__ v)
{
    int b = blockIdx.x, t = threadIdx.x;
    v[(long long)b * 770 + 256 + t] = fps[(long long)b * 256 + t];
    if (t == 0) {
        v[(long long)b * 770 + 768] = invT[b];
        v[(long long)b * 770 + 769] = T[b];
    }
}

// out[b] = v[b,:770]·W + b
__global__ __launch_bounds__(256) void final_k(
    const float* __restrict__ v, const float* __restrict__ W,
    const float* __restrict__ bptr, float* __restrict__ out)
{
    int b = blockIdx.x, t = threadIdx.x;
    float s = 0.f;
    for (int i = t; i < 770; i += 256) s += v[(long long)b * 770 + i] * W[i];
    __shared__ float red[256];
    red[t] = s; __syncthreads();
    for (int off = 128; off > 0; off >>= 1) {
        if (t < off) red[t] += red[t + off];
        __syncthreads();
    }
    if (t == 0) out[b] = red[0] + bptr[0];
}

extern "C" void kernel_launch(void* const* d_in, const int* in_sizes, int n_in,
                              void* d_out, int out_size, void* d_ws, size_t ws_size,
                              hipStream_t stream)
{
    const float* atoms_emb = (const float*)d_in[0];
    const int*   adjacency = (const int*)d_in[1];
    const float* atoms_mask= (const float*)d_in[2];
    const float* amino_emb = (const float*)d_in[3];
    const float* amino_mask= (const float*)d_in[4];
    const float* fps       = (const float*)d_in[5];
    const float* inv_Temp  = (const float*)d_in[6];
    const float* Temp      = (const float*)d_in[7];
    const float* bert_W    = (const float*)d_in[8];
    const float* bert_b    = (const float*)d_in[9];
    const float* gat_W     = (const float*)d_in[10];
    const float* gat_a     = (const float*)d_in[11];
    const float* gatout_W  = (const float*)d_in[12];
    const float* gatout_a  = (const float*)d_in[13];
    const float* Wcomp_W   = (const float*)d_in[14];
    const float* Wcomp_b   = (const float*)d_in[15];
    const float* prot_W    = (const float*)d_in[16];
    const float* prot_b    = (const float*)d_in[17];
    const float* conv_W    = (const float*)d_in[18];
    const float* conv_b    = (const float*)d_in[19];
    const float* Wprot_W   = (const float*)d_in[20];
    const float* Wprot_b   = (const float*)d_in[21];
    const float* U         = (const float*)d_in[22];
    const float* tc2p_W    = (const float*)d_in[23];
    const float* tc2p_b    = (const float*)d_in[24];
    const float* tp2c_W    = (const float*)d_in[25];
    const float* tp2c_b    = (const float*)d_in[26];
    const float* bhc_W     = (const float*)d_in[27];
    const float* bhc_b     = (const float*)d_in[28];
    const float* bhp_W     = (const float*)d_in[29];
    const float* bhp_b     = (const float*)d_in[30];
    const float* battc_W   = (const float*)d_in[31];
    const float* battc_b   = (const float*)d_in[32];
    const float* battp_W   = (const float*)d_in[33];
    const float* battp_b   = (const float*)d_in[34];
    const float* combc_W   = (const float*)d_in[35];
    const float* combc_b   = (const float*)d_in[36];
    const float* combp_W   = (const float*)d_in[37];
    const float* combp_b   = (const float*)d_in[38];
    const float* Wout_W    = (const float*)d_in[39];
    const float* Wout_b    = (const float*)d_in[40];
    const float* out_W     = (const float*)d_in[41];
    const float* out_b     = (const float*)d_in[42];
    float* out = (float*)d_out;

    // ---- workspace layout (floats) ----
    float* w = (float*)d_ws;
    float* av    = w; w += (long long)Bq*Nq*LDq;
    float* pv    = w; w += (long long)Bq*Mq*LDq;
    float* sx    = w; w += (long long)Bq*Mq*LDq;   // early scratch -> precomp pool
    float* Abuf  = w; w += (long long)Bq*Nq*Mq;
    float* bufU  = w; w += (long long)Bq*Nq*LDq;
    float* bufTC = w; w += (long long)Bq*Nq*LDq;   // wsum partials
    float* esrc  = w; w += (long long)NHq*Bq*Nq;
    float* edst  = w; w += (long long)NHq*Bq*Nq;
    float* scoreC= w; w += (long long)Bq*Nq;
    float* scoreP= w; w += (long long)Bq*Mq;
    float* rbuf  = w; w += (long long)Bq*Mq;
    float* qbuf  = w; w += (long long)Bq*Nq;
    float* csum  = w; w += (long long)Bq*Mq;
    float* cf    = w; w += (long long)Bq*4*LDq;
    float* pf    = w; w += (long long)Bq*4*LDq;
    float* v1    = w; w += (long long)Bq*770;
    float* v2    = w; w += (long long)Bq*770;
    // bf16 buffers (carved as float-space, used as ushort)
    ushort_t* pv_bf  = (ushort_t*)w; w += (long long)Bq*Mq*LDq/2;
    ushort_t* av_bf  = (ushort_t*)w; w += (long long)Bq*Nq*LDq/2;
    ushort_t* avU_bf = (ushort_t*)w; w += (long long)Bq*Nq*LDq/2;
    ushort_t* Ut_bf    = (ushort_t*)w; w += (long long)4*LDq*LDq/2;
    ushort_t* tp2cT_bf = (ushort_t*)w; w += (long long)4*LDq*LDq/2;
    ushort_t* tc2pT_bf = (ushort_t*)w; w += (long long)4*LDq*LDq/2;
    ushort_t* bhcT_bf  = (ushort_t*)w; w += (long long)4*LDq*LDq/2;
    ushort_t* bhpT_bf  = (ushort_t*)w; w += (long long)4*LDq*LDq/2;
    ushort_t* protWt_bf= (ushort_t*)w; w += (long long)48*1024/2;

    int rowsA = Bq * Nq;     // 4096
    int rowsP = Bq * Mq;     // 32768

    // early-phase aliases inside sx (dead before BIDAT precompute)
    float* h     = sx;
    float* WhAll = h + (long long)Bq*Nq*CDq;
    float* multi = WhAll + (long long)Bq*Nq*NHq*GDq;
    float* Wh2   = multi + (long long)Bq*Nq*NHq*GDq;
    float* avp   = Wh2 + (long long)Bq*Nq*CDq;
    float* c0    = avp + (long long)Bq*Nq*CDq;
    float* c1    = c0 + (long long)Bq*Mq*PDq;

    // BIDAT-precompute pool in sx (loop-invariant, batched over z=4)
    float*    rbuf_all   = sx;                                    // 4*rowsP
    float*    hpbdot_all = rbuf_all   + (long long)4*rowsP;       // 4*rowsP
    float*    qbuf_all   = hpbdot_all + (long long)4*rowsP;       // 4*rowsA
    float*    hbdot_all  = qbuf_all   + (long long)4*rowsA;       // 4*rowsA
    float*    bufU_all   = hbdot_all  + (long long)4*rowsA;       // 4*rowsA*LDq
    ushort_t* avU_all_bf = (ushort_t*)(bufU_all + (long long)4*rowsA*LDq); // 4*rowsA*LDq bf16

    float* wpart = bufTC;   // wsum partials

    // ---- weight transpose-converts (once) ----
    wtcvt_k<<<dim3(256, 1, 4), 256, 0, stream>>>(U,      Ut_bf,    LDq, LDq, LDq, LDq);
    wtcvt_k<<<dim3(256, 1, 4), 256, 0, stream>>>(tp2c_W, tp2cT_bf, LDq, LDq, LDq, LDq);
    wtcvt_k<<<dim3(256, 1, 4), 256, 0, stream>>>(tc2p_W, tc2pT_bf, LDq, LDq, LDq, LDq);
    wtcvt_k<<<dim3(256, 1, 4), 256, 0, stream>>>(bhc_W,  bhcT_bf,  LDq, LDq, LDq, LDq);
    wtcvt_k<<<dim3(256, 1, 4), 256, 0, stream>>>(bhp_W,  bhpT_bf,  LDq, LDq, LDq, LDq);
    wtcvt_k<<<dim3((48*1024+255)/256, 1, 1), 256, 0, stream>>>(prot_W, protWt_bf, 1024, 40, 48, 1024);

    // 1. h = atoms_emb @ bert_W + bert_b   (K=300, fp32)
    run_gemm(stream, 0, false, rowsA, CDq, 300, atoms_emb, 300, 0,
             bert_W, CDq, 0, bert_b, h, CDq, 0, 1);

    // 2. Wh_all = h @ gat_W[k] (batched heads)
    run_gemm(stream, 0, false, rowsA, GDq, CDq, h, CDq, 0,
             gat_W, GDq, (long long)CDq*GDq, nullptr,
             WhAll, NHq*GDq, GDq, NHq);

    // 3-4. GAT heads -> multi (ELU)
    gat_e_k<<<dim3(rowsA, NHq), 128, 0, stream>>>(WhAll, NHq*GDq, GDq, gat_a, 2*GDq,
                                                  esrc, edst, rowsA);
    gat_attn_k<<<dim3(rowsA, NHq), 128, 0, stream>>>(WhAll, NHq*GDq, GDq, adjacency,
                                                     esrc, edst, multi, NHq*GDq);

    // 5-7. GAT out layer -> avp (ELU)
    run_gemm(stream, 0, false, rowsA, CDq, NHq*GDq, multi, NHq*GDq, 0,
             gatout_W, CDq, 0, nullptr, Wh2, CDq, 0, 1);
    gat_e_k<<<dim3(rowsA, 1), 128, 0, stream>>>(Wh2, CDq, CDq, gatout_a, 2*CDq,
                                                esrc, edst, rowsA);
    gat_attn_k<<<dim3(rowsA, 1), 128, 0, stream>>>(Wh2, CDq, CDq, adjacency,
                                                   esrc, edst, avp, CDq);

    // 8. av = leaky(avp @ Wcomp_W + b)
    run_gemm(stream, 1, false, rowsA, LDq, CDq, avp, CDq, 0,
             Wcomp_W, LDq, 0, Wcomp_b, av, LDq, 0, 1);
    cvt_bf16_k<<<(rowsA*LDq/4 + 255)/256, 256, 0, stream>>>(av, av_bf, (long long)rowsA*LDq/4);

    // 9. pv0 = amino_emb @ prot_W + b  -> MFMA (AF32 A-operand, N padded to 48)
    mfma_nt_k<0, 0, 1, 3, 1><<<dim3(rowsP/64, 1, 1), 256, 0, stream>>>(
        rowsP, 48, 1024, 40,
        (const void*)amino_emb, 1024, 0,
        protWt_bf, 1024, 0,
        prot_b, 0, c0, PDq, 0, nullptr, 0, nullptr);

    // 10. 3x conv 11x11 + leaky
    {
        long long total = (long long)Bq*Mq*PDq;
        int blocks = (int)((total + 255) / 256);
        conv_k<<<blocks, 256, 0, stream>>>(c0, conv_W + 0*121, conv_b + 0, c1);
        conv_k<<<blocks, 256, 0, stream>>>(c1, conv_W + 1*121, conv_b + 1, c0);
        conv_k<<<blocks, 256, 0, stream>>>(c0, conv_W + 2*121, conv_b + 2, c1);
    }

    // 11. pv = leaky(x @ Wprot_W + b)  (K=40, fp32)
    run_gemm(stream, 1, false, rowsP, LDq, PDq, c1, PDq, 0,
             Wprot_W, LDq, 0, Wprot_b, pv, LDq, 0, 1);
    cvt_bf16_k<<<(rowsP*LDq/4 + 255)/256, 256, 0, stream>>>(pv, pv_bf, (long long)rowsP*LDq/4);

    // ---- BIDAT precompute (loop-invariant, batched over z = i = 0..3) ----
    // r9: occupancy-optimized reduce kernel, 32 rows x 2 col-halves per block
    // r_all[i]      = tanh(pv@tp2c[i]+b)·battc2[i]   (4096 blocks)
    mfma_reduce_k<<<dim3(rowsP/32, 1, 4), 256, 0, stream>>>(
        rowsP, LDq, pv_bf, LDq,
        tp2cT_bf, LDq, (long long)LDq*LDq,
        tp2c_b, LDq, battc_W + LDq, 2*LDq,
        rbuf_all, rowsP);
    // hpbdot_all[i] = tanh(pv@bhp[i]+b)·battp1[i]
    mfma_reduce_k<<<dim3(rowsP/32, 1, 4), 256, 0, stream>>>(
        rowsP, LDq, pv_bf, LDq,
        bhpT_bf, LDq, (long long)LDq*LDq,
        bhp_b, LDq, battp_W, 2*LDq,
        hpbdot_all, rowsP);
    // q_all[i]      = tanh(av@tc2p[i]+b)·battp2[i]   (512 blocks)
    mfma_reduce_k<<<dim3(rowsA/32, 1, 4), 256, 0, stream>>>(
        rowsA, LDq, av_bf, LDq,
        tc2pT_bf, LDq, (long long)LDq*LDq,
        tc2p_b, LDq, battp_W + LDq, 2*LDq,
        qbuf_all, rowsA);
    // hbdot_all[i]  = tanh(av@bhc[i]+b)·battc1[i]
    mfma_reduce_k<<<dim3(rowsA/32, 1, 4), 256, 0, stream>>>(
        rowsA, LDq, av_bf, LDq,
        bhcT_bf, LDq, (long long)LDq*LDq,
        bhc_b, LDq, battc_W, 2*LDq,
        hbdot_all, rowsA);
    // avU_all[i] = av @ U[i]   (NT=4, 1024 blocks)
    mfma_nt_k<0, 0, 0, 4, 0><<<dim3(rowsA/64, 4, 4), 256, 0, stream>>>(
        rowsA, LDq, LDq, LDq, (const void*)av_bf, LDq, 0,
        Ut_bf, LDq, (long long)LDq*LDq,
        nullptr, 0, bufU_all, LDq, (long long)rowsA*LDq,
        nullptr, 0, nullptr);
    cvt_bf16_k<<<((long long)4*rowsA*LDq/4 + 255)/256, 256, 0, stream>>>(
        bufU_all, avU_all_bf, (long long)4*rowsA*LDq/4);

    // ---- 12. BIDAT loop (per-iter: A-GEMM + reductions + softmax + pool) ----
    for (int i = 0; i < 4; i++) {
        const float* battcbi = battc_b + i;
        const float* battpbi = battp_b + i;
        const ushort_t* avUI = avU_all_bf + (long long)i*rowsA*LDq;
        const float* rI    = rbuf_all   + (long long)i*rowsP;
        const float* hpI   = hpbdot_all + (long long)i*rowsP;
        const float* qI    = qbuf_all   + (long long)i*rowsA;
        const float* hbI   = hbdot_all  + (long long)i*rowsA;

        // A = tanh(avU @ pv^T) * masks   (r9: NT=4 -> 1024 blocks)
        mfma_nt_k<2, 1, 0, 4, 0><<<dim3(Nq/64, Mq/64, Bq), 256, 0, stream>>>(
            Nq, Mq, LDq, Mq,
            (const void*)avUI, LDq, (long long)Nq*LDq,
            pv_bf, LDq, (long long)Mq*LDq,
            nullptr, 0, Abuf, Mq, (long long)Nq*Mq,
            atoms_mask, 0, amino_mask);

        // csum[b,m] = sum_n A[b,n,m]*q[b,n]
        colsum_k<<<dim3(Mq/256, Bq), 256, 0, stream>>>(Abuf, qI, csum);
        // attention scores
        scoreC_k<<<rowsA, 256, 0, stream>>>(hbI, Abuf, rI, battcbi, scoreC);
        scorePadd_k<<<rowsP/256, 256, 0, stream>>>(scoreP, hpI, csum, battpbi);
        // masked softmax
        msoftmax_k<<<Bq, 256, 0, stream>>>(scoreC, atoms_mask, Nq);
        msoftmax_k<<<Bq, 256, 0, stream>>>(scoreP, amino_mask, Mq);
        // pooled features
        wsum1_k<<<dim3(Bq, 16), 256, 0, stream>>>(av, scoreC, wpart, Nq);
        wsum2_k<<<Bq, 256, 0, stream>>>(wpart, cf + (long long)i*LDq, 4*LDq);
        wsum1_k<<<dim3(Bq, 16), 256, 0, stream>>>(pv, scoreP, wpart, Mq);
        wsum2_k<<<Bq, 256, 0, stream>>>(wpart, pf + (long long)i*LDq, 4*LDq);
    }

    // 13. head: per-layer skinny kernels
    headlin_k<0><<<dim3(Bq, 4), 256, 0, stream>>>(cf, 4*LDq, 4*LDq,
        combc_W, LDq, combc_b, v1, 770, LDq, 0);
    headlin_k<0><<<dim3(Bq, 4), 256, 0, stream>>>(pf, 4*LDq, 4*LDq,
        combp_W, LDq, combp_b, v1, 770, LDq, 512);
    vfill_k<<<Bq, 256, 0, stream>>>(fps, inv_Temp, Temp, v1);

    headlin_k<1><<<dim3(Bq, 13), 256, 0, stream>>>(v1, 770, 770,
        Wout_W + 0ll*770*770, 770, Wout_b + 0*770, v2, 770, 770, 0);
    headlin_k<1><<<dim3(Bq, 13), 256, 0, stream>>>(v2, 770, 770,
        Wout_W + 1ll*770*770, 770, Wout_b + 1*770, v1, 770, 770, 0);
    headlin_k<1><<<dim3(Bq, 13), 256, 0, stream>>>(v1, 770, 770,
        Wout_W + 2ll*770*770, 770, Wout_b + 2*770, v2, 770, 770, 0);

    final_k<<<Bq, 256, 0, stream>>>(v2, out_W, out_b, out);

    (void)in_sizes; (void)n_in; (void)out_size; (void)ws_size;
    (void)bufU; (void)avU_bf; (void)rbuf; (void)qbuf;
}

// Round 10
// 1114.109 us; speedup vs baseline: 3.6531x; 1.1277x over previous
//
#include <hip/hip_runtime.h>
#include <math.h>

#define ALPHA_LR 0.2f

#define Bq  32
#define Nq  128
#define Mq  1024
#define CDq 128
#define GDq 64
#define NHq 4
#define LDq 256
#define PDq 40

typedef unsigned short ushort_t;
typedef __attribute__((ext_vector_type(8))) short bf16x8;
typedef __attribute__((ext_vector_type(4))) float f32x4;

__device__ __forceinline__ ushort_t f2bf(float f) {
    union { float f; unsigned u; } x; x.f = f;
    unsigned r = x.u + 0x7FFFu + ((x.u >> 16) & 1u);   // RNE
    return (ushort_t)(r >> 16);
}

// ---------------------------------------------------------------------------
// MFMA bf16 NT GEMM: C = act(A @ Bt^T + bias) [* masks]
// A: [M][lda] bf16 (or fp32 if AF32), Bt: [Npad][ldb] bf16 (= B^T, K-major)
// Each wave: 16 rows x NT*16 cols. grid.x = M/64 (4 waves/block),
// grid.y = N/(NT*16), grid.z = batch. K % 32 == 0. M % 16 == 0.
// C/D layout (m89-verified): col = lane&15, row = (lane>>4)*4 + reg.
// ---------------------------------------------------------------------------
template<int ACT, int MASKED, int HAS_BIAS, int NT, int AF32>
__global__ __launch_bounds__(256) void mfma_nt_k(
    int M, int N, int K, int Nout,
    const void* __restrict__ Av, int lda, long long sA,
    const ushort_t* __restrict__ Bt, int ldb, long long sB,
    const float* __restrict__ bias, long long sBias,
    float* __restrict__ C, int ldc, long long sC,
    const float* __restrict__ maskR, long long sW2,
    const float* __restrict__ maskC)
{
    int z = blockIdx.z;
    Bt += (long long)z * sB;
    C  += (long long)z * sC;
    if (HAS_BIAS) bias += (long long)z * sBias;

    int wave = threadIdx.x >> 6;
    int lane = threadIdx.x & 63;
    int lr = lane & 15;
    int kg = lane >> 4;
    int m0 = (blockIdx.x * 4 + wave) * 16;
    int n0 = blockIdx.y * (NT * 16);
    if (m0 >= M) return;

    f32x4 acc[NT];
    #pragma unroll
    for (int t = 0; t < NT; t++) acc[t] = (f32x4){0.f, 0.f, 0.f, 0.f};

    const ushort_t* Ab = nullptr;
    const float*    Af = nullptr;
    if (AF32) Af = (const float*)Av + (long long)z * sA + (long long)(m0 + lr) * lda + kg * 8;
    else      Ab = (const ushort_t*)Av + (long long)z * sA + (long long)(m0 + lr) * lda + kg * 8;
    const ushort_t* Bbase = Bt + (long long)(n0 + lr) * ldb + kg * 8;

    for (int k0 = 0; k0 < K; k0 += 32) {
        bf16x8 a;
        if (AF32) {
            float4 a0 = *(const float4*)(Af + k0);
            float4 a1 = *(const float4*)(Af + k0 + 4);
            a[0] = (short)f2bf(a0.x); a[1] = (short)f2bf(a0.y);
            a[2] = (short)f2bf(a0.z); a[3] = (short)f2bf(a0.w);
            a[4] = (short)f2bf(a1.x); a[5] = (short)f2bf(a1.y);
            a[6] = (short)f2bf(a1.z); a[7] = (short)f2bf(a1.w);
        } else {
            a = *(const bf16x8*)(Ab + k0);
        }
        #pragma unroll
        for (int t = 0; t < NT; t++) {
            bf16x8 b = *(const bf16x8*)(Bbase + (long long)t * 16 * ldb + k0);
            acc[t] = __builtin_amdgcn_mfma_f32_16x16x32_bf16(a, b, acc[t], 0, 0, 0);
        }
    }

    int row0 = m0 + kg * 4;
    #pragma unroll
    for (int t = 0; t < NT; t++) {
        int col = n0 + t * 16 + lr;
        if (col >= Nout) continue;
        float bv = HAS_BIAS ? bias[col] : 0.f;
        float mC = MASKED ? maskC[(long long)z * N + col] : 1.f;
        #pragma unroll
        for (int r = 0; r < 4; r++) {
            float v = acc[t][r] + bv;
            if (ACT == 1) v = v > 0.f ? v : ALPHA_LR * v;
            else if (ACT == 2) v = tanhf(v);
            if (MASKED) v *= maskR[(long long)z * M + row0 + r] * mC;
            C[(long long)(row0 + r) * ldc + col] = v;
        }
    }
}

// ---------------------------------------------------------------------------
// r10: LDS-staged reduce GEMM for the large (rowsP) reduces.
// r9's version had every block re-reading the full 128 KB weight matrix from
// L2 (1 GB hot-line traffic/dispatch). Here: block = 8 waves x 16 rows = 128
// rows; two phases, each staging a 64 KB B-half into XOR-swizzled LDS
// (byte ^= (row&7)<<4 -> stride-512B ds_read_b128 becomes 2-way = free);
// both halves accumulate into the same registers (no partials).
// out[z][row] = sum_col tanh((A @ Bt[z]^T)[row,col]+bias[z][col])*w2[z][col]
// grid = (M/128, 1, Z). K == 256 == N.
// ---------------------------------------------------------------------------
__global__ __launch_bounds__(512) void mfma_reduce_lds_k(
    int M, int K,
    const ushort_t* __restrict__ A, int lda,
    const ushort_t* __restrict__ Bt, int ldb, long long sB,
    const float* __restrict__ bias, long long sBias,
    const float* __restrict__ w2, long long sW2,
    float* __restrict__ C, long long sC)
{
    int z = blockIdx.z;
    Bt   += (long long)z * sB;
    bias += (long long)z * sBias;
    w2   += (long long)z * sW2;
    C    += (long long)z * sC;

    __shared__ ushort_t Bs[128 * 256];   // 64 KB, swizzled

    int wave = threadIdx.x >> 6;         // 0..7
    int lane = threadIdx.x & 63;
    int lr = lane & 15;
    int kg = lane >> 4;
    int m0 = blockIdx.x * 128 + wave * 16;

    const ushort_t* Ab = A + (long long)(m0 + lr) * lda + kg * 8;
    float rs[4] = {0.f, 0.f, 0.f, 0.f};

    for (int ph = 0; ph < 2; ph++) {
        int n0 = ph * 128;
        // stage B rows n0..n0+127 (swizzled): 8 steps x 512 thr x 16 B
        #pragma unroll
        for (int step = 0; step < 8; step++) {
            int g = step * 512 + threadIdx.x;
            int row = g >> 5;            // 0..127
            int slot = g & 31;           // 16B granule within row
            uint4 v = *(const uint4*)(Bt + (long long)(n0 + row) * ldb + slot * 8);
            int dst = row * 512 + ((slot * 16) ^ ((row & 7) << 4));
            *(uint4*)((char*)Bs + dst) = v;
        }
        __syncthreads();

        f32x4 acc[8];
        #pragma unroll
        for (int t = 0; t < 8; t++) acc[t] = (f32x4){0.f, 0.f, 0.f, 0.f};

        for (int k0 = 0; k0 < K; k0 += 32) {
            bf16x8 a = *(const bf16x8*)(Ab + k0);
            #pragma unroll
            for (int t = 0; t < 8; t++) {
                int rowl = t * 16 + lr;
                int colb = (kg * 16 + k0 * 2) ^ ((rowl & 7) << 4);
                bf16x8 b = *(const bf16x8*)((char*)Bs + rowl * 512 + colb);
                acc[t] = __builtin_amdgcn_mfma_f32_16x16x32_bf16(a, b, acc[t], 0, 0, 0);
            }
        }
        #pragma unroll
        for (int t = 0; t < 8; t++) {
            int col = n0 + t * 16 + lr;
            float bv = bias[col];
            float wv = w2[col];
            #pragma unroll
            for (int r = 0; r < 4; r++)
                rs[r] += tanhf(acc[t][r] + bv) * wv;
        }
        __syncthreads();   // protect Bs before next phase overwrites
    }

    #pragma unroll
    for (int r = 0; r < 4; r++) {
        rs[r] += __shfl_xor(rs[r], 1, 64);
        rs[r] += __shfl_xor(rs[r], 2, 64);
        rs[r] += __shfl_xor(rs[r], 4, 64);
        rs[r] += __shfl_xor(rs[r], 8, 64);
    }
    if (lr == 0) {
        int row0 = m0 + kg * 4;
        #pragma unroll
        for (int r = 0; r < 4; r++)
            C[row0 + r] = rs[r];
    }
}

// ---------------------------------------------------------------------------
// Small reduce GEMM (kept for rowsA: too few blocks for the LDS variant)
// ---------------------------------------------------------------------------
__global__ __launch_bounds__(256) void mfma_reduce_k(
    int M, int K,
    const ushort_t* __restrict__ A, int lda,
    const ushort_t* __restrict__ Bt, int ldb, long long sB,
    const float* __restrict__ bias, long long sBias,
    const float* __restrict__ w2, long long sW2,
    float* __restrict__ C, long long sC)
{
    int z = blockIdx.z;
    Bt   += (long long)z * sB;
    bias += (long long)z * sBias;
    w2   += (long long)z * sW2;
    C    += (long long)z * sC;

    int wave = threadIdx.x >> 6;
    int lane = threadIdx.x & 63;
    int lr = lane & 15;
    int kg = lane >> 4;
    int rg = wave >> 1;
    int half = wave & 1;
    int m0 = (blockIdx.x * 2 + rg) * 16;
    int n0 = half * 128;

    f32x4 acc[8];
    #pragma unroll
    for (int t = 0; t < 8; t++) acc[t] = (f32x4){0.f, 0.f, 0.f, 0.f};

    const ushort_t* Ab = A + (long long)(m0 + lr) * lda + kg * 8;
    const ushort_t* Bb = Bt + (long long)(n0 + lr) * ldb + kg * 8;

    for (int k0 = 0; k0 < K; k0 += 32) {
        bf16x8 a = *(const bf16x8*)(Ab + k0);
        #pragma unroll
        for (int t = 0; t < 8; t++) {
            bf16x8 b = *(const bf16x8*)(Bb + (long long)t * 16 * ldb + k0);
            acc[t] = __builtin_amdgcn_mfma_f32_16x16x32_bf16(a, b, acc[t], 0, 0, 0);
        }
    }

    float rs[4] = {0.f, 0.f, 0.f, 0.f};
    #pragma unroll
    for (int t = 0; t < 8; t++) {
        int col = n0 + t * 16 + lr;
        float bv = bias[col];
        float wv = w2[col];
        #pragma unroll
        for (int r = 0; r < 4; r++)
            rs[r] += tanhf(acc[t][r] + bv) * wv;
    }
    #pragma unroll
    for (int r = 0; r < 4; r++) {
        rs[r] += __shfl_xor(rs[r], 1, 64);
        rs[r] += __shfl_xor(rs[r], 2, 64);
        rs[r] += __shfl_xor(rs[r], 4, 64);
        rs[r] += __shfl_xor(rs[r], 8, 64);
    }
    __shared__ float lds[2][16][2];
    if (lr == 0) {
        #pragma unroll
        for (int r = 0; r < 4; r++)
            lds[rg][kg * 4 + r][half] = rs[r];
    }
    __syncthreads();
    int t = threadIdx.x;
    if (t < 32) {
        int g = t >> 4, row = t & 15;
        C[(long long)(blockIdx.x * 2 + g) * 16 + row] = lds[g][row][0] + lds[g][row][1];
    }
}

// fp32 -> bf16, 4 elems/thread, n % 4 == 0
__global__ __launch_bounds__(256) void cvt_bf16_k(
    const float* __restrict__ in, ushort_t* __restrict__ out, long long n4)
{
    long long i = (long long)blockIdx.x * 256 + threadIdx.x;
    if (i >= n4) return;
    float4 v = ((const float4*)in)[i];
    ushort4 o;
    o.x = f2bf(v.x); o.y = f2bf(v.y); o.z = f2bf(v.z); o.w = f2bf(v.w);
    ((ushort4*)out)[i] = o;
}

// W[K][Nsrc] fp32 -> Wt[Npad][Kp] bf16 (transposed, zero-padded), batched z
__global__ __launch_bounds__(256) void wtcvt_k(
    const float* __restrict__ W, ushort_t* __restrict__ Wt,
    int K, int Nsrc, int Npad, int Kp)
{
    int z = blockIdx.z;
    const float* Wz = W + (long long)z * K * Nsrc;
    ushort_t* Oz = Wt + (long long)z * Npad * Kp;
    int idx = blockIdx.x * 256 + threadIdx.x;
    if (idx >= Npad * Kp) return;
    int n = idx / Kp, k = idx % Kp;
    float v = (k < K && n < Nsrc) ? Wz[(long long)k * Nsrc + n] : 0.f;
    Oz[idx] = f2bf(v);
}

// ---------------------------------------------------------------------------
// Generic tiled fp32 GEMM (kept for small/odd-K GEMMs)
// ---------------------------------------------------------------------------
template<int ACT, int TA, int TB, int MASKED>
__global__ __launch_bounds__(256) void gemm_k(
    int M, int N, int K,
    const float* __restrict__ A, int lda, long long sA,
    const float* __restrict__ Bm, int ldb, long long sB,
    const float* __restrict__ bias,
    float* __restrict__ C, int ldc, long long sC,
    const float* __restrict__ maskR, const float* __restrict__ maskC)
{
    int z = blockIdx.z;
    A  += (long long)z * sA;
    Bm += (long long)z * sB;
    C  += (long long)z * sC;

    __shared__ float As[16][68];
    __shared__ float Bs[16][68];

    int tid = threadIdx.x;
    int tx = tid % 16, ty = tid / 16;
    int m0 = blockIdx.y * 64, n0 = blockIdx.x * 64;

    float acc[4][4] = {};

    for (int k0 = 0; k0 < K; k0 += 16) {
        if (!TA) {
            int k = tid % 16, mBase = tid / 16;
            #pragma unroll
            for (int p = 0; p < 4; p++) {
                int m = mBase + p * 16;
                int gm = m0 + m, gk = k0 + k;
                float v = 0.f;
                if (gm < M && gk < K) v = A[(long long)gm * lda + gk];
                As[k][m] = v;
            }
        } else {
            int m = tid % 64, kBase = tid / 64;
            #pragma unroll
            for (int p = 0; p < 4; p++) {
                int k = kBase + p * 4;
                int gm = m0 + m, gk = k0 + k;
                float v = 0.f;
                if (gm < M && gk < K) v = A[(long long)gk * lda + gm];
                As[k][m] = v;
            }
        }
        if (!TB) {
            int n = tid % 64, kBase = tid / 64;
            #pragma unroll
            for (int p = 0; p < 4; p++) {
                int k = kBase + p * 4;
                int gn = n0 + n, gk = k0 + k;
                float v = 0.f;
                if (gn < N && gk < K) v = Bm[(long long)gk * ldb + gn];
                Bs[k][n] = v;
            }
        } else {
            int k = tid % 16, nBase = tid / 16;
            #pragma unroll
            for (int p = 0; p < 4; p++) {
                int n = nBase + p * 16;
                int gn = n0 + n, gk = k0 + k;
                float v = 0.f;
                if (gn < N && gk < K) v = Bm[(long long)gn * ldb + gk];
                Bs[k][n] = v;
            }
        }
        __syncthreads();
        #pragma unroll
        for (int kk = 0; kk < 16; kk++) {
            float a[4], b[4];
            #pragma unroll
            for (int i = 0; i < 4; i++) a[i] = As[kk][ty * 4 + i];
            #pragma unroll
            for (int j = 0; j < 4; j++) b[j] = Bs[kk][tx * 4 + j];
            #pragma unroll
            for (int i = 0; i < 4; i++)
                #pragma unroll
                for (int j = 0; j < 4; j++)
                    acc[i][j] += a[i] * b[j];
        }
        __syncthreads();
    }

    #pragma unroll
    for (int i = 0; i < 4; i++) {
        int gm = m0 + ty * 4 + i;
        if (gm >= M) continue;
        #pragma unroll
        for (int j = 0; j < 4; j++) {
            int gn = n0 + tx * 4 + j;
            if (gn >= N) continue;
            float v = acc[i][j];
            if (bias) v += bias[gn];
            if (ACT == 1) v = v > 0.f ? v : ALPHA_LR * v;
            else if (ACT == 2) v = tanhf(v);
            if (MASKED) v *= maskR[(long long)z * M + gm] * maskC[(long long)z * N + gn];
            C[(long long)gm * ldc + gn] = v;
        }
    }
}

static inline void run_gemm(hipStream_t stream, int act, bool tb_masked,
    int M, int N, int K,
    const float* A, int lda, long long sA,
    const float* B, int ldb, long long sB,
    const float* bias, float* C, int ldc, long long sC,
    int batch, const float* maskR = nullptr, const float* maskC = nullptr)
{
    dim3 grid((N + 63) / 64, (M + 63) / 64, batch);
    dim3 blk(256);
    if (tb_masked) {
        gemm_k<2, 0, 1, 1><<<grid, blk, 0, stream>>>(M, N, K, A, lda, sA, B, ldb, sB,
                                                     bias, C, ldc, sC, maskR, maskC);
    } else if (act == 0) {
        gemm_k<0, 0, 0, 0><<<grid, blk, 0, stream>>>(M, N, K, A, lda, sA, B, ldb, sB,
                                                     bias, C, ldc, sC, nullptr, nullptr);
    } else if (act == 1) {
        gemm_k<1, 0, 0, 0><<<grid, blk, 0, stream>>>(M, N, K, A, lda, sA, B, ldb, sB,
                                                     bias, C, ldc, sC, nullptr, nullptr);
    } else {
        gemm_k<2, 0, 0, 0><<<grid, blk, 0, stream>>>(M, N, K, A, lda, sA, B, ldb, sB,
                                                     bias, C, ldc, sC, nullptr, nullptr);
    }
}

// per-row GAT source/dest attention logits
__global__ __launch_bounds__(128) void gat_e_k(
    const float* __restrict__ Wh, int ldWh, int GD,
    const float* __restrict__ a, int aStride,
    float* __restrict__ esrc, float* __restrict__ edst, int rows)
{
    int row = blockIdx.x;
    int k = blockIdx.y;
    int g = threadIdx.x;
    float ws = 0.f, wd = 0.f;
    if (g < GD) {
        float wv = Wh[(long long)row * ldWh + k * GD + g];
        ws = wv * a[k * aStride + g];
        wd = wv * a[k * aStride + GD + g];
    }
    __shared__ float sb[2][128];
    sb[0][threadIdx.x] = ws; sb[1][threadIdx.x] = wd;
    __syncthreads();
    for (int off = 64; off > 0; off >>= 1) {
        if (threadIdx.x < off) {
            sb[0][threadIdx.x] += sb[0][threadIdx.x + off];
            sb[1][threadIdx.x] += sb[1][threadIdx.x + off];
        }
        __syncthreads();
    }
    if (threadIdx.x == 0) {
        esrc[(long long)k * rows + row] = sb[0][0];
        edst[(long long)k * rows + row] = sb[1][0];
    }
}

// GAT attention: softmax over neighbors + weighted sum + ELU
__global__ __launch_bounds__(128) void gat_attn_k(
    const float* __restrict__ Wh, int ldWh, int GD,
    const int* __restrict__ adj,
    const float* __restrict__ esrc, const float* __restrict__ edst,
    float* __restrict__ out, int ldOut)
{
    int row = blockIdx.x;          // b*N + n
    int k = blockIdx.y;
    int rows = gridDim.x;
    int b = row / Nq, n = row % Nq;
    int m = threadIdx.x;

    __shared__ float att[Nq];
    __shared__ float red[Nq];

    float e = esrc[(long long)k * rows + row] + edst[(long long)k * rows + b * Nq + m];
    e = e > 0.f ? e : ALPHA_LR * e;
    if (adj[(long long)b * Nq * Nq + n * Nq + m] <= 0) e = -9.0e15f;

    red[m] = e; __syncthreads();
    for (int off = 64; off > 0; off >>= 1) {
        if (m < off) red[m] = fmaxf(red[m], red[m + off]);
        __syncthreads();
    }
    float mx = red[0]; __syncthreads();
    float ex = expf(e - mx);
    att[m] = ex; red[m] = ex; __syncthreads();
    for (int off = 64; off > 0; off >>= 1) {
        if (m < off) red[m] += red[m + off];
        __syncthreads();
    }
    float inv = 1.0f / red[0];

    for (int g = threadIdx.x; g < GD; g += blockDim.x) {
        float s = 0.f;
        for (int mm = 0; mm < Nq; mm++)
            s += att[mm] * Wh[(long long)(b * Nq + mm) * ldWh + k * GD + g];
        s *= inv;
        s = s > 0.f ? s : expm1f(s);   // ELU
        out[(long long)row * ldOut + k * GD + g] = s;
    }
}

// 11x11 same-pad conv over (M, PD), single channel, + leaky
__global__ __launch_bounds__(256) void conv_k(
    const float* __restrict__ x, const float* __restrict__ W,
    const float* __restrict__ bptr, float* __restrict__ y)
{
    __shared__ float w[121];
    if (threadIdx.x < 121) w[threadIdx.x] = W[threadIdx.x];
    __syncthreads();
    long long idx = (long long)blockIdx.x * blockDim.x + threadIdx.x;
    long long total = (long long)Bq * Mq * PDq;
    if (idx >= total) return;
    int d = (int)(idx % PDq);
    long long t = idx / PDq;
    int m = (int)(t % Mq);
    int b = (int)(t / Mq);
    const float* xb = x + (long long)b * Mq * PDq;
    float s = 0.f;
    #pragma unroll
    for (int i = 0; i < 11; i++) {
        int mm = m + i - 5;
        if (mm < 0 || mm >= Mq) continue;
        #pragma unroll
        for (int j = 0; j < 11; j++) {
            int dd = d + j - 5;
            if (dd < 0 || dd >= PDq) continue;
            s += xb[(long long)mm * PDq + dd] * w[i * 11 + j];
        }
    }
    s += *bptr;
    y[idx] = s > 0.f ? s : ALPHA_LR * s;
}

// out[b,m] = sum_n A[b,n,m] * q[b,n]
__global__ __launch_bounds__(256) void colsum_k(
    const float* __restrict__ A, const float* __restrict__ q, float* __restrict__ out)
{
    int b = blockIdx.y;
    int m = blockIdx.x * 256 + threadIdx.x;
    const float* Ab = A + (long long)b * Nq * Mq;
    const float* qb = q + (long long)b * Nq;
    float s = 0.f;
    for (int n = 0; n < Nq; n++) s += Ab[(long long)n * Mq + m] * qb[n];
    out[(long long)b * Mq + m] = s;
}

// score_c[row=b*N+n] = hbdot[row] + A[b,n,:]·r[b,:] + bias
__global__ __launch_bounds__(256) void scoreC_k(
    const float* __restrict__ hbdot, const float* __restrict__ A,
    const float* __restrict__ r,
    const float* __restrict__ bptr, float* __restrict__ score)
{
    int row = blockIdx.x;
    int b = row / Nq;
    int t = threadIdx.x;
    const float* Ar = A + (long long)row * Mq;
    const float* rb = r + (long long)b * Mq;
    float s = 0.f;
    for (int m = t; m < Mq; m += 256) s += Ar[m] * rb[m];
    __shared__ float red[256];
    red[t] = s; __syncthreads();
    for (int off = 128; off > 0; off >>= 1) {
        if (t < off) red[t] += red[t + off];
        __syncthreads();
    }
    if (t == 0) score[row] = red[0] + hbdot[row] + bptr[0];
}

// score_p[i] = hpbdot[i] + csum[i] + bias
__global__ __launch_bounds__(256) void scorePadd_k(
    float* __restrict__ score, const float* __restrict__ hpbdot,
    const float* __restrict__ csum, const float* __restrict__ bptr)
{
    int i = blockIdx.x * 256 + threadIdx.x;
    score[i] = hpbdot[i] + csum[i] + bptr[0];
}

// masked softmax in place over L, one block per batch row
__global__ __launch_bounds__(256) void msoftmax_k(
    float* __restrict__ score, const float* __restrict__ mask, int L)
{
    int b = blockIdx.x;
    float* s = score + (long long)b * L;
    const float* mk = mask + (long long)b * L;
    int t = threadIdx.x;
    __shared__ float red[256];
    float mx = -1e30f;
    for (int i = t; i < L; i += 256) mx = fmaxf(mx, s[i]);
    red[t] = mx; __syncthreads();
    for (int off = 128; off > 0; off >>= 1) {
        if (t < off) red[t] = fmaxf(red[t], red[t + off]);
        __syncthreads();
    }
    mx = red[0]; __syncthreads();
    float sum = 0.f;
    for (int i = t; i < L; i += 256) {
        float e = expf(s[i] - mx) * mk[i];
        s[i] = e; sum += e;
    }
    red[t] = sum; __syncthreads();
    for (int off = 128; off > 0; off >>= 1) {
        if (t < off) red[t] += red[t + off];
        __syncthreads();
    }
    float inv = 1.0f / (red[0] + 1e-6f);
    __syncthreads();
    for (int i = t; i < L; i += 256) s[i] *= inv;
}

// weighted sum stage 1: partial over 16 chunks
__global__ __launch_bounds__(256) void wsum1_k(
    const float* __restrict__ feat, const float* __restrict__ att,
    float* __restrict__ partial, int L)
{
    int b = blockIdx.x, c = blockIdx.y, l = threadIdx.x;
    int chunk = L / 16;
    const float* fb = feat + (long long)b * L * LDq;
    const float* ab = att + (long long)b * L;
    float s = 0.f;
    int r0 = c * chunk, r1 = r0 + chunk;
    for (int r = r0; r < r1; r++) s += fb[(long long)r * LDq + l] * ab[r];
    partial[((long long)b * 16 + c) * LDq + l] = s;
}

// weighted sum stage 2
__global__ __launch_bounds__(256) void wsum2_k(
    const float* __restrict__ partial, float* __restrict__ out, int outStride)
{
    int b = blockIdx.x, l = threadIdx.x;
    float s = 0.f;
    #pragma unroll
    for (int c = 0; c < 16; c++) s += partial[((long long)b * 16 + c) * LDq + l];
    out[(long long)b * outStride + l] = s;
}

// ---------------------------------------------------------------------------
// Skinny dense layer for the head
// ---------------------------------------------------------------------------
template<int ACT>
__global__ __launch_bounds__(256) void headlin_k(
    const float* __restrict__ vin, int ldv, int VD,
    const float* __restrict__ W, int ldw,
    const float* __restrict__ bias,
    float* __restrict__ vout, int ldo, int OD, int colBase)
{
    int b = blockIdx.x;
    int c = threadIdx.x & 63;
    int s = threadIdx.x >> 6;
    int col = blockIdx.y * 64 + c;

    __shared__ float vs[1024];
    for (int i = threadIdx.x; i < VD; i += 256) vs[i] = vin[(long long)b * ldv + i];
    __syncthreads();

    float sum = 0.f;
    if (col < OD) {
        int k0 = (VD * s) >> 2, k1 = (VD * (s + 1)) >> 2;
        #pragma unroll 4
        for (int k = k0; k < k1; k++)
            sum += vs[k] * W[(long long)k * ldw + col];
    }
    __shared__ float red[4][64];
    red[s][c] = sum;
    __syncthreads();
    if (s == 0 && col < OD) {
        float t = red[0][c] + red[1][c] + red[2][c] + red[3][c] + bias[col];
        if (ACT == 1) t = t > 0.f ? t : ALPHA_LR * t;
        vout[(long long)b * ldo + colBase + col] = t;
    }
}

// v[b,256:512]=fps, v[b,768]=invT, v[b,769]=T
__global__ __launch_bounds__(256) void vfill_k(
    const float* __restrict__ fps, const float* __restrict__ invT,
    const float* __restrict__ T, float* __restrict__ v)
{
    int b = blockIdx.x, t = threadIdx.x;
    v[(long long)b * 770 + 256 + t] = fps[(long long)b * 256 + t];
    if (t == 0) {
        v[(long long)b * 770 + 768] = invT[b];
        v[(long long)b * 770 + 769] = T[b];
    }
}

// out[b] = v[b,:770]·W + b
__global__ __launch_bounds__(256) void final_k(
    const float* __restrict__ v, const float* __restrict__ W,
    const float* __restrict__ bptr, float* __restrict__ out)
{
    int b = blockIdx.x, t = threadIdx.x;
    float s = 0.f;
    for (int i = t; i < 770; i += 256) s += v[(long long)b * 770 + i] * W[i];
    __shared__ float red[256];
    red[t] = s; __syncthreads();
    for (int off = 128; off > 0; off >>= 1) {
        if (t < off) red[t] += red[t + off];
        __syncthreads();
    }
    if (t == 0) out[b] = red[0] + bptr[0];
}

extern "C" void kernel_launch(void* const* d_in, const int* in_sizes, int n_in,
                              void* d_out, int out_size, void* d_ws, size_t ws_size,
                              hipStream_t stream)
{
    const float* atoms_emb = (const float*)d_in[0];
    const int*   adjacency = (const int*)d_in[1];
    const float* atoms_mask= (const float*)d_in[2];
    const float* amino_emb = (const float*)d_in[3];
    const float* amino_mask= (const float*)d_in[4];
    const float* fps       = (const float*)d_in[5];
    const float* inv_Temp  = (const float*)d_in[6];
    const float* Temp      = (const float*)d_in[7];
    const float* bert_W    = (const float*)d_in[8];
    const float* bert_b    = (const float*)d_in[9];
    const float* gat_W     = (const float*)d_in[10];
    const float* gat_a     = (const float*)d_in[11];
    const float* gatout_W  = (const float*)d_in[12];
    const float* gatout_a  = (const float*)d_in[13];
    const float* Wcomp_W   = (const float*)d_in[14];
    const float* Wcomp_b   = (const float*)d_in[15];
    const float* prot_W    = (const float*)d_in[16];
    const float* prot_b    = (const float*)d_in[17];
    const float* conv_W    = (const float*)d_in[18];
    const float* conv_b    = (const float*)d_in[19];
    const float* Wprot_W   = (const float*)d_in[20];
    const float* Wprot_b   = (const float*)d_in[21];
    const float* U         = (const float*)d_in[22];
    const float* tc2p_W    = (const float*)d_in[23];
    const float* tc2p_b    = (const float*)d_in[24];
    const float* tp2c_W    = (const float*)d_in[25];
    const float* tp2c_b    = (const float*)d_in[26];
    const float* bhc_W     = (const float*)d_in[27];
    const float* bhc_b     = (const float*)d_in[28];
    const float* bhp_W     = (const float*)d_in[29];
    const float* bhp_b     = (const float*)d_in[30];
    const float* battc_W   = (const float*)d_in[31];
    const float* battc_b   = (const float*)d_in[32];
    const float* battp_W   = (const float*)d_in[33];
    const float* battp_b   = (const float*)d_in[34];
    const float* combc_W   = (const float*)d_in[35];
    const float* combc_b   = (const float*)d_in[36];
    const float* combp_W   = (const float*)d_in[37];
    const float* combp_b   = (const float*)d_in[38];
    const float* Wout_W    = (const float*)d_in[39];
    const float* Wout_b    = (const float*)d_in[40];
    const float* out_W     = (const float*)d_in[41];
    const float* out_b     = (const float*)d_in[42];
    float* out = (float*)d_out;

    // ---- workspace layout (floats) ----
    float* w = (float*)d_ws;
    float* av    = w; w += (long long)Bq*Nq*LDq;
    float* pv    = w; w += (long long)Bq*Mq*LDq;
    float* sx    = w; w += (long long)Bq*Mq*LDq;   // early scratch -> precomp pool
    float* Abuf  = w; w += (long long)Bq*Nq*Mq;
    float* bufU  = w; w += (long long)Bq*Nq*LDq;
    float* bufTC = w; w += (long long)Bq*Nq*LDq;   // wsum partials
    float* esrc  = w; w += (long long)NHq*Bq*Nq;
    float* edst  = w; w += (long long)NHq*Bq*Nq;
    float* scoreC= w; w += (long long)Bq*Nq;
    float* scoreP= w; w += (long long)Bq*Mq;
    float* rbuf  = w; w += (long long)Bq*Mq;
    float* qbuf  = w; w += (long long)Bq*Nq;
    float* csum  = w; w += (long long)Bq*Mq;
    float* cf    = w; w += (long long)Bq*4*LDq;
    float* pf    = w; w += (long long)Bq*4*LDq;
    float* v1    = w; w += (long long)Bq*770;
    float* v2    = w; w += (long long)Bq*770;
    // bf16 buffers (carved as float-space, used as ushort)
    ushort_t* pv_bf  = (ushort_t*)w; w += (long long)Bq*Mq*LDq/2;
    ushort_t* av_bf  = (ushort_t*)w; w += (long long)Bq*Nq*LDq/2;
    ushort_t* avU_bf = (ushort_t*)w; w += (long long)Bq*Nq*LDq/2;
    ushort_t* Ut_bf    = (ushort_t*)w; w += (long long)4*LDq*LDq/2;
    ushort_t* tp2cT_bf = (ushort_t*)w; w += (long long)4*LDq*LDq/2;
    ushort_t* tc2pT_bf = (ushort_t*)w; w += (long long)4*LDq*LDq/2;
    ushort_t* bhcT_bf  = (ushort_t*)w; w += (long long)4*LDq*LDq/2;
    ushort_t* bhpT_bf  = (ushort_t*)w; w += (long long)4*LDq*LDq/2;
    ushort_t* protWt_bf= (ushort_t*)w; w += (long long)48*1024/2;

    int rowsA = Bq * Nq;     // 4096
    int rowsP = Bq * Mq;     // 32768

    // early-phase aliases inside sx (dead before BIDAT precompute)
    float* h     = sx;
    float* WhAll = h + (long long)Bq*Nq*CDq;
    float* multi = WhAll + (long long)Bq*Nq*NHq*GDq;
    float* Wh2   = multi + (long long)Bq*Nq*NHq*GDq;
    float* avp   = Wh2 + (long long)Bq*Nq*CDq;
    float* c0    = avp + (long long)Bq*Nq*CDq;
    float* c1    = c0 + (long long)Bq*Mq*PDq;

    // BIDAT-precompute pool in sx (loop-invariant, batched over z=4)
    float*    rbuf_all   = sx;                                    // 4*rowsP
    float*    hpbdot_all = rbuf_all   + (long long)4*rowsP;       // 4*rowsP
    float*    qbuf_all   = hpbdot_all + (long long)4*rowsP;       // 4*rowsA
    float*    hbdot_all  = qbuf_all   + (long long)4*rowsA;       // 4*rowsA
    float*    bufU_all   = hbdot_all  + (long long)4*rowsA;       // 4*rowsA*LDq
    ushort_t* avU_all_bf = (ushort_t*)(bufU_all + (long long)4*rowsA*LDq); // 4*rowsA*LDq bf16

    float* wpart = bufTC;   // wsum partials

    // ---- weight transpose-converts (once) ----
    wtcvt_k<<<dim3(256, 1, 4), 256, 0, stream>>>(U,      Ut_bf,    LDq, LDq, LDq, LDq);
    wtcvt_k<<<dim3(256, 1, 4), 256, 0, stream>>>(tp2c_W, tp2cT_bf, LDq, LDq, LDq, LDq);
    wtcvt_k<<<dim3(256, 1, 4), 256, 0, stream>>>(tc2p_W, tc2pT_bf, LDq, LDq, LDq, LDq);
    wtcvt_k<<<dim3(256, 1, 4), 256, 0, stream>>>(bhc_W,  bhcT_bf,  LDq, LDq, LDq, LDq);
    wtcvt_k<<<dim3(256, 1, 4), 256, 0, stream>>>(bhp_W,  bhpT_bf,  LDq, LDq, LDq, LDq);
    wtcvt_k<<<dim3((48*1024+255)/256, 1, 1), 256, 0, stream>>>(prot_W, protWt_bf, 1024, 40, 48, 1024);

    // 1. h = atoms_emb @ bert_W + bert_b   (K=300, fp32)
    run_gemm(stream, 0, false, rowsA, CDq, 300, atoms_emb, 300, 0,
             bert_W, CDq, 0, bert_b, h, CDq, 0, 1);

    // 2. Wh_all = h @ gat_W[k] (batched heads)
    run_gemm(stream, 0, false, rowsA, GDq, CDq, h, CDq, 0,
             gat_W, GDq, (long long)CDq*GDq, nullptr,
             WhAll, NHq*GDq, GDq, NHq);

    // 3-4. GAT heads -> multi (ELU)
    gat_e_k<<<dim3(rowsA, NHq), 128, 0, stream>>>(WhAll, NHq*GDq, GDq, gat_a, 2*GDq,
                                                  esrc, edst, rowsA);
    gat_attn_k<<<dim3(rowsA, NHq), 128, 0, stream>>>(WhAll, NHq*GDq, GDq, adjacency,
                                                     esrc, edst, multi, NHq*GDq);

    // 5-7. GAT out layer -> avp (ELU)
    run_gemm(stream, 0, false, rowsA, CDq, NHq*GDq, multi, NHq*GDq, 0,
             gatout_W, CDq, 0, nullptr, Wh2, CDq, 0, 1);
    gat_e_k<<<dim3(rowsA, 1), 128, 0, stream>>>(Wh2, CDq, CDq, gatout_a, 2*CDq,
                                                esrc, edst, rowsA);
    gat_attn_k<<<dim3(rowsA, 1), 128, 0, stream>>>(Wh2, CDq, CDq, adjacency,
                                                   esrc, edst, avp, CDq);

    // 8. av = leaky(avp @ Wcomp_W + b)
    run_gemm(stream, 1, false, rowsA, LDq, CDq, avp, CDq, 0,
             Wcomp_W, LDq, 0, Wcomp_b, av, LDq, 0, 1);
    cvt_bf16_k<<<(rowsA*LDq/4 + 255)/256, 256, 0, stream>>>(av, av_bf, (long long)rowsA*LDq/4);

    // 9. pv0 = amino_emb @ prot_W + b  -> MFMA (AF32 A-operand, N padded to 48)
    mfma_nt_k<0, 0, 1, 3, 1><<<dim3(rowsP/64, 1, 1), 256, 0, stream>>>(
        rowsP, 48, 1024, 40,
        (const void*)amino_emb, 1024, 0,
        protWt_bf, 1024, 0,
        prot_b, 0, c0, PDq, 0, nullptr, 0, nullptr);

    // 10. 3x conv 11x11 + leaky
    {
        long long total = (long long)Bq*Mq*PDq;
        int blocks = (int)((total + 255) / 256);
        conv_k<<<blocks, 256, 0, stream>>>(c0, conv_W + 0*121, conv_b + 0, c1);
        conv_k<<<blocks, 256, 0, stream>>>(c1, conv_W + 1*121, conv_b + 1, c0);
        conv_k<<<blocks, 256, 0, stream>>>(c0, conv_W + 2*121, conv_b + 2, c1);
    }

    // 11. pv = leaky(x @ Wprot_W + b)  (K=40, fp32)
    run_gemm(stream, 1, false, rowsP, LDq, PDq, c1, PDq, 0,
             Wprot_W, LDq, 0, Wprot_b, pv, LDq, 0, 1);
    cvt_bf16_k<<<(rowsP*LDq/4 + 255)/256, 256, 0, stream>>>(pv, pv_bf, (long long)rowsP*LDq/4);

    // ---- BIDAT precompute (loop-invariant, batched over z = i = 0..3) ----
    // r10: LDS-staged reduce for rowsP (hot-B L2 traffic 1 GB -> 128 MB)
    mfma_reduce_lds_k<<<dim3(rowsP/128, 1, 4), 512, 0, stream>>>(
        rowsP, LDq, pv_bf, LDq,
        tp2cT_bf, LDq, (long long)LDq*LDq,
        tp2c_b, LDq, battc_W + LDq, 2*LDq,
        rbuf_all, rowsP);
    mfma_reduce_lds_k<<<dim3(rowsP/128, 1, 4), 512, 0, stream>>>(
        rowsP, LDq, pv_bf, LDq,
        bhpT_bf, LDq, (long long)LDq*LDq,
        bhp_b, LDq, battp_W, 2*LDq,
        hpbdot_all, rowsP);
    // q_all[i] = tanh(av@tc2p[i]+b)·battp2[i]   (rowsA, small)
    mfma_reduce_k<<<dim3(rowsA/32, 1, 4), 256, 0, stream>>>(
        rowsA, LDq, av_bf, LDq,
        tc2pT_bf, LDq, (long long)LDq*LDq,
        tc2p_b, LDq, battp_W + LDq, 2*LDq,
        qbuf_all, rowsA);
    // hbdot_all[i] = tanh(av@bhc[i]+b)·battc1[i]
    mfma_reduce_k<<<dim3(rowsA/32, 1, 4), 256, 0, stream>>>(
        rowsA, LDq, av_bf, LDq,
        bhcT_bf, LDq, (long long)LDq*LDq,
        bhc_b, LDq, battc_W, 2*LDq,
        hbdot_all, rowsA);
    // avU_all[i] = av @ U[i]   (NT=4, 1024 blocks)
    mfma_nt_k<0, 0, 0, 4, 0><<<dim3(rowsA/64, 4, 4), 256, 0, stream>>>(
        rowsA, LDq, LDq, LDq, (const void*)av_bf, LDq, 0,
        Ut_bf, LDq, (long long)LDq*LDq,
        nullptr, 0, bufU_all, LDq, (long long)rowsA*LDq,
        nullptr, 0, nullptr);
    cvt_bf16_k<<<((long long)4*rowsA*LDq/4 + 255)/256, 256, 0, stream>>>(
        bufU_all, avU_all_bf, (long long)4*rowsA*LDq/4);

    // ---- 12. BIDAT loop (per-iter: A-GEMM + reductions + softmax + pool) ----
    for (int i = 0; i < 4; i++) {
        const float* battcbi = battc_b + i;
        const float* battpbi = battp_b + i;
        const ushort_t* avUI = avU_all_bf + (long long)i*rowsA*LDq;
        const float* rI    = rbuf_all   + (long long)i*rowsP;
        const float* hpI   = hpbdot_all + (long long)i*rowsP;
        const float* qI    = qbuf_all   + (long long)i*rowsA;
        const float* hbI   = hbdot_all  + (long long)i*rowsA;

        // A = tanh(avU @ pv^T) * masks   (NT=4 -> 1024 blocks)
        mfma_nt_k<2, 1, 0, 4, 0><<<dim3(Nq/64, Mq/64, Bq), 256, 0, stream>>>(
            Nq, Mq, LDq, Mq,
            (const void*)avUI, LDq, (long long)Nq*LDq,
            pv_bf, LDq, (long long)Mq*LDq,
            nullptr, 0, Abuf, Mq, (long long)Nq*Mq,
            atoms_mask, 0, amino_mask);

        // csum[b,m] = sum_n A[b,n,m]*q[b,n]
        colsum_k<<<dim3(Mq/256, Bq), 256, 0, stream>>>(Abuf, qI, csum);
        // attention scores
        scoreC_k<<<rowsA, 256, 0, stream>>>(hbI, Abuf, rI, battcbi, scoreC);
        scorePadd_k<<<rowsP/256, 256, 0, stream>>>(scoreP, hpI, csum, battpbi);
        // masked softmax
        msoftmax_k<<<Bq, 256, 0, stream>>>(scoreC, atoms_mask, Nq);
        msoftmax_k<<<Bq, 256, 0, stream>>>(scoreP, amino_mask, Mq);
        // pooled features
        wsum1_k<<<dim3(Bq, 16), 256, 0, stream>>>(av, scoreC, wpart, Nq);
        wsum2_k<<<Bq, 256, 0, stream>>>(wpart, cf + (long long)i*LDq, 4*LDq);
        wsum1_k<<<dim3(Bq, 16), 256, 0, stream>>>(pv, scoreP, wpart, Mq);
        wsum2_k<<<Bq, 256, 0, stream>>>(wpart, pf + (long long)i*LDq, 4*LDq);
    }

    // 13. head: per-layer skinny kernels
    headlin_k<0><<<dim3(Bq, 4), 256, 0, stream>>>(cf, 4*LDq, 4*LDq,
        combc_W, LDq, combc_b, v1, 770, LDq, 0);
    headlin_k<0><<<dim3(Bq, 4), 256, 0, stream>>>(pf, 4*LDq, 4*LDq,
        combp_W, LDq, combp_b, v1, 770, LDq, 512);
    vfill_k<<<Bq, 256, 0, stream>>>(fps, inv_Temp, Temp, v1);

    headlin_k<1><<<dim3(Bq, 13), 256, 0, stream>>>(v1, 770, 770,
        Wout_W + 0ll*770*770, 770, Wout_b + 0*770, v2, 770, 770, 0);
    headlin_k<1><<<dim3(Bq, 13), 256, 0, stream>>>(v2, 770, 770,
        Wout_W + 1ll*770*770, 770, Wout_b + 1*770, v1, 770, 770, 0);
    headlin_k<1><<<dim3(Bq, 13), 256, 0, stream>>>(v1, 770, 770,
        Wout_W + 2ll*770*770, 770, Wout_b + 2*770, v2, 770, 770, 0);

    final_k<<<Bq, 256, 0, stream>>>(v2, out_W, out_b, out);

    (void)in_sizes; (void)n_in; (void)out_size; (void)ws_size;
    (void)bufU; (void)avU_bf; (void)rbuf; (void)qbuf;
}

// Round 11
// 938.164 us; speedup vs baseline: 4.3382x; 1.1875x over previous
//
#include <hip/hip_runtime.h>
#include <math.h>

#define ALPHA_LR 0.2f

#define Bq  32
#define Nq  128
#define Mq  1024
#define CDq 128
#define GDq 64
#define NHq 4
#define LDq 256
#define PDq 40

typedef unsigned short ushort_t;
typedef __attribute__((ext_vector_type(8))) short bf16x8;
typedef __attribute__((ext_vector_type(4))) float f32x4;

__device__ __forceinline__ ushort_t f2bf(float f) {
    union { float f; unsigned u; } x; x.f = f;
    unsigned r = x.u + 0x7FFFu + ((x.u >> 16) & 1u);   // RNE
    return (ushort_t)(r >> 16);
}

// ---------------------------------------------------------------------------
// MFMA bf16 NT GEMM (kept for pv0 and avU): C = act(A @ Bt^T + bias)
// ---------------------------------------------------------------------------
template<int ACT, int MASKED, int HAS_BIAS, int NT, int AF32>
__global__ __launch_bounds__(256) void mfma_nt_k(
    int M, int N, int K, int Nout,
    const void* __restrict__ Av, int lda, long long sA,
    const ushort_t* __restrict__ Bt, int ldb, long long sB,
    const float* __restrict__ bias, long long sBias,
    float* __restrict__ C, int ldc, long long sC,
    const float* __restrict__ maskR, long long sW2,
    const float* __restrict__ maskC)
{
    int z = blockIdx.z;
    Bt += (long long)z * sB;
    C  += (long long)z * sC;
    if (HAS_BIAS) bias += (long long)z * sBias;

    int wave = threadIdx.x >> 6;
    int lane = threadIdx.x & 63;
    int lr = lane & 15;
    int kg = lane >> 4;
    int m0 = (blockIdx.x * 4 + wave) * 16;
    int n0 = blockIdx.y * (NT * 16);
    if (m0 >= M) return;

    f32x4 acc[NT];
    #pragma unroll
    for (int t = 0; t < NT; t++) acc[t] = (f32x4){0.f, 0.f, 0.f, 0.f};

    const ushort_t* Ab = nullptr;
    const float*    Af = nullptr;
    if (AF32) Af = (const float*)Av + (long long)z * sA + (long long)(m0 + lr) * lda + kg * 8;
    else      Ab = (const ushort_t*)Av + (long long)z * sA + (long long)(m0 + lr) * lda + kg * 8;
    const ushort_t* Bbase = Bt + (long long)(n0 + lr) * ldb + kg * 8;

    for (int k0 = 0; k0 < K; k0 += 32) {
        bf16x8 a;
        if (AF32) {
            float4 a0 = *(const float4*)(Af + k0);
            float4 a1 = *(const float4*)(Af + k0 + 4);
            a[0] = (short)f2bf(a0.x); a[1] = (short)f2bf(a0.y);
            a[2] = (short)f2bf(a0.z); a[3] = (short)f2bf(a0.w);
            a[4] = (short)f2bf(a1.x); a[5] = (short)f2bf(a1.y);
            a[6] = (short)f2bf(a1.z); a[7] = (short)f2bf(a1.w);
        } else {
            a = *(const bf16x8*)(Ab + k0);
        }
        #pragma unroll
        for (int t = 0; t < NT; t++) {
            bf16x8 b = *(const bf16x8*)(Bbase + (long long)t * 16 * ldb + k0);
            acc[t] = __builtin_amdgcn_mfma_f32_16x16x32_bf16(a, b, acc[t], 0, 0, 0);
        }
    }

    int row0 = m0 + kg * 4;
    #pragma unroll
    for (int t = 0; t < NT; t++) {
        int col = n0 + t * 16 + lr;
        if (col >= Nout) continue;
        float bv = HAS_BIAS ? bias[col] : 0.f;
        float mC = MASKED ? maskC[(long long)z * N + col] : 1.f;
        #pragma unroll
        for (int r = 0; r < 4; r++) {
            float v = acc[t][r] + bv;
            if (ACT == 1) v = v > 0.f ? v : ALPHA_LR * v;
            else if (ACT == 2) v = tanhf(v);
            if (MASKED) v *= maskR[(long long)z * M + row0 + r] * mC;
            C[(long long)(row0 + r) * ldc + col] = v;
        }
    }
}

// ---------------------------------------------------------------------------
// r11: fused BIDAT A-chain. A = tanh(avU@pv^T)*masks is ONLY consumed via
//   scoreC[n] = sum_m A*r[m]  and  csum[m] = sum_n A*q[n]
// so compute each 64x64 tile in registers and accumulate BOTH reductions
// without materializing A (kills 16.7MB Abuf write + 33.5MB reads per iter).
// All 4 BIDAT iterations batched: grid (gx=2 n-half, gy=16 m-block, z=i*32+b).
// Outputs: scoreCp[z][16 gy][128 n], csump[z][2 gx][1024 m] partials.
// ---------------------------------------------------------------------------
__global__ __launch_bounds__(256) void bidat_fused_k(
    const ushort_t* __restrict__ avU_all,  // [4][4096][256] bf16
    const ushort_t* __restrict__ pv_bf,    // [32768][256] bf16
    const float* __restrict__ rbuf_all,    // [4][32768]
    const float* __restrict__ qbuf_all,    // [4][4096]
    const float* __restrict__ atoms_mask,  // [32][128]
    const float* __restrict__ amino_mask,  // [32][1024]
    float* __restrict__ scoreCp,           // [128][16][128]
    float* __restrict__ csump)             // [128][2][1024]
{
    int z = blockIdx.z;               // i*32 + b
    int i = z >> 5, b = z & 31;
    int gx = blockIdx.x;              // n-half
    int gy = blockIdx.y;              // m-block
    int wave = threadIdx.x >> 6;
    int lane = threadIdx.x & 63;
    int lr = lane & 15, kg = lane >> 4;

    int n0 = gx * 64 + wave * 16;     // 0..127 (batch-local atom row)
    int m0 = gy * 64;                 // 0..1023 (batch-local amino col)

    const ushort_t* Ab = avU_all + ((long long)i * 4096 + (long long)b * 128 + n0 + lr) * 256 + kg * 8;
    const ushort_t* Bb = pv_bf   + ((long long)b * 1024 + m0 + lr) * 256 + kg * 8;

    f32x4 acc[4];
    #pragma unroll
    for (int t = 0; t < 4; t++) acc[t] = (f32x4){0.f, 0.f, 0.f, 0.f};

    for (int k0 = 0; k0 < 256; k0 += 32) {
        bf16x8 a = *(const bf16x8*)(Ab + k0);
        #pragma unroll
        for (int t = 0; t < 4; t++) {
            bf16x8 bf = *(const bf16x8*)(Bb + (long long)t * 16 * 256 + k0);
            acc[t] = __builtin_amdgcn_mfma_f32_16x16x32_bf16(a, bf, acc[t], 0, 0, 0);
        }
    }

    const float* rI = rbuf_all + (long long)i * 32768 + (long long)b * 1024;
    const float* qI = qbuf_all + (long long)i * 4096 + (long long)b * 128;
    const float* mR = atoms_mask + (long long)b * 128;
    const float* mC = amino_mask + (long long)b * 1024;

    float sc[4] = {0.f, 0.f, 0.f, 0.f};   // scoreC partial per output row r
    float cs[4] = {0.f, 0.f, 0.f, 0.f};   // csum partial per col-frag t
    #pragma unroll
    for (int t = 0; t < 4; t++) {
        int m = m0 + t * 16 + lr;
        float mc = mC[m];
        float rv = rI[m];
        #pragma unroll
        for (int r = 0; r < 4; r++) {
            int n = n0 + kg * 4 + r;
            float a = tanhf(acc[t][r]) * mR[n] * mc;
            sc[r] += a * rv;
            cs[t] += a * qI[n];
        }
    }

    // scoreC: reduce over lr (cols within wave)
    #pragma unroll
    for (int r = 0; r < 4; r++) {
        sc[r] += __shfl_xor(sc[r], 1, 64);
        sc[r] += __shfl_xor(sc[r], 2, 64);
        sc[r] += __shfl_xor(sc[r], 4, 64);
        sc[r] += __shfl_xor(sc[r], 8, 64);
    }
    if (lr == 0) {
        #pragma unroll
        for (int r = 0; r < 4; r++) {
            int n = gx * 64 + wave * 16 + kg * 4 + r;
            scoreCp[((long long)z * 16 + gy) * 128 + n] = sc[r];
        }
    }

    // csum: reduce over kg (rows within wave), then across 4 waves via LDS
    #pragma unroll
    for (int t = 0; t < 4; t++) {
        cs[t] += __shfl_xor(cs[t], 16, 64);
        cs[t] += __shfl_xor(cs[t], 32, 64);
    }
    __shared__ float cl[4][64];
    if (kg == 0) {
        #pragma unroll
        for (int t = 0; t < 4; t++) cl[wave][t * 16 + lr] = cs[t];
    }
    __syncthreads();
    if (threadIdx.x < 64) {
        float s = cl[0][threadIdx.x] + cl[1][threadIdx.x]
                + cl[2][threadIdx.x] + cl[3][threadIdx.x];
        csump[((long long)z * 2 + gx) * 1024 + m0 + threadIdx.x] = s;
    }
}

// scoreC_all[z][n] = sum_gy scoreCp + hbdot + bias
__global__ __launch_bounds__(128) void finishC_k(
    const float* __restrict__ scoreCp, const float* __restrict__ hbdot_all,
    const float* __restrict__ battc_b, float* __restrict__ scoreC_all)
{
    int z = blockIdx.x;           // i*32+b
    int i = z >> 5, b = z & 31;
    int n = threadIdx.x;
    float s = 0.f;
    #pragma unroll
    for (int gy = 0; gy < 16; gy++)
        s += scoreCp[((long long)z * 16 + gy) * 128 + n];
    scoreC_all[(long long)z * 128 + n] =
        s + hbdot_all[(long long)i * 4096 + b * 128 + n] + battc_b[i];
}

// scoreP_all[z][m] = csump[z][0][m]+csump[z][1][m] + hpbdot + bias
__global__ __launch_bounds__(256) void finishP_k(
    const float* __restrict__ csump, const float* __restrict__ hpbdot_all,
    const float* __restrict__ battp_b, float* __restrict__ scoreP_all)
{
    int z = blockIdx.x;
    int i = z >> 5, b = z & 31;
    int m = blockIdx.y * 256 + threadIdx.x;
    float s = csump[((long long)z * 2 + 0) * 1024 + m]
            + csump[((long long)z * 2 + 1) * 1024 + m];
    scoreP_all[(long long)z * 1024 + m] =
        s + hpbdot_all[(long long)i * 32768 + (long long)b * 1024 + m] + battp_b[i];
}

// ---------------------------------------------------------------------------
// r10: LDS-staged reduce GEMM for the large (rowsP) reduces.
// ---------------------------------------------------------------------------
__global__ __launch_bounds__(512) void mfma_reduce_lds_k(
    int M, int K,
    const ushort_t* __restrict__ A, int lda,
    const ushort_t* __restrict__ Bt, int ldb, long long sB,
    const float* __restrict__ bias, long long sBias,
    const float* __restrict__ w2, long long sW2,
    float* __restrict__ C, long long sC)
{
    int z = blockIdx.z;
    Bt   += (long long)z * sB;
    bias += (long long)z * sBias;
    w2   += (long long)z * sW2;
    C    += (long long)z * sC;

    __shared__ ushort_t Bs[128 * 256];   // 64 KB, swizzled

    int wave = threadIdx.x >> 6;
    int lane = threadIdx.x & 63;
    int lr = lane & 15;
    int kg = lane >> 4;
    int m0 = blockIdx.x * 128 + wave * 16;

    const ushort_t* Ab = A + (long long)(m0 + lr) * lda + kg * 8;
    float rs[4] = {0.f, 0.f, 0.f, 0.f};

    for (int ph = 0; ph < 2; ph++) {
        int n0 = ph * 128;
        #pragma unroll
        for (int step = 0; step < 8; step++) {
            int g = step * 512 + threadIdx.x;
            int row = g >> 5;
            int slot = g & 31;
            uint4 v = *(const uint4*)(Bt + (long long)(n0 + row) * ldb + slot * 8);
            int dst = row * 512 + ((slot * 16) ^ ((row & 7) << 4));
            *(uint4*)((char*)Bs + dst) = v;
        }
        __syncthreads();

        f32x4 acc[8];
        #pragma unroll
        for (int t = 0; t < 8; t++) acc[t] = (f32x4){0.f, 0.f, 0.f, 0.f};

        for (int k0 = 0; k0 < K; k0 += 32) {
            bf16x8 a = *(const bf16x8*)(Ab + k0);
            #pragma unroll
            for (int t = 0; t < 8; t++) {
                int rowl = t * 16 + lr;
                int colb = (kg * 16 + k0 * 2) ^ ((rowl & 7) << 4);
                bf16x8 b = *(const bf16x8*)((char*)Bs + rowl * 512 + colb);
                acc[t] = __builtin_amdgcn_mfma_f32_16x16x32_bf16(a, b, acc[t], 0, 0, 0);
            }
        }
        #pragma unroll
        for (int t = 0; t < 8; t++) {
            int col = n0 + t * 16 + lr;
            float bv = bias[col];
            float wv = w2[col];
            #pragma unroll
            for (int r = 0; r < 4; r++)
                rs[r] += tanhf(acc[t][r] + bv) * wv;
        }
        __syncthreads();
    }

    #pragma unroll
    for (int r = 0; r < 4; r++) {
        rs[r] += __shfl_xor(rs[r], 1, 64);
        rs[r] += __shfl_xor(rs[r], 2, 64);
        rs[r] += __shfl_xor(rs[r], 4, 64);
        rs[r] += __shfl_xor(rs[r], 8, 64);
    }
    if (lr == 0) {
        int row0 = m0 + kg * 4;
        #pragma unroll
        for (int r = 0; r < 4; r++)
            C[row0 + r] = rs[r];
    }
}

// Small reduce GEMM (rowsA)
__global__ __launch_bounds__(256) void mfma_reduce_k(
    int M, int K,
    const ushort_t* __restrict__ A, int lda,
    const ushort_t* __restrict__ Bt, int ldb, long long sB,
    const float* __restrict__ bias, long long sBias,
    const float* __restrict__ w2, long long sW2,
    float* __restrict__ C, long long sC)
{
    int z = blockIdx.z;
    Bt   += (long long)z * sB;
    bias += (long long)z * sBias;
    w2   += (long long)z * sW2;
    C    += (long long)z * sC;

    int wave = threadIdx.x >> 6;
    int lane = threadIdx.x & 63;
    int lr = lane & 15;
    int kg = lane >> 4;
    int rg = wave >> 1;
    int half = wave & 1;
    int m0 = (blockIdx.x * 2 + rg) * 16;
    int n0 = half * 128;

    f32x4 acc[8];
    #pragma unroll
    for (int t = 0; t < 8; t++) acc[t] = (f32x4){0.f, 0.f, 0.f, 0.f};

    const ushort_t* Ab = A + (long long)(m0 + lr) * lda + kg * 8;
    const ushort_t* Bb = Bt + (long long)(n0 + lr) * ldb + kg * 8;

    for (int k0 = 0; k0 < K; k0 += 32) {
        bf16x8 a = *(const bf16x8*)(Ab + k0);
        #pragma unroll
        for (int t = 0; t < 8; t++) {
            bf16x8 b = *(const bf16x8*)(Bb + (long long)t * 16 * ldb + k0);
            acc[t] = __builtin_amdgcn_mfma_f32_16x16x32_bf16(a, b, acc[t], 0, 0, 0);
        }
    }

    float rs[4] = {0.f, 0.f, 0.f, 0.f};
    #pragma unroll
    for (int t = 0; t < 8; t++) {
        int col = n0 + t * 16 + lr;
        float bv = bias[col];
        float wv = w2[col];
        #pragma unroll
        for (int r = 0; r < 4; r++)
            rs[r] += tanhf(acc[t][r] + bv) * wv;
    }
    #pragma unroll
    for (int r = 0; r < 4; r++) {
        rs[r] += __shfl_xor(rs[r], 1, 64);
        rs[r] += __shfl_xor(rs[r], 2, 64);
        rs[r] += __shfl_xor(rs[r], 4, 64);
        rs[r] += __shfl_xor(rs[r], 8, 64);
    }
    __shared__ float lds[2][16][2];
    if (lr == 0) {
        #pragma unroll
        for (int r = 0; r < 4; r++)
            lds[rg][kg * 4 + r][half] = rs[r];
    }
    __syncthreads();
    int t = threadIdx.x;
    if (t < 32) {
        int g = t >> 4, row = t & 15;
        C[(long long)(blockIdx.x * 2 + g) * 16 + row] = lds[g][row][0] + lds[g][row][1];
    }
}

// fp32 -> bf16
__global__ __launch_bounds__(256) void cvt_bf16_k(
    const float* __restrict__ in, ushort_t* __restrict__ out, long long n4)
{
    long long i = (long long)blockIdx.x * 256 + threadIdx.x;
    if (i >= n4) return;
    float4 v = ((const float4*)in)[i];
    ushort4 o;
    o.x = f2bf(v.x); o.y = f2bf(v.y); o.z = f2bf(v.z); o.w = f2bf(v.w);
    ((ushort4*)out)[i] = o;
}

// W[K][Nsrc] fp32 -> Wt[Npad][Kp] bf16 (transposed, padded), batched z
__global__ __launch_bounds__(256) void wtcvt_k(
    const float* __restrict__ W, ushort_t* __restrict__ Wt,
    int K, int Nsrc, int Npad, int Kp)
{
    int z = blockIdx.z;
    const float* Wz = W + (long long)z * K * Nsrc;
    ushort_t* Oz = Wt + (long long)z * Npad * Kp;
    int idx = blockIdx.x * 256 + threadIdx.x;
    if (idx >= Npad * Kp) return;
    int n = idx / Kp, k = idx % Kp;
    float v = (k < K && n < Nsrc) ? Wz[(long long)k * Nsrc + n] : 0.f;
    Oz[idx] = f2bf(v);
}

// ---------------------------------------------------------------------------
// Generic tiled fp32 GEMM (early phase)
// ---------------------------------------------------------------------------
template<int ACT, int TA, int TB, int MASKED>
__global__ __launch_bounds__(256) void gemm_k(
    int M, int N, int K,
    const float* __restrict__ A, int lda, long long sA,
    const float* __restrict__ Bm, int ldb, long long sB,
    const float* __restrict__ bias,
    float* __restrict__ C, int ldc, long long sC,
    const float* __restrict__ maskR, const float* __restrict__ maskC)
{
    int z = blockIdx.z;
    A  += (long long)z * sA;
    Bm += (long long)z * sB;
    C  += (long long)z * sC;

    __shared__ float As[16][68];
    __shared__ float Bs[16][68];

    int tid = threadIdx.x;
    int tx = tid % 16, ty = tid / 16;
    int m0 = blockIdx.y * 64, n0 = blockIdx.x * 64;

    float acc[4][4] = {};

    for (int k0 = 0; k0 < K; k0 += 16) {
        if (!TA) {
            int k = tid % 16, mBase = tid / 16;
            #pragma unroll
            for (int p = 0; p < 4; p++) {
                int m = mBase + p * 16;
                int gm = m0 + m, gk = k0 + k;
                float v = 0.f;
                if (gm < M && gk < K) v = A[(long long)gm * lda + gk];
                As[k][m] = v;
            }
        } else {
            int m = tid % 64, kBase = tid / 64;
            #pragma unroll
            for (int p = 0; p < 4; p++) {
                int k = kBase + p * 4;
                int gm = m0 + m, gk = k0 + k;
                float v = 0.f;
                if (gm < M && gk < K) v = A[(long long)gk * lda + gm];
                As[k][m] = v;
            }
        }
        if (!TB) {
            int n = tid % 64, kBase = tid / 64;
            #pragma unroll
            for (int p = 0; p < 4; p++) {
                int k = kBase + p * 4;
                int gn = n0 + n, gk = k0 + k;
                float v = 0.f;
                if (gn < N && gk < K) v = Bm[(long long)gk * ldb + gn];
                Bs[k][n] = v;
            }
        } else {
            int k = tid % 16, nBase = tid / 16;
            #pragma unroll
            for (int p = 0; p < 4; p++) {
                int n = nBase + p * 16;
                int gn = n0 + n, gk = k0 + k;
                float v = 0.f;
                if (gn < N && gk < K) v = Bm[(long long)gn * ldb + gk];
                Bs[k][n] = v;
            }
        }
        __syncthreads();
        #pragma unroll
        for (int kk = 0; kk < 16; kk++) {
            float a[4], b[4];
            #pragma unroll
            for (int i = 0; i < 4; i++) a[i] = As[kk][ty * 4 + i];
            #pragma unroll
            for (int j = 0; j < 4; j++) b[j] = Bs[kk][tx * 4 + j];
            #pragma unroll
            for (int i = 0; i < 4; i++)
                #pragma unroll
                for (int j = 0; j < 4; j++)
                    acc[i][j] += a[i] * b[j];
        }
        __syncthreads();
    }

    #pragma unroll
    for (int i = 0; i < 4; i++) {
        int gm = m0 + ty * 4 + i;
        if (gm >= M) continue;
        #pragma unroll
        for (int j = 0; j < 4; j++) {
            int gn = n0 + tx * 4 + j;
            if (gn >= N) continue;
            float v = acc[i][j];
            if (bias) v += bias[gn];
            if (ACT == 1) v = v > 0.f ? v : ALPHA_LR * v;
            else if (ACT == 2) v = tanhf(v);
            if (MASKED) v *= maskR[(long long)z * M + gm] * maskC[(long long)z * N + gn];
            C[(long long)gm * ldc + gn] = v;
        }
    }
}

static inline void run_gemm(hipStream_t stream, int act, bool tb_masked,
    int M, int N, int K,
    const float* A, int lda, long long sA,
    const float* B, int ldb, long long sB,
    const float* bias, float* C, int ldc, long long sC,
    int batch, const float* maskR = nullptr, const float* maskC = nullptr)
{
    dim3 grid((N + 63) / 64, (M + 63) / 64, batch);
    dim3 blk(256);
    if (tb_masked) {
        gemm_k<2, 0, 1, 1><<<grid, blk, 0, stream>>>(M, N, K, A, lda, sA, B, ldb, sB,
                                                     bias, C, ldc, sC, maskR, maskC);
    } else if (act == 0) {
        gemm_k<0, 0, 0, 0><<<grid, blk, 0, stream>>>(M, N, K, A, lda, sA, B, ldb, sB,
                                                     bias, C, ldc, sC, nullptr, nullptr);
    } else if (act == 1) {
        gemm_k<1, 0, 0, 0><<<grid, blk, 0, stream>>>(M, N, K, A, lda, sA, B, ldb, sB,
                                                     bias, C, ldc, sC, nullptr, nullptr);
    } else {
        gemm_k<2, 0, 0, 0><<<grid, blk, 0, stream>>>(M, N, K, A, lda, sA, B, ldb, sB,
                                                     bias, C, ldc, sC, nullptr, nullptr);
    }
}

// per-row GAT source/dest attention logits
__global__ __launch_bounds__(128) void gat_e_k(
    const float* __restrict__ Wh, int ldWh, int GD,
    const float* __restrict__ a, int aStride,
    float* __restrict__ esrc, float* __restrict__ edst, int rows)
{
    int row = blockIdx.x;
    int k = blockIdx.y;
    int g = threadIdx.x;
    float ws = 0.f, wd = 0.f;
    if (g < GD) {
        float wv = Wh[(long long)row * ldWh + k * GD + g];
        ws = wv * a[k * aStride + g];
        wd = wv * a[k * aStride + GD + g];
    }
    __shared__ float sb[2][128];
    sb[0][threadIdx.x] = ws; sb[1][threadIdx.x] = wd;
    __syncthreads();
    for (int off = 64; off > 0; off >>= 1) {
        if (threadIdx.x < off) {
            sb[0][threadIdx.x] += sb[0][threadIdx.x + off];
            sb[1][threadIdx.x] += sb[1][threadIdx.x + off];
        }
        __syncthreads();
    }
    if (threadIdx.x == 0) {
        esrc[(long long)k * rows + row] = sb[0][0];
        edst[(long long)k * rows + row] = sb[1][0];
    }
}

// GAT attention: softmax over neighbors + weighted sum + ELU
__global__ __launch_bounds__(128) void gat_attn_k(
    const float* __restrict__ Wh, int ldWh, int GD,
    const int* __restrict__ adj,
    const float* __restrict__ esrc, const float* __restrict__ edst,
    float* __restrict__ out, int ldOut)
{
    int row = blockIdx.x;
    int k = blockIdx.y;
    int rows = gridDim.x;
    int b = row / Nq, n = row % Nq;
    int m = threadIdx.x;

    __shared__ float att[Nq];
    __shared__ float red[Nq];

    float e = esrc[(long long)k * rows + row] + edst[(long long)k * rows + b * Nq + m];
    e = e > 0.f ? e : ALPHA_LR * e;
    if (adj[(long long)b * Nq * Nq + n * Nq + m] <= 0) e = -9.0e15f;

    red[m] = e; __syncthreads();
    for (int off = 64; off > 0; off >>= 1) {
        if (m < off) red[m] = fmaxf(red[m], red[m + off]);
        __syncthreads();
    }
    float mx = red[0]; __syncthreads();
    float ex = expf(e - mx);
    att[m] = ex; red[m] = ex; __syncthreads();
    for (int off = 64; off > 0; off >>= 1) {
        if (m < off) red[m] += red[m + off];
        __syncthreads();
    }
    float inv = 1.0f / red[0];

    for (int g = threadIdx.x; g < GD; g += blockDim.x) {
        float s = 0.f;
        for (int mm = 0; mm < Nq; mm++)
            s += att[mm] * Wh[(long long)(b * Nq + mm) * ldWh + k * GD + g];
        s *= inv;
        s = s > 0.f ? s : expm1f(s);   // ELU
        out[(long long)row * ldOut + k * GD + g] = s;
    }
}

// 11x11 same-pad conv + leaky
__global__ __launch_bounds__(256) void conv_k(
    const float* __restrict__ x, const float* __restrict__ W,
    const float* __restrict__ bptr, float* __restrict__ y)
{
    __shared__ float w[121];
    if (threadIdx.x < 121) w[threadIdx.x] = W[threadIdx.x];
    __syncthreads();
    long long idx = (long long)blockIdx.x * blockDim.x + threadIdx.x;
    long long total = (long long)Bq * Mq * PDq;
    if (idx >= total) return;
    int d = (int)(idx % PDq);
    long long t = idx / PDq;
    int m = (int)(t % Mq);
    int b = (int)(t / Mq);
    const float* xb = x + (long long)b * Mq * PDq;
    float s = 0.f;
    #pragma unroll
    for (int i = 0; i < 11; i++) {
        int mm = m + i - 5;
        if (mm < 0 || mm >= Mq) continue;
        #pragma unroll
        for (int j = 0; j < 11; j++) {
            int dd = d + j - 5;
            if (dd < 0 || dd >= PDq) continue;
            s += xb[(long long)mm * PDq + dd] * w[i * 11 + j];
        }
    }
    s += *bptr;
    y[idx] = s > 0.f ? s : ALPHA_LR * s;
}

// masked softmax over L, batched over i: grid (Bq, 4); mask row = blockIdx.x
__global__ __launch_bounds__(256) void msoftmaxB_k(
    float* __restrict__ score, const float* __restrict__ mask, int L)
{
    int b = blockIdx.x, i = blockIdx.y;
    float* s = score + ((long long)i * Bq + b) * L;
    const float* mk = mask + (long long)b * L;
    int t = threadIdx.x;
    __shared__ float red[256];
    float mx = -1e30f;
    for (int j = t; j < L; j += 256) mx = fmaxf(mx, s[j]);
    red[t] = mx; __syncthreads();
    for (int off = 128; off > 0; off >>= 1) {
        if (t < off) red[t] = fmaxf(red[t], red[t + off]);
        __syncthreads();
    }
    mx = red[0]; __syncthreads();
    float sum = 0.f;
    for (int j = t; j < L; j += 256) {
        float e = expf(s[j] - mx) * mk[j];
        s[j] = e; sum += e;
    }
    red[t] = sum; __syncthreads();
    for (int off = 128; off > 0; off >>= 1) {
        if (t < off) red[t] += red[t + off];
        __syncthreads();
    }
    float inv = 1.0f / (red[0] + 1e-6f);
    __syncthreads();
    for (int j = t; j < L; j += 256) s[j] *= inv;
}

// weighted sum stage 1, batched over i: partial[((i*Bq+b)*16+c)*256+l]
__global__ __launch_bounds__(256) void wsum1B_k(
    const float* __restrict__ feat, const float* __restrict__ att_all,
    float* __restrict__ partial, int L)
{
    int b = blockIdx.x, c = blockIdx.y, i = blockIdx.z, l = threadIdx.x;
    int chunk = L / 16;
    const float* fb = feat + (long long)b * L * LDq;
    const float* ab = att_all + ((long long)i * Bq + b) * L;
    float s = 0.f;
    int r0 = c * chunk, r1 = r0 + chunk;
    for (int r = r0; r < r1; r++) s += fb[(long long)r * LDq + l] * ab[r];
    partial[(((long long)i * Bq + b) * 16 + c) * LDq + l] = s;
}

// weighted sum stage 2, batched: out[b*4*LDq + i*LDq + l]
__global__ __launch_bounds__(256) void wsum2B_k(
    const float* __restrict__ partial, float* __restrict__ out)
{
    int b = blockIdx.x, i = blockIdx.y, l = threadIdx.x;
    float s = 0.f;
    #pragma unroll
    for (int c = 0; c < 16; c++)
        s += partial[(((long long)i * Bq + b) * 16 + c) * LDq + l];
    out[(long long)b * 4 * LDq + i * LDq + l] = s;
}

// ---------------------------------------------------------------------------
// Skinny dense layer for the head
// ---------------------------------------------------------------------------
template<int ACT>
__global__ __launch_bounds__(256) void headlin_k(
    const float* __restrict__ vin, int ldv, int VD,
    const float* __restrict__ W, int ldw,
    const float* __restrict__ bias,
    float* __restrict__ vout, int ldo, int OD, int colBase)
{
    int b = blockIdx.x;
    int c = threadIdx.x & 63;
    int s = threadIdx.x >> 6;
    int col = blockIdx.y * 64 + c;

    __shared__ float vs[1024];
    for (int i = threadIdx.x; i < VD; i += 256) vs[i] = vin[(long long)b * ldv + i];
    __syncthreads();

    float sum = 0.f;
    if (col < OD) {
        int k0 = (VD * s) >> 2, k1 = (VD * (s + 1)) >> 2;
        #pragma unroll 4
        for (int k = k0; k < k1; k++)
            sum += vs[k] * W[(long long)k * ldw + col];
    }
    __shared__ float red[4][64];
    red[s][c] = sum;
    __syncthreads();
    if (s == 0 && col < OD) {
        float t = red[0][c] + red[1][c] + red[2][c] + red[3][c] + bias[col];
        if (ACT == 1) t = t > 0.f ? t : ALPHA_LR * t;
        vout[(long long)b * ldo + colBase + col] = t;
    }
}

// v[b,256:512]=fps, v[b,768]=invT, v[b,769]=T
__global__ __launch_bounds__(256) void vfill_k(
    const float* __restrict__ fps, const float* __restrict__ invT,
    const float* __restrict__ T, float* __restrict__ v)
{
    int b = blockIdx.x, t = threadIdx.x;
    v[(long long)b * 770 + 256 + t] = fps[(long long)b * 256 + t];
    if (t == 0) {
        v[(long long)b * 770 + 768] = invT[b];
        v[(long long)b * 770 + 769] = T[b];
    }
}

// out[b] = v[b,:770]·W + b
__global__ __launch_bounds__(256) void final_k(
    const float* __restrict__ v, const float* __restrict__ W,
    const float* __restrict__ bptr, float* __restrict__ out)
{
    int b = blockIdx.x, t = threadIdx.x;
    float s = 0.f;
    for (int i = t; i < 770; i += 256) s += v[(long long)b * 770 + i] * W[i];
    __shared__ float red[256];
    red[t] = s; __syncthreads();
    for (int off = 128; off > 0; off >>= 1) {
        if (t < off) red[t] += red[t + off];
        __syncthreads();
    }
    if (t == 0) out[b] = red[0] + bptr[0];
}

extern "C" void kernel_launch(void* const* d_in, const int* in_sizes, int n_in,
                              void* d_out, int out_size, void* d_ws, size_t ws_size,
                              hipStream_t stream)
{
    const float* atoms_emb = (const float*)d_in[0];
    const int*   adjacency = (const int*)d_in[1];
    const float* atoms_mask= (const float*)d_in[2];
    const float* amino_emb = (const float*)d_in[3];
    const float* amino_mask= (const float*)d_in[4];
    const float* fps       = (const float*)d_in[5];
    const float* inv_Temp  = (const float*)d_in[6];
    const float* Temp      = (const float*)d_in[7];
    const float* bert_W    = (const float*)d_in[8];
    const float* bert_b    = (const float*)d_in[9];
    const float* gat_W     = (const float*)d_in[10];
    const float* gat_a     = (const float*)d_in[11];
    const float* gatout_W  = (const float*)d_in[12];
    const float* gatout_a  = (const float*)d_in[13];
    const float* Wcomp_W   = (const float*)d_in[14];
    const float* Wcomp_b   = (const float*)d_in[15];
    const float* prot_W    = (const float*)d_in[16];
    const float* prot_b    = (const float*)d_in[17];
    const float* conv_W    = (const float*)d_in[18];
    const float* conv_b    = (const float*)d_in[19];
    const float* Wprot_W   = (const float*)d_in[20];
    const float* Wprot_b   = (const float*)d_in[21];
    const float* U         = (const float*)d_in[22];
    const float* tc2p_W    = (const float*)d_in[23];
    const float* tc2p_b    = (const float*)d_in[24];
    const float* tp2c_W    = (const float*)d_in[25];
    const float* tp2c_b    = (const float*)d_in[26];
    const float* bhc_W     = (const float*)d_in[27];
    const float* bhc_b     = (const float*)d_in[28];
    const float* bhp_W     = (const float*)d_in[29];
    const float* bhp_b     = (const float*)d_in[30];
    const float* battc_W   = (const float*)d_in[31];
    const float* battc_b   = (const float*)d_in[32];
    const float* battp_W   = (const float*)d_in[33];
    const float* battp_b   = (const float*)d_in[34];
    const float* combc_W   = (const float*)d_in[35];
    const float* combc_b   = (const float*)d_in[36];
    const float* combp_W   = (const float*)d_in[37];
    const float* combp_b   = (const float*)d_in[38];
    const float* Wout_W    = (const float*)d_in[39];
    const float* Wout_b    = (const float*)d_in[40];
    const float* out_W     = (const float*)d_in[41];
    const float* out_b     = (const float*)d_in[42];
    float* out = (float*)d_out;

    // ---- workspace layout (floats) ----
    float* w = (float*)d_ws;
    float* av    = w; w += (long long)Bq*Nq*LDq;
    float* pv    = w; w += (long long)Bq*Mq*LDq;
    float* sx    = w; w += (long long)Bq*Mq*LDq;   // early scratch -> precomp pool
    float* pool  = w; w += (long long)Bq*Nq*Mq;    // partials pool (old Abuf)
    float* bufU  = w; w += (long long)Bq*Nq*LDq;
    float* bufTC = w; w += (long long)Bq*Nq*LDq;   // wsum partials
    float* esrc  = w; w += (long long)NHq*Bq*Nq;
    float* edst  = w; w += (long long)NHq*Bq*Nq;
    float* scoreC= w; w += (long long)Bq*Nq;
    float* scoreP= w; w += (long long)Bq*Mq;
    float* rbuf  = w; w += (long long)Bq*Mq;
    float* qbuf  = w; w += (long long)Bq*Nq;
    float* csum  = w; w += (long long)Bq*Mq;
    float* cf    = w; w += (long long)Bq*4*LDq;
    float* pf    = w; w += (long long)Bq*4*LDq;
    float* v1    = w; w += (long long)Bq*770;
    float* v2    = w; w += (long long)Bq*770;
    // bf16 buffers
    ushort_t* pv_bf  = (ushort_t*)w; w += (long long)Bq*Mq*LDq/2;
    ushort_t* av_bf  = (ushort_t*)w; w += (long long)Bq*Nq*LDq/2;
    ushort_t* avU_bf = (ushort_t*)w; w += (long long)Bq*Nq*LDq/2;
    ushort_t* Ut_bf    = (ushort_t*)w; w += (long long)4*LDq*LDq/2;
    ushort_t* tp2cT_bf = (ushort_t*)w; w += (long long)4*LDq*LDq/2;
    ushort_t* tc2pT_bf = (ushort_t*)w; w += (long long)4*LDq*LDq/2;
    ushort_t* bhcT_bf  = (ushort_t*)w; w += (long long)4*LDq*LDq/2;
    ushort_t* bhpT_bf  = (ushort_t*)w; w += (long long)4*LDq*LDq/2;
    ushort_t* protWt_bf= (ushort_t*)w; w += (long long)48*1024/2;

    int rowsA = Bq * Nq;     // 4096
    int rowsP = Bq * Mq;     // 32768

    // early-phase aliases inside sx (dead before BIDAT precompute)
    float* h     = sx;
    float* WhAll = h + (long long)Bq*Nq*CDq;
    float* multi = WhAll + (long long)Bq*Nq*NHq*GDq;
    float* Wh2   = multi + (long long)Bq*Nq*NHq*GDq;
    float* avp   = Wh2 + (long long)Bq*Nq*CDq;
    float* c0    = avp + (long long)Bq*Nq*CDq;
    float* c1    = c0 + (long long)Bq*Mq*PDq;

    // BIDAT-precompute pool in sx (loop-invariant, batched over z=4)
    float*    rbuf_all   = sx;
    float*    hpbdot_all = rbuf_all   + (long long)4*rowsP;
    float*    qbuf_all   = hpbdot_all + (long long)4*rowsP;
    float*    hbdot_all  = qbuf_all   + (long long)4*rowsA;
    float*    bufU_all   = hbdot_all  + (long long)4*rowsA;
    ushort_t* avU_all_bf = (ushort_t*)(bufU_all + (long long)4*rowsA*LDq);

    // partials pool (r11): replaces Abuf entirely
    float* scoreCp    = pool;                        // 128*16*128 = 262144
    float* csump      = scoreCp + 262144;            // 128*2*1024 = 262144
    float* scoreC_all = csump + 262144;              // 128*128    = 16384
    float* scoreP_all = scoreC_all + 16384;          // 128*1024   = 131072

    float* wpart = bufTC;   // batched wsum partials (4*32*16*256 = 524288)

    // ---- weight transpose-converts (once) ----
    wtcvt_k<<<dim3(256, 1, 4), 256, 0, stream>>>(U,      Ut_bf,    LDq, LDq, LDq, LDq);
    wtcvt_k<<<dim3(256, 1, 4), 256, 0, stream>>>(tp2c_W, tp2cT_bf, LDq, LDq, LDq, LDq);
    wtcvt_k<<<dim3(256, 1, 4), 256, 0, stream>>>(tc2p_W, tc2pT_bf, LDq, LDq, LDq, LDq);
    wtcvt_k<<<dim3(256, 1, 4), 256, 0, stream>>>(bhc_W,  bhcT_bf,  LDq, LDq, LDq, LDq);
    wtcvt_k<<<dim3(256, 1, 4), 256, 0, stream>>>(bhp_W,  bhpT_bf,  LDq, LDq, LDq, LDq);
    wtcvt_k<<<dim3((48*1024+255)/256, 1, 1), 256, 0, stream>>>(prot_W, protWt_bf, 1024, 40, 48, 1024);

    // 1. h = atoms_emb @ bert_W + bert_b
    run_gemm(stream, 0, false, rowsA, CDq, 300, atoms_emb, 300, 0,
             bert_W, CDq, 0, bert_b, h, CDq, 0, 1);

    // 2. Wh_all = h @ gat_W[k]
    run_gemm(stream, 0, false, rowsA, GDq, CDq, h, CDq, 0,
             gat_W, GDq, (long long)CDq*GDq, nullptr,
             WhAll, NHq*GDq, GDq, NHq);

    // 3-4. GAT heads -> multi (ELU)
    gat_e_k<<<dim3(rowsA, NHq), 128, 0, stream>>>(WhAll, NHq*GDq, GDq, gat_a, 2*GDq,
                                                  esrc, edst, rowsA);
    gat_attn_k<<<dim3(rowsA, NHq), 128, 0, stream>>>(WhAll, NHq*GDq, GDq, adjacency,
                                                     esrc, edst, multi, NHq*GDq);

    // 5-7. GAT out layer -> avp (ELU)
    run_gemm(stream, 0, false, rowsA, CDq, NHq*GDq, multi, NHq*GDq, 0,
             gatout_W, CDq, 0, nullptr, Wh2, CDq, 0, 1);
    gat_e_k<<<dim3(rowsA, 1), 128, 0, stream>>>(Wh2, CDq, CDq, gatout_a, 2*CDq,
                                                esrc, edst, rowsA);
    gat_attn_k<<<dim3(rowsA, 1), 128, 0, stream>>>(Wh2, CDq, CDq, adjacency,
                                                   esrc, edst, avp, CDq);

    // 8. av = leaky(avp @ Wcomp_W + b)
    run_gemm(stream, 1, false, rowsA, LDq, CDq, avp, CDq, 0,
             Wcomp_W, LDq, 0, Wcomp_b, av, LDq, 0, 1);
    cvt_bf16_k<<<(rowsA*LDq/4 + 255)/256, 256, 0, stream>>>(av, av_bf, (long long)rowsA*LDq/4);

    // 9. pv0 = amino_emb @ prot_W + b
    mfma_nt_k<0, 0, 1, 3, 1><<<dim3(rowsP/64, 1, 1), 256, 0, stream>>>(
        rowsP, 48, 1024, 40,
        (const void*)amino_emb, 1024, 0,
        protWt_bf, 1024, 0,
        prot_b, 0, c0, PDq, 0, nullptr, 0, nullptr);

    // 10. 3x conv 11x11 + leaky
    {
        long long total = (long long)Bq*Mq*PDq;
        int blocks = (int)((total + 255) / 256);
        conv_k<<<blocks, 256, 0, stream>>>(c0, conv_W + 0*121, conv_b + 0, c1);
        conv_k<<<blocks, 256, 0, stream>>>(c1, conv_W + 1*121, conv_b + 1, c0);
        conv_k<<<blocks, 256, 0, stream>>>(c0, conv_W + 2*121, conv_b + 2, c1);
    }

    // 11. pv = leaky(x @ Wprot_W + b)
    run_gemm(stream, 1, false, rowsP, LDq, PDq, c1, PDq, 0,
             Wprot_W, LDq, 0, Wprot_b, pv, LDq, 0, 1);
    cvt_bf16_k<<<(rowsP*LDq/4 + 255)/256, 256, 0, stream>>>(pv, pv_bf, (long long)rowsP*LDq/4);

    // ---- BIDAT precompute (loop-invariant, batched over z = i = 0..3) ----
    mfma_reduce_lds_k<<<dim3(rowsP/128, 1, 4), 512, 0, stream>>>(
        rowsP, LDq, pv_bf, LDq,
        tp2cT_bf, LDq, (long long)LDq*LDq,
        tp2c_b, LDq, battc_W + LDq, 2*LDq,
        rbuf_all, rowsP);
    mfma_reduce_lds_k<<<dim3(rowsP/128, 1, 4), 512, 0, stream>>>(
        rowsP, LDq, pv_bf, LDq,
        bhpT_bf, LDq, (long long)LDq*LDq,
        bhp_b, LDq, battp_W, 2*LDq,
        hpbdot_all, rowsP);
    mfma_reduce_k<<<dim3(rowsA/32, 1, 4), 256, 0, stream>>>(
        rowsA, LDq, av_bf, LDq,
        tc2pT_bf, LDq, (long long)LDq*LDq,
        tc2p_b, LDq, battp_W + LDq, 2*LDq,
        qbuf_all, rowsA);
    mfma_reduce_k<<<dim3(rowsA/32, 1, 4), 256, 0, stream>>>(
        rowsA, LDq, av_bf, LDq,
        bhcT_bf, LDq, (long long)LDq*LDq,
        bhc_b, LDq, battc_W, 2*LDq,
        hbdot_all, rowsA);
    mfma_nt_k<0, 0, 0, 4, 0><<<dim3(rowsA/64, 4, 4), 256, 0, stream>>>(
        rowsA, LDq, LDq, LDq, (const void*)av_bf, LDq, 0,
        Ut_bf, LDq, (long long)LDq*LDq,
        nullptr, 0, bufU_all, LDq, (long long)rowsA*LDq,
        nullptr, 0, nullptr);
    cvt_bf16_k<<<((long long)4*rowsA*LDq/4 + 255)/256, 256, 0, stream>>>(
        bufU_all, avU_all_bf, (long long)4*rowsA*LDq/4);

    // ---- 12. fused BIDAT A-chain (all 4 iterations, no Abuf) ----
    bidat_fused_k<<<dim3(2, 16, 128), 256, 0, stream>>>(
        avU_all_bf, pv_bf, rbuf_all, qbuf_all,
        atoms_mask, amino_mask, scoreCp, csump);
    finishC_k<<<128, 128, 0, stream>>>(scoreCp, hbdot_all, battc_b, scoreC_all);
    finishP_k<<<dim3(128, 4), 256, 0, stream>>>(csump, hpbdot_all, battp_b, scoreP_all);

    msoftmaxB_k<<<dim3(Bq, 4), 256, 0, stream>>>(scoreC_all, atoms_mask, Nq);
    msoftmaxB_k<<<dim3(Bq, 4), 256, 0, stream>>>(scoreP_all, amino_mask, Mq);

    wsum1B_k<<<dim3(Bq, 16, 4), 256, 0, stream>>>(av, scoreC_all, wpart, Nq);
    wsum2B_k<<<dim3(Bq, 4), 256, 0, stream>>>(wpart, cf);
    wsum1B_k<<<dim3(Bq, 16, 4), 256, 0, stream>>>(pv, scoreP_all, wpart, Mq);
    wsum2B_k<<<dim3(Bq, 4), 256, 0, stream>>>(wpart, pf);

    // 13. head
    headlin_k<0><<<dim3(Bq, 4), 256, 0, stream>>>(cf, 4*LDq, 4*LDq,
        combc_W, LDq, combc_b, v1, 770, LDq, 0);
    headlin_k<0><<<dim3(Bq, 4), 256, 0, stream>>>(pf, 4*LDq, 4*LDq,
        combp_W, LDq, combp_b, v1, 770, LDq, 512);
    vfill_k<<<Bq, 256, 0, stream>>>(fps, inv_Temp, Temp, v1);

    headlin_k<1><<<dim3(Bq, 13), 256, 0, stream>>>(v1, 770, 770,
        Wout_W + 0ll*770*770, 770, Wout_b + 0*770, v2, 770, 770, 0);
    headlin_k<1><<<dim3(Bq, 13), 256, 0, stream>>>(v2, 770, 770,
        Wout_W + 1ll*770*770, 770, Wout_b + 1*770, v1, 770, 770, 0);
    headlin_k<1><<<dim3(Bq, 13), 256, 0, stream>>>(v1, 770, 770,
        Wout_W + 2ll*770*770, 770, Wout_b + 2*770, v2, 770, 770, 0);

    final_k<<<Bq, 256, 0, stream>>>(v2, out_W, out_b, out);

    (void)in_sizes; (void)n_in; (void)out_size; (void)ws_size;
    (void)bufU; (void)avU_bf; (void)rbuf; (void)qbuf; (void)scoreC; (void)scoreP; (void)csum;
}

// Round 12
// 785.764 us; speedup vs baseline: 5.1796x; 1.1940x over previous
//
#include <hip/hip_runtime.h>
#include <math.h>

#define ALPHA_LR 0.2f

#define Bq  32
#define Nq  128
#define Mq  1024
#define CDq 128
#define GDq 64
#define NHq 4
#define LDq 256
#define PDq 40

typedef unsigned short ushort_t;
typedef __attribute__((ext_vector_type(8))) short bf16x8;
typedef __attribute__((ext_vector_type(4))) float f32x4;

__device__ __forceinline__ ushort_t f2bf(float f) {
    union { float f; unsigned u; } x; x.f = f;
    unsigned r = x.u + 0x7FFFu + ((x.u >> 16) & 1u);   // RNE
    return (ushort_t)(r >> 16);
}

// ---------------------------------------------------------------------------
// MFMA bf16 NT GEMM: C = act(A @ Bt^T + bias)
// ---------------------------------------------------------------------------
template<int ACT, int MASKED, int HAS_BIAS, int NT, int AF32>
__global__ __launch_bounds__(256) void mfma_nt_k(
    int M, int N, int K, int Nout,
    const void* __restrict__ Av, int lda, long long sA,
    const ushort_t* __restrict__ Bt, int ldb, long long sB,
    const float* __restrict__ bias, long long sBias,
    float* __restrict__ C, int ldc, long long sC,
    const float* __restrict__ maskR, long long sW2,
    const float* __restrict__ maskC)
{
    int z = blockIdx.z;
    Bt += (long long)z * sB;
    C  += (long long)z * sC;
    if (HAS_BIAS) bias += (long long)z * sBias;

    int wave = threadIdx.x >> 6;
    int lane = threadIdx.x & 63;
    int lr = lane & 15;
    int kg = lane >> 4;
    int m0 = (blockIdx.x * 4 + wave) * 16;
    int n0 = blockIdx.y * (NT * 16);
    if (m0 >= M) return;

    f32x4 acc[NT];
    #pragma unroll
    for (int t = 0; t < NT; t++) acc[t] = (f32x4){0.f, 0.f, 0.f, 0.f};

    const ushort_t* Ab = nullptr;
    const float*    Af = nullptr;
    if (AF32) Af = (const float*)Av + (long long)z * sA + (long long)(m0 + lr) * lda + kg * 8;
    else      Ab = (const ushort_t*)Av + (long long)z * sA + (long long)(m0 + lr) * lda + kg * 8;
    const ushort_t* Bbase = Bt + (long long)(n0 + lr) * ldb + kg * 8;

    for (int k0 = 0; k0 < K; k0 += 32) {
        bf16x8 a;
        if (AF32) {
            float4 a0 = *(const float4*)(Af + k0);
            float4 a1 = *(const float4*)(Af + k0 + 4);
            a[0] = (short)f2bf(a0.x); a[1] = (short)f2bf(a0.y);
            a[2] = (short)f2bf(a0.z); a[3] = (short)f2bf(a0.w);
            a[4] = (short)f2bf(a1.x); a[5] = (short)f2bf(a1.y);
            a[6] = (short)f2bf(a1.z); a[7] = (short)f2bf(a1.w);
        } else {
            a = *(const bf16x8*)(Ab + k0);
        }
        #pragma unroll
        for (int t = 0; t < NT; t++) {
            bf16x8 b = *(const bf16x8*)(Bbase + (long long)t * 16 * ldb + k0);
            acc[t] = __builtin_amdgcn_mfma_f32_16x16x32_bf16(a, b, acc[t], 0, 0, 0);
        }
    }

    int row0 = m0 + kg * 4;
    #pragma unroll
    for (int t = 0; t < NT; t++) {
        int col = n0 + t * 16 + lr;
        if (col >= Nout) continue;
        float bv = HAS_BIAS ? bias[col] : 0.f;
        float mC = MASKED ? maskC[(long long)z * N + col] : 1.f;
        #pragma unroll
        for (int r = 0; r < 4; r++) {
            float v = acc[t][r] + bv;
            if (ACT == 1) v = v > 0.f ? v : ALPHA_LR * v;
            else if (ACT == 2) v = tanhf(v);
            if (MASKED) v *= maskR[(long long)z * M + row0 + r] * mC;
            C[(long long)(row0 + r) * ldc + col] = v;
        }
    }
}

// ---------------------------------------------------------------------------
// r12: high-occupancy fused reduce GEMM.
//   out[z][row] = sum_col tanh((A @ W8[z]^T)[row,col] + bias8[z][col]) * w28[z][col]
// Block = 8 waves x 16 rows = 128 rows; 4 phases x 64 B-rows (32 KB LDS ->
// 3-4 blocks/CU vs r10's 1); A row hoisted to registers once (kills 4x
// redundant A reads); swizzle (row&31)<<4 (4-way vs 8-way conflicts).
// Z=8 batches both weight families (packed contiguous). K == N == 256.
// ---------------------------------------------------------------------------
__global__ __launch_bounds__(512) void mfma_reduceF_k(
    int M,
    const ushort_t* __restrict__ A,        // [M][256] bf16
    const ushort_t* __restrict__ W8,       // [Z][256][256] bf16
    const float* __restrict__ bias8,       // [Z][256]
    const float* __restrict__ w28,         // [Z][256]
    float* __restrict__ C)                 // [Z][M]
{
    int z = blockIdx.z;
    const ushort_t* W = W8 + (long long)z * 65536;
    const float* bias = bias8 + z * 256;
    const float* w2   = w28 + z * 256;
    float* Cz = C + (long long)z * M;

    __shared__ ushort_t Bs[64 * 256];   // 32 KB

    int tid = threadIdx.x;
    int wave = tid >> 6, lane = tid & 63;
    int lr = lane & 15, kg = lane >> 4;
    int m0 = blockIdx.x * 128 + wave * 16;

    const ushort_t* Ab = A + (long long)(m0 + lr) * 256 + kg * 8;
    bf16x8 areg[8];
    #pragma unroll
    for (int kb = 0; kb < 8; kb++) areg[kb] = *(const bf16x8*)(Ab + kb * 32);

    float rs[4] = {0.f, 0.f, 0.f, 0.f};

    for (int ph = 0; ph < 4; ph++) {
        int n0 = ph * 64;
        #pragma unroll
        for (int step = 0; step < 4; step++) {
            int g = step * 512 + tid;
            int row = g >> 5, slot = g & 31;
            uint4 v = *(const uint4*)(W + (long long)(n0 + row) * 256 + slot * 8);
            int dst = row * 512 + ((slot * 16) ^ ((row & 31) << 4));
            *(uint4*)((char*)Bs + dst) = v;
        }
        __syncthreads();

        f32x4 acc[4];
        #pragma unroll
        for (int t = 0; t < 4; t++) acc[t] = (f32x4){0.f, 0.f, 0.f, 0.f};

        #pragma unroll
        for (int kb = 0; kb < 8; kb++) {
            #pragma unroll
            for (int t = 0; t < 4; t++) {
                int rowl = t * 16 + lr;
                int colb = (kg * 16 + kb * 64) ^ ((rowl & 31) << 4);
                bf16x8 b = *(const bf16x8*)((char*)Bs + rowl * 512 + colb);
                acc[t] = __builtin_amdgcn_mfma_f32_16x16x32_bf16(areg[kb], b, acc[t], 0, 0, 0);
            }
        }
        #pragma unroll
        for (int t = 0; t < 4; t++) {
            int col = n0 + t * 16 + lr;
            float bv = bias[col], wv = w2[col];
            #pragma unroll
            for (int r = 0; r < 4; r++)
                rs[r] += tanhf(acc[t][r] + bv) * wv;
        }
        __syncthreads();
    }

    #pragma unroll
    for (int r = 0; r < 4; r++) {
        rs[r] += __shfl_xor(rs[r], 1, 64);
        rs[r] += __shfl_xor(rs[r], 2, 64);
        rs[r] += __shfl_xor(rs[r], 4, 64);
        rs[r] += __shfl_xor(rs[r], 8, 64);
    }
    if (lr == 0) {
        int row0 = m0 + kg * 4;
        #pragma unroll
        for (int r = 0; r < 4; r++)
            Cz[row0 + r] = rs[r];
    }
}

// pack biases and w2 vectors for z=8 fused reduce:
// slot<4: bias=b1[slot*256+c], w2=w1[slot*512+w1Off+c]
// slot>=4: bias=b2[(slot-4)*256+c], w2=w2v[(slot-4)*512+w2Off+c]
__global__ __launch_bounds__(256) void pack8_k(
    const float* __restrict__ b1, const float* __restrict__ b2,
    const float* __restrict__ w1, int w1Off,
    const float* __restrict__ w2v, int w2Off,
    float* __restrict__ bias8, float* __restrict__ w28)
{
    int j = blockIdx.x * 256 + threadIdx.x;   // 0..2047
    int slot = j >> 8, c = j & 255;
    bias8[j] = slot < 4 ? b1[slot * 256 + c] : b2[(slot - 4) * 256 + c];
    w28[j]   = slot < 4 ? w1[slot * 512 + w1Off + c] : w2v[(slot - 4) * 512 + w2Off + c];
}

// ---------------------------------------------------------------------------
// r11: fused BIDAT A-chain (no Abuf)
// ---------------------------------------------------------------------------
__global__ __launch_bounds__(256) void bidat_fused_k(
    const ushort_t* __restrict__ avU_all,
    const ushort_t* __restrict__ pv_bf,
    const float* __restrict__ rbuf_all,
    const float* __restrict__ qbuf_all,
    const float* __restrict__ atoms_mask,
    const float* __restrict__ amino_mask,
    float* __restrict__ scoreCp,
    float* __restrict__ csump)
{
    int z = blockIdx.z;
    int i = z >> 5, b = z & 31;
    int gx = blockIdx.x;
    int gy = blockIdx.y;
    int wave = threadIdx.x >> 6;
    int lane = threadIdx.x & 63;
    int lr = lane & 15, kg = lane >> 4;

    int n0 = gx * 64 + wave * 16;
    int m0 = gy * 64;

    const ushort_t* Ab = avU_all + ((long long)i * 4096 + (long long)b * 128 + n0 + lr) * 256 + kg * 8;
    const ushort_t* Bb = pv_bf   + ((long long)b * 1024 + m0 + lr) * 256 + kg * 8;

    f32x4 acc[4];
    #pragma unroll
    for (int t = 0; t < 4; t++) acc[t] = (f32x4){0.f, 0.f, 0.f, 0.f};

    for (int k0 = 0; k0 < 256; k0 += 32) {
        bf16x8 a = *(const bf16x8*)(Ab + k0);
        #pragma unroll
        for (int t = 0; t < 4; t++) {
            bf16x8 bf = *(const bf16x8*)(Bb + (long long)t * 16 * 256 + k0);
            acc[t] = __builtin_amdgcn_mfma_f32_16x16x32_bf16(a, bf, acc[t], 0, 0, 0);
        }
    }

    const float* rI = rbuf_all + (long long)i * 32768 + (long long)b * 1024;
    const float* qI = qbuf_all + (long long)i * 4096 + (long long)b * 128;
    const float* mR = atoms_mask + (long long)b * 128;
    const float* mC = amino_mask + (long long)b * 1024;

    float sc[4] = {0.f, 0.f, 0.f, 0.f};
    float cs[4] = {0.f, 0.f, 0.f, 0.f};
    #pragma unroll
    for (int t = 0; t < 4; t++) {
        int m = m0 + t * 16 + lr;
        float mc = mC[m];
        float rv = rI[m];
        #pragma unroll
        for (int r = 0; r < 4; r++) {
            int n = n0 + kg * 4 + r;
            float a = tanhf(acc[t][r]) * mR[n] * mc;
            sc[r] += a * rv;
            cs[t] += a * qI[n];
        }
    }

    #pragma unroll
    for (int r = 0; r < 4; r++) {
        sc[r] += __shfl_xor(sc[r], 1, 64);
        sc[r] += __shfl_xor(sc[r], 2, 64);
        sc[r] += __shfl_xor(sc[r], 4, 64);
        sc[r] += __shfl_xor(sc[r], 8, 64);
    }
    if (lr == 0) {
        #pragma unroll
        for (int r = 0; r < 4; r++) {
            int n = gx * 64 + wave * 16 + kg * 4 + r;
            scoreCp[((long long)z * 16 + gy) * 128 + n] = sc[r];
        }
    }

    #pragma unroll
    for (int t = 0; t < 4; t++) {
        cs[t] += __shfl_xor(cs[t], 16, 64);
        cs[t] += __shfl_xor(cs[t], 32, 64);
    }
    __shared__ float cl[4][64];
    if (kg == 0) {
        #pragma unroll
        for (int t = 0; t < 4; t++) cl[wave][t * 16 + lr] = cs[t];
    }
    __syncthreads();
    if (threadIdx.x < 64) {
        float s = cl[0][threadIdx.x] + cl[1][threadIdx.x]
                + cl[2][threadIdx.x] + cl[3][threadIdx.x];
        csump[((long long)z * 2 + gx) * 1024 + m0 + threadIdx.x] = s;
    }
}

__global__ __launch_bounds__(128) void finishC_k(
    const float* __restrict__ scoreCp, const float* __restrict__ hbdot_all,
    const float* __restrict__ battc_b, float* __restrict__ scoreC_all)
{
    int z = blockIdx.x;
    int i = z >> 5, b = z & 31;
    int n = threadIdx.x;
    float s = 0.f;
    #pragma unroll
    for (int gy = 0; gy < 16; gy++)
        s += scoreCp[((long long)z * 16 + gy) * 128 + n];
    scoreC_all[(long long)z * 128 + n] =
        s + hbdot_all[(long long)i * 4096 + b * 128 + n] + battc_b[i];
}

__global__ __launch_bounds__(256) void finishP_k(
    const float* __restrict__ csump, const float* __restrict__ hpbdot_all,
    const float* __restrict__ battp_b, float* __restrict__ scoreP_all)
{
    int z = blockIdx.x;
    int i = z >> 5, b = z & 31;
    int m = blockIdx.y * 256 + threadIdx.x;
    float s = csump[((long long)z * 2 + 0) * 1024 + m]
            + csump[((long long)z * 2 + 1) * 1024 + m];
    scoreP_all[(long long)z * 1024 + m] =
        s + hpbdot_all[(long long)i * 32768 + (long long)b * 1024 + m] + battp_b[i];
}

// fp32 -> bf16 (contiguous)
__global__ __launch_bounds__(256) void cvt_bf16_k(
    const float* __restrict__ in, ushort_t* __restrict__ out, long long n4)
{
    long long i = (long long)blockIdx.x * 256 + threadIdx.x;
    if (i >= n4) return;
    float4 v = ((const float4*)in)[i];
    ushort4 o;
    o.x = f2bf(v.x); o.y = f2bf(v.y); o.z = f2bf(v.z); o.w = f2bf(v.w);
    ((ushort4*)out)[i] = o;
}

// fp32 [rows][Ksrc] -> bf16 [rows][Kdst] zero-padded
__global__ __launch_bounds__(256) void cvtpad_bf16_k(
    const float* __restrict__ in, ushort_t* __restrict__ out,
    int rows, int Ksrc, int Kdst)
{
    long long idx = (long long)blockIdx.x * 256 + threadIdx.x;
    long long total = (long long)rows * Kdst;
    if (idx >= total) return;
    int r = (int)(idx / Kdst), k = (int)(idx % Kdst);
    out[idx] = (k < Ksrc) ? f2bf(in[(long long)r * Ksrc + k]) : (ushort_t)0;
}

// W[K][Nsrc] fp32 -> Wt[Npad][Kp] bf16 (transposed, padded), batched z
__global__ __launch_bounds__(256) void wtcvt_k(
    const float* __restrict__ W, ushort_t* __restrict__ Wt,
    int K, int Nsrc, int Npad, int Kp)
{
    int z = blockIdx.z;
    const float* Wz = W + (long long)z * K * Nsrc;
    ushort_t* Oz = Wt + (long long)z * Npad * Kp;
    int idx = blockIdx.x * 256 + threadIdx.x;
    if (idx >= Npad * Kp) return;
    int n = idx / Kp, k = idx % Kp;
    float v = (k < K && n < Nsrc) ? Wz[(long long)k * Nsrc + n] : 0.f;
    Oz[idx] = f2bf(v);
}

// per-row GAT source/dest attention logits
__global__ __launch_bounds__(128) void gat_e_k(
    const float* __restrict__ Wh, int ldWh, int GD,
    const float* __restrict__ a, int aStride,
    float* __restrict__ esrc, float* __restrict__ edst, int rows)
{
    int row = blockIdx.x;
    int k = blockIdx.y;
    int g = threadIdx.x;
    float ws = 0.f, wd = 0.f;
    if (g < GD) {
        float wv = Wh[(long long)row * ldWh + k * GD + g];
        ws = wv * a[k * aStride + g];
        wd = wv * a[k * aStride + GD + g];
    }
    __shared__ float sb[2][128];
    sb[0][threadIdx.x] = ws; sb[1][threadIdx.x] = wd;
    __syncthreads();
    for (int off = 64; off > 0; off >>= 1) {
        if (threadIdx.x < off) {
            sb[0][threadIdx.x] += sb[0][threadIdx.x + off];
            sb[1][threadIdx.x] += sb[1][threadIdx.x + off];
        }
        __syncthreads();
    }
    if (threadIdx.x == 0) {
        esrc[(long long)k * rows + row] = sb[0][0];
        edst[(long long)k * rows + row] = sb[1][0];
    }
}

// GAT attention: softmax over neighbors + weighted sum + ELU
__global__ __launch_bounds__(128) void gat_attn_k(
    const float* __restrict__ Wh, int ldWh, int GD,
    const int* __restrict__ adj,
    const float* __restrict__ esrc, const float* __restrict__ edst,
    float* __restrict__ out, int ldOut)
{
    int row = blockIdx.x;
    int k = blockIdx.y;
    int rows = gridDim.x;
    int b = row / Nq, n = row % Nq;
    int m = threadIdx.x;

    __shared__ float att[Nq];
    __shared__ float red[Nq];

    float e = esrc[(long long)k * rows + row] + edst[(long long)k * rows + b * Nq + m];
    e = e > 0.f ? e : ALPHA_LR * e;
    if (adj[(long long)b * Nq * Nq + n * Nq + m] <= 0) e = -9.0e15f;

    red[m] = e; __syncthreads();
    for (int off = 64; off > 0; off >>= 1) {
        if (m < off) red[m] = fmaxf(red[m], red[m + off]);
        __syncthreads();
    }
    float mx = red[0]; __syncthreads();
    float ex = expf(e - mx);
    att[m] = ex; red[m] = ex; __syncthreads();
    for (int off = 64; off > 0; off >>= 1) {
        if (m < off) red[m] += red[m + off];
        __syncthreads();
    }
    float inv = 1.0f / red[0];

    for (int g = threadIdx.x; g < GD; g += blockDim.x) {
        float s = 0.f;
        for (int mm = 0; mm < Nq; mm++)
            s += att[mm] * Wh[(long long)(b * Nq + mm) * ldWh + k * GD + g];
        s *= inv;
        s = s > 0.f ? s : expm1f(s);   // ELU
        out[(long long)row * ldOut + k * GD + g] = s;
    }
}

// 11x11 same-pad conv + leaky
__global__ __launch_bounds__(256) void conv_k(
    const float* __restrict__ x, const float* __restrict__ W,
    const float* __restrict__ bptr, float* __restrict__ y)
{
    __shared__ float w[121];
    if (threadIdx.x < 121) w[threadIdx.x] = W[threadIdx.x];
    __syncthreads();
    long long idx = (long long)blockIdx.x * blockDim.x + threadIdx.x;
    long long total = (long long)Bq * Mq * PDq;
    if (idx >= total) return;
    int d = (int)(idx % PDq);
    long long t = idx / PDq;
    int m = (int)(t % Mq);
    int b = (int)(t / Mq);
    const float* xb = x + (long long)b * Mq * PDq;
    float s = 0.f;
    #pragma unroll
    for (int i = 0; i < 11; i++) {
        int mm = m + i - 5;
        if (mm < 0 || mm >= Mq) continue;
        #pragma unroll
        for (int j = 0; j < 11; j++) {
            int dd = d + j - 5;
            if (dd < 0 || dd >= PDq) continue;
            s += xb[(long long)mm * PDq + dd] * w[i * 11 + j];
        }
    }
    s += *bptr;
    y[idx] = s > 0.f ? s : ALPHA_LR * s;
}

// masked softmax over L, batched over i
__global__ __launch_bounds__(256) void msoftmaxB_k(
    float* __restrict__ score, const float* __restrict__ mask, int L)
{
    int b = blockIdx.x, i = blockIdx.y;
    float* s = score + ((long long)i * Bq + b) * L;
    const float* mk = mask + (long long)b * L;
    int t = threadIdx.x;
    __shared__ float red[256];
    float mx = -1e30f;
    for (int j = t; j < L; j += 256) mx = fmaxf(mx, s[j]);
    red[t] = mx; __syncthreads();
    for (int off = 128; off > 0; off >>= 1) {
        if (t < off) red[t] = fmaxf(red[t], red[t + off]);
        __syncthreads();
    }
    mx = red[0]; __syncthreads();
    float sum = 0.f;
    for (int j = t; j < L; j += 256) {
        float e = expf(s[j] - mx) * mk[j];
        s[j] = e; sum += e;
    }
    red[t] = sum; __syncthreads();
    for (int off = 128; off > 0; off >>= 1) {
        if (t < off) red[t] += red[t + off];
        __syncthreads();
    }
    float inv = 1.0f / (red[0] + 1e-6f);
    __syncthreads();
    for (int j = t; j < L; j += 256) s[j] *= inv;
}

// weighted sum stage 1, batched over i
__global__ __launch_bounds__(256) void wsum1B_k(
    const float* __restrict__ feat, const float* __restrict__ att_all,
    float* __restrict__ partial, int L)
{
    int b = blockIdx.x, c = blockIdx.y, i = blockIdx.z, l = threadIdx.x;
    int chunk = L / 16;
    const float* fb = feat + (long long)b * L * LDq;
    const float* ab = att_all + ((long long)i * Bq + b) * L;
    float s = 0.f;
    int r0 = c * chunk, r1 = r0 + chunk;
    for (int r = r0; r < r1; r++) s += fb[(long long)r * LDq + l] * ab[r];
    partial[(((long long)i * Bq + b) * 16 + c) * LDq + l] = s;
}

// weighted sum stage 2, batched
__global__ __launch_bounds__(256) void wsum2B_k(
    const float* __restrict__ partial, float* __restrict__ out)
{
    int b = blockIdx.x, i = blockIdx.y, l = threadIdx.x;
    float s = 0.f;
    #pragma unroll
    for (int c = 0; c < 16; c++)
        s += partial[(((long long)i * Bq + b) * 16 + c) * LDq + l];
    out[(long long)b * 4 * LDq + i * LDq + l] = s;
}

// ---------------------------------------------------------------------------
// Skinny dense layer for the head
// ---------------------------------------------------------------------------
template<int ACT>
__global__ __launch_bounds__(256) void headlin_k(
    const float* __restrict__ vin, int ldv, int VD,
    const float* __restrict__ W, int ldw,
    const float* __restrict__ bias,
    float* __restrict__ vout, int ldo, int OD, int colBase)
{
    int b = blockIdx.x;
    int c = threadIdx.x & 63;
    int s = threadIdx.x >> 6;
    int col = blockIdx.y * 64 + c;

    __shared__ float vs[1024];
    for (int i = threadIdx.x; i < VD; i += 256) vs[i] = vin[(long long)b * ldv + i];
    __syncthreads();

    float sum = 0.f;
    if (col < OD) {
        int k0 = (VD * s) >> 2, k1 = (VD * (s + 1)) >> 2;
        #pragma unroll 4
        for (int k = k0; k < k1; k++)
            sum += vs[k] * W[(long long)k * ldw + col];
    }
    __shared__ float red[4][64];
    red[s][c] = sum;
    __syncthreads();
    if (s == 0 && col < OD) {
        float t = red[0][c] + red[1][c] + red[2][c] + red[3][c] + bias[col];
        if (ACT == 1) t = t > 0.f ? t : ALPHA_LR * t;
        vout[(long long)b * ldo + colBase + col] = t;
    }
}

// v[b,256:512]=fps, v[b,768]=invT, v[b,769]=T
__global__ __launch_bounds__(256) void vfill_k(
    const float* __restrict__ fps, const float* __restrict__ invT,
    const float* __restrict__ T, float* __restrict__ v)
{
    int b = blockIdx.x, t = threadIdx.x;
    v[(long long)b * 770 + 256 + t] = fps[(long long)b * 256 + t];
    if (t == 0) {
        v[(long long)b * 770 + 768] = invT[b];
        v[(long long)b * 770 + 769] = T[b];
    }
}

// out[b] = v[b,:770]·W + b
__global__ __launch_bounds__(256) void final_k(
    const float* __restrict__ v, const float* __restrict__ W,
    const float* __restrict__ bptr, float* __restrict__ out)
{
    int b = blockIdx.x, t = threadIdx.x;
    float s = 0.f;
    for (int i = t; i < 770; i += 256) s += v[(long long)b * 770 + i] * W[i];
    __shared__ float red[256];
    red[t] = s; __syncthreads();
    for (int off = 128; off > 0; off >>= 1) {
        if (t < off) red[t] += red[t + off];
        __syncthreads();
    }
    if (t == 0) out[b] = red[0] + bptr[0];
}

extern "C" void kernel_launch(void* const* d_in, const int* in_sizes, int n_in,
                              void* d_out, int out_size, void* d_ws, size_t ws_size,
                              hipStream_t stream)
{
    const float* atoms_emb = (const float*)d_in[0];
    const int*   adjacency = (const int*)d_in[1];
    const float* atoms_mask= (const float*)d_in[2];
    const float* amino_emb = (const float*)d_in[3];
    const float* amino_mask= (const float*)d_in[4];
    const float* fps       = (const float*)d_in[5];
    const float* inv_Temp  = (const float*)d_in[6];
    const float* Temp      = (const float*)d_in[7];
    const float* bert_W    = (const float*)d_in[8];
    const float* bert_b    = (const float*)d_in[9];
    const float* gat_W     = (const float*)d_in[10];
    const float* gat_a     = (const float*)d_in[11];
    const float* gatout_W  = (const float*)d_in[12];
    const float* gatout_a  = (const float*)d_in[13];
    const float* Wcomp_W   = (const float*)d_in[14];
    const float* Wcomp_b   = (const float*)d_in[15];
    const float* prot_W    = (const float*)d_in[16];
    const float* prot_b    = (const float*)d_in[17];
    const float* conv_W    = (const float*)d_in[18];
    const float* conv_b    = (const float*)d_in[19];
    const float* Wprot_W   = (const float*)d_in[20];
    const float* Wprot_b   = (const float*)d_in[21];
    const float* U         = (const float*)d_in[22];
    const float* tc2p_W    = (const float*)d_in[23];
    const float* tc2p_b    = (const float*)d_in[24];
    const float* tp2c_W    = (const float*)d_in[25];
    const float* tp2c_b    = (const float*)d_in[26];
    const float* bhc_W     = (const float*)d_in[27];
    const float* bhc_b     = (const float*)d_in[28];
    const float* bhp_W     = (const float*)d_in[29];
    const float* bhp_b     = (const float*)d_in[30];
    const float* battc_W   = (const float*)d_in[31];
    const float* battc_b   = (const float*)d_in[32];
    const float* battp_W   = (const float*)d_in[33];
    const float* battp_b   = (const float*)d_in[34];
    const float* combc_W   = (const float*)d_in[35];
    const float* combc_b   = (const float*)d_in[36];
    const float* combp_W   = (const float*)d_in[37];
    const float* combp_b   = (const float*)d_in[38];
    const float* Wout_W    = (const float*)d_in[39];
    const float* Wout_b    = (const float*)d_in[40];
    const float* out_W     = (const float*)d_in[41];
    const float* out_b     = (const float*)d_in[42];
    float* out = (float*)d_out;

    // ---- workspace layout (floats) ----
    float* w = (float*)d_ws;
    float* av    = w; w += (long long)Bq*Nq*LDq;
    float* pv    = w; w += (long long)Bq*Mq*LDq;
    float* sx    = w; w += (long long)Bq*Mq*LDq;   // early fp32 scratch -> precomp pool
    float* pool  = w; w += (long long)Bq*Nq*Mq;    // early bf16 staging -> partials
    float* bufU  = w; w += (long long)Bq*Nq*LDq;
    float* bufTC = w; w += (long long)Bq*Nq*LDq;   // wsum partials
    float* esrc  = w; w += (long long)NHq*Bq*Nq;
    float* edst  = w; w += (long long)NHq*Bq*Nq;
    float* scoreC= w; w += (long long)Bq*Nq;
    float* scoreP= w; w += (long long)Bq*Mq;
    float* rbuf  = w; w += (long long)Bq*Mq;       // -> pack8 outputs
    float* qbuf  = w; w += (long long)Bq*Nq;
    float* csum  = w; w += (long long)Bq*Mq;
    float* cf    = w; w += (long long)Bq*4*LDq;
    float* pf    = w; w += (long long)Bq*4*LDq;
    float* v1    = w; w += (long long)Bq*770;
    float* v2    = w; w += (long long)Bq*770;
    // bf16 buffers
    ushort_t* pv_bf  = (ushort_t*)w; w += (long long)Bq*Mq*LDq/2;
    ushort_t* av_bf  = (ushort_t*)w; w += (long long)Bq*Nq*LDq/2;
    ushort_t* avU_bf = (ushort_t*)w; w += (long long)Bq*Nq*LDq/2;
    ushort_t* Ut_bf     = (ushort_t*)w; w += (long long)4*LDq*LDq/2;
    ushort_t* protWt_bf = (ushort_t*)w; w += (long long)48*1024/2;
    ushort_t* bertWt_bf = (ushort_t*)w; w += (long long)128*320/2;
    ushort_t* gatWt_bf  = (ushort_t*)w; w += (long long)4*64*128/2;
    ushort_t* gatoutWt_bf=(ushort_t*)w; w += (long long)128*256/2;
    ushort_t* WcompT_bf = (ushort_t*)w; w += (long long)256*128/2;
    ushort_t* WprotT_bf = (ushort_t*)w; w += (long long)256*64/2;
    ushort_t* wP_bf     = (ushort_t*)w; w += (long long)8*256*256/2;
    ushort_t* wA_bf     = (ushort_t*)w; w += (long long)8*256*256/2;

    int rowsA = Bq * Nq;     // 4096
    int rowsP = Bq * Mq;     // 32768

    // early fp32 aliases inside sx (dead before BIDAT precompute)
    float* h     = sx;
    float* WhAll = h + (long long)rowsA*CDq;
    float* multi = WhAll + (long long)rowsA*NHq*GDq;
    float* Wh2   = multi + (long long)rowsA*NHq*GDq;
    float* avp   = Wh2 + (long long)rowsA*CDq;
    float* c0    = avp + (long long)rowsA*CDq;
    float* c1    = c0 + (long long)rowsP*PDq;

    // early bf16 aliases inside pool (dead before partials phase)
    ushort_t* atoms_bf = (ushort_t*)pool;
    ushort_t* h_bf     = atoms_bf + (long long)rowsA*320;
    ushort_t* multi_bf = h_bf + (long long)rowsA*128;
    ushort_t* avp_bf   = multi_bf + (long long)rowsA*256;
    ushort_t* c1_bf    = avp_bf + (long long)rowsA*128;

    // BIDAT-precompute pool in sx (z=8 reduce outputs land contiguously)
    float*    rbuf_all   = sx;
    float*    hpbdot_all = rbuf_all   + (long long)4*rowsP;
    float*    qbuf_all   = hpbdot_all + (long long)4*rowsP;
    float*    hbdot_all  = qbuf_all   + (long long)4*rowsA;
    float*    bufU_all   = hbdot_all  + (long long)4*rowsA;
    ushort_t* avU_all_bf = (ushort_t*)(bufU_all + (long long)4*rowsA*LDq);

    // partials pool (after bidat)
    float* scoreCp    = pool;
    float* csump      = scoreCp + 262144;
    float* scoreC_all = csump + 262144;
    float* scoreP_all = scoreC_all + 16384;

    float* wpart = bufTC;

    // pack8 outputs (rbuf region, 32768 floats available)
    float* bias8P = rbuf;
    float* w28P   = rbuf + 2048;
    float* bias8A = rbuf + 4096;
    float* w28A   = rbuf + 6144;

    // ---- weight transpose-converts + packs (no activation deps) ----
    wtcvt_k<<<dim3(256, 1, 4), 256, 0, stream>>>(U,      Ut_bf,    LDq, LDq, LDq, LDq);
    wtcvt_k<<<dim3((48*1024+255)/256, 1, 1), 256, 0, stream>>>(prot_W, protWt_bf, 1024, 40, 48, 1024);
    wtcvt_k<<<dim3((128*320+255)/256, 1, 1), 256, 0, stream>>>(bert_W, bertWt_bf, 300, 128, 128, 320);
    wtcvt_k<<<dim3((64*128+255)/256, 1, 4), 256, 0, stream>>>(gat_W, gatWt_bf, 128, 64, 64, 128);
    wtcvt_k<<<dim3((128*256+255)/256, 1, 1), 256, 0, stream>>>(gatout_W, gatoutWt_bf, 256, 128, 128, 256);
    wtcvt_k<<<dim3((256*128+255)/256, 1, 1), 256, 0, stream>>>(Wcomp_W, WcompT_bf, 128, 256, 256, 128);
    wtcvt_k<<<dim3((256*64+255)/256, 1, 1), 256, 0, stream>>>(Wprot_W, WprotT_bf, 40, 256, 256, 64);
    // fused reduce weights: P = {tp2c x4, bhp x4}; A = {tc2p x4, bhc x4}
    wtcvt_k<<<dim3(256, 1, 4), 256, 0, stream>>>(tp2c_W, wP_bf,             LDq, LDq, LDq, LDq);
    wtcvt_k<<<dim3(256, 1, 4), 256, 0, stream>>>(bhp_W,  wP_bf + 4*65536,   LDq, LDq, LDq, LDq);
    wtcvt_k<<<dim3(256, 1, 4), 256, 0, stream>>>(tc2p_W, wA_bf,             LDq, LDq, LDq, LDq);
    wtcvt_k<<<dim3(256, 1, 4), 256, 0, stream>>>(bhc_W,  wA_bf + 4*65536,   LDq, LDq, LDq, LDq);
    pack8_k<<<8, 256, 0, stream>>>(tp2c_b, bhp_b, battc_W, 256, battp_W, 0, bias8P, w28P);
    pack8_k<<<8, 256, 0, stream>>>(tc2p_b, bhc_b, battp_W, 256, battc_W, 0, bias8A, w28A);

    // 1. h = atoms_emb @ bert_W + bert_b  (MFMA, K padded 300->320)
    cvtpad_bf16_k<<<(int)(((long long)rowsA*320 + 255)/256), 256, 0, stream>>>(
        atoms_emb, atoms_bf, rowsA, 300, 320);
    mfma_nt_k<0, 0, 1, 2, 0><<<dim3(rowsA/64, 4, 1), 256, 0, stream>>>(
        rowsA, CDq, 320, CDq, (const void*)atoms_bf, 320, 0,
        bertWt_bf, 320, 0, bert_b, 0, h, CDq, 0, nullptr, 0, nullptr);
    cvt_bf16_k<<<(rowsA*CDq/4 + 255)/256, 256, 0, stream>>>(h, h_bf, (long long)rowsA*CDq/4);

    // 2. Wh_all = h @ gat_W[k]  (MFMA, z=4, C head-offset via sC=64)
    mfma_nt_k<0, 0, 0, 4, 0><<<dim3(rowsA/64, 1, 4), 256, 0, stream>>>(
        rowsA, GDq, CDq, GDq, (const void*)h_bf, CDq, 0,
        gatWt_bf, CDq, (long long)GDq*CDq,
        nullptr, 0, WhAll, NHq*GDq, GDq, nullptr, 0, nullptr);

    // 3-4. GAT heads -> multi (ELU)
    gat_e_k<<<dim3(rowsA, NHq), 128, 0, stream>>>(WhAll, NHq*GDq, GDq, gat_a, 2*GDq,
                                                  esrc, edst, rowsA);
    gat_attn_k<<<dim3(rowsA, NHq), 128, 0, stream>>>(WhAll, NHq*GDq, GDq, adjacency,
                                                     esrc, edst, multi, NHq*GDq);

    // 5-7. GAT out layer -> avp (ELU)
    cvt_bf16_k<<<(rowsA*256/4 + 255)/256, 256, 0, stream>>>(multi, multi_bf, (long long)rowsA*256/4);
    mfma_nt_k<0, 0, 0, 2, 0><<<dim3(rowsA/64, 4, 1), 256, 0, stream>>>(
        rowsA, CDq, 256, CDq, (const void*)multi_bf, 256, 0,
        gatoutWt_bf, 256, 0, nullptr, 0, Wh2, CDq, 0, nullptr, 0, nullptr);
    gat_e_k<<<dim3(rowsA, 1), 128, 0, stream>>>(Wh2, CDq, CDq, gatout_a, 2*CDq,
                                                esrc, edst, rowsA);
    gat_attn_k<<<dim3(rowsA, 1), 128, 0, stream>>>(Wh2, CDq, CDq, adjacency,
                                                   esrc, edst, avp, CDq);

    // 8. av = leaky(avp @ Wcomp_W + b)  (MFMA)
    cvt_bf16_k<<<(rowsA*CDq/4 + 255)/256, 256, 0, stream>>>(avp, avp_bf, (long long)rowsA*CDq/4);
    mfma_nt_k<1, 0, 1, 4, 0><<<dim3(rowsA/64, 4, 1), 256, 0, stream>>>(
        rowsA, LDq, CDq, LDq, (const void*)avp_bf, CDq, 0,
        WcompT_bf, CDq, 0, Wcomp_b, 0, av, LDq, 0, nullptr, 0, nullptr);
    cvt_bf16_k<<<(rowsA*LDq/4 + 255)/256, 256, 0, stream>>>(av, av_bf, (long long)rowsA*LDq/4);

    // 9. pv0 = amino_emb @ prot_W + b  (MFMA, AF32 A)
    mfma_nt_k<0, 0, 1, 3, 1><<<dim3(rowsP/64, 1, 1), 256, 0, stream>>>(
        rowsP, 48, 1024, 40,
        (const void*)amino_emb, 1024, 0,
        protWt_bf, 1024, 0,
        prot_b, 0, c0, PDq, 0, nullptr, 0, nullptr);

    // 10. 3x conv 11x11 + leaky
    {
        long long total = (long long)Bq*Mq*PDq;
        int blocks = (int)((total + 255) / 256);
        conv_k<<<blocks, 256, 0, stream>>>(c0, conv_W + 0*121, conv_b + 0, c1);
        conv_k<<<blocks, 256, 0, stream>>>(c1, conv_W + 1*121, conv_b + 1, c0);
        conv_k<<<blocks, 256, 0, stream>>>(c0, conv_W + 2*121, conv_b + 2, c1);
    }

    // 11. pv = leaky(x @ Wprot_W + b)  (MFMA, K padded 40->64)
    cvtpad_bf16_k<<<(int)(((long long)rowsP*64 + 255)/256), 256, 0, stream>>>(
        c1, c1_bf, rowsP, 40, 64);
    mfma_nt_k<1, 0, 1, 4, 0><<<dim3(rowsP/64, 4, 1), 256, 0, stream>>>(
        rowsP, LDq, 64, LDq, (const void*)c1_bf, 64, 0,
        WprotT_bf, 64, 0, Wprot_b, 0, pv, LDq, 0, nullptr, 0, nullptr);
    cvt_bf16_k<<<(rowsP*LDq/4 + 255)/256, 256, 0, stream>>>(pv, pv_bf, (long long)rowsP*LDq/4);

    // ---- BIDAT precompute: fused z=8 reduces ----
    mfma_reduceF_k<<<dim3(rowsP/128, 1, 8), 512, 0, stream>>>(
        rowsP, pv_bf, wP_bf, bias8P, w28P, rbuf_all);     // -> rbuf_all | hpbdot_all
    mfma_reduceF_k<<<dim3(rowsA/128, 1, 8), 512, 0, stream>>>(
        rowsA, av_bf, wA_bf, bias8A, w28A, qbuf_all);     // -> qbuf_all | hbdot_all
    // avU_all[i] = av @ U[i]
    mfma_nt_k<0, 0, 0, 4, 0><<<dim3(rowsA/64, 4, 4), 256, 0, stream>>>(
        rowsA, LDq, LDq, LDq, (const void*)av_bf, LDq, 0,
        Ut_bf, LDq, (long long)LDq*LDq,
        nullptr, 0, bufU_all, LDq, (long long)rowsA*LDq,
        nullptr, 0, nullptr);
    cvt_bf16_k<<<((long long)4*rowsA*LDq/4 + 255)/256, 256, 0, stream>>>(
        bufU_all, avU_all_bf, (long long)4*rowsA*LDq/4);

    // ---- fused BIDAT A-chain ----
    bidat_fused_k<<<dim3(2, 16, 128), 256, 0, stream>>>(
        avU_all_bf, pv_bf, rbuf_all, qbuf_all,
        atoms_mask, amino_mask, scoreCp, csump);
    finishC_k<<<128, 128, 0, stream>>>(scoreCp, hbdot_all, battc_b, scoreC_all);
    finishP_k<<<dim3(128, 4), 256, 0, stream>>>(csump, hpbdot_all, battp_b, scoreP_all);

    msoftmaxB_k<<<dim3(Bq, 4), 256, 0, stream>>>(scoreC_all, atoms_mask, Nq);
    msoftmaxB_k<<<dim3(Bq, 4), 256, 0, stream>>>(scoreP_all, amino_mask, Mq);

    wsum1B_k<<<dim3(Bq, 16, 4), 256, 0, stream>>>(av, scoreC_all, wpart, Nq);
    wsum2B_k<<<dim3(Bq, 4), 256, 0, stream>>>(wpart, cf);
    wsum1B_k<<<dim3(Bq, 16, 4), 256, 0, stream>>>(pv, scoreP_all, wpart, Mq);
    wsum2B_k<<<dim3(Bq, 4), 256, 0, stream>>>(wpart, pf);

    // head
    headlin_k<0><<<dim3(Bq, 4), 256, 0, stream>>>(cf, 4*LDq, 4*LDq,
        combc_W, LDq, combc_b, v1, 770, LDq, 0);
    headlin_k<0><<<dim3(Bq, 4), 256, 0, stream>>>(pf, 4*LDq, 4*LDq,
        combp_W, LDq, combp_b, v1, 770, LDq, 512);
    vfill_k<<<Bq, 256, 0, stream>>>(fps, inv_Temp, Temp, v1);

    headlin_k<1><<<dim3(Bq, 13), 256, 0, stream>>>(v1, 770, 770,
        Wout_W + 0ll*770*770, 770, Wout_b + 0*770, v2, 770, 770, 0);
    headlin_k<1><<<dim3(Bq, 13), 256, 0, stream>>>(v2, 770, 770,
        Wout_W + 1ll*770*770, 770, Wout_b + 1*770, v1, 770, 770, 0);
    headlin_k<1><<<dim3(Bq, 13), 256, 0, stream>>>(v1, 770, 770,
        Wout_W + 2ll*770*770, 770, Wout_b + 2*770, v2, 770, 770, 0);

    final_k<<<Bq, 256, 0, stream>>>(v2, out_W, out_b, out);

    (void)in_sizes; (void)n_in; (void)out_size; (void)ws_size;
    (void)bufU; (void)avU_bf; (void)qbuf; (void)csum; (void)scoreC; (void)scoreP;
}

// Round 13
// 718.826 us; speedup vs baseline: 5.6619x; 1.0931x over previous
//
#include <hip/hip_runtime.h>
#include <math.h>

#define ALPHA_LR 0.2f

#define Bq  32
#define Nq  128
#define Mq  1024
#define CDq 128
#define GDq 64
#define NHq 4
#define LDq 256
#define PDq 40

typedef unsigned short ushort_t;
typedef __attribute__((ext_vector_type(8))) short bf16x8;
typedef __attribute__((ext_vector_type(4))) float f32x4;

__device__ __forceinline__ ushort_t f2bf(float f) {
    union { float f; unsigned u; } x; x.f = f;
    unsigned r = x.u + 0x7FFFu + ((x.u >> 16) & 1u);   // RNE
    return (ushort_t)(r >> 16);
}
__device__ __forceinline__ float bf2f(ushort_t u) {
    union { unsigned u; float f; } x; x.u = ((unsigned)u) << 16;
    return x.f;
}
// r13: fast tanh via v_exp_f32: tanh(x) = 1 - 2/(e^{2x}+1).
// Saturates correctly (x->+inf: 1; x->-inf: -1); rel err ~1e-6.
// tanhf was ~15 VALU inst and made the reduce kernels VALU-bound
// (r12: VALUBusy 38% vs MfmaUtil 8%).
__device__ __forceinline__ float ftanh(float x) {
    float e = __expf(2.f * x);
    return 1.f - 2.f / (e + 1.f);
}

// ---------------------------------------------------------------------------
// MFMA bf16 NT GEMM: C = act(A @ Bt^T + bias)
// ---------------------------------------------------------------------------
template<int ACT, int MASKED, int HAS_BIAS, int NT, int AF32>
__global__ __launch_bounds__(256) void mfma_nt_k(
    int M, int N, int K, int Nout,
    const void* __restrict__ Av, int lda, long long sA,
    const ushort_t* __restrict__ Bt, int ldb, long long sB,
    const float* __restrict__ bias, long long sBias,
    float* __restrict__ C, int ldc, long long sC,
    const float* __restrict__ maskR, long long sW2,
    const float* __restrict__ maskC)
{
    int z = blockIdx.z;
    Bt += (long long)z * sB;
    C  += (long long)z * sC;
    if (HAS_BIAS) bias += (long long)z * sBias;

    int wave = threadIdx.x >> 6;
    int lane = threadIdx.x & 63;
    int lr = lane & 15;
    int kg = lane >> 4;
    int m0 = (blockIdx.x * 4 + wave) * 16;
    int n0 = blockIdx.y * (NT * 16);
    if (m0 >= M) return;

    f32x4 acc[NT];
    #pragma unroll
    for (int t = 0; t < NT; t++) acc[t] = (f32x4){0.f, 0.f, 0.f, 0.f};

    const ushort_t* Ab = nullptr;
    const float*    Af = nullptr;
    if (AF32) Af = (const float*)Av + (long long)z * sA + (long long)(m0 + lr) * lda + kg * 8;
    else      Ab = (const ushort_t*)Av + (long long)z * sA + (long long)(m0 + lr) * lda + kg * 8;
    const ushort_t* Bbase = Bt + (long long)(n0 + lr) * ldb + kg * 8;

    for (int k0 = 0; k0 < K; k0 += 32) {
        bf16x8 a;
        if (AF32) {
            float4 a0 = *(const float4*)(Af + k0);
            float4 a1 = *(const float4*)(Af + k0 + 4);
            a[0] = (short)f2bf(a0.x); a[1] = (short)f2bf(a0.y);
            a[2] = (short)f2bf(a0.z); a[3] = (short)f2bf(a0.w);
            a[4] = (short)f2bf(a1.x); a[5] = (short)f2bf(a1.y);
            a[6] = (short)f2bf(a1.z); a[7] = (short)f2bf(a1.w);
        } else {
            a = *(const bf16x8*)(Ab + k0);
        }
        #pragma unroll
        for (int t = 0; t < NT; t++) {
            bf16x8 b = *(const bf16x8*)(Bbase + (long long)t * 16 * ldb + k0);
            acc[t] = __builtin_amdgcn_mfma_f32_16x16x32_bf16(a, b, acc[t], 0, 0, 0);
        }
    }

    int row0 = m0 + kg * 4;
    #pragma unroll
    for (int t = 0; t < NT; t++) {
        int col = n0 + t * 16 + lr;
        if (col >= Nout) continue;
        float bv = HAS_BIAS ? bias[col] : 0.f;
        float mC = MASKED ? maskC[(long long)z * N + col] : 1.f;
        #pragma unroll
        for (int r = 0; r < 4; r++) {
            float v = acc[t][r] + bv;
            if (ACT == 1) v = v > 0.f ? v : ALPHA_LR * v;
            else if (ACT == 2) v = ftanh(v);
            if (MASKED) v *= maskR[(long long)z * M + row0 + r] * mC;
            C[(long long)(row0 + r) * ldc + col] = v;
        }
    }
}

// ---------------------------------------------------------------------------
// r13: fused reduce GEMM, 256-thread blocks (64 rows), fast tanh.
//   out[z][row] = sum_col ftanh((A @ W8[z]^T)[row,col] + bias8[z][col]) * w28[z][col]
// 4 waves x 16 rows; 4 phases x 64 B-rows in 32 KB swizzled LDS; A row
// hoisted to registers. Z=8 batches both weight families.
// ---------------------------------------------------------------------------
__global__ __launch_bounds__(256) void mfma_reduceF_k(
    int M,
    const ushort_t* __restrict__ A,        // [M][256] bf16
    const ushort_t* __restrict__ W8,       // [Z][256][256] bf16
    const float* __restrict__ bias8,       // [Z][256]
    const float* __restrict__ w28,         // [Z][256]
    float* __restrict__ C)                 // [Z][M]
{
    int z = blockIdx.z;
    const ushort_t* W = W8 + (long long)z * 65536;
    const float* bias = bias8 + z * 256;
    const float* w2   = w28 + z * 256;
    float* Cz = C + (long long)z * M;

    __shared__ ushort_t Bs[64 * 256];   // 32 KB

    int tid = threadIdx.x;
    int wave = tid >> 6, lane = tid & 63;
    int lr = lane & 15, kg = lane >> 4;
    int m0 = blockIdx.x * 64 + wave * 16;

    const ushort_t* Ab = A + (long long)(m0 + lr) * 256 + kg * 8;
    bf16x8 areg[8];
    #pragma unroll
    for (int kb = 0; kb < 8; kb++) areg[kb] = *(const bf16x8*)(Ab + kb * 32);

    float rs[4] = {0.f, 0.f, 0.f, 0.f};

    for (int ph = 0; ph < 4; ph++) {
        int n0 = ph * 64;
        #pragma unroll
        for (int step = 0; step < 8; step++) {
            int g = step * 256 + tid;
            int row = g >> 5, slot = g & 31;
            uint4 v = *(const uint4*)(W + (long long)(n0 + row) * 256 + slot * 8);
            int dst = row * 512 + ((slot * 16) ^ ((row & 31) << 4));
            *(uint4*)((char*)Bs + dst) = v;
        }
        __syncthreads();

        f32x4 acc[4];
        #pragma unroll
        for (int t = 0; t < 4; t++) acc[t] = (f32x4){0.f, 0.f, 0.f, 0.f};

        #pragma unroll
        for (int kb = 0; kb < 8; kb++) {
            #pragma unroll
            for (int t = 0; t < 4; t++) {
                int rowl = t * 16 + lr;
                int colb = (kg * 16 + kb * 64) ^ ((rowl & 31) << 4);
                bf16x8 b = *(const bf16x8*)((char*)Bs + rowl * 512 + colb);
                acc[t] = __builtin_amdgcn_mfma_f32_16x16x32_bf16(areg[kb], b, acc[t], 0, 0, 0);
            }
        }
        #pragma unroll
        for (int t = 0; t < 4; t++) {
            int col = n0 + t * 16 + lr;
            float bv = bias[col], wv = w2[col];
            #pragma unroll
            for (int r = 0; r < 4; r++)
                rs[r] += ftanh(acc[t][r] + bv) * wv;
        }
        __syncthreads();
    }

    #pragma unroll
    for (int r = 0; r < 4; r++) {
        rs[r] += __shfl_xor(rs[r], 1, 64);
        rs[r] += __shfl_xor(rs[r], 2, 64);
        rs[r] += __shfl_xor(rs[r], 4, 64);
        rs[r] += __shfl_xor(rs[r], 8, 64);
    }
    if (lr == 0) {
        int row0 = m0 + kg * 4;
        #pragma unroll
        for (int r = 0; r < 4; r++)
            Cz[row0 + r] = rs[r];
    }
}

// pack biases and w2 vectors for z=8 fused reduce
__global__ __launch_bounds__(256) void pack8_k(
    const float* __restrict__ b1, const float* __restrict__ b2,
    const float* __restrict__ w1, int w1Off,
    const float* __restrict__ w2v, int w2Off,
    float* __restrict__ bias8, float* __restrict__ w28)
{
    int j = blockIdx.x * 256 + threadIdx.x;   // 0..2047
    int slot = j >> 8, c = j & 255;
    bias8[j] = slot < 4 ? b1[slot * 256 + c] : b2[(slot - 4) * 256 + c];
    w28[j]   = slot < 4 ? w1[slot * 512 + w1Off + c] : w2v[(slot - 4) * 512 + w2Off + c];
}

// ---------------------------------------------------------------------------
// fused BIDAT A-chain (no Abuf), fast tanh
// ---------------------------------------------------------------------------
__global__ __launch_bounds__(256) void bidat_fused_k(
    const ushort_t* __restrict__ avU_all,
    const ushort_t* __restrict__ pv_bf,
    const float* __restrict__ rbuf_all,
    const float* __restrict__ qbuf_all,
    const float* __restrict__ atoms_mask,
    const float* __restrict__ amino_mask,
    float* __restrict__ scoreCp,
    float* __restrict__ csump)
{
    int z = blockIdx.z;
    int i = z >> 5, b = z & 31;
    int gx = blockIdx.x;
    int gy = blockIdx.y;
    int wave = threadIdx.x >> 6;
    int lane = threadIdx.x & 63;
    int lr = lane & 15, kg = lane >> 4;

    int n0 = gx * 64 + wave * 16;
    int m0 = gy * 64;

    const ushort_t* Ab = avU_all + ((long long)i * 4096 + (long long)b * 128 + n0 + lr) * 256 + kg * 8;
    const ushort_t* Bb = pv_bf   + ((long long)b * 1024 + m0 + lr) * 256 + kg * 8;

    f32x4 acc[4];
    #pragma unroll
    for (int t = 0; t < 4; t++) acc[t] = (f32x4){0.f, 0.f, 0.f, 0.f};

    for (int k0 = 0; k0 < 256; k0 += 32) {
        bf16x8 a = *(const bf16x8*)(Ab + k0);
        #pragma unroll
        for (int t = 0; t < 4; t++) {
            bf16x8 bf = *(const bf16x8*)(Bb + (long long)t * 16 * 256 + k0);
            acc[t] = __builtin_amdgcn_mfma_f32_16x16x32_bf16(a, bf, acc[t], 0, 0, 0);
        }
    }

    const float* rI = rbuf_all + (long long)i * 32768 + (long long)b * 1024;
    const float* qI = qbuf_all + (long long)i * 4096 + (long long)b * 128;
    const float* mR = atoms_mask + (long long)b * 128;
    const float* mC = amino_mask + (long long)b * 1024;

    float sc[4] = {0.f, 0.f, 0.f, 0.f};
    float cs[4] = {0.f, 0.f, 0.f, 0.f};
    #pragma unroll
    for (int t = 0; t < 4; t++) {
        int m = m0 + t * 16 + lr;
        float mc = mC[m];
        float rv = rI[m];
        #pragma unroll
        for (int r = 0; r < 4; r++) {
            int n = n0 + kg * 4 + r;
            float a = ftanh(acc[t][r]) * mR[n] * mc;
            sc[r] += a * rv;
            cs[t] += a * qI[n];
        }
    }

    #pragma unroll
    for (int r = 0; r < 4; r++) {
        sc[r] += __shfl_xor(sc[r], 1, 64);
        sc[r] += __shfl_xor(sc[r], 2, 64);
        sc[r] += __shfl_xor(sc[r], 4, 64);
        sc[r] += __shfl_xor(sc[r], 8, 64);
    }
    if (lr == 0) {
        #pragma unroll
        for (int r = 0; r < 4; r++) {
            int n = gx * 64 + wave * 16 + kg * 4 + r;
            scoreCp[((long long)z * 16 + gy) * 128 + n] = sc[r];
        }
    }

    #pragma unroll
    for (int t = 0; t < 4; t++) {
        cs[t] += __shfl_xor(cs[t], 16, 64);
        cs[t] += __shfl_xor(cs[t], 32, 64);
    }
    __shared__ float cl[4][64];
    if (kg == 0) {
        #pragma unroll
        for (int t = 0; t < 4; t++) cl[wave][t * 16 + lr] = cs[t];
    }
    __syncthreads();
    if (threadIdx.x < 64) {
        float s = cl[0][threadIdx.x] + cl[1][threadIdx.x]
                + cl[2][threadIdx.x] + cl[3][threadIdx.x];
        csump[((long long)z * 2 + gx) * 1024 + m0 + threadIdx.x] = s;
    }
}

__global__ __launch_bounds__(128) void finishC_k(
    const float* __restrict__ scoreCp, const float* __restrict__ hbdot_all,
    const float* __restrict__ battc_b, float* __restrict__ scoreC_all)
{
    int z = blockIdx.x;
    int i = z >> 5, b = z & 31;
    int n = threadIdx.x;
    float s = 0.f;
    #pragma unroll
    for (int gy = 0; gy < 16; gy++)
        s += scoreCp[((long long)z * 16 + gy) * 128 + n];
    scoreC_all[(long long)z * 128 + n] =
        s + hbdot_all[(long long)i * 4096 + b * 128 + n] + battc_b[i];
}

__global__ __launch_bounds__(256) void finishP_k(
    const float* __restrict__ csump, const float* __restrict__ hpbdot_all,
    const float* __restrict__ battp_b, float* __restrict__ scoreP_all)
{
    int z = blockIdx.x;
    int i = z >> 5, b = z & 31;
    int m = blockIdx.y * 256 + threadIdx.x;
    float s = csump[((long long)z * 2 + 0) * 1024 + m]
            + csump[((long long)z * 2 + 1) * 1024 + m];
    scoreP_all[(long long)z * 1024 + m] =
        s + hpbdot_all[(long long)i * 32768 + (long long)b * 1024 + m] + battp_b[i];
}

// fp32 -> bf16 (contiguous)
__global__ __launch_bounds__(256) void cvt_bf16_k(
    const float* __restrict__ in, ushort_t* __restrict__ out, long long n4)
{
    long long i = (long long)blockIdx.x * 256 + threadIdx.x;
    if (i >= n4) return;
    float4 v = ((const float4*)in)[i];
    ushort4 o;
    o.x = f2bf(v.x); o.y = f2bf(v.y); o.z = f2bf(v.z); o.w = f2bf(v.w);
    ((ushort4*)out)[i] = o;
}

// fp32 [rows][Ksrc] -> bf16 [rows][Kdst] zero-padded
__global__ __launch_bounds__(256) void cvtpad_bf16_k(
    const float* __restrict__ in, ushort_t* __restrict__ out,
    int rows, int Ksrc, int Kdst)
{
    long long idx = (long long)blockIdx.x * 256 + threadIdx.x;
    long long total = (long long)rows * Kdst;
    if (idx >= total) return;
    int r = (int)(idx / Kdst), k = (int)(idx % Kdst);
    out[idx] = (k < Ksrc) ? f2bf(in[(long long)r * Ksrc + k]) : (ushort_t)0;
}

// W[K][Nsrc] fp32 -> Wt[Npad][Kp] bf16 (transposed, padded), batched z
__global__ __launch_bounds__(256) void wtcvt_k(
    const float* __restrict__ W, ushort_t* __restrict__ Wt,
    int K, int Nsrc, int Npad, int Kp)
{
    int z = blockIdx.z;
    const float* Wz = W + (long long)z * K * Nsrc;
    ushort_t* Oz = Wt + (long long)z * Npad * Kp;
    int idx = blockIdx.x * 256 + threadIdx.x;
    if (idx >= Npad * Kp) return;
    int n = idx / Kp, k = idx % Kp;
    float v = (k < K && n < Nsrc) ? Wz[(long long)k * Nsrc + n] : 0.f;
    Oz[idx] = f2bf(v);
}

// per-row GAT source/dest attention logits
__global__ __launch_bounds__(128) void gat_e_k(
    const float* __restrict__ Wh, int ldWh, int GD,
    const float* __restrict__ a, int aStride,
    float* __restrict__ esrc, float* __restrict__ edst, int rows)
{
    int row = blockIdx.x;
    int k = blockIdx.y;
    int g = threadIdx.x;
    float ws = 0.f, wd = 0.f;
    if (g < GD) {
        float wv = Wh[(long long)row * ldWh + k * GD + g];
        ws = wv * a[k * aStride + g];
        wd = wv * a[k * aStride + GD + g];
    }
    __shared__ float sb[2][128];
    sb[0][threadIdx.x] = ws; sb[1][threadIdx.x] = wd;
    __syncthreads();
    for (int off = 64; off > 0; off >>= 1) {
        if (threadIdx.x < off) {
            sb[0][threadIdx.x] += sb[0][threadIdx.x + off];
            sb[1][threadIdx.x] += sb[1][threadIdx.x + off];
        }
        __syncthreads();
    }
    if (threadIdx.x == 0) {
        esrc[(long long)k * rows + row] = sb[0][0];
        edst[(long long)k * rows + row] = sb[1][0];
    }
}

// GAT attention: softmax over neighbors + weighted sum + ELU
__global__ __launch_bounds__(128) void gat_attn_k(
    const float* __restrict__ Wh, int ldWh, int GD,
    const int* __restrict__ adj,
    const float* __restrict__ esrc, const float* __restrict__ edst,
    float* __restrict__ out, int ldOut)
{
    int row = blockIdx.x;
    int k = blockIdx.y;
    int rows = gridDim.x;
    int b = row / Nq, n = row % Nq;
    int m = threadIdx.x;

    __shared__ float att[Nq];
    __shared__ float red[Nq];

    float e = esrc[(long long)k * rows + row] + edst[(long long)k * rows + b * Nq + m];
    e = e > 0.f ? e : ALPHA_LR * e;
    if (adj[(long long)b * Nq * Nq + n * Nq + m] <= 0) e = -9.0e15f;

    red[m] = e; __syncthreads();
    for (int off = 64; off > 0; off >>= 1) {
        if (m < off) red[m] = fmaxf(red[m], red[m + off]);
        __syncthreads();
    }
    float mx = red[0]; __syncthreads();
    float ex = __expf(e - mx);
    att[m] = ex; red[m] = ex; __syncthreads();
    for (int off = 64; off > 0; off >>= 1) {
        if (m < off) red[m] += red[m + off];
        __syncthreads();
    }
    float inv = 1.0f / red[0];

    for (int g = threadIdx.x; g < GD; g += blockDim.x) {
        float s = 0.f;
        for (int mm = 0; mm < Nq; mm++)
            s += att[mm] * Wh[(long long)(b * Nq + mm) * ldWh + k * GD + g];
        s *= inv;
        s = s > 0.f ? s : expm1f(s);   // ELU
        out[(long long)row * ldOut + k * GD + g] = s;
    }
}

// 11x11 same-pad conv + leaky
__global__ __launch_bounds__(256) void conv_k(
    const float* __restrict__ x, const float* __restrict__ W,
    const float* __restrict__ bptr, float* __restrict__ y)
{
    __shared__ float w[121];
    if (threadIdx.x < 121) w[threadIdx.x] = W[threadIdx.x];
    __syncthreads();
    long long idx = (long long)blockIdx.x * blockDim.x + threadIdx.x;
    long long total = (long long)Bq * Mq * PDq;
    if (idx >= total) return;
    int d = (int)(idx % PDq);
    long long t = idx / PDq;
    int m = (int)(t % Mq);
    int b = (int)(t / Mq);
    const float* xb = x + (long long)b * Mq * PDq;
    float s = 0.f;
    #pragma unroll
    for (int i = 0; i < 11; i++) {
        int mm = m + i - 5;
        if (mm < 0 || mm >= Mq) continue;
        #pragma unroll
        for (int j = 0; j < 11; j++) {
            int dd = d + j - 5;
            if (dd < 0 || dd >= PDq) continue;
            s += xb[(long long)mm * PDq + dd] * w[i * 11 + j];
        }
    }
    s += *bptr;
    y[idx] = s > 0.f ? s : ALPHA_LR * s;
}

// masked softmax over L, batched over i
__global__ __launch_bounds__(256) void msoftmaxB_k(
    float* __restrict__ score, const float* __restrict__ mask, int L)
{
    int b = blockIdx.x, i = blockIdx.y;
    float* s = score + ((long long)i * Bq + b) * L;
    const float* mk = mask + (long long)b * L;
    int t = threadIdx.x;
    __shared__ float red[256];
    float mx = -1e30f;
    for (int j = t; j < L; j += 256) mx = fmaxf(mx, s[j]);
    red[t] = mx; __syncthreads();
    for (int off = 128; off > 0; off >>= 1) {
        if (t < off) red[t] = fmaxf(red[t], red[t + off]);
        __syncthreads();
    }
    mx = red[0]; __syncthreads();
    float sum = 0.f;
    for (int j = t; j < L; j += 256) {
        float e = __expf(s[j] - mx) * mk[j];
        s[j] = e; sum += e;
    }
    red[t] = sum; __syncthreads();
    for (int off = 128; off > 0; off >>= 1) {
        if (t < off) red[t] += red[t + off];
        __syncthreads();
    }
    float inv = 1.0f / (red[0] + 1e-6f);
    __syncthreads();
    for (int j = t; j < L; j += 256) s[j] *= inv;
}

// weighted sum stage 1, batched over i, bf16 features (r13: half the traffic)
__global__ __launch_bounds__(256) void wsum1B_k(
    const ushort_t* __restrict__ feat, const float* __restrict__ att_all,
    float* __restrict__ partial, int L)
{
    int b = blockIdx.x, c = blockIdx.y, i = blockIdx.z, l = threadIdx.x;
    int chunk = L / 16;
    const ushort_t* fb = feat + (long long)b * L * LDq;
    const float* ab = att_all + ((long long)i * Bq + b) * L;
    float s = 0.f;
    int r0 = c * chunk, r1 = r0 + chunk;
    for (int r = r0; r < r1; r++) s += bf2f(fb[(long long)r * LDq + l]) * ab[r];
    partial[(((long long)i * Bq + b) * 16 + c) * LDq + l] = s;
}

// weighted sum stage 2, batched
__global__ __launch_bounds__(256) void wsum2B_k(
    const float* __restrict__ partial, float* __restrict__ out)
{
    int b = blockIdx.x, i = blockIdx.y, l = threadIdx.x;
    float s = 0.f;
    #pragma unroll
    for (int c = 0; c < 16; c++)
        s += partial[(((long long)i * Bq + b) * 16 + c) * LDq + l];
    out[(long long)b * 4 * LDq + i * LDq + l] = s;
}

// ---------------------------------------------------------------------------
// Skinny dense layer for the head
// ---------------------------------------------------------------------------
template<int ACT>
__global__ __launch_bounds__(256) void headlin_k(
    const float* __restrict__ vin, int ldv, int VD,
    const float* __restrict__ W, int ldw,
    const float* __restrict__ bias,
    float* __restrict__ vout, int ldo, int OD, int colBase)
{
    int b = blockIdx.x;
    int c = threadIdx.x & 63;
    int s = threadIdx.x >> 6;
    int col = blockIdx.y * 64 + c;

    __shared__ float vs[1024];
    for (int i = threadIdx.x; i < VD; i += 256) vs[i] = vin[(long long)b * ldv + i];
    __syncthreads();

    float sum = 0.f;
    if (col < OD) {
        int k0 = (VD * s) >> 2, k1 = (VD * (s + 1)) >> 2;
        #pragma unroll 4
        for (int k = k0; k < k1; k++)
            sum += vs[k] * W[(long long)k * ldw + col];
    }
    __shared__ float red[4][64];
    red[s][c] = sum;
    __syncthreads();
    if (s == 0 && col < OD) {
        float t = red[0][c] + red[1][c] + red[2][c] + red[3][c] + bias[col];
        if (ACT == 1) t = t > 0.f ? t : ALPHA_LR * t;
        vout[(long long)b * ldo + colBase + col] = t;
    }
}

// v[b,256:512]=fps, v[b,768]=invT, v[b,769]=T
__global__ __launch_bounds__(256) void vfill_k(
    const float* __restrict__ fps, const float* __restrict__ invT,
    const float* __restrict__ T, float* __restrict__ v)
{
    int b = blockIdx.x, t = threadIdx.x;
    v[(long long)b * 770 + 256 + t] = fps[(long long)b * 256 + t];
    if (t == 0) {
        v[(long long)b * 770 + 768] = invT[b];
        v[(long long)b * 770 + 769] = T[b];
    }
}

// out[b] = v[b,:770]·W + b
__global__ __launch_bounds__(256) void final_k(
    const float* __restrict__ v, const float* __restrict__ W,
    const float* __restrict__ bptr, float* __restrict__ out)
{
    int b = blockIdx.x, t = threadIdx.x;
    float s = 0.f;
    for (int i = t; i < 770; i += 256) s += v[(long long)b * 770 + i] * W[i];
    __shared__ float red[256];
    red[t] = s; __syncthreads();
    for (int off = 128; off > 0; off >>= 1) {
        if (t < off) red[t] += red[t + off];
        __syncthreads();
    }
    if (t == 0) out[b] = red[0] + bptr[0];
}

extern "C" void kernel_launch(void* const* d_in, const int* in_sizes, int n_in,
                              void* d_out, int out_size, void* d_ws, size_t ws_size,
                              hipStream_t stream)
{
    const float* atoms_emb = (const float*)d_in[0];
    const int*   adjacency = (const int*)d_in[1];
    const float* atoms_mask= (const float*)d_in[2];
    const float* amino_emb = (const float*)d_in[3];
    const float* amino_mask= (const float*)d_in[4];
    const float* fps       = (const float*)d_in[5];
    const float* inv_Temp  = (const float*)d_in[6];
    const float* Temp      = (const float*)d_in[7];
    const float* bert_W    = (const float*)d_in[8];
    const float* bert_b    = (const float*)d_in[9];
    const float* gat_W     = (const float*)d_in[10];
    const float* gat_a     = (const float*)d_in[11];
    const float* gatout_W  = (const float*)d_in[12];
    const float* gatout_a  = (const float*)d_in[13];
    const float* Wcomp_W   = (const float*)d_in[14];
    const float* Wcomp_b   = (const float*)d_in[15];
    const float* prot_W    = (const float*)d_in[16];
    const float* prot_b    = (const float*)d_in[17];
    const float* conv_W    = (const float*)d_in[18];
    const float* conv_b    = (const float*)d_in[19];
    const float* Wprot_W   = (const float*)d_in[20];
    const float* Wprot_b   = (const float*)d_in[21];
    const float* U         = (const float*)d_in[22];
    const float* tc2p_W    = (const float*)d_in[23];
    const float* tc2p_b    = (const float*)d_in[24];
    const float* tp2c_W    = (const float*)d_in[25];
    const float* tp2c_b    = (const float*)d_in[26];
    const float* bhc_W     = (const float*)d_in[27];
    const float* bhc_b     = (const float*)d_in[28];
    const float* bhp_W     = (const float*)d_in[29];
    const float* bhp_b     = (const float*)d_in[30];
    const float* battc_W   = (const float*)d_in[31];
    const float* battc_b   = (const float*)d_in[32];
    const float* battp_W   = (const float*)d_in[33];
    const float* battp_b   = (const float*)d_in[34];
    const float* combc_W   = (const float*)d_in[35];
    const float* combc_b   = (const float*)d_in[36];
    const float* combp_W   = (const float*)d_in[37];
    const float* combp_b   = (const float*)d_in[38];
    const float* Wout_W    = (const float*)d_in[39];
    const float* Wout_b    = (const float*)d_in[40];
    const float* out_W     = (const float*)d_in[41];
    const float* out_b     = (const float*)d_in[42];
    float* out = (float*)d_out;

    // ---- workspace layout (floats) ----
    float* w = (float*)d_ws;
    float* av    = w; w += (long long)Bq*Nq*LDq;
    float* pv    = w; w += (long long)Bq*Mq*LDq;
    float* sx    = w; w += (long long)Bq*Mq*LDq;   // early fp32 scratch -> precomp pool
    float* pool  = w; w += (long long)Bq*Nq*Mq;    // early bf16 staging -> partials
    float* bufU  = w; w += (long long)Bq*Nq*LDq;
    float* bufTC = w; w += (long long)Bq*Nq*LDq;   // wsum partials
    float* esrc  = w; w += (long long)NHq*Bq*Nq;
    float* edst  = w; w += (long long)NHq*Bq*Nq;
    float* scoreC= w; w += (long long)Bq*Nq;
    float* scoreP= w; w += (long long)Bq*Mq;
    float* rbuf  = w; w += (long long)Bq*Mq;       // -> pack8 outputs
    float* qbuf  = w; w += (long long)Bq*Nq;
    float* csum  = w; w += (long long)Bq*Mq;
    float* cf    = w; w += (long long)Bq*4*LDq;
    float* pf    = w; w += (long long)Bq*4*LDq;
    float* v1    = w; w += (long long)Bq*770;
    float* v2    = w; w += (long long)Bq*770;
    // bf16 buffers
    ushort_t* pv_bf  = (ushort_t*)w; w += (long long)Bq*Mq*LDq/2;
    ushort_t* av_bf  = (ushort_t*)w; w += (long long)Bq*Nq*LDq/2;
    ushort_t* avU_bf = (ushort_t*)w; w += (long long)Bq*Nq*LDq/2;
    ushort_t* Ut_bf     = (ushort_t*)w; w += (long long)4*LDq*LDq/2;
    ushort_t* protWt_bf = (ushort_t*)w; w += (long long)48*1024/2;
    ushort_t* bertWt_bf = (ushort_t*)w; w += (long long)128*320/2;
    ushort_t* gatWt_bf  = (ushort_t*)w; w += (long long)4*64*128/2;
    ushort_t* gatoutWt_bf=(ushort_t*)w; w += (long long)128*256/2;
    ushort_t* WcompT_bf = (ushort_t*)w; w += (long long)256*128/2;
    ushort_t* WprotT_bf = (ushort_t*)w; w += (long long)256*64/2;
    ushort_t* wP_bf     = (ushort_t*)w; w += (long long)8*256*256/2;
    ushort_t* wA_bf     = (ushort_t*)w; w += (long long)8*256*256/2;

    int rowsA = Bq * Nq;     // 4096
    int rowsP = Bq * Mq;     // 32768

    // early fp32 aliases inside sx (dead before BIDAT precompute)
    float* h     = sx;
    float* WhAll = h + (long long)rowsA*CDq;
    float* multi = WhAll + (long long)rowsA*NHq*GDq;
    float* Wh2   = multi + (long long)rowsA*NHq*GDq;
    float* avp   = Wh2 + (long long)rowsA*CDq;
    float* c0    = avp + (long long)rowsA*CDq;
    float* c1    = c0 + (long long)rowsP*PDq;

    // early bf16 aliases inside pool (dead before partials phase)
    ushort_t* atoms_bf = (ushort_t*)pool;
    ushort_t* h_bf     = atoms_bf + (long long)rowsA*320;
    ushort_t* multi_bf = h_bf + (long long)rowsA*128;
    ushort_t* avp_bf   = multi_bf + (long long)rowsA*256;
    ushort_t* c1_bf    = avp_bf + (long long)rowsA*128;

    // BIDAT-precompute pool in sx (z=8 reduce outputs land contiguously)
    float*    rbuf_all   = sx;
    float*    hpbdot_all = rbuf_all   + (long long)4*rowsP;
    float*    qbuf_all   = hpbdot_all + (long long)4*rowsP;
    float*    hbdot_all  = qbuf_all   + (long long)4*rowsA;
    float*    bufU_all   = hbdot_all  + (long long)4*rowsA;
    ushort_t* avU_all_bf = (ushort_t*)(bufU_all + (long long)4*rowsA*LDq);

    // partials pool (after bidat)
    float* scoreCp    = pool;
    float* csump      = scoreCp + 262144;
    float* scoreC_all = csump + 262144;
    float* scoreP_all = scoreC_all + 16384;

    float* wpart = bufTC;

    // pack8 outputs
    float* bias8P = rbuf;
    float* w28P   = rbuf + 2048;
    float* bias8A = rbuf + 4096;
    float* w28A   = rbuf + 6144;

    // ---- weight transpose-converts + packs ----
    wtcvt_k<<<dim3(256, 1, 4), 256, 0, stream>>>(U,      Ut_bf,    LDq, LDq, LDq, LDq);
    wtcvt_k<<<dim3((48*1024+255)/256, 1, 1), 256, 0, stream>>>(prot_W, protWt_bf, 1024, 40, 48, 1024);
    wtcvt_k<<<dim3((128*320+255)/256, 1, 1), 256, 0, stream>>>(bert_W, bertWt_bf, 300, 128, 128, 320);
    wtcvt_k<<<dim3((64*128+255)/256, 1, 4), 256, 0, stream>>>(gat_W, gatWt_bf, 128, 64, 64, 128);
    wtcvt_k<<<dim3((128*256+255)/256, 1, 1), 256, 0, stream>>>(gatout_W, gatoutWt_bf, 256, 128, 128, 256);
    wtcvt_k<<<dim3((256*128+255)/256, 1, 1), 256, 0, stream>>>(Wcomp_W, WcompT_bf, 128, 256, 256, 128);
    wtcvt_k<<<dim3((256*64+255)/256, 1, 1), 256, 0, stream>>>(Wprot_W, WprotT_bf, 40, 256, 256, 64);
    wtcvt_k<<<dim3(256, 1, 4), 256, 0, stream>>>(tp2c_W, wP_bf,             LDq, LDq, LDq, LDq);
    wtcvt_k<<<dim3(256, 1, 4), 256, 0, stream>>>(bhp_W,  wP_bf + 4*65536,   LDq, LDq, LDq, LDq);
    wtcvt_k<<<dim3(256, 1, 4), 256, 0, stream>>>(tc2p_W, wA_bf,             LDq, LDq, LDq, LDq);
    wtcvt_k<<<dim3(256, 1, 4), 256, 0, stream>>>(bhc_W,  wA_bf + 4*65536,   LDq, LDq, LDq, LDq);
    pack8_k<<<8, 256, 0, stream>>>(tp2c_b, bhp_b, battc_W, 256, battp_W, 0, bias8P, w28P);
    pack8_k<<<8, 256, 0, stream>>>(tc2p_b, bhc_b, battp_W, 256, battc_W, 0, bias8A, w28A);

    // 1. h = atoms_emb @ bert_W + bert_b  (MFMA, K padded 300->320)
    cvtpad_bf16_k<<<(int)(((long long)rowsA*320 + 255)/256), 256, 0, stream>>>(
        atoms_emb, atoms_bf, rowsA, 300, 320);
    mfma_nt_k<0, 0, 1, 2, 0><<<dim3(rowsA/64, 4, 1), 256, 0, stream>>>(
        rowsA, CDq, 320, CDq, (const void*)atoms_bf, 320, 0,
        bertWt_bf, 320, 0, bert_b, 0, h, CDq, 0, nullptr, 0, nullptr);
    cvt_bf16_k<<<(rowsA*CDq/4 + 255)/256, 256, 0, stream>>>(h, h_bf, (long long)rowsA*CDq/4);

    // 2. Wh_all = h @ gat_W[k]  (MFMA, z=4)
    mfma_nt_k<0, 0, 0, 4, 0><<<dim3(rowsA/64, 1, 4), 256, 0, stream>>>(
        rowsA, GDq, CDq, GDq, (const void*)h_bf, CDq, 0,
        gatWt_bf, CDq, (long long)GDq*CDq,
        nullptr, 0, WhAll, NHq*GDq, GDq, nullptr, 0, nullptr);

    // 3-4. GAT heads -> multi (ELU)
    gat_e_k<<<dim3(rowsA, NHq), 128, 0, stream>>>(WhAll, NHq*GDq, GDq, gat_a, 2*GDq,
                                                  esrc, edst, rowsA);
    gat_attn_k<<<dim3(rowsA, NHq), 128, 0, stream>>>(WhAll, NHq*GDq, GDq, adjacency,
                                                     esrc, edst, multi, NHq*GDq);

    // 5-7. GAT out layer -> avp (ELU)
    cvt_bf16_k<<<(rowsA*256/4 + 255)/256, 256, 0, stream>>>(multi, multi_bf, (long long)rowsA*256/4);
    mfma_nt_k<0, 0, 0, 2, 0><<<dim3(rowsA/64, 4, 1), 256, 0, stream>>>(
        rowsA, CDq, 256, CDq, (const void*)multi_bf, 256, 0,
        gatoutWt_bf, 256, 0, nullptr, 0, Wh2, CDq, 0, nullptr, 0, nullptr);
    gat_e_k<<<dim3(rowsA, 1), 128, 0, stream>>>(Wh2, CDq, CDq, gatout_a, 2*CDq,
                                                esrc, edst, rowsA);
    gat_attn_k<<<dim3(rowsA, 1), 128, 0, stream>>>(Wh2, CDq, CDq, adjacency,
                                                   esrc, edst, avp, CDq);

    // 8. av = leaky(avp @ Wcomp_W + b)  (MFMA)
    cvt_bf16_k<<<(rowsA*CDq/4 + 255)/256, 256, 0, stream>>>(avp, avp_bf, (long long)rowsA*CDq/4);
    mfma_nt_k<1, 0, 1, 4, 0><<<dim3(rowsA/64, 4, 1), 256, 0, stream>>>(
        rowsA, LDq, CDq, LDq, (const void*)avp_bf, CDq, 0,
        WcompT_bf, CDq, 0, Wcomp_b, 0, av, LDq, 0, nullptr, 0, nullptr);
    cvt_bf16_k<<<(rowsA*LDq/4 + 255)/256, 256, 0, stream>>>(av, av_bf, (long long)rowsA*LDq/4);

    // 9. pv0 = amino_emb @ prot_W + b  (MFMA, AF32 A)
    mfma_nt_k<0, 0, 1, 3, 1><<<dim3(rowsP/64, 1, 1), 256, 0, stream>>>(
        rowsP, 48, 1024, 40,
        (const void*)amino_emb, 1024, 0,
        protWt_bf, 1024, 0,
        prot_b, 0, c0, PDq, 0, nullptr, 0, nullptr);

    // 10. 3x conv 11x11 + leaky
    {
        long long total = (long long)Bq*Mq*PDq;
        int blocks = (int)((total + 255) / 256);
        conv_k<<<blocks, 256, 0, stream>>>(c0, conv_W + 0*121, conv_b + 0, c1);
        conv_k<<<blocks, 256, 0, stream>>>(c1, conv_W + 1*121, conv_b + 1, c0);
        conv_k<<<blocks, 256, 0, stream>>>(c0, conv_W + 2*121, conv_b + 2, c1);
    }

    // 11. pv = leaky(x @ Wprot_W + b)  (MFMA, K padded 40->64)
    cvtpad_bf16_k<<<(int)(((long long)rowsP*64 + 255)/256), 256, 0, stream>>>(
        c1, c1_bf, rowsP, 40, 64);
    mfma_nt_k<1, 0, 1, 4, 0><<<dim3(rowsP/64, 4, 1), 256, 0, stream>>>(
        rowsP, LDq, 64, LDq, (const void*)c1_bf, 64, 0,
        WprotT_bf, 64, 0, Wprot_b, 0, pv, LDq, 0, nullptr, 0, nullptr);
    cvt_bf16_k<<<(rowsP*LDq/4 + 255)/256, 256, 0, stream>>>(pv, pv_bf, (long long)rowsP*LDq/4);

    // ---- BIDAT precompute: fused z=8 reduces (r13: 64-row blocks) ----
    mfma_reduceF_k<<<dim3(rowsP/64, 1, 8), 256, 0, stream>>>(
        rowsP, pv_bf, wP_bf, bias8P, w28P, rbuf_all);     // -> rbuf_all | hpbdot_all
    mfma_reduceF_k<<<dim3(rowsA/64, 1, 8), 256, 0, stream>>>(
        rowsA, av_bf, wA_bf, bias8A, w28A, qbuf_all);     // -> qbuf_all | hbdot_all
    // avU_all[i] = av @ U[i]
    mfma_nt_k<0, 0, 0, 4, 0><<<dim3(rowsA/64, 4, 4), 256, 0, stream>>>(
        rowsA, LDq, LDq, LDq, (const void*)av_bf, LDq, 0,
        Ut_bf, LDq, (long long)LDq*LDq,
        nullptr, 0, bufU_all, LDq, (long long)rowsA*LDq,
        nullptr, 0, nullptr);
    cvt_bf16_k<<<((long long)4*rowsA*LDq/4 + 255)/256, 256, 0, stream>>>(
        bufU_all, avU_all_bf, (long long)4*rowsA*LDq/4);

    // ---- fused BIDAT A-chain ----
    bidat_fused_k<<<dim3(2, 16, 128), 256, 0, stream>>>(
        avU_all_bf, pv_bf, rbuf_all, qbuf_all,
        atoms_mask, amino_mask, scoreCp, csump);
    finishC_k<<<128, 128, 0, stream>>>(scoreCp, hbdot_all, battc_b, scoreC_all);
    finishP_k<<<dim3(128, 4), 256, 0, stream>>>(csump, hpbdot_all, battp_b, scoreP_all);

    msoftmaxB_k<<<dim3(Bq, 4), 256, 0, stream>>>(scoreC_all, atoms_mask, Nq);
    msoftmaxB_k<<<dim3(Bq, 4), 256, 0, stream>>>(scoreP_all, amino_mask, Mq);

    wsum1B_k<<<dim3(Bq, 16, 4), 256, 0, stream>>>(av_bf, scoreC_all, wpart, Nq);
    wsum2B_k<<<dim3(Bq, 4), 256, 0, stream>>>(wpart, cf);
    wsum1B_k<<<dim3(Bq, 16, 4), 256, 0, stream>>>(pv_bf, scoreP_all, wpart, Mq);
    wsum2B_k<<<dim3(Bq, 4), 256, 0, stream>>>(wpart, pf);

    // head
    headlin_k<0><<<dim3(Bq, 4), 256, 0, stream>>>(cf, 4*LDq, 4*LDq,
        combc_W, LDq, combc_b, v1, 770, LDq, 0);
    headlin_k<0><<<dim3(Bq, 4), 256, 0, stream>>>(pf, 4*LDq, 4*LDq,
        combp_W, LDq, combp_b, v1, 770, LDq, 512);
    vfill_k<<<Bq, 256, 0, stream>>>(fps, inv_Temp, Temp, v1);

    headlin_k<1><<<dim3(Bq, 13), 256, 0, stream>>>(v1, 770, 770,
        Wout_W + 0ll*770*770, 770, Wout_b + 0*770, v2, 770, 770, 0);
    headlin_k<1><<<dim3(Bq, 13), 256, 0, stream>>>(v2, 770, 770,
        Wout_W + 1ll*770*770, 770, Wout_b + 1*770, v1, 770, 770, 0);
    headlin_k<1><<<dim3(Bq, 13), 256, 0, stream>>>(v1, 770, 770,
        Wout_W + 2ll*770*770, 770, Wout_b + 2*770, v2, 770, 770, 0);

    final_k<<<Bq, 256, 0, stream>>>(v2, out_W, out_b, out);

    (void)in_sizes; (void)n_in; (void)out_size; (void)ws_size;
    (void)bufU; (void)avU_bf; (void)qbuf; (void)csum; (void)scoreC; (void)scoreP;
}